// Round 2
// 6727.020 us; speedup vs baseline: 8.3241x; 8.3241x over previous
//
#include <hip/hip_runtime.h>
#include <stdint.h>
#include <math.h>

// Round 15 = Round 14 resubmitted verbatim (bench infra failed; no kernel
// signal). Bit-packed binary pipeline.
// L1 (float conv + f64-ordered stats + f32 sign) is VERBATIM from R13 —
// its summation order is numerics-critical. Everything downstream of the
// first sign is exact integer arithmetic, re-expressed as two-bitplane
// XOR/AND/popcount (B = sign>0, NZ = sign!=0), which is bit-identical to
// the R13 int8 convolutions including ternary zeros (zero activations and
// zero weights) and padded taps (skipped => exact 0).
// Conv BN stats are parallelized with int64 atomics: integer sums are
// order-independent => identical mu/Ad/Bd doubles to R13's sequential f64.

typedef unsigned long long u64;

// ---------- L1: verbatim R13 ----------
__global__ void k1_conv(const float* __restrict__ x, const float* __restrict__ w1,
                        float* __restrict__ out, int grp) {
    int hw = blockIdx.x * 64 + threadIdx.x;      // 0..1023
    int cg = blockIdx.y;                         // 0..7
    int n  = blockIdx.z;
    int co = grp * 8 + cg;
    int y = hw >> 5, x0 = hw & 31;
    const float* ip0 = x + ((size_t)n * 3 + 0) * 1024;
    const float* ip1 = x + ((size_t)n * 3 + 1) * 1024;
    const float* ip2 = x + ((size_t)n * 3 + 2) * 1024;
    const float* wp  = w1 + (size_t)co * 27;     // OIHW: (ci,ky,kx)
    float acc = 0.f;
    for (int ky = 0; ky < 3; ++ky) {
        int yy = y + ky - 1;
        if (yy < 0 || yy > 31) continue;
        for (int kx = 0; kx < 3; ++kx) {
            int xc = x0 + kx - 1;
            if (xc < 0 || xc > 31) continue;
            int sp = yy * 32 + xc;
            int wk = ky * 3 + kx;
            float w0 = wp[wk], w1v = wp[9 + wk], w2 = wp[18 + wk];
            acc += (w0  > 0.f) ? ip0[sp] : ((w0  < 0.f) ? -ip0[sp] : 0.f);
            acc += (w1v > 0.f) ? ip1[sp] : ((w1v < 0.f) ? -ip1[sp] : 0.f);
            acc += (w2  > 0.f) ? ip2[sp] : ((w2  < 0.f) ? -ip2[sp] : 0.f);
        }
    }
    out[((size_t)n * 8 + cg) * 1024 + hw] = acc;
}

__device__ __forceinline__ float ld1(const float* v, int cg, int e) {
    return v[((size_t)(e >> 10) * 8 + cg) * 1024 + (e & 1023)];
}

__global__ void k1_stats(const float* __restrict__ v, float* __restrict__ muF,
                         float* __restrict__ rF, int grp, int N) {
    int cg = blockIdx.x;
    __shared__ double sh[256], sh2[256];
    double s = 0.0, s2 = 0.0;
    int M = N * 1024;
    for (int m = threadIdx.x; m < M; m += 256) {
        double t = (double)ld1(v, cg, m);
        s += t; s2 += t * t;
    }
    sh[threadIdx.x] = s; sh2[threadIdx.x] = s2;
    __syncthreads();
    for (int o = 128; o > 0; o >>= 1) {
        if ((int)threadIdx.x < o) { sh[threadIdx.x] += sh[threadIdx.x + o]; sh2[threadIdx.x] += sh2[threadIdx.x + o]; }
        __syncthreads();
    }
    if (threadIdx.x == 0) {
        double mean = sh[0] / M;
        double var  = sh2[0] / M - mean * mean;
        if (var < 0.0) var = 0.0;
        muF[grp * 8 + cg] = (float)mean;
        rF[grp * 8 + cg]  = 1.0f / sqrtf((float)var + 1e-5f);
    }
}

__global__ void k1_sign(const float* __restrict__ v, const float* __restrict__ muF,
                        const float* __restrict__ rF, const float* __restrict__ g,
                        const float* __restrict__ b, int8_t* __restrict__ sgn, int grp) {
    int hw = blockIdx.x * 256 + threadIdx.x;
    if (hw >= 1024) return;
    int cg = blockIdx.y, n = blockIdx.z;
    int c = grp * 8 + cg;
    float d  = v[((size_t)n * 8 + cg) * 1024 + hw] - muF[c];
    float t  = (d * rF[c]) * g[c] + b[c];
    sgn[((size_t)n * 64 + c) * 1024 + hw] = (int8_t)((t > 0.f) - (t < 0.f));
}

// ---------- packing ----------
// int8 signs [N,C,HW] -> planes [(n*HW+hw)*WRD + wd], bit j = channel wd*64+j
__global__ void kpack_sgn8(const int8_t* __restrict__ s, u64* __restrict__ B,
                           u64* __restrict__ NZ, int C, int HW) {
    int hw = blockIdx.x * 64 + threadIdx.x;
    if (hw >= HW) return;
    int wd = blockIdx.y, n = blockIdx.z;
    int WRD = C >> 6;
    u64 b = 0, nz = 0;
    const int8_t* sp = s + ((size_t)n * C + wd * 64) * HW + hw;
    for (int j = 0; j < 64; ++j) {
        int v = sp[(size_t)j * HW];
        b  |= (u64)(v > 0) << j;
        nz |= (u64)(v != 0) << j;
    }
    size_t o = ((size_t)n * HW + hw) * WRD + wd;
    B[o] = b; NZ[o] = nz;
}

// conv weights OIHW float -> packed [(co*9+tap)*WRD + wd]
__global__ void kpack_wconv(const float* __restrict__ w, u64* __restrict__ WB,
                            u64* __restrict__ WNZ, int Ci, int Co) {
    int idx = blockIdx.x * 256 + threadIdx.x;
    int WRD = Ci >> 6;
    if (idx >= Co * 9 * WRD) return;
    int wd = idx % WRD, t = (idx / WRD) % 9, co = idx / (9 * WRD);
    u64 b = 0, nz = 0;
    const float* wp = w + ((size_t)co * Ci + wd * 64) * 9 + t;
    for (int j = 0; j < 64; ++j) {
        float v = wp[(size_t)j * 9];
        b  |= (u64)(v > 0.f) << j;
        nz |= (u64)(v != 0.f) << j;
    }
    WB[idx] = b; WNZ[idx] = nz;
}

// linear weights [O,K] float -> packed rows [o*WRD + wd]
__global__ void kpack_wlin(const float* __restrict__ w, u64* __restrict__ WB,
                           u64* __restrict__ WNZ, int K, int O) {
    int idx = blockIdx.x * 256 + threadIdx.x;
    int WRD = K >> 6;
    if (idx >= O * WRD) return;
    int wd = idx % WRD, o = idx / WRD;
    u64 b = 0, nz = 0;
    const float* wp = w + (size_t)o * K + wd * 64;
    for (int j = 0; j < 64; ++j) {
        float v = wp[j];
        b  |= (u64)(v > 0.f) << j;
        nz |= (u64)(v != 0.f) << j;
    }
    WB[idx] = b; WNZ[idx] = nz;
}

// ---------- binary conv (exact integers via popcount) ----------
template <int WRD>
__device__ __forceinline__ int bconv_at(const u64* __restrict__ ib, const u64* __restrict__ iz,
                                        const u64* __restrict__ wb, const u64* __restrict__ wz,
                                        int H, int Wi, int y, int x) {
    int acc = 0;
    for (int ky = 0; ky < 3; ++ky) {
        int yy = y + ky - 1;
        if ((unsigned)yy >= (unsigned)H) continue;   // padded: exact 0
        for (int kx = 0; kx < 3; ++kx) {
            int xc = x + kx - 1;
            if ((unsigned)xc >= (unsigned)Wi) continue;
            int p = yy * Wi + xc;
            int t = ky * 3 + kx;
#pragma unroll
            for (int w = 0; w < WRD; ++w) {
                u64 e = iz[(size_t)p * WRD + w] & wz[t * WRD + w];
                acc += __popcll(e) - 2 * __popcll((ib[(size_t)p * WRD + w] ^ wb[t * WRD + w]) & e);
            }
        }
    }
    return acc;
}

template <int WRD>
__global__ void kbconv(const u64* __restrict__ B, const u64* __restrict__ NZ,
                       const u64* __restrict__ WB, const u64* __restrict__ WNZ,
                       int16_t* __restrict__ out, int Co, int H, int Wi) {
    int hw = blockIdx.x * 64 + threadIdx.x;
    if (hw >= H * Wi) return;
    int co = blockIdx.y, n = blockIdx.z;
    int y = hw / Wi, x = hw % Wi;
    const u64* ib = B  + (size_t)n * H * Wi * WRD;
    const u64* iz = NZ + (size_t)n * H * Wi * WRD;
    const u64* wb = WB  + (size_t)co * 9 * WRD;
    const u64* wz = WNZ + (size_t)co * 9 * WRD;
    out[((size_t)n * Co + co) * H * Wi + hw] =
        (int16_t)bconv_at<WRD>(ib, iz, wb, wz, H, Wi, y, x);
}

template <int WRD>
__global__ void kbconv_pool(const u64* __restrict__ B, const u64* __restrict__ NZ,
                            const u64* __restrict__ WB, const u64* __restrict__ WNZ,
                            int16_t* __restrict__ out, int Co, int H, int Wi) {
    int Ho = H >> 1, Wo = Wi >> 1;
    int hw = blockIdx.x * 64 + threadIdx.x;
    if (hw >= Ho * Wo) return;
    int co = blockIdx.y, n = blockIdx.z;
    int yo = hw / Wo, xo = hw % Wo;
    const u64* ib = B  + (size_t)n * H * Wi * WRD;
    const u64* iz = NZ + (size_t)n * H * Wi * WRD;
    const u64* wb = WB  + (size_t)co * 9 * WRD;
    const u64* wz = WNZ + (size_t)co * 9 * WRD;
    int best = -(1 << 30);
    for (int dy = 0; dy < 2; ++dy)
        for (int dx = 0; dx < 2; ++dx) {
            int v = bconv_at<WRD>(ib, iz, wb, wz, H, Wi, 2 * yo + dy, 2 * xo + dx);
            if (v > best) best = v;
        }
    out[((size_t)n * Co + co) * Ho * Wo + hw] = (int16_t)best;
}

// ---------- conv BN stats: parallel int64 (order-independent, exact) ----------
__global__ void kzero(long long* __restrict__ p, int n) {
    int i = blockIdx.x * 256 + threadIdx.x;
    if (i < n) p[i] = 0;
}

__global__ void kaccum16(const int16_t* __restrict__ v, long long* __restrict__ S,
                         long long* __restrict__ S2, int C, int HW, int M) {
    int c = blockIdx.x;
    long long s = 0, s2 = 0;
    for (int m = blockIdx.y * 256 + threadIdx.x; m < M; m += gridDim.y * 256) {
        int t = v[((size_t)(m / HW) * C + c) * HW + (m % HW)];
        s += t; s2 += (long long)t * t;
    }
    __shared__ long long sh[256], sh2[256];
    sh[threadIdx.x] = s; sh2[threadIdx.x] = s2;
    __syncthreads();
    for (int o = 128; o > 0; o >>= 1) {
        if ((int)threadIdx.x < o) { sh[threadIdx.x] += sh[threadIdx.x + o]; sh2[threadIdx.x] += sh2[threadIdx.x + o]; }
        __syncthreads();
    }
    if (threadIdx.x == 0) {
        atomicAdd((u64*)&S[c],  (u64)sh[0]);
        atomicAdd((u64*)&S2[c], (u64)sh2[0]);
    }
}

__global__ void kfinal(const long long* __restrict__ S, const long long* __restrict__ S2,
                       const float* __restrict__ g, const float* __restrict__ b,
                       double* __restrict__ mu, double* __restrict__ Ad,
                       double* __restrict__ Bd, int C, int M) {
    int c = blockIdx.x * 64 + threadIdx.x;
    if (c >= C) return;
    double mean = (double)S[c] / M;
    double var  = (double)S2[c] / M - mean * mean;
    if (var < 0.0) var = 0.0;
    mu[c] = mean;
    Ad[c] = (g ? (double)g[c] : 1.0) / sqrt(var + 1e-5);
    Bd[c] = b ? (double)b[c] : 0.0;
}

// ---------- BN sign + pack (conv layout) ----------
__global__ void ksp_conv(const int16_t* __restrict__ v, const double* __restrict__ mu,
                         const double* __restrict__ Ad, const double* __restrict__ Bd,
                         u64* __restrict__ B, u64* __restrict__ NZ, int C, int HW) {
    int hw = blockIdx.x * 64 + threadIdx.x;
    if (hw >= HW) return;
    int wd = blockIdx.y, n = blockIdx.z;
    int WRD = C >> 6;
    u64 b = 0, nz = 0;
    for (int j = 0; j < 64; ++j) {
        int c = wd * 64 + j;
        double t = ((double)v[((size_t)n * C + c) * HW + hw] - mu[c]) * Ad[c] + Bd[c];
        b  |= (u64)(t > 0.0) << j;
        nz |= (u64)(t != 0.0) << j;
    }
    size_t o = ((size_t)n * HW + hw) * WRD + wd;
    B[o] = b; NZ[o] = nz;
}

// L6 sign + pack in flatten order (k = c*16 + hw, contiguous in t6)
__global__ void ksp_flat(const int16_t* __restrict__ v, const double* __restrict__ mu,
                         const double* __restrict__ Ad, const double* __restrict__ Bd,
                         u64* __restrict__ B, u64* __restrict__ NZ) {
    int wd = threadIdx.x;        // 0..63
    int n  = blockIdx.x;
    u64 b = 0, nz = 0;
    const int16_t* vp = v + (size_t)n * 4096 + wd * 64;
    for (int j = 0; j < 64; ++j) {
        int k = wd * 64 + j;
        int c = k >> 4;
        double t = ((double)vp[j] - mu[c]) * Ad[c] + Bd[c];
        b  |= (u64)(t > 0.0) << j;
        nz |= (u64)(t != 0.0) << j;
    }
    B[(size_t)n * 64 + wd] = b; NZ[(size_t)n * 64 + wd] = nz;
}

// FC sign + pack (int input, per-feature stats)
__global__ void ksp_fc(const int* __restrict__ v, const double* __restrict__ mu,
                       const double* __restrict__ Ad, const double* __restrict__ Bd,
                       u64* __restrict__ B, u64* __restrict__ NZ, int C, int WRD, int N) {
    int tid = blockIdx.x * 64 + threadIdx.x;
    if (tid >= N * WRD) return;
    int n = tid / WRD, wd = tid % WRD;
    u64 b = 0, nz = 0;
    for (int j = 0; j < 64; ++j) {
        int c = wd * 64 + j;
        double t = ((double)v[(size_t)n * C + c] - mu[c]) * Ad[c] + Bd[c];
        b  |= (u64)(t > 0.0) << j;
        nz |= (u64)(t != 0.0) << j;
    }
    B[(size_t)n * WRD + wd] = b; NZ[(size_t)n * WRD + wd] = nz;
}

// ---------- binary FC ----------
__global__ void kbfc(const u64* __restrict__ aB, const u64* __restrict__ aNZ,
                     const u64* __restrict__ wB, const u64* __restrict__ wNZ,
                     int* __restrict__ out, int WRD, int O) {
    int o = blockIdx.x * 64 + threadIdx.x;
    if (o >= O) return;
    int n = blockIdx.y;
    const u64* ab = aB  + (size_t)n * WRD;
    const u64* az = aNZ + (size_t)n * WRD;
    const u64* wb = wB  + (size_t)o * WRD;
    const u64* wz = wNZ + (size_t)o * WRD;
    int acc = 0;
    for (int w = 0; w < WRD; ++w) {
        u64 e = az[w] & wz[w];
        acc += __popcll(e) - 2 * __popcll((ab[w] ^ wb[w]) & e);
    }
    out[(size_t)n * O + o] = acc;
}

// ---------- FC stats / output: verbatim R13 ----------
__global__ void k3_stats(const int* __restrict__ v, int N, int C,
                         const float* __restrict__ g, const float* __restrict__ b,
                         double* __restrict__ mu, double* __restrict__ Ad,
                         double* __restrict__ Bd) {
    int c = blockIdx.x;
    __shared__ double sh[256], sh2[256];
    double s = 0.0, s2 = 0.0;
    for (int n = threadIdx.x; n < N; n += 256) {
        double t = (double)v[(size_t)n * C + c];
        s += t; s2 += t * t;
    }
    sh[threadIdx.x] = s; sh2[threadIdx.x] = s2;
    __syncthreads();
    for (int o = 128; o > 0; o >>= 1) {
        if ((int)threadIdx.x < o) { sh[threadIdx.x] += sh[threadIdx.x + o]; sh2[threadIdx.x] += sh2[threadIdx.x + o]; }
        __syncthreads();
    }
    if (threadIdx.x == 0) {
        double mean = sh[0] / N;
        double var  = sh2[0] / N - mean * mean;
        if (var < 0.0) var = 0.0;
        mu[c] = mean;
        Ad[c] = (g ? (double)g[c] : 1.0) / sqrt(var + 1e-5);
        Bd[c] = b ? (double)b[c] : 0.0;
    }
}

__global__ void k4_out(const int* __restrict__ v, const double* __restrict__ mu,
                       const double* __restrict__ Ad, float* __restrict__ out, int N) {
    int n = blockIdx.x * 256 + threadIdx.x;
    if (n >= N) return;
    double z[10];
    double mx = -1e300;
    for (int o = 0; o < 10; ++o) {
        z[o] = ((double)v[n * 10 + o] - mu[o]) * Ad[o];
        if (z[o] > mx) mx = z[o];
    }
    double s = 0.0;
    for (int o = 0; o < 10; ++o) s += exp(z[o] - mx);
    double l = mx + log(s);
    for (int o = 0; o < 10; ++o) out[n * 10 + o] = (float)(z[o] - l);
}

// ---------------- host ----------------
extern "C" void kernel_launch(void* const* d_in, const int* in_sizes, int n_in,
                              void* d_out, int out_size, void* d_ws, size_t ws_size,
                              hipStream_t stream) {
    const int N = in_sizes[0] / (3 * 32 * 32);   // 512

    const float* x   = (const float*)d_in[0];
    const float* w1  = (const float*)d_in[1];
    const float* g1  = (const float*)d_in[2];
    const float* b1  = (const float*)d_in[3];
    const float* w2  = (const float*)d_in[4];
    const float* g2  = (const float*)d_in[5];
    const float* b2  = (const float*)d_in[6];
    const float* w3  = (const float*)d_in[7];
    const float* g3  = (const float*)d_in[8];
    const float* b3  = (const float*)d_in[9];
    const float* w4  = (const float*)d_in[10];
    const float* g4  = (const float*)d_in[11];
    const float* b4  = (const float*)d_in[12];
    const float* w5  = (const float*)d_in[13];
    const float* g5  = (const float*)d_in[14];
    const float* b5  = (const float*)d_in[15];
    const float* w6  = (const float*)d_in[16];
    const float* g6  = (const float*)d_in[17];
    const float* b6  = (const float*)d_in[18];
    const float* wf1 = (const float*)d_in[19];
    const float* gf1 = (const float*)d_in[20];
    const float* bf1 = (const float*)d_in[21];
    const float* wf2 = (const float*)d_in[22];
    const float* gf2 = (const float*)d_in[23];
    const float* bf2 = (const float*)d_in[24];
    const float* wf3 = (const float*)d_in[25];

    char* ws = (char*)d_ws;
    size_t off = 0;
    auto alloc = [&](size_t bytes) -> char* {
        char* p = ws + off;
        off = (off + bytes + 511) & ~(size_t)511;
        return p;
    };

    // R1 33.6MB: sgnA (L1 int8) -> t3 (L3 int16)
    char* R1 = alloc((size_t)N * 64 * 1024);
    int8_t*  sgnA = (int8_t*)R1;
    int16_t* t3   = (int16_t*)R1;
    // R2 16.8MB: c1buf (f32) -> t2 (int16) -> t5 (int16)
    char* R2 = alloc((size_t)N * 8 * 1024 * 4);
    float*   c1buf = (float*)R2;
    int16_t* t2    = (int16_t*)R2;
    int16_t* t5    = (int16_t*)R2;
    // R3 8.4MB: planes1 (L1 packed, dead after L2 conv) -> t4 (int16)
    char* R3 = alloc((size_t)N * 1024 * 8 * 2);
    u64* p1B = (u64*)R3;
    u64* p1Z = (u64*)(R3 + (size_t)N * 1024 * 8);
    int16_t* t4 = (int16_t*)R3;

    u64* p2B = (u64*)alloc((size_t)N * 256 * 8);
    u64* p2Z = (u64*)alloc((size_t)N * 256 * 8);
    u64* p3B = (u64*)alloc((size_t)N * 256 * 2 * 8);
    u64* p3Z = (u64*)alloc((size_t)N * 256 * 2 * 8);
    u64* p4B = (u64*)alloc((size_t)N * 64 * 2 * 8);
    u64* p4Z = (u64*)alloc((size_t)N * 64 * 2 * 8);
    u64* p5B = (u64*)alloc((size_t)N * 64 * 4 * 8);
    u64* p5Z = (u64*)alloc((size_t)N * 64 * 4 * 8);
    int16_t* t6 = (int16_t*)alloc((size_t)N * 256 * 16 * 2);
    u64* p6B = (u64*)alloc((size_t)N * 64 * 8);
    u64* p6Z = (u64*)alloc((size_t)N * 64 * 8);

    int* fc1 = (int*)alloc((size_t)N * 512 * 4);
    int* fc2 = (int*)alloc((size_t)N * 512 * 4);
    int* fc3 = (int*)alloc((size_t)N * 10 * 4);
    u64* pF1B = (u64*)alloc((size_t)N * 8 * 8);
    u64* pF1Z = (u64*)alloc((size_t)N * 8 * 8);
    u64* pF2B = (u64*)alloc((size_t)N * 8 * 8);
    u64* pF2Z = (u64*)alloc((size_t)N * 8 * 8);

    u64* wb2B = (u64*)alloc(64  * 9 * 1 * 8);  u64* wb2Z = (u64*)alloc(64  * 9 * 1 * 8);
    u64* wb3B = (u64*)alloc(128 * 9 * 1 * 8);  u64* wb3Z = (u64*)alloc(128 * 9 * 1 * 8);
    u64* wb4B = (u64*)alloc(128 * 9 * 2 * 8);  u64* wb4Z = (u64*)alloc(128 * 9 * 2 * 8);
    u64* wb5B = (u64*)alloc(256 * 9 * 2 * 8);  u64* wb5Z = (u64*)alloc(256 * 9 * 2 * 8);
    u64* wb6B = (u64*)alloc(256 * 9 * 4 * 8);  u64* wb6Z = (u64*)alloc(256 * 9 * 4 * 8);
    u64* wf1B = (u64*)alloc(512 * 64 * 8);     u64* wf1Z = (u64*)alloc(512 * 64 * 8);
    u64* wf2B = (u64*)alloc(512 * 8 * 8);      u64* wf2Z = (u64*)alloc(512 * 8 * 8);
    u64* wf3B = (u64*)alloc(10 * 8 * 8);       u64* wf3Z = (u64*)alloc(10 * 8 * 8);

    long long* S  = (long long*)alloc(512 * 8);
    long long* S2 = (long long*)alloc(512 * 8);
    double* mu = (double*)alloc(512 * 8);
    double* Ad = (double*)alloc(512 * 8);
    double* Bd = (double*)alloc(512 * 8);
    float*  muF = (float*)alloc(64 * 4);
    float*  rF  = (float*)alloc(64 * 4);
    (void)ws_size;

    auto cdiv = [](int a, int b) { return (a + b - 1) / b; };

    // ---- pack weights ----
    kpack_wconv<<<cdiv(64 * 9 * 1, 256), 256, 0, stream>>>(w2, wb2B, wb2Z, 64, 64);
    kpack_wconv<<<cdiv(128 * 9 * 1, 256), 256, 0, stream>>>(w3, wb3B, wb3Z, 64, 128);
    kpack_wconv<<<cdiv(128 * 9 * 2, 256), 256, 0, stream>>>(w4, wb4B, wb4Z, 128, 128);
    kpack_wconv<<<cdiv(256 * 9 * 2, 256), 256, 0, stream>>>(w5, wb5B, wb5Z, 128, 256);
    kpack_wconv<<<cdiv(256 * 9 * 4, 256), 256, 0, stream>>>(w6, wb6B, wb6Z, 256, 256);
    kpack_wlin<<<cdiv(512 * 64, 256), 256, 0, stream>>>(wf1, wf1B, wf1Z, 4096, 512);
    kpack_wlin<<<cdiv(512 * 8, 256), 256, 0, stream>>>(wf2, wf2B, wf2Z, 512, 512);
    kpack_wlin<<<cdiv(10 * 8, 256), 256, 0, stream>>>(wf3, wf3B, wf3Z, 512, 10);

    // ---- L1 (verbatim R13 numerics) + pack ----
    for (int grp = 0; grp < 8; ++grp) {
        k1_conv<<<dim3(16, 8, N), 64, 0, stream>>>(x, w1, c1buf, grp);
        k1_stats<<<8, 256, 0, stream>>>(c1buf, muF, rF, grp, N);
        k1_sign<<<dim3(4, 8, N), 256, 0, stream>>>(c1buf, muF, rF, g1, b1, sgnA, grp);
    }
    kpack_sgn8<<<dim3(16, 1, N), 64, 0, stream>>>(sgnA, p1B, p1Z, 64, 1024);

    // ---- L2: conv+pool (Ci=64, 32x32 -> 16x16), stats, sign+pack ----
    kbconv_pool<1><<<dim3(4, 64, N), 64, 0, stream>>>(p1B, p1Z, wb2B, wb2Z, t2, 64, 32, 32);
    kzero<<<4, 256, 0, stream>>>(S, 512); kzero<<<4, 256, 0, stream>>>(S2, 512);
    kaccum16<<<dim3(64, 32), 256, 0, stream>>>(t2, S, S2, 64, 256, N * 256);
    kfinal<<<1, 64, 0, stream>>>(S, S2, g2, b2, mu, Ad, Bd, 64, N * 256);
    ksp_conv<<<dim3(4, 1, N), 64, 0, stream>>>(t2, mu, Ad, Bd, p2B, p2Z, 64, 256);

    // ---- L3: conv (Ci=64, 16x16) ----
    kbconv<1><<<dim3(4, 128, N), 64, 0, stream>>>(p2B, p2Z, wb3B, wb3Z, t3, 128, 16, 16);
    kzero<<<4, 256, 0, stream>>>(S, 512); kzero<<<4, 256, 0, stream>>>(S2, 512);
    kaccum16<<<dim3(128, 16), 256, 0, stream>>>(t3, S, S2, 128, 256, N * 256);
    kfinal<<<2, 64, 0, stream>>>(S, S2, g3, b3, mu, Ad, Bd, 128, N * 256);
    ksp_conv<<<dim3(4, 2, N), 64, 0, stream>>>(t3, mu, Ad, Bd, p3B, p3Z, 128, 256);

    // ---- L4: conv+pool (Ci=128, 16x16 -> 8x8) ----
    kbconv_pool<2><<<dim3(1, 128, N), 64, 0, stream>>>(p3B, p3Z, wb4B, wb4Z, t4, 128, 16, 16);
    kzero<<<4, 256, 0, stream>>>(S, 512); kzero<<<4, 256, 0, stream>>>(S2, 512);
    kaccum16<<<dim3(128, 16), 256, 0, stream>>>(t4, S, S2, 128, 64, N * 64);
    kfinal<<<2, 64, 0, stream>>>(S, S2, g4, b4, mu, Ad, Bd, 128, N * 64);
    ksp_conv<<<dim3(1, 2, N), 64, 0, stream>>>(t4, mu, Ad, Bd, p4B, p4Z, 128, 64);

    // ---- L5: conv (Ci=128, 8x8) ----
    kbconv<2><<<dim3(1, 256, N), 64, 0, stream>>>(p4B, p4Z, wb5B, wb5Z, t5, 256, 8, 8);
    kzero<<<4, 256, 0, stream>>>(S, 512); kzero<<<4, 256, 0, stream>>>(S2, 512);
    kaccum16<<<dim3(256, 8), 256, 0, stream>>>(t5, S, S2, 256, 64, N * 64);
    kfinal<<<4, 64, 0, stream>>>(S, S2, g5, b5, mu, Ad, Bd, 256, N * 64);
    ksp_conv<<<dim3(1, 4, N), 64, 0, stream>>>(t5, mu, Ad, Bd, p5B, p5Z, 256, 64);

    // ---- L6: conv+pool (Ci=256, 8x8 -> 4x4) ----
    kbconv_pool<4><<<dim3(1, 256, N), 64, 0, stream>>>(p5B, p5Z, wb6B, wb6Z, t6, 256, 8, 8);
    kzero<<<4, 256, 0, stream>>>(S, 512); kzero<<<4, 256, 0, stream>>>(S2, 512);
    kaccum16<<<dim3(256, 2), 256, 0, stream>>>(t6, S, S2, 256, 16, N * 16);
    kfinal<<<4, 64, 0, stream>>>(S, S2, g6, b6, mu, Ad, Bd, 256, N * 16);
    ksp_flat<<<N, 64, 0, stream>>>(t6, mu, Ad, Bd, p6B, p6Z);

    // ---- FC1 ----
    kbfc<<<dim3(8, N), 64, 0, stream>>>(p6B, p6Z, wf1B, wf1Z, fc1, 64, 512);
    k3_stats<<<512, 256, 0, stream>>>(fc1, N, 512, gf1, bf1, mu, Ad, Bd);
    ksp_fc<<<cdiv(N * 8, 64), 64, 0, stream>>>(fc1, mu, Ad, Bd, pF1B, pF1Z, 512, 8, N);

    // ---- FC2 ----
    kbfc<<<dim3(8, N), 64, 0, stream>>>(pF1B, pF1Z, wf2B, wf2Z, fc2, 8, 512);
    k3_stats<<<512, 256, 0, stream>>>(fc2, N, 512, gf2, bf2, mu, Ad, Bd);
    ksp_fc<<<cdiv(N * 8, 64), 64, 0, stream>>>(fc2, mu, Ad, Bd, pF2B, pF2Z, 512, 8, N);

    // ---- FC3 + bn(no affine) + log_softmax ----
    kbfc<<<dim3(1, N), 64, 0, stream>>>(pF2B, pF2Z, wf3B, wf3Z, fc3, 8, 10);
    k3_stats<<<10, 256, 0, stream>>>(fc3, N, 10, nullptr, nullptr, mu, Ad, Bd);
    k4_out<<<cdiv(N, 256), 256, 0, stream>>>(fc3, mu, Ad, (float*)d_out, N);
}

// Round 3
// 1471.393 us; speedup vs baseline: 38.0565x; 4.5719x over previous
//
#include <hip/hip_runtime.h>
#include <stdint.h>
#include <math.h>

// Round 16: L1 single-pass (thread=pixel, 64 co in regs, ternary-FMA — bit-exact
// vs R13 order), merged 64-block stats (identical per-channel tree), fused
// sign+pack. Binary convs co-blocked 8 channels/thread (integer-exact).
// Fallback to the R14 grp-8 L1 path if ws_size is too small for the 134MB buf.

typedef unsigned long long u64;

// ---------- L1 new path ----------
// ternary transposed weights wt[k=ci*9+wk][co] in {-1,0,+1} floats
__global__ void kw1t(const float* __restrict__ w1, float* __restrict__ wt) {
    int i = blockIdx.x * 64 + threadIdx.x;     // 64*27
    if (i >= 64 * 27) return;
    int co = i / 27, k = i % 27;
    float v = w1[i];
    wt[k * 64 + co] = (v > 0.f) ? 1.f : ((v < 0.f) ? -1.f : 0.f);
}

__global__ __launch_bounds__(256) void k1_conv_all(const float* __restrict__ x,
                                                   const float* __restrict__ wt,
                                                   float* __restrict__ out) {
    int gid = blockIdx.x * 256 + threadIdx.x;  // n*1024 + hw
    int n = gid >> 10, hw = gid & 1023;
    int y = hw >> 5, x0 = hw & 31;
    const float* ip = x + (size_t)n * 3 * 1024;
    float xv[27];
#pragma unroll
    for (int wk = 0; wk < 9; ++wk) {
        int ky = wk / 3, kx = wk % 3;
        int yy = y + ky - 1, xc = x0 + kx - 1;
        bool ok = ((unsigned)yy < 32u) && ((unsigned)xc < 32u);
        int sp = yy * 32 + xc;
        xv[wk]      = ok ? ip[sp]        : 0.f;
        xv[9 + wk]  = ok ? ip[1024 + sp] : 0.f;
        xv[18 + wk] = ok ? ip[2048 + sp] : 0.f;
    }
    float acc[64];
#pragma unroll
    for (int c = 0; c < 64; ++c) acc[c] = 0.f;
    // accumulation order per co: (ky,kx) outer, ci inner — identical to R13.
#pragma unroll
    for (int wk = 0; wk < 9; ++wk)
#pragma unroll
        for (int ci = 0; ci < 3; ++ci) {
            float xs = xv[ci * 9 + wk];
            const float* wrow = wt + (ci * 9 + wk) * 64;
#pragma unroll
            for (int c = 0; c < 64; ++c) acc[c] = fmaf(wrow[c], xs, acc[c]);
        }
    float* op = out + ((size_t)n * 64) * 1024 + hw;
#pragma unroll
    for (int c = 0; c < 64; ++c) op[(size_t)c * 1024] = acc[c];
}

__global__ void k1_stats64(const float* __restrict__ v, float* __restrict__ muF,
                           float* __restrict__ rF, int N) {
    int c = blockIdx.x;                        // 0..63
    __shared__ double sh[256], sh2[256];
    double s = 0.0, s2 = 0.0;
    int M = N * 1024;
    for (int m = threadIdx.x; m < M; m += 256) {
        double t = (double)v[((size_t)(m >> 10) * 64 + c) * 1024 + (m & 1023)];
        s += t; s2 += t * t;
    }
    sh[threadIdx.x] = s; sh2[threadIdx.x] = s2;
    __syncthreads();
    for (int o = 128; o > 0; o >>= 1) {
        if ((int)threadIdx.x < o) { sh[threadIdx.x] += sh[threadIdx.x + o]; sh2[threadIdx.x] += sh2[threadIdx.x + o]; }
        __syncthreads();
    }
    if (threadIdx.x == 0) {
        double mean = sh[0] / M;
        double var  = sh2[0] / M - mean * mean;
        if (var < 0.0) var = 0.0;
        muF[c] = (float)mean;
        rF[c]  = 1.0f / sqrtf((float)var + 1e-5f);
    }
}

__global__ void k1_signpack(const float* __restrict__ v, const float* __restrict__ muF,
                            const float* __restrict__ rF, const float* __restrict__ g,
                            const float* __restrict__ b, u64* __restrict__ B,
                            u64* __restrict__ NZ) {
    int gid = blockIdx.x * 64 + threadIdx.x;   // n*1024 + hw
    int n = gid >> 10, hw = gid & 1023;
    u64 bb = 0, nz = 0;
    for (int c = 0; c < 64; ++c) {
        float d = v[((size_t)n * 64 + c) * 1024 + hw] - muF[c];
        float t = (d * rF[c]) * g[c] + b[c];
        bb |= (u64)(t > 0.f) << c;
        nz |= (u64)(t != 0.f) << c;
    }
    B[gid] = bb; NZ[gid] = nz;
}

// ---------- L1 fallback path (verbatim R13/R14) ----------
__global__ void k1_conv(const float* __restrict__ x, const float* __restrict__ w1,
                        float* __restrict__ out, int grp) {
    int hw = blockIdx.x * 64 + threadIdx.x;
    int cg = blockIdx.y;
    int n  = blockIdx.z;
    int co = grp * 8 + cg;
    int y = hw >> 5, x0 = hw & 31;
    const float* ip0 = x + ((size_t)n * 3 + 0) * 1024;
    const float* ip1 = x + ((size_t)n * 3 + 1) * 1024;
    const float* ip2 = x + ((size_t)n * 3 + 2) * 1024;
    const float* wp  = w1 + (size_t)co * 27;
    float acc = 0.f;
    for (int ky = 0; ky < 3; ++ky) {
        int yy = y + ky - 1;
        if (yy < 0 || yy > 31) continue;
        for (int kx = 0; kx < 3; ++kx) {
            int xc = x0 + kx - 1;
            if (xc < 0 || xc > 31) continue;
            int sp = yy * 32 + xc;
            int wk = ky * 3 + kx;
            float w0 = wp[wk], w1v = wp[9 + wk], w2 = wp[18 + wk];
            acc += (w0  > 0.f) ? ip0[sp] : ((w0  < 0.f) ? -ip0[sp] : 0.f);
            acc += (w1v > 0.f) ? ip1[sp] : ((w1v < 0.f) ? -ip1[sp] : 0.f);
            acc += (w2  > 0.f) ? ip2[sp] : ((w2  < 0.f) ? -ip2[sp] : 0.f);
        }
    }
    out[((size_t)n * 8 + cg) * 1024 + hw] = acc;
}

__device__ __forceinline__ float ld1(const float* v, int cg, int e) {
    return v[((size_t)(e >> 10) * 8 + cg) * 1024 + (e & 1023)];
}

__global__ void k1_stats(const float* __restrict__ v, float* __restrict__ muF,
                         float* __restrict__ rF, int grp, int N) {
    int cg = blockIdx.x;
    __shared__ double sh[256], sh2[256];
    double s = 0.0, s2 = 0.0;
    int M = N * 1024;
    for (int m = threadIdx.x; m < M; m += 256) {
        double t = (double)ld1(v, cg, m);
        s += t; s2 += t * t;
    }
    sh[threadIdx.x] = s; sh2[threadIdx.x] = s2;
    __syncthreads();
    for (int o = 128; o > 0; o >>= 1) {
        if ((int)threadIdx.x < o) { sh[threadIdx.x] += sh[threadIdx.x + o]; sh2[threadIdx.x] += sh2[threadIdx.x + o]; }
        __syncthreads();
    }
    if (threadIdx.x == 0) {
        double mean = sh[0] / M;
        double var  = sh2[0] / M - mean * mean;
        if (var < 0.0) var = 0.0;
        muF[grp * 8 + cg] = (float)mean;
        rF[grp * 8 + cg]  = 1.0f / sqrtf((float)var + 1e-5f);
    }
}

__global__ void k1_sign(const float* __restrict__ v, const float* __restrict__ muF,
                        const float* __restrict__ rF, const float* __restrict__ g,
                        const float* __restrict__ b, int8_t* __restrict__ sgn, int grp) {
    int hw = blockIdx.x * 256 + threadIdx.x;
    if (hw >= 1024) return;
    int cg = blockIdx.y, n = blockIdx.z;
    int c = grp * 8 + cg;
    float d  = v[((size_t)n * 8 + cg) * 1024 + hw] - muF[c];
    float t  = (d * rF[c]) * g[c] + b[c];
    sgn[((size_t)n * 64 + c) * 1024 + hw] = (int8_t)((t > 0.f) - (t < 0.f));
}

__global__ void kpack_sgn8(const int8_t* __restrict__ s, u64* __restrict__ B,
                           u64* __restrict__ NZ, int C, int HW) {
    int hw = blockIdx.x * 64 + threadIdx.x;
    if (hw >= HW) return;
    int wd = blockIdx.y, n = blockIdx.z;
    int WRD = C >> 6;
    u64 b = 0, nz = 0;
    const int8_t* sp = s + ((size_t)n * C + wd * 64) * HW + hw;
    for (int j = 0; j < 64; ++j) {
        int v = sp[(size_t)j * HW];
        b  |= (u64)(v > 0) << j;
        nz |= (u64)(v != 0) << j;
    }
    size_t o = ((size_t)n * HW + hw) * WRD + wd;
    B[o] = b; NZ[o] = nz;
}

// ---------- weight packing ----------
__global__ void kpack_wconv(const float* __restrict__ w, u64* __restrict__ WB,
                            u64* __restrict__ WNZ, int Ci, int Co) {
    int idx = blockIdx.x * 256 + threadIdx.x;
    int WRD = Ci >> 6;
    if (idx >= Co * 9 * WRD) return;
    int wd = idx % WRD, t = (idx / WRD) % 9, co = idx / (9 * WRD);
    u64 b = 0, nz = 0;
    const float* wp = w + ((size_t)co * Ci + wd * 64) * 9 + t;
    for (int j = 0; j < 64; ++j) {
        float v = wp[(size_t)j * 9];
        b  |= (u64)(v > 0.f) << j;
        nz |= (u64)(v != 0.f) << j;
    }
    WB[idx] = b; WNZ[idx] = nz;
}

__global__ void kpack_wlin(const float* __restrict__ w, u64* __restrict__ WB,
                           u64* __restrict__ WNZ, int K, int O) {
    int idx = blockIdx.x * 256 + threadIdx.x;
    int WRD = K >> 6;
    if (idx >= O * WRD) return;
    int wd = idx % WRD, o = idx / WRD;
    u64 b = 0, nz = 0;
    const float* wp = w + (size_t)o * K + wd * 64;
    for (int j = 0; j < 64; ++j) {
        float v = wp[j];
        b  |= (u64)(v > 0.f) << j;
        nz |= (u64)(v != 0.f) << j;
    }
    WB[idx] = b; WNZ[idx] = nz;
}

// ---------- binary conv, co-blocked (integer-exact) ----------
template <int WRD, int CB>
__global__ void kbconv2(const u64* __restrict__ B, const u64* __restrict__ NZ,
                        const u64* __restrict__ WB, const u64* __restrict__ WNZ,
                        int16_t* __restrict__ out, int Co, int H, int Wi) {
    int hw = blockIdx.x * 64 + threadIdx.x;
    if (hw >= H * Wi) return;
    int co0 = blockIdx.y * CB, n = blockIdx.z;
    int y = hw / Wi, x = hw % Wi;
    const u64* ib = B  + (size_t)n * H * Wi * WRD;
    const u64* iz = NZ + (size_t)n * H * Wi * WRD;
    int acc[CB];
#pragma unroll
    for (int c = 0; c < CB; ++c) acc[c] = 0;
    for (int ky = 0; ky < 3; ++ky) {
        int yy = y + ky - 1;
        if ((unsigned)yy >= (unsigned)H) continue;
        for (int kx = 0; kx < 3; ++kx) {
            int xc = x + kx - 1;
            if ((unsigned)xc >= (unsigned)Wi) continue;
            int p = yy * Wi + xc, t = ky * 3 + kx;
            u64 xb[WRD], xz[WRD];
#pragma unroll
            for (int w = 0; w < WRD; ++w) {
                xb[w] = ib[(size_t)p * WRD + w];
                xz[w] = iz[(size_t)p * WRD + w];
            }
#pragma unroll
            for (int c = 0; c < CB; ++c) {
                const u64* wb = WB  + ((size_t)(co0 + c) * 9 + t) * WRD;
                const u64* wz = WNZ + ((size_t)(co0 + c) * 9 + t) * WRD;
#pragma unroll
                for (int w = 0; w < WRD; ++w) {
                    u64 e = xz[w] & wz[w];
                    acc[c] += __popcll(e) - 2 * __popcll((xb[w] ^ wb[w]) & e);
                }
            }
        }
    }
#pragma unroll
    for (int c = 0; c < CB; ++c)
        out[((size_t)n * Co + co0 + c) * H * Wi + hw] = (int16_t)acc[c];
}

template <int WRD, int CB>
__global__ void kbconv_pool2(const u64* __restrict__ B, const u64* __restrict__ NZ,
                             const u64* __restrict__ WB, const u64* __restrict__ WNZ,
                             int16_t* __restrict__ out, int Co, int H, int Wi) {
    int Ho = H >> 1, Wo = Wi >> 1;
    int hw = blockIdx.x * 64 + threadIdx.x;
    if (hw >= Ho * Wo) return;
    int co0 = blockIdx.y * CB, n = blockIdx.z;
    int yo = hw / Wo, xo = hw % Wo;
    const u64* ib = B  + (size_t)n * H * Wi * WRD;
    const u64* iz = NZ + (size_t)n * H * Wi * WRD;
    int best[CB];
#pragma unroll
    for (int c = 0; c < CB; ++c) best[c] = -(1 << 30);
    for (int dy = 0; dy < 2; ++dy)
        for (int dx = 0; dx < 2; ++dx) {
            int y = 2 * yo + dy, x = 2 * xo + dx;
            int acc[CB];
#pragma unroll
            for (int c = 0; c < CB; ++c) acc[c] = 0;
            for (int ky = 0; ky < 3; ++ky) {
                int yy = y + ky - 1;
                if ((unsigned)yy >= (unsigned)H) continue;
                for (int kx = 0; kx < 3; ++kx) {
                    int xc = x + kx - 1;
                    if ((unsigned)xc >= (unsigned)Wi) continue;
                    int p = yy * Wi + xc, t = ky * 3 + kx;
                    u64 xb[WRD], xz[WRD];
#pragma unroll
                    for (int w = 0; w < WRD; ++w) {
                        xb[w] = ib[(size_t)p * WRD + w];
                        xz[w] = iz[(size_t)p * WRD + w];
                    }
#pragma unroll
                    for (int c = 0; c < CB; ++c) {
                        const u64* wb = WB  + ((size_t)(co0 + c) * 9 + t) * WRD;
                        const u64* wz = WNZ + ((size_t)(co0 + c) * 9 + t) * WRD;
#pragma unroll
                        for (int w = 0; w < WRD; ++w) {
                            u64 e = xz[w] & wz[w];
                            acc[c] += __popcll(e) - 2 * __popcll((xb[w] ^ wb[w]) & e);
                        }
                    }
                }
            }
#pragma unroll
            for (int c = 0; c < CB; ++c) best[c] = acc[c] > best[c] ? acc[c] : best[c];
        }
#pragma unroll
    for (int c = 0; c < CB; ++c)
        out[((size_t)n * Co + co0 + c) * Ho * Wo + hw] = (int16_t)best[c];
}

// pool variant for Ho*Wo==16: 64 lanes = 16 pixels x 4 pool positions,
// integer max via shuffles (exact).
template <int WRD, int CB>
__global__ void kbconv_pool2s(const u64* __restrict__ B, const u64* __restrict__ NZ,
                              const u64* __restrict__ WB, const u64* __restrict__ WNZ,
                              int16_t* __restrict__ out, int Co, int H, int Wi) {
    int Ho = H >> 1, Wo = Wi >> 1;       // Ho*Wo == 16
    int t0 = threadIdx.x;
    int pix = t0 & 15, pos = t0 >> 4;    // pos 0..3
    int co0 = blockIdx.y * CB, n = blockIdx.z;
    int yo = pix / Wo, xo = pix % Wo;
    int y = 2 * yo + (pos >> 1), x = 2 * xo + (pos & 1);
    const u64* ib = B  + (size_t)n * H * Wi * WRD;
    const u64* iz = NZ + (size_t)n * H * Wi * WRD;
    int acc[CB];
#pragma unroll
    for (int c = 0; c < CB; ++c) acc[c] = 0;
    for (int ky = 0; ky < 3; ++ky) {
        int yy = y + ky - 1;
        if ((unsigned)yy >= (unsigned)H) continue;
        for (int kx = 0; kx < 3; ++kx) {
            int xc = x + kx - 1;
            if ((unsigned)xc >= (unsigned)Wi) continue;
            int p = yy * Wi + xc, t = ky * 3 + kx;
            u64 xb[WRD], xz[WRD];
#pragma unroll
            for (int w = 0; w < WRD; ++w) {
                xb[w] = ib[(size_t)p * WRD + w];
                xz[w] = iz[(size_t)p * WRD + w];
            }
#pragma unroll
            for (int c = 0; c < CB; ++c) {
                const u64* wb = WB  + ((size_t)(co0 + c) * 9 + t) * WRD;
                const u64* wz = WNZ + ((size_t)(co0 + c) * 9 + t) * WRD;
#pragma unroll
                for (int w = 0; w < WRD; ++w) {
                    u64 e = xz[w] & wz[w];
                    acc[c] += __popcll(e) - 2 * __popcll((xb[w] ^ wb[w]) & e);
                }
            }
        }
    }
#pragma unroll
    for (int c = 0; c < CB; ++c) {
        int v = acc[c];
        int v1 = __shfl_xor(v, 16); v = v1 > v ? v1 : v;
        int v2 = __shfl_xor(v, 32); v = v2 > v ? v2 : v;
        acc[c] = v;
    }
    if (pos == 0) {
#pragma unroll
        for (int c = 0; c < CB; ++c)
            out[((size_t)n * Co + co0 + c) * Ho * Wo + pix] = (int16_t)acc[c];
    }
}

// ---------- conv BN stats (order-independent exact integers) ----------
__global__ void kzero(long long* __restrict__ p, int n) {
    int i = blockIdx.x * 256 + threadIdx.x;
    if (i < n) p[i] = 0;
}

__global__ void kaccum16(const int16_t* __restrict__ v, long long* __restrict__ S,
                         long long* __restrict__ S2, int C, int HW, int M) {
    int c = blockIdx.x;
    long long s = 0, s2 = 0;
    for (int m = blockIdx.y * 256 + threadIdx.x; m < M; m += gridDim.y * 256) {
        int t = v[((size_t)(m / HW) * C + c) * HW + (m % HW)];
        s += t; s2 += (long long)t * t;
    }
    __shared__ long long sh[256], sh2[256];
    sh[threadIdx.x] = s; sh2[threadIdx.x] = s2;
    __syncthreads();
    for (int o = 128; o > 0; o >>= 1) {
        if ((int)threadIdx.x < o) { sh[threadIdx.x] += sh[threadIdx.x + o]; sh2[threadIdx.x] += sh2[threadIdx.x + o]; }
        __syncthreads();
    }
    if (threadIdx.x == 0) {
        atomicAdd((u64*)&S[c],  (u64)sh[0]);
        atomicAdd((u64*)&S2[c], (u64)sh2[0]);
    }
}

__global__ void kfinal(const long long* __restrict__ S, const long long* __restrict__ S2,
                       const float* __restrict__ g, const float* __restrict__ b,
                       double* __restrict__ mu, double* __restrict__ Ad,
                       double* __restrict__ Bd, int C, int M) {
    int c = blockIdx.x * 64 + threadIdx.x;
    if (c >= C) return;
    double mean = (double)S[c] / M;
    double var  = (double)S2[c] / M - mean * mean;
    if (var < 0.0) var = 0.0;
    mu[c] = mean;
    Ad[c] = (g ? (double)g[c] : 1.0) / sqrt(var + 1e-5);
    Bd[c] = b ? (double)b[c] : 0.0;
}

// ---------- BN sign + pack ----------
__global__ void ksp_conv(const int16_t* __restrict__ v, const double* __restrict__ mu,
                         const double* __restrict__ Ad, const double* __restrict__ Bd,
                         u64* __restrict__ B, u64* __restrict__ NZ, int C, int HW) {
    int hw = blockIdx.x * 64 + threadIdx.x;
    if (hw >= HW) return;
    int wd = blockIdx.y, n = blockIdx.z;
    int WRD = C >> 6;
    u64 b = 0, nz = 0;
    for (int j = 0; j < 64; ++j) {
        int c = wd * 64 + j;
        double t = ((double)v[((size_t)n * C + c) * HW + hw] - mu[c]) * Ad[c] + Bd[c];
        b  |= (u64)(t > 0.0) << j;
        nz |= (u64)(t != 0.0) << j;
    }
    size_t o = ((size_t)n * HW + hw) * WRD + wd;
    B[o] = b; NZ[o] = nz;
}

__global__ void ksp_flat(const int16_t* __restrict__ v, const double* __restrict__ mu,
                         const double* __restrict__ Ad, const double* __restrict__ Bd,
                         u64* __restrict__ B, u64* __restrict__ NZ) {
    int wd = threadIdx.x;
    int n  = blockIdx.x;
    u64 b = 0, nz = 0;
    const int16_t* vp = v + (size_t)n * 4096 + wd * 64;
    for (int j = 0; j < 64; ++j) {
        int k = wd * 64 + j;
        int c = k >> 4;
        double t = ((double)vp[j] - mu[c]) * Ad[c] + Bd[c];
        b  |= (u64)(t > 0.0) << j;
        nz |= (u64)(t != 0.0) << j;
    }
    B[(size_t)n * 64 + wd] = b; NZ[(size_t)n * 64 + wd] = nz;
}

__global__ void ksp_fc(const int* __restrict__ v, const double* __restrict__ mu,
                       const double* __restrict__ Ad, const double* __restrict__ Bd,
                       u64* __restrict__ B, u64* __restrict__ NZ, int C, int WRD, int N) {
    int tid = blockIdx.x * 64 + threadIdx.x;
    if (tid >= N * WRD) return;
    int n = tid / WRD, wd = tid % WRD;
    u64 b = 0, nz = 0;
    for (int j = 0; j < 64; ++j) {
        int c = wd * 64 + j;
        double t = ((double)v[(size_t)n * C + c] - mu[c]) * Ad[c] + Bd[c];
        b  |= (u64)(t > 0.0) << j;
        nz |= (u64)(t != 0.0) << j;
    }
    B[(size_t)n * WRD + wd] = b; NZ[(size_t)n * WRD + wd] = nz;
}

// ---------- binary FC ----------
__global__ void kbfc(const u64* __restrict__ aB, const u64* __restrict__ aNZ,
                     const u64* __restrict__ wB, const u64* __restrict__ wNZ,
                     int* __restrict__ out, int WRD, int O) {
    int o = blockIdx.x * 64 + threadIdx.x;
    if (o >= O) return;
    int n = blockIdx.y;
    const u64* ab = aB  + (size_t)n * WRD;
    const u64* az = aNZ + (size_t)n * WRD;
    const u64* wb = wB  + (size_t)o * WRD;
    const u64* wz = wNZ + (size_t)o * WRD;
    int acc = 0;
    for (int w = 0; w < WRD; ++w) {
        u64 e = az[w] & wz[w];
        acc += __popcll(e) - 2 * __popcll((ab[w] ^ wb[w]) & e);
    }
    out[(size_t)n * O + o] = acc;
}

// ---------- FC stats / output ----------
__global__ void k3_stats(const int* __restrict__ v, int N, int C,
                         const float* __restrict__ g, const float* __restrict__ b,
                         double* __restrict__ mu, double* __restrict__ Ad,
                         double* __restrict__ Bd) {
    int c = blockIdx.x;
    __shared__ double sh[256], sh2[256];
    double s = 0.0, s2 = 0.0;
    for (int n = threadIdx.x; n < N; n += 256) {
        double t = (double)v[(size_t)n * C + c];
        s += t; s2 += t * t;
    }
    sh[threadIdx.x] = s; sh2[threadIdx.x] = s2;
    __syncthreads();
    for (int o = 128; o > 0; o >>= 1) {
        if ((int)threadIdx.x < o) { sh[threadIdx.x] += sh[threadIdx.x + o]; sh2[threadIdx.x] += sh2[threadIdx.x + o]; }
        __syncthreads();
    }
    if (threadIdx.x == 0) {
        double mean = sh[0] / N;
        double var  = sh2[0] / N - mean * mean;
        if (var < 0.0) var = 0.0;
        mu[c] = mean;
        Ad[c] = (g ? (double)g[c] : 1.0) / sqrt(var + 1e-5);
        Bd[c] = b ? (double)b[c] : 0.0;
    }
}

__global__ void k4_out(const int* __restrict__ v, const double* __restrict__ mu,
                       const double* __restrict__ Ad, float* __restrict__ out, int N) {
    int n = blockIdx.x * 256 + threadIdx.x;
    if (n >= N) return;
    double z[10];
    double mx = -1e300;
    for (int o = 0; o < 10; ++o) {
        z[o] = ((double)v[n * 10 + o] - mu[o]) * Ad[o];
        if (z[o] > mx) mx = z[o];
    }
    double s = 0.0;
    for (int o = 0; o < 10; ++o) s += exp(z[o] - mx);
    double l = mx + log(s);
    for (int o = 0; o < 10; ++o) out[n * 10 + o] = (float)(z[o] - l);
}

// ---------------- host ----------------
extern "C" void kernel_launch(void* const* d_in, const int* in_sizes, int n_in,
                              void* d_out, int out_size, void* d_ws, size_t ws_size,
                              hipStream_t stream) {
    const int N = in_sizes[0] / (3 * 32 * 32);   // 512

    const float* x   = (const float*)d_in[0];
    const float* w1  = (const float*)d_in[1];
    const float* g1  = (const float*)d_in[2];
    const float* b1  = (const float*)d_in[3];
    const float* w2  = (const float*)d_in[4];
    const float* g2  = (const float*)d_in[5];
    const float* b2  = (const float*)d_in[6];
    const float* w3  = (const float*)d_in[7];
    const float* g3  = (const float*)d_in[8];
    const float* b3  = (const float*)d_in[9];
    const float* w4  = (const float*)d_in[10];
    const float* g4  = (const float*)d_in[11];
    const float* b4  = (const float*)d_in[12];
    const float* w5  = (const float*)d_in[13];
    const float* g5  = (const float*)d_in[14];
    const float* b5  = (const float*)d_in[15];
    const float* w6  = (const float*)d_in[16];
    const float* g6  = (const float*)d_in[17];
    const float* b6  = (const float*)d_in[18];
    const float* wf1 = (const float*)d_in[19];
    const float* gf1 = (const float*)d_in[20];
    const float* bf1 = (const float*)d_in[21];
    const float* wf2 = (const float*)d_in[22];
    const float* gf2 = (const float*)d_in[23];
    const float* bf2 = (const float*)d_in[24];
    const float* wf3 = (const float*)d_in[25];

    char* ws = (char*)d_ws;
    size_t off = 0;
    auto alloc = [&](size_t bytes) -> char* {
        char* p = ws + off;
        off = (off + bytes + 511) & ~(size_t)511;
        return p;
    };

    // ---- DOWN region: all post-L1 buffers at distinct offsets (~92MB) ----
    int16_t* t2  = (int16_t*)alloc((size_t)N * 64 * 256 * 2);
    u64* p2B = (u64*)alloc((size_t)N * 256 * 8);
    u64* p2Z = (u64*)alloc((size_t)N * 256 * 8);
    int16_t* t3  = (int16_t*)alloc((size_t)N * 128 * 256 * 2);
    u64* p3B = (u64*)alloc((size_t)N * 256 * 2 * 8);
    u64* p3Z = (u64*)alloc((size_t)N * 256 * 2 * 8);
    int16_t* t4  = (int16_t*)alloc((size_t)N * 128 * 64 * 2);
    u64* p4B = (u64*)alloc((size_t)N * 64 * 2 * 8);
    u64* p4Z = (u64*)alloc((size_t)N * 64 * 2 * 8);
    int16_t* t5  = (int16_t*)alloc((size_t)N * 256 * 64 * 2);
    u64* p5B = (u64*)alloc((size_t)N * 64 * 4 * 8);
    u64* p5Z = (u64*)alloc((size_t)N * 64 * 4 * 8);
    int16_t* t6  = (int16_t*)alloc((size_t)N * 256 * 16 * 2);
    u64* p6B = (u64*)alloc((size_t)N * 64 * 8);
    u64* p6Z = (u64*)alloc((size_t)N * 64 * 8);
    int* fc1 = (int*)alloc((size_t)N * 512 * 4);
    int* fc2 = (int*)alloc((size_t)N * 512 * 4);
    int* fc3 = (int*)alloc((size_t)N * 10 * 4);
    u64* pF1B = (u64*)alloc((size_t)N * 8 * 8);
    u64* pF1Z = (u64*)alloc((size_t)N * 8 * 8);
    u64* pF2B = (u64*)alloc((size_t)N * 8 * 8);
    u64* pF2Z = (u64*)alloc((size_t)N * 8 * 8);
    size_t down_end = off;

    // ---- L1 head overlays (dead before any DOWN buffer is written) ----
    size_t head_big = (size_t)N * 64 * 1024 * 4;      // 134.2MB f32, 64 channels
    bool big = ws_size >= head_big + ((size_t)16 << 20);
    float*  c1buf = (float*)ws;                        // big: [N][64][1024]
    float*  c1buf8 = (float*)ws;                       // fallback: [N][8][1024]
    int8_t* sgnA  = (int8_t*)(ws + (size_t)N * 8 * 1024 * 4);  // fallback only

    // ---- tail (coexists with L1 head) ----
    off = big ? (head_big > down_end ? head_big : down_end) : down_end;
    off = (off + 511) & ~(size_t)511;
    u64* p1B = (u64*)alloc((size_t)N * 1024 * 8);
    u64* p1Z = (u64*)alloc((size_t)N * 1024 * 8);
    u64* wb2B = (u64*)alloc(64  * 9 * 1 * 8);  u64* wb2Z = (u64*)alloc(64  * 9 * 1 * 8);
    u64* wb3B = (u64*)alloc(128 * 9 * 1 * 8);  u64* wb3Z = (u64*)alloc(128 * 9 * 1 * 8);
    u64* wb4B = (u64*)alloc(128 * 9 * 2 * 8);  u64* wb4Z = (u64*)alloc(128 * 9 * 2 * 8);
    u64* wb5B = (u64*)alloc(256 * 9 * 2 * 8);  u64* wb5Z = (u64*)alloc(256 * 9 * 2 * 8);
    u64* wb6B = (u64*)alloc(256 * 9 * 4 * 8);  u64* wb6Z = (u64*)alloc(256 * 9 * 4 * 8);
    u64* wf1B = (u64*)alloc(512 * 64 * 8);     u64* wf1Z = (u64*)alloc(512 * 64 * 8);
    u64* wf2B = (u64*)alloc(512 * 8 * 8);      u64* wf2Z = (u64*)alloc(512 * 8 * 8);
    u64* wf3B = (u64*)alloc(10 * 8 * 8);       u64* wf3Z = (u64*)alloc(10 * 8 * 8);
    float* wt = (float*)alloc(27 * 64 * 4);
    long long* SS = (long long*)alloc(1024 * 8);
    long long* S  = SS;
    long long* S2 = SS + 512;
    double* mu = (double*)alloc(512 * 8);
    double* Ad = (double*)alloc(512 * 8);
    double* Bd = (double*)alloc(512 * 8);
    float*  muF = (float*)alloc(64 * 4);
    float*  rF  = (float*)alloc(64 * 4);

    auto cdiv = [](int a, int b) { return (a + b - 1) / b; };

    // ---- pack weights ----
    kpack_wconv<<<cdiv(64 * 9 * 1, 256), 256, 0, stream>>>(w2, wb2B, wb2Z, 64, 64);
    kpack_wconv<<<cdiv(128 * 9 * 1, 256), 256, 0, stream>>>(w3, wb3B, wb3Z, 64, 128);
    kpack_wconv<<<cdiv(128 * 9 * 2, 256), 256, 0, stream>>>(w4, wb4B, wb4Z, 128, 128);
    kpack_wconv<<<cdiv(256 * 9 * 2, 256), 256, 0, stream>>>(w5, wb5B, wb5Z, 128, 256);
    kpack_wconv<<<cdiv(256 * 9 * 4, 256), 256, 0, stream>>>(w6, wb6B, wb6Z, 256, 256);
    kpack_wlin<<<cdiv(512 * 64, 256), 256, 0, stream>>>(wf1, wf1B, wf1Z, 4096, 512);
    kpack_wlin<<<cdiv(512 * 8, 256), 256, 0, stream>>>(wf2, wf2B, wf2Z, 512, 512);
    kpack_wlin<<<cdiv(10 * 8, 256), 256, 0, stream>>>(wf3, wf3B, wf3Z, 512, 10);

    // ---- L1 ----
    if (big) {
        kw1t<<<27, 64, 0, stream>>>(w1, wt);
        k1_conv_all<<<(N * 1024) / 256, 256, 0, stream>>>(x, wt, c1buf);
        k1_stats64<<<64, 256, 0, stream>>>(c1buf, muF, rF, N);
        k1_signpack<<<(N * 1024) / 64, 64, 0, stream>>>(c1buf, muF, rF, g1, b1, p1B, p1Z);
    } else {
        for (int grp = 0; grp < 8; ++grp) {
            k1_conv<<<dim3(16, 8, N), 64, 0, stream>>>(x, w1, c1buf8, grp);
            k1_stats<<<8, 256, 0, stream>>>(c1buf8, muF, rF, grp, N);
            k1_sign<<<dim3(4, 8, N), 256, 0, stream>>>(c1buf8, muF, rF, g1, b1, sgnA, grp);
        }
        kpack_sgn8<<<dim3(16, 1, N), 64, 0, stream>>>(sgnA, p1B, p1Z, 64, 1024);
    }

    // ---- L2: conv+pool (Ci=64, 32x32 -> 16x16) ----
    kbconv_pool2<1, 8><<<dim3(4, 8, N), 64, 0, stream>>>(p1B, p1Z, wb2B, wb2Z, t2, 64, 32, 32);
    kzero<<<4, 256, 0, stream>>>(SS, 1024);
    kaccum16<<<dim3(64, 32), 256, 0, stream>>>(t2, S, S2, 64, 256, N * 256);
    kfinal<<<1, 64, 0, stream>>>(S, S2, g2, b2, mu, Ad, Bd, 64, N * 256);
    ksp_conv<<<dim3(4, 1, N), 64, 0, stream>>>(t2, mu, Ad, Bd, p2B, p2Z, 64, 256);

    // ---- L3: conv (Ci=64, 16x16) ----
    kbconv2<1, 8><<<dim3(4, 16, N), 64, 0, stream>>>(p2B, p2Z, wb3B, wb3Z, t3, 128, 16, 16);
    kzero<<<4, 256, 0, stream>>>(SS, 1024);
    kaccum16<<<dim3(128, 16), 256, 0, stream>>>(t3, S, S2, 128, 256, N * 256);
    kfinal<<<2, 64, 0, stream>>>(S, S2, g3, b3, mu, Ad, Bd, 128, N * 256);
    ksp_conv<<<dim3(4, 2, N), 64, 0, stream>>>(t3, mu, Ad, Bd, p3B, p3Z, 128, 256);

    // ---- L4: conv+pool (Ci=128, 16x16 -> 8x8) ----
    kbconv_pool2<2, 8><<<dim3(1, 16, N), 64, 0, stream>>>(p3B, p3Z, wb4B, wb4Z, t4, 128, 16, 16);
    kzero<<<4, 256, 0, stream>>>(SS, 1024);
    kaccum16<<<dim3(128, 16), 256, 0, stream>>>(t4, S, S2, 128, 64, N * 64);
    kfinal<<<2, 64, 0, stream>>>(S, S2, g4, b4, mu, Ad, Bd, 128, N * 64);
    ksp_conv<<<dim3(1, 2, N), 64, 0, stream>>>(t4, mu, Ad, Bd, p4B, p4Z, 128, 64);

    // ---- L5: conv (Ci=128, 8x8) ----
    kbconv2<2, 8><<<dim3(1, 32, N), 64, 0, stream>>>(p4B, p4Z, wb5B, wb5Z, t5, 256, 8, 8);
    kzero<<<4, 256, 0, stream>>>(SS, 1024);
    kaccum16<<<dim3(256, 8), 256, 0, stream>>>(t5, S, S2, 256, 64, N * 64);
    kfinal<<<4, 64, 0, stream>>>(S, S2, g5, b5, mu, Ad, Bd, 256, N * 64);
    ksp_conv<<<dim3(1, 4, N), 64, 0, stream>>>(t5, mu, Ad, Bd, p5B, p5Z, 256, 64);

    // ---- L6: conv+pool (Ci=256, 8x8 -> 4x4), positions-in-lanes ----
    kbconv_pool2s<4, 8><<<dim3(1, 32, N), 64, 0, stream>>>(p5B, p5Z, wb6B, wb6Z, t6, 256, 8, 8);
    kzero<<<4, 256, 0, stream>>>(SS, 1024);
    kaccum16<<<dim3(256, 2), 256, 0, stream>>>(t6, S, S2, 256, 16, N * 16);
    kfinal<<<4, 64, 0, stream>>>(S, S2, g6, b6, mu, Ad, Bd, 256, N * 16);
    ksp_flat<<<N, 64, 0, stream>>>(t6, mu, Ad, Bd, p6B, p6Z);

    // ---- FC1 ----
    kbfc<<<dim3(8, N), 64, 0, stream>>>(p6B, p6Z, wf1B, wf1Z, fc1, 64, 512);
    k3_stats<<<512, 256, 0, stream>>>(fc1, N, 512, gf1, bf1, mu, Ad, Bd);
    ksp_fc<<<cdiv(N * 8, 64), 64, 0, stream>>>(fc1, mu, Ad, Bd, pF1B, pF1Z, 512, 8, N);

    // ---- FC2 ----
    kbfc<<<dim3(8, N), 64, 0, stream>>>(pF1B, pF1Z, wf2B, wf2Z, fc2, 8, 512);
    k3_stats<<<512, 256, 0, stream>>>(fc2, N, 512, gf2, bf2, mu, Ad, Bd);
    ksp_fc<<<cdiv(N * 8, 64), 64, 0, stream>>>(fc2, mu, Ad, Bd, pF2B, pF2Z, 512, 8, N);

    // ---- FC3 + bn(no affine) + log_softmax ----
    kbfc<<<dim3(1, N), 64, 0, stream>>>(pF2B, pF2Z, wf3B, wf3Z, fc3, 8, 10);
    k3_stats<<<10, 256, 0, stream>>>(fc3, N, 10, nullptr, nullptr, mu, Ad, Bd);
    k4_out<<<cdiv(N, 256), 256, 0, stream>>>(fc3, mu, Ad, (float*)d_out, N);
}

// Round 4
// 1420.978 us; speedup vs baseline: 39.4068x; 1.0355x over previous
//
#include <hip/hip_runtime.h>
#include <stdint.h>
#include <math.h>

// Round 17 = R16 + exact 2-stage L1 stats (4x CU coverage, bit-identical):
// stage A computes the 16384 independent per-slot f64 chains (identical
// element order per slot) on 256 single-wave blocks; stage B replays the
// verbatim 256-slot shared-memory tree. All other kernels verbatim R16.

typedef unsigned long long u64;

// ---------- L1 ----------
__global__ void kw1t(const float* __restrict__ w1, float* __restrict__ wt) {
    int i = blockIdx.x * 64 + threadIdx.x;     // 64*27
    if (i >= 64 * 27) return;
    int co = i / 27, k = i % 27;
    float v = w1[i];
    wt[k * 64 + co] = (v > 0.f) ? 1.f : ((v < 0.f) ? -1.f : 0.f);
}

__global__ __launch_bounds__(256) void k1_conv_all(const float* __restrict__ x,
                                                   const float* __restrict__ wt,
                                                   float* __restrict__ out) {
    int gid = blockIdx.x * 256 + threadIdx.x;  // n*1024 + hw
    int n = gid >> 10, hw = gid & 1023;
    int y = hw >> 5, x0 = hw & 31;
    const float* ip = x + (size_t)n * 3 * 1024;
    float xv[27];
#pragma unroll
    for (int wk = 0; wk < 9; ++wk) {
        int ky = wk / 3, kx = wk % 3;
        int yy = y + ky - 1, xc = x0 + kx - 1;
        bool ok = ((unsigned)yy < 32u) && ((unsigned)xc < 32u);
        int sp = yy * 32 + xc;
        xv[wk]      = ok ? ip[sp]        : 0.f;
        xv[9 + wk]  = ok ? ip[1024 + sp] : 0.f;
        xv[18 + wk] = ok ? ip[2048 + sp] : 0.f;
    }
    float acc[64];
#pragma unroll
    for (int c = 0; c < 64; ++c) acc[c] = 0.f;
    // accumulation order per co: (ky,kx) outer, ci inner — identical to R13.
#pragma unroll
    for (int wk = 0; wk < 9; ++wk)
#pragma unroll
        for (int ci = 0; ci < 3; ++ci) {
            float xs = xv[ci * 9 + wk];
            const float* wrow = wt + (ci * 9 + wk) * 64;
#pragma unroll
            for (int c = 0; c < 64; ++c) acc[c] = fmaf(wrow[c], xs, acc[c]);
        }
    float* op = out + ((size_t)n * 64) * 1024 + hw;
#pragma unroll
    for (int c = 0; c < 64; ++c) op[(size_t)c * 1024] = acc[c];
}

// stage A: per-slot partial chains, identical order to R16's k1_stats64 thread
// tid==slot (m = slot, slot+256, ...). 256 single-wave blocks.
__global__ void k1_statsA(const float* __restrict__ v, double* __restrict__ Sp,
                          double* __restrict__ S2p, int N) {
    int c = blockIdx.x;                         // 0..63
    int slot = blockIdx.y * 64 + threadIdx.x;   // 0..255
    double s = 0.0, s2 = 0.0;
    int M = N * 1024;
    for (int m = slot; m < M; m += 256) {
        double t = (double)v[((size_t)(m >> 10) * 64 + c) * 1024 + (m & 1023)];
        s += t; s2 += t * t;
    }
    Sp[c * 256 + slot] = s; S2p[c * 256 + slot] = s2;
}

// stage B: verbatim 256-slot tree + mu/r finalization (bit-identical to R16).
__global__ void k1_statsB(const double* __restrict__ Sp, const double* __restrict__ S2p,
                          float* __restrict__ muF, float* __restrict__ rF, int N) {
    int c = blockIdx.x;
    __shared__ double sh[256], sh2[256];
    sh[threadIdx.x]  = Sp[c * 256 + threadIdx.x];
    sh2[threadIdx.x] = S2p[c * 256 + threadIdx.x];
    __syncthreads();
    for (int o = 128; o > 0; o >>= 1) {
        if ((int)threadIdx.x < o) { sh[threadIdx.x] += sh[threadIdx.x + o]; sh2[threadIdx.x] += sh2[threadIdx.x + o]; }
        __syncthreads();
    }
    if (threadIdx.x == 0) {
        int M = N * 1024;
        double mean = sh[0] / M;
        double var  = sh2[0] / M - mean * mean;
        if (var < 0.0) var = 0.0;
        muF[c] = (float)mean;
        rF[c]  = 1.0f / sqrtf((float)var + 1e-5f);
    }
}

__global__ void k1_signpack(const float* __restrict__ v, const float* __restrict__ muF,
                            const float* __restrict__ rF, const float* __restrict__ g,
                            const float* __restrict__ b, u64* __restrict__ B,
                            u64* __restrict__ NZ) {
    int gid = blockIdx.x * 64 + threadIdx.x;   // n*1024 + hw
    int n = gid >> 10, hw = gid & 1023;
    u64 bb = 0, nz = 0;
    for (int c = 0; c < 64; ++c) {
        float d = v[((size_t)n * 64 + c) * 1024 + hw] - muF[c];
        float t = (d * rF[c]) * g[c] + b[c];
        bb |= (u64)(t > 0.f) << c;
        nz |= (u64)(t != 0.f) << c;
    }
    B[gid] = bb; NZ[gid] = nz;
}

// ---------- L1 fallback path (verbatim R13/R14) ----------
__global__ void k1_conv(const float* __restrict__ x, const float* __restrict__ w1,
                        float* __restrict__ out, int grp) {
    int hw = blockIdx.x * 64 + threadIdx.x;
    int cg = blockIdx.y;
    int n  = blockIdx.z;
    int co = grp * 8 + cg;
    int y = hw >> 5, x0 = hw & 31;
    const float* ip0 = x + ((size_t)n * 3 + 0) * 1024;
    const float* ip1 = x + ((size_t)n * 3 + 1) * 1024;
    const float* ip2 = x + ((size_t)n * 3 + 2) * 1024;
    const float* wp  = w1 + (size_t)co * 27;
    float acc = 0.f;
    for (int ky = 0; ky < 3; ++ky) {
        int yy = y + ky - 1;
        if (yy < 0 || yy > 31) continue;
        for (int kx = 0; kx < 3; ++kx) {
            int xc = x0 + kx - 1;
            if (xc < 0 || xc > 31) continue;
            int sp = yy * 32 + xc;
            int wk = ky * 3 + kx;
            float w0 = wp[wk], w1v = wp[9 + wk], w2 = wp[18 + wk];
            acc += (w0  > 0.f) ? ip0[sp] : ((w0  < 0.f) ? -ip0[sp] : 0.f);
            acc += (w1v > 0.f) ? ip1[sp] : ((w1v < 0.f) ? -ip1[sp] : 0.f);
            acc += (w2  > 0.f) ? ip2[sp] : ((w2  < 0.f) ? -ip2[sp] : 0.f);
        }
    }
    out[((size_t)n * 8 + cg) * 1024 + hw] = acc;
}

__device__ __forceinline__ float ld1(const float* v, int cg, int e) {
    return v[((size_t)(e >> 10) * 8 + cg) * 1024 + (e & 1023)];
}

__global__ void k1_stats(const float* __restrict__ v, float* __restrict__ muF,
                         float* __restrict__ rF, int grp, int N) {
    int cg = blockIdx.x;
    __shared__ double sh[256], sh2[256];
    double s = 0.0, s2 = 0.0;
    int M = N * 1024;
    for (int m = threadIdx.x; m < M; m += 256) {
        double t = (double)ld1(v, cg, m);
        s += t; s2 += t * t;
    }
    sh[threadIdx.x] = s; sh2[threadIdx.x] = s2;
    __syncthreads();
    for (int o = 128; o > 0; o >>= 1) {
        if ((int)threadIdx.x < o) { sh[threadIdx.x] += sh[threadIdx.x + o]; sh2[threadIdx.x] += sh2[threadIdx.x + o]; }
        __syncthreads();
    }
    if (threadIdx.x == 0) {
        double mean = sh[0] / M;
        double var  = sh2[0] / M - mean * mean;
        if (var < 0.0) var = 0.0;
        muF[grp * 8 + cg] = (float)mean;
        rF[grp * 8 + cg]  = 1.0f / sqrtf((float)var + 1e-5f);
    }
}

__global__ void k1_sign(const float* __restrict__ v, const float* __restrict__ muF,
                        const float* __restrict__ rF, const float* __restrict__ g,
                        const float* __restrict__ b, int8_t* __restrict__ sgn, int grp) {
    int hw = blockIdx.x * 256 + threadIdx.x;
    if (hw >= 1024) return;
    int cg = blockIdx.y, n = blockIdx.z;
    int c = grp * 8 + cg;
    float d  = v[((size_t)n * 8 + cg) * 1024 + hw] - muF[c];
    float t  = (d * rF[c]) * g[c] + b[c];
    sgn[((size_t)n * 64 + c) * 1024 + hw] = (int8_t)((t > 0.f) - (t < 0.f));
}

__global__ void kpack_sgn8(const int8_t* __restrict__ s, u64* __restrict__ B,
                           u64* __restrict__ NZ, int C, int HW) {
    int hw = blockIdx.x * 64 + threadIdx.x;
    if (hw >= HW) return;
    int wd = blockIdx.y, n = blockIdx.z;
    int WRD = C >> 6;
    u64 b = 0, nz = 0;
    const int8_t* sp = s + ((size_t)n * C + wd * 64) * HW + hw;
    for (int j = 0; j < 64; ++j) {
        int v = sp[(size_t)j * HW];
        b  |= (u64)(v > 0) << j;
        nz |= (u64)(v != 0) << j;
    }
    size_t o = ((size_t)n * HW + hw) * WRD + wd;
    B[o] = b; NZ[o] = nz;
}

// ---------- weight packing ----------
__global__ void kpack_wconv(const float* __restrict__ w, u64* __restrict__ WB,
                            u64* __restrict__ WNZ, int Ci, int Co) {
    int idx = blockIdx.x * 256 + threadIdx.x;
    int WRD = Ci >> 6;
    if (idx >= Co * 9 * WRD) return;
    int wd = idx % WRD, t = (idx / WRD) % 9, co = idx / (9 * WRD);
    u64 b = 0, nz = 0;
    const float* wp = w + ((size_t)co * Ci + wd * 64) * 9 + t;
    for (int j = 0; j < 64; ++j) {
        float v = wp[(size_t)j * 9];
        b  |= (u64)(v > 0.f) << j;
        nz |= (u64)(v != 0.f) << j;
    }
    WB[idx] = b; WNZ[idx] = nz;
}

__global__ void kpack_wlin(const float* __restrict__ w, u64* __restrict__ WB,
                           u64* __restrict__ WNZ, int K, int O) {
    int idx = blockIdx.x * 256 + threadIdx.x;
    int WRD = K >> 6;
    if (idx >= O * WRD) return;
    int wd = idx % WRD, o = idx / WRD;
    u64 b = 0, nz = 0;
    const float* wp = w + (size_t)o * K + wd * 64;
    for (int j = 0; j < 64; ++j) {
        float v = wp[j];
        b  |= (u64)(v > 0.f) << j;
        nz |= (u64)(v != 0.f) << j;
    }
    WB[idx] = b; WNZ[idx] = nz;
}

// ---------- binary conv, co-blocked (integer-exact) ----------
template <int WRD, int CB>
__global__ void kbconv2(const u64* __restrict__ B, const u64* __restrict__ NZ,
                        const u64* __restrict__ WB, const u64* __restrict__ WNZ,
                        int16_t* __restrict__ out, int Co, int H, int Wi) {
    int hw = blockIdx.x * 64 + threadIdx.x;
    if (hw >= H * Wi) return;
    int co0 = blockIdx.y * CB, n = blockIdx.z;
    int y = hw / Wi, x = hw % Wi;
    const u64* ib = B  + (size_t)n * H * Wi * WRD;
    const u64* iz = NZ + (size_t)n * H * Wi * WRD;
    int acc[CB];
#pragma unroll
    for (int c = 0; c < CB; ++c) acc[c] = 0;
    for (int ky = 0; ky < 3; ++ky) {
        int yy = y + ky - 1;
        if ((unsigned)yy >= (unsigned)H) continue;
        for (int kx = 0; kx < 3; ++kx) {
            int xc = x + kx - 1;
            if ((unsigned)xc >= (unsigned)Wi) continue;
            int p = yy * Wi + xc, t = ky * 3 + kx;
            u64 xb[WRD], xz[WRD];
#pragma unroll
            for (int w = 0; w < WRD; ++w) {
                xb[w] = ib[(size_t)p * WRD + w];
                xz[w] = iz[(size_t)p * WRD + w];
            }
#pragma unroll
            for (int c = 0; c < CB; ++c) {
                const u64* wb = WB  + ((size_t)(co0 + c) * 9 + t) * WRD;
                const u64* wz = WNZ + ((size_t)(co0 + c) * 9 + t) * WRD;
#pragma unroll
                for (int w = 0; w < WRD; ++w) {
                    u64 e = xz[w] & wz[w];
                    acc[c] += __popcll(e) - 2 * __popcll((xb[w] ^ wb[w]) & e);
                }
            }
        }
    }
#pragma unroll
    for (int c = 0; c < CB; ++c)
        out[((size_t)n * Co + co0 + c) * H * Wi + hw] = (int16_t)acc[c];
}

template <int WRD, int CB>
__global__ void kbconv_pool2(const u64* __restrict__ B, const u64* __restrict__ NZ,
                             const u64* __restrict__ WB, const u64* __restrict__ WNZ,
                             int16_t* __restrict__ out, int Co, int H, int Wi) {
    int Ho = H >> 1, Wo = Wi >> 1;
    int hw = blockIdx.x * 64 + threadIdx.x;
    if (hw >= Ho * Wo) return;
    int co0 = blockIdx.y * CB, n = blockIdx.z;
    int yo = hw / Wo, xo = hw % Wo;
    const u64* ib = B  + (size_t)n * H * Wi * WRD;
    const u64* iz = NZ + (size_t)n * H * Wi * WRD;
    int best[CB];
#pragma unroll
    for (int c = 0; c < CB; ++c) best[c] = -(1 << 30);
    for (int dy = 0; dy < 2; ++dy)
        for (int dx = 0; dx < 2; ++dx) {
            int y = 2 * yo + dy, x = 2 * xo + dx;
            int acc[CB];
#pragma unroll
            for (int c = 0; c < CB; ++c) acc[c] = 0;
            for (int ky = 0; ky < 3; ++ky) {
                int yy = y + ky - 1;
                if ((unsigned)yy >= (unsigned)H) continue;
                for (int kx = 0; kx < 3; ++kx) {
                    int xc = x + kx - 1;
                    if ((unsigned)xc >= (unsigned)Wi) continue;
                    int p = yy * Wi + xc, t = ky * 3 + kx;
                    u64 xb[WRD], xz[WRD];
#pragma unroll
                    for (int w = 0; w < WRD; ++w) {
                        xb[w] = ib[(size_t)p * WRD + w];
                        xz[w] = iz[(size_t)p * WRD + w];
                    }
#pragma unroll
                    for (int c = 0; c < CB; ++c) {
                        const u64* wb = WB  + ((size_t)(co0 + c) * 9 + t) * WRD;
                        const u64* wz = WNZ + ((size_t)(co0 + c) * 9 + t) * WRD;
#pragma unroll
                        for (int w = 0; w < WRD; ++w) {
                            u64 e = xz[w] & wz[w];
                            acc[c] += __popcll(e) - 2 * __popcll((xb[w] ^ wb[w]) & e);
                        }
                    }
                }
            }
#pragma unroll
            for (int c = 0; c < CB; ++c) best[c] = acc[c] > best[c] ? acc[c] : best[c];
        }
#pragma unroll
    for (int c = 0; c < CB; ++c)
        out[((size_t)n * Co + co0 + c) * Ho * Wo + hw] = (int16_t)best[c];
}

// pool variant for Ho*Wo==16: 64 lanes = 16 pixels x 4 pool positions,
// integer max via shuffles (exact).
template <int WRD, int CB>
__global__ void kbconv_pool2s(const u64* __restrict__ B, const u64* __restrict__ NZ,
                              const u64* __restrict__ WB, const u64* __restrict__ WNZ,
                              int16_t* __restrict__ out, int Co, int H, int Wi) {
    int Ho = H >> 1, Wo = Wi >> 1;       // Ho*Wo == 16
    int t0 = threadIdx.x;
    int pix = t0 & 15, pos = t0 >> 4;    // pos 0..3
    int co0 = blockIdx.y * CB, n = blockIdx.z;
    int yo = pix / Wo, xo = pix % Wo;
    int y = 2 * yo + (pos >> 1), x = 2 * xo + (pos & 1);
    const u64* ib = B  + (size_t)n * H * Wi * WRD;
    const u64* iz = NZ + (size_t)n * H * Wi * WRD;
    int acc[CB];
#pragma unroll
    for (int c = 0; c < CB; ++c) acc[c] = 0;
    for (int ky = 0; ky < 3; ++ky) {
        int yy = y + ky - 1;
        if ((unsigned)yy >= (unsigned)H) continue;
        for (int kx = 0; kx < 3; ++kx) {
            int xc = x + kx - 1;
            if ((unsigned)xc >= (unsigned)Wi) continue;
            int p = yy * Wi + xc, t = ky * 3 + kx;
            u64 xb[WRD], xz[WRD];
#pragma unroll
            for (int w = 0; w < WRD; ++w) {
                xb[w] = ib[(size_t)p * WRD + w];
                xz[w] = iz[(size_t)p * WRD + w];
            }
#pragma unroll
            for (int c = 0; c < CB; ++c) {
                const u64* wb = WB  + ((size_t)(co0 + c) * 9 + t) * WRD;
                const u64* wz = WNZ + ((size_t)(co0 + c) * 9 + t) * WRD;
#pragma unroll
                for (int w = 0; w < WRD; ++w) {
                    u64 e = xz[w] & wz[w];
                    acc[c] += __popcll(e) - 2 * __popcll((xb[w] ^ wb[w]) & e);
                }
            }
        }
    }
#pragma unroll
    for (int c = 0; c < CB; ++c) {
        int v = acc[c];
        int v1 = __shfl_xor(v, 16); v = v1 > v ? v1 : v;
        int v2 = __shfl_xor(v, 32); v = v2 > v ? v2 : v;
        acc[c] = v;
    }
    if (pos == 0) {
#pragma unroll
        for (int c = 0; c < CB; ++c)
            out[((size_t)n * Co + co0 + c) * Ho * Wo + pix] = (int16_t)acc[c];
    }
}

// ---------- conv BN stats (order-independent exact integers) ----------
__global__ void kzero(long long* __restrict__ p, int n) {
    int i = blockIdx.x * 256 + threadIdx.x;
    if (i < n) p[i] = 0;
}

__global__ void kaccum16(const int16_t* __restrict__ v, long long* __restrict__ S,
                         long long* __restrict__ S2, int C, int HW, int M) {
    int c = blockIdx.x;
    long long s = 0, s2 = 0;
    for (int m = blockIdx.y * 256 + threadIdx.x; m < M; m += gridDim.y * 256) {
        int t = v[((size_t)(m / HW) * C + c) * HW + (m % HW)];
        s += t; s2 += (long long)t * t;
    }
    __shared__ long long sh[256], sh2[256];
    sh[threadIdx.x] = s; sh2[threadIdx.x] = s2;
    __syncthreads();
    for (int o = 128; o > 0; o >>= 1) {
        if ((int)threadIdx.x < o) { sh[threadIdx.x] += sh[threadIdx.x + o]; sh2[threadIdx.x] += sh2[threadIdx.x + o]; }
        __syncthreads();
    }
    if (threadIdx.x == 0) {
        atomicAdd((u64*)&S[c],  (u64)sh[0]);
        atomicAdd((u64*)&S2[c], (u64)sh2[0]);
    }
}

__global__ void kfinal(const long long* __restrict__ S, const long long* __restrict__ S2,
                       const float* __restrict__ g, const float* __restrict__ b,
                       double* __restrict__ mu, double* __restrict__ Ad,
                       double* __restrict__ Bd, int C, int M) {
    int c = blockIdx.x * 64 + threadIdx.x;
    if (c >= C) return;
    double mean = (double)S[c] / M;
    double var  = (double)S2[c] / M - mean * mean;
    if (var < 0.0) var = 0.0;
    mu[c] = mean;
    Ad[c] = (g ? (double)g[c] : 1.0) / sqrt(var + 1e-5);
    Bd[c] = b ? (double)b[c] : 0.0;
}

// ---------- BN sign + pack ----------
__global__ void ksp_conv(const int16_t* __restrict__ v, const double* __restrict__ mu,
                         const double* __restrict__ Ad, const double* __restrict__ Bd,
                         u64* __restrict__ B, u64* __restrict__ NZ, int C, int HW) {
    int hw = blockIdx.x * 64 + threadIdx.x;
    if (hw >= HW) return;
    int wd = blockIdx.y, n = blockIdx.z;
    int WRD = C >> 6;
    u64 b = 0, nz = 0;
    for (int j = 0; j < 64; ++j) {
        int c = wd * 64 + j;
        double t = ((double)v[((size_t)n * C + c) * HW + hw] - mu[c]) * Ad[c] + Bd[c];
        b  |= (u64)(t > 0.0) << j;
        nz |= (u64)(t != 0.0) << j;
    }
    size_t o = ((size_t)n * HW + hw) * WRD + wd;
    B[o] = b; NZ[o] = nz;
}

__global__ void ksp_flat(const int16_t* __restrict__ v, const double* __restrict__ mu,
                         const double* __restrict__ Ad, const double* __restrict__ Bd,
                         u64* __restrict__ B, u64* __restrict__ NZ) {
    int wd = threadIdx.x;
    int n  = blockIdx.x;
    u64 b = 0, nz = 0;
    const int16_t* vp = v + (size_t)n * 4096 + wd * 64;
    for (int j = 0; j < 64; ++j) {
        int k = wd * 64 + j;
        int c = k >> 4;
        double t = ((double)vp[j] - mu[c]) * Ad[c] + Bd[c];
        b  |= (u64)(t > 0.0) << j;
        nz |= (u64)(t != 0.0) << j;
    }
    B[(size_t)n * 64 + wd] = b; NZ[(size_t)n * 64 + wd] = nz;
}

__global__ void ksp_fc(const int* __restrict__ v, const double* __restrict__ mu,
                       const double* __restrict__ Ad, const double* __restrict__ Bd,
                       u64* __restrict__ B, u64* __restrict__ NZ, int C, int WRD, int N) {
    int tid = blockIdx.x * 64 + threadIdx.x;
    if (tid >= N * WRD) return;
    int n = tid / WRD, wd = tid % WRD;
    u64 b = 0, nz = 0;
    for (int j = 0; j < 64; ++j) {
        int c = wd * 64 + j;
        double t = ((double)v[(size_t)n * C + c] - mu[c]) * Ad[c] + Bd[c];
        b  |= (u64)(t > 0.0) << j;
        nz |= (u64)(t != 0.0) << j;
    }
    B[(size_t)n * WRD + wd] = b; NZ[(size_t)n * WRD + wd] = nz;
}

// ---------- binary FC ----------
__global__ void kbfc(const u64* __restrict__ aB, const u64* __restrict__ aNZ,
                     const u64* __restrict__ wB, const u64* __restrict__ wNZ,
                     int* __restrict__ out, int WRD, int O) {
    int o = blockIdx.x * 64 + threadIdx.x;
    if (o >= O) return;
    int n = blockIdx.y;
    const u64* ab = aB  + (size_t)n * WRD;
    const u64* az = aNZ + (size_t)n * WRD;
    const u64* wb = wB  + (size_t)o * WRD;
    const u64* wz = wNZ + (size_t)o * WRD;
    int acc = 0;
    for (int w = 0; w < WRD; ++w) {
        u64 e = az[w] & wz[w];
        acc += __popcll(e) - 2 * __popcll((ab[w] ^ wb[w]) & e);
    }
    out[(size_t)n * O + o] = acc;
}

// ---------- FC stats / output ----------
__global__ void k3_stats(const int* __restrict__ v, int N, int C,
                         const float* __restrict__ g, const float* __restrict__ b,
                         double* __restrict__ mu, double* __restrict__ Ad,
                         double* __restrict__ Bd) {
    int c = blockIdx.x;
    __shared__ double sh[256], sh2[256];
    double s = 0.0, s2 = 0.0;
    for (int n = threadIdx.x; n < N; n += 256) {
        double t = (double)v[(size_t)n * C + c];
        s += t; s2 += t * t;
    }
    sh[threadIdx.x] = s; sh2[threadIdx.x] = s2;
    __syncthreads();
    for (int o = 128; o > 0; o >>= 1) {
        if ((int)threadIdx.x < o) { sh[threadIdx.x] += sh[threadIdx.x + o]; sh2[threadIdx.x] += sh2[threadIdx.x + o]; }
        __syncthreads();
    }
    if (threadIdx.x == 0) {
        double mean = sh[0] / N;
        double var  = sh2[0] / N - mean * mean;
        if (var < 0.0) var = 0.0;
        mu[c] = mean;
        Ad[c] = (g ? (double)g[c] : 1.0) / sqrt(var + 1e-5);
        Bd[c] = b ? (double)b[c] : 0.0;
    }
}

__global__ void k4_out(const int* __restrict__ v, const double* __restrict__ mu,
                       const double* __restrict__ Ad, float* __restrict__ out, int N) {
    int n = blockIdx.x * 256 + threadIdx.x;
    if (n >= N) return;
    double z[10];
    double mx = -1e300;
    for (int o = 0; o < 10; ++o) {
        z[o] = ((double)v[n * 10 + o] - mu[o]) * Ad[o];
        if (z[o] > mx) mx = z[o];
    }
    double s = 0.0;
    for (int o = 0; o < 10; ++o) s += exp(z[o] - mx);
    double l = mx + log(s);
    for (int o = 0; o < 10; ++o) out[n * 10 + o] = (float)(z[o] - l);
}

// ---------------- host ----------------
extern "C" void kernel_launch(void* const* d_in, const int* in_sizes, int n_in,
                              void* d_out, int out_size, void* d_ws, size_t ws_size,
                              hipStream_t stream) {
    const int N = in_sizes[0] / (3 * 32 * 32);   // 512

    const float* x   = (const float*)d_in[0];
    const float* w1  = (const float*)d_in[1];
    const float* g1  = (const float*)d_in[2];
    const float* b1  = (const float*)d_in[3];
    const float* w2  = (const float*)d_in[4];
    const float* g2  = (const float*)d_in[5];
    const float* b2  = (const float*)d_in[6];
    const float* w3  = (const float*)d_in[7];
    const float* g3  = (const float*)d_in[8];
    const float* b3  = (const float*)d_in[9];
    const float* w4  = (const float*)d_in[10];
    const float* g4  = (const float*)d_in[11];
    const float* b4  = (const float*)d_in[12];
    const float* w5  = (const float*)d_in[13];
    const float* g5  = (const float*)d_in[14];
    const float* b5  = (const float*)d_in[15];
    const float* w6  = (const float*)d_in[16];
    const float* g6  = (const float*)d_in[17];
    const float* b6  = (const float*)d_in[18];
    const float* wf1 = (const float*)d_in[19];
    const float* gf1 = (const float*)d_in[20];
    const float* bf1 = (const float*)d_in[21];
    const float* wf2 = (const float*)d_in[22];
    const float* gf2 = (const float*)d_in[23];
    const float* bf2 = (const float*)d_in[24];
    const float* wf3 = (const float*)d_in[25];

    char* ws = (char*)d_ws;
    size_t off = 0;
    auto alloc = [&](size_t bytes) -> char* {
        char* p = ws + off;
        off = (off + bytes + 511) & ~(size_t)511;
        return p;
    };

    // ---- DOWN region: all post-L1 buffers at distinct offsets ----
    int16_t* t2  = (int16_t*)alloc((size_t)N * 64 * 256 * 2);
    u64* p2B = (u64*)alloc((size_t)N * 256 * 8);
    u64* p2Z = (u64*)alloc((size_t)N * 256 * 8);
    int16_t* t3  = (int16_t*)alloc((size_t)N * 128 * 256 * 2);
    u64* p3B = (u64*)alloc((size_t)N * 256 * 2 * 8);
    u64* p3Z = (u64*)alloc((size_t)N * 256 * 2 * 8);
    int16_t* t4  = (int16_t*)alloc((size_t)N * 128 * 64 * 2);
    u64* p4B = (u64*)alloc((size_t)N * 64 * 2 * 8);
    u64* p4Z = (u64*)alloc((size_t)N * 64 * 2 * 8);
    int16_t* t5  = (int16_t*)alloc((size_t)N * 256 * 64 * 2);
    u64* p5B = (u64*)alloc((size_t)N * 64 * 4 * 8);
    u64* p5Z = (u64*)alloc((size_t)N * 64 * 4 * 8);
    int16_t* t6  = (int16_t*)alloc((size_t)N * 256 * 16 * 2);
    u64* p6B = (u64*)alloc((size_t)N * 64 * 8);
    u64* p6Z = (u64*)alloc((size_t)N * 64 * 8);
    int* fc1 = (int*)alloc((size_t)N * 512 * 4);
    int* fc2 = (int*)alloc((size_t)N * 512 * 4);
    int* fc3 = (int*)alloc((size_t)N * 10 * 4);
    u64* pF1B = (u64*)alloc((size_t)N * 8 * 8);
    u64* pF1Z = (u64*)alloc((size_t)N * 8 * 8);
    u64* pF2B = (u64*)alloc((size_t)N * 8 * 8);
    u64* pF2Z = (u64*)alloc((size_t)N * 8 * 8);
    size_t down_end = off;

    // ---- L1 head overlays (dead before any DOWN buffer is written) ----
    size_t head_big = (size_t)N * 64 * 1024 * 4;      // 134.2MB f32, 64 channels
    bool big = ws_size >= head_big + ((size_t)20 << 20);
    float*  c1buf = (float*)ws;                        // big: [N][64][1024]
    float*  c1buf8 = (float*)ws;                       // fallback: [N][8][1024]
    int8_t* sgnA  = (int8_t*)(ws + (size_t)N * 8 * 1024 * 4);  // fallback only

    // ---- tail (coexists with L1 head) ----
    off = big ? (head_big > down_end ? head_big : down_end) : down_end;
    off = (off + 511) & ~(size_t)511;
    u64* p1B = (u64*)alloc((size_t)N * 1024 * 8);
    u64* p1Z = (u64*)alloc((size_t)N * 1024 * 8);
    u64* wb2B = (u64*)alloc(64  * 9 * 1 * 8);  u64* wb2Z = (u64*)alloc(64  * 9 * 1 * 8);
    u64* wb3B = (u64*)alloc(128 * 9 * 1 * 8);  u64* wb3Z = (u64*)alloc(128 * 9 * 1 * 8);
    u64* wb4B = (u64*)alloc(128 * 9 * 2 * 8);  u64* wb4Z = (u64*)alloc(128 * 9 * 2 * 8);
    u64* wb5B = (u64*)alloc(256 * 9 * 2 * 8);  u64* wb5Z = (u64*)alloc(256 * 9 * 2 * 8);
    u64* wb6B = (u64*)alloc(256 * 9 * 4 * 8);  u64* wb6Z = (u64*)alloc(256 * 9 * 4 * 8);
    u64* wf1B = (u64*)alloc(512 * 64 * 8);     u64* wf1Z = (u64*)alloc(512 * 64 * 8);
    u64* wf2B = (u64*)alloc(512 * 8 * 8);      u64* wf2Z = (u64*)alloc(512 * 8 * 8);
    u64* wf3B = (u64*)alloc(10 * 8 * 8);       u64* wf3Z = (u64*)alloc(10 * 8 * 8);
    float* wt = (float*)alloc(27 * 64 * 4);
    double* Sp  = (double*)alloc(64 * 256 * 8);
    double* S2p = (double*)alloc(64 * 256 * 8);
    long long* SS = (long long*)alloc(1024 * 8);
    long long* S  = SS;
    long long* S2 = SS + 512;
    double* mu = (double*)alloc(512 * 8);
    double* Ad = (double*)alloc(512 * 8);
    double* Bd = (double*)alloc(512 * 8);
    float*  muF = (float*)alloc(64 * 4);
    float*  rF  = (float*)alloc(64 * 4);

    auto cdiv = [](int a, int b) { return (a + b - 1) / b; };

    // ---- pack weights ----
    kpack_wconv<<<cdiv(64 * 9 * 1, 256), 256, 0, stream>>>(w2, wb2B, wb2Z, 64, 64);
    kpack_wconv<<<cdiv(128 * 9 * 1, 256), 256, 0, stream>>>(w3, wb3B, wb3Z, 64, 128);
    kpack_wconv<<<cdiv(128 * 9 * 2, 256), 256, 0, stream>>>(w4, wb4B, wb4Z, 128, 128);
    kpack_wconv<<<cdiv(256 * 9 * 2, 256), 256, 0, stream>>>(w5, wb5B, wb5Z, 128, 256);
    kpack_wconv<<<cdiv(256 * 9 * 4, 256), 256, 0, stream>>>(w6, wb6B, wb6Z, 256, 256);
    kpack_wlin<<<cdiv(512 * 64, 256), 256, 0, stream>>>(wf1, wf1B, wf1Z, 4096, 512);
    kpack_wlin<<<cdiv(512 * 8, 256), 256, 0, stream>>>(wf2, wf2B, wf2Z, 512, 512);
    kpack_wlin<<<cdiv(10 * 8, 256), 256, 0, stream>>>(wf3, wf3B, wf3Z, 512, 10);

    // ---- L1 ----
    if (big) {
        kw1t<<<27, 64, 0, stream>>>(w1, wt);
        k1_conv_all<<<(N * 1024) / 256, 256, 0, stream>>>(x, wt, c1buf);
        k1_statsA<<<dim3(64, 4), 64, 0, stream>>>(c1buf, Sp, S2p, N);
        k1_statsB<<<64, 256, 0, stream>>>(Sp, S2p, muF, rF, N);
        k1_signpack<<<(N * 1024) / 64, 64, 0, stream>>>(c1buf, muF, rF, g1, b1, p1B, p1Z);
    } else {
        for (int grp = 0; grp < 8; ++grp) {
            k1_conv<<<dim3(16, 8, N), 64, 0, stream>>>(x, w1, c1buf8, grp);
            k1_stats<<<8, 256, 0, stream>>>(c1buf8, muF, rF, grp, N);
            k1_sign<<<dim3(4, 8, N), 256, 0, stream>>>(c1buf8, muF, rF, g1, b1, sgnA, grp);
        }
        kpack_sgn8<<<dim3(16, 1, N), 64, 0, stream>>>(sgnA, p1B, p1Z, 64, 1024);
    }

    // ---- L2: conv+pool (Ci=64, 32x32 -> 16x16) ----
    kbconv_pool2<1, 8><<<dim3(4, 8, N), 64, 0, stream>>>(p1B, p1Z, wb2B, wb2Z, t2, 64, 32, 32);
    kzero<<<4, 256, 0, stream>>>(SS, 1024);
    kaccum16<<<dim3(64, 32), 256, 0, stream>>>(t2, S, S2, 64, 256, N * 256);
    kfinal<<<1, 64, 0, stream>>>(S, S2, g2, b2, mu, Ad, Bd, 64, N * 256);
    ksp_conv<<<dim3(4, 1, N), 64, 0, stream>>>(t2, mu, Ad, Bd, p2B, p2Z, 64, 256);

    // ---- L3: conv (Ci=64, 16x16) ----
    kbconv2<1, 8><<<dim3(4, 16, N), 64, 0, stream>>>(p2B, p2Z, wb3B, wb3Z, t3, 128, 16, 16);
    kzero<<<4, 256, 0, stream>>>(SS, 1024);
    kaccum16<<<dim3(128, 16), 256, 0, stream>>>(t3, S, S2, 128, 256, N * 256);
    kfinal<<<2, 64, 0, stream>>>(S, S2, g3, b3, mu, Ad, Bd, 128, N * 256);
    ksp_conv<<<dim3(4, 2, N), 64, 0, stream>>>(t3, mu, Ad, Bd, p3B, p3Z, 128, 256);

    // ---- L4: conv+pool (Ci=128, 16x16 -> 8x8) ----
    kbconv_pool2<2, 8><<<dim3(1, 16, N), 64, 0, stream>>>(p3B, p3Z, wb4B, wb4Z, t4, 128, 16, 16);
    kzero<<<4, 256, 0, stream>>>(SS, 1024);
    kaccum16<<<dim3(128, 16), 256, 0, stream>>>(t4, S, S2, 128, 64, N * 64);
    kfinal<<<2, 64, 0, stream>>>(S, S2, g4, b4, mu, Ad, Bd, 128, N * 64);
    ksp_conv<<<dim3(1, 2, N), 64, 0, stream>>>(t4, mu, Ad, Bd, p4B, p4Z, 128, 64);

    // ---- L5: conv (Ci=128, 8x8) ----
    kbconv2<2, 8><<<dim3(1, 32, N), 64, 0, stream>>>(p4B, p4Z, wb5B, wb5Z, t5, 256, 8, 8);
    kzero<<<4, 256, 0, stream>>>(SS, 1024);
    kaccum16<<<dim3(256, 8), 256, 0, stream>>>(t5, S, S2, 256, 64, N * 64);
    kfinal<<<4, 64, 0, stream>>>(S, S2, g5, b5, mu, Ad, Bd, 256, N * 64);
    ksp_conv<<<dim3(1, 4, N), 64, 0, stream>>>(t5, mu, Ad, Bd, p5B, p5Z, 256, 64);

    // ---- L6: conv+pool (Ci=256, 8x8 -> 4x4), positions-in-lanes ----
    kbconv_pool2s<4, 8><<<dim3(1, 32, N), 64, 0, stream>>>(p5B, p5Z, wb6B, wb6Z, t6, 256, 8, 8);
    kzero<<<4, 256, 0, stream>>>(SS, 1024);
    kaccum16<<<dim3(256, 2), 256, 0, stream>>>(t6, S, S2, 256, 16, N * 16);
    kfinal<<<4, 64, 0, stream>>>(S, S2, g6, b6, mu, Ad, Bd, 256, N * 16);
    ksp_flat<<<N, 64, 0, stream>>>(t6, mu, Ad, Bd, p6B, p6Z);

    // ---- FC1 ----
    kbfc<<<dim3(8, N), 64, 0, stream>>>(p6B, p6Z, wf1B, wf1Z, fc1, 64, 512);
    k3_stats<<<512, 256, 0, stream>>>(fc1, N, 512, gf1, bf1, mu, Ad, Bd);
    ksp_fc<<<cdiv(N * 8, 64), 64, 0, stream>>>(fc1, mu, Ad, Bd, pF1B, pF1Z, 512, 8, N);

    // ---- FC2 ----
    kbfc<<<dim3(8, N), 64, 0, stream>>>(pF1B, pF1Z, wf2B, wf2Z, fc2, 8, 512);
    k3_stats<<<512, 256, 0, stream>>>(fc2, N, 512, gf2, bf2, mu, Ad, Bd);
    ksp_fc<<<cdiv(N * 8, 64), 64, 0, stream>>>(fc2, mu, Ad, Bd, pF2B, pF2Z, 512, 8, N);

    // ---- FC3 + bn(no affine) + log_softmax ----
    kbfc<<<dim3(1, N), 64, 0, stream>>>(pF2B, pF2Z, wf3B, wf3Z, fc3, 8, 10);
    k3_stats<<<10, 256, 0, stream>>>(fc3, N, 10, nullptr, nullptr, mu, Ad, Bd);
    k4_out<<<cdiv(N, 256), 256, 0, stream>>>(fc3, mu, Ad, (float*)d_out, N);
}

// Round 5
// 922.927 us; speedup vs baseline: 60.6723x; 1.5396x over previous
//
#include <hip/hip_runtime.h>
#include <stdint.h>
#include <math.h>

// Round 18 = R17 with k1_statsA rewritten for ILP: 32-deep independent load
// batches (hides ~630cy latency that the compiler's no-unroll 1-outstanding
// loop paid per element), accumulation replayed in ascending-m order => the
// f64 chain per slot is BIT-IDENTICAL to R16/R17. All else verbatim R17.

typedef unsigned long long u64;

// ---------- L1 ----------
__global__ void kw1t(const float* __restrict__ w1, float* __restrict__ wt) {
    int i = blockIdx.x * 64 + threadIdx.x;     // 64*27
    if (i >= 64 * 27) return;
    int co = i / 27, k = i % 27;
    float v = w1[i];
    wt[k * 64 + co] = (v > 0.f) ? 1.f : ((v < 0.f) ? -1.f : 0.f);
}

__global__ __launch_bounds__(256) void k1_conv_all(const float* __restrict__ x,
                                                   const float* __restrict__ wt,
                                                   float* __restrict__ out) {
    int gid = blockIdx.x * 256 + threadIdx.x;  // n*1024 + hw
    int n = gid >> 10, hw = gid & 1023;
    int y = hw >> 5, x0 = hw & 31;
    const float* ip = x + (size_t)n * 3 * 1024;
    float xv[27];
#pragma unroll
    for (int wk = 0; wk < 9; ++wk) {
        int ky = wk / 3, kx = wk % 3;
        int yy = y + ky - 1, xc = x0 + kx - 1;
        bool ok = ((unsigned)yy < 32u) && ((unsigned)xc < 32u);
        int sp = yy * 32 + xc;
        xv[wk]      = ok ? ip[sp]        : 0.f;
        xv[9 + wk]  = ok ? ip[1024 + sp] : 0.f;
        xv[18 + wk] = ok ? ip[2048 + sp] : 0.f;
    }
    float acc[64];
#pragma unroll
    for (int c = 0; c < 64; ++c) acc[c] = 0.f;
    // accumulation order per co: (ky,kx) outer, ci inner — identical to R13.
#pragma unroll
    for (int wk = 0; wk < 9; ++wk)
#pragma unroll
        for (int ci = 0; ci < 3; ++ci) {
            float xs = xv[ci * 9 + wk];
            const float* wrow = wt + (ci * 9 + wk) * 64;
#pragma unroll
            for (int c = 0; c < 64; ++c) acc[c] = fmaf(wrow[c], xs, acc[c]);
        }
    float* op = out + ((size_t)n * 64) * 1024 + hw;
#pragma unroll
    for (int c = 0; c < 64; ++c) op[(size_t)c * 1024] = acc[c];
}

// stage A: per-slot partial chains, identical m-order to R16's k1_stats64.
// 32-deep independent load batches hide memory latency; the f64 adds are
// replayed in ascending m (j ascending) => bit-identical chain.
__global__ void k1_statsA(const float* __restrict__ v, double* __restrict__ Sp,
                          double* __restrict__ S2p, int N) {
    int c = blockIdx.x;                         // 0..63
    int slot = blockIdx.y * 64 + threadIdx.x;   // 0..255
    double s = 0.0, s2 = 0.0;
    int K = N * 4;                              // chain length (m = slot + 256k)
    const float* vp = v + (size_t)c * 1024 + slot;
    int k0 = 0;
    for (; k0 + 32 <= K; k0 += 32) {
        const float* p0 = vp + (size_t)(k0 >> 2) * 65536;
        float buf[32];
#pragma unroll
        for (int j = 0; j < 32; ++j)
            buf[j] = p0[(size_t)(j >> 2) * 65536 + (j & 3) * 256];
#pragma unroll
        for (int j = 0; j < 32; ++j) {
            double t = (double)buf[j];
            s += t; s2 += t * t;
        }
    }
    for (; k0 < K; ++k0) {                      // tail (unused at N=512)
        int m = slot + k0 * 256;
        double t = (double)v[((size_t)(m >> 10) * 64 + c) * 1024 + (m & 1023)];
        s += t; s2 += t * t;
    }
    Sp[c * 256 + slot] = s; S2p[c * 256 + slot] = s2;
}

// stage B: verbatim 256-slot tree + mu/r finalization (bit-identical to R16).
__global__ void k1_statsB(const double* __restrict__ Sp, const double* __restrict__ S2p,
                          float* __restrict__ muF, float* __restrict__ rF, int N) {
    int c = blockIdx.x;
    __shared__ double sh[256], sh2[256];
    sh[threadIdx.x]  = Sp[c * 256 + threadIdx.x];
    sh2[threadIdx.x] = S2p[c * 256 + threadIdx.x];
    __syncthreads();
    for (int o = 128; o > 0; o >>= 1) {
        if ((int)threadIdx.x < o) { sh[threadIdx.x] += sh[threadIdx.x + o]; sh2[threadIdx.x] += sh2[threadIdx.x + o]; }
        __syncthreads();
    }
    if (threadIdx.x == 0) {
        int M = N * 1024;
        double mean = sh[0] / M;
        double var  = sh2[0] / M - mean * mean;
        if (var < 0.0) var = 0.0;
        muF[c] = (float)mean;
        rF[c]  = 1.0f / sqrtf((float)var + 1e-5f);
    }
}

__global__ void k1_signpack(const float* __restrict__ v, const float* __restrict__ muF,
                            const float* __restrict__ rF, const float* __restrict__ g,
                            const float* __restrict__ b, u64* __restrict__ B,
                            u64* __restrict__ NZ) {
    int gid = blockIdx.x * 64 + threadIdx.x;   // n*1024 + hw
    int n = gid >> 10, hw = gid & 1023;
    u64 bb = 0, nz = 0;
    for (int c = 0; c < 64; ++c) {
        float d = v[((size_t)n * 64 + c) * 1024 + hw] - muF[c];
        float t = (d * rF[c]) * g[c] + b[c];
        bb |= (u64)(t > 0.f) << c;
        nz |= (u64)(t != 0.f) << c;
    }
    B[gid] = bb; NZ[gid] = nz;
}

// ---------- L1 fallback path (verbatim R13/R14) ----------
__global__ void k1_conv(const float* __restrict__ x, const float* __restrict__ w1,
                        float* __restrict__ out, int grp) {
    int hw = blockIdx.x * 64 + threadIdx.x;
    int cg = blockIdx.y;
    int n  = blockIdx.z;
    int co = grp * 8 + cg;
    int y = hw >> 5, x0 = hw & 31;
    const float* ip0 = x + ((size_t)n * 3 + 0) * 1024;
    const float* ip1 = x + ((size_t)n * 3 + 1) * 1024;
    const float* ip2 = x + ((size_t)n * 3 + 2) * 1024;
    const float* wp  = w1 + (size_t)co * 27;
    float acc = 0.f;
    for (int ky = 0; ky < 3; ++ky) {
        int yy = y + ky - 1;
        if (yy < 0 || yy > 31) continue;
        for (int kx = 0; kx < 3; ++kx) {
            int xc = x0 + kx - 1;
            if (xc < 0 || xc > 31) continue;
            int sp = yy * 32 + xc;
            int wk = ky * 3 + kx;
            float w0 = wp[wk], w1v = wp[9 + wk], w2 = wp[18 + wk];
            acc += (w0  > 0.f) ? ip0[sp] : ((w0  < 0.f) ? -ip0[sp] : 0.f);
            acc += (w1v > 0.f) ? ip1[sp] : ((w1v < 0.f) ? -ip1[sp] : 0.f);
            acc += (w2  > 0.f) ? ip2[sp] : ((w2  < 0.f) ? -ip2[sp] : 0.f);
        }
    }
    out[((size_t)n * 8 + cg) * 1024 + hw] = acc;
}

__device__ __forceinline__ float ld1(const float* v, int cg, int e) {
    return v[((size_t)(e >> 10) * 8 + cg) * 1024 + (e & 1023)];
}

__global__ void k1_stats(const float* __restrict__ v, float* __restrict__ muF,
                         float* __restrict__ rF, int grp, int N) {
    int cg = blockIdx.x;
    __shared__ double sh[256], sh2[256];
    double s = 0.0, s2 = 0.0;
    int M = N * 1024;
    for (int m = threadIdx.x; m < M; m += 256) {
        double t = (double)ld1(v, cg, m);
        s += t; s2 += t * t;
    }
    sh[threadIdx.x] = s; sh2[threadIdx.x] = s2;
    __syncthreads();
    for (int o = 128; o > 0; o >>= 1) {
        if ((int)threadIdx.x < o) { sh[threadIdx.x] += sh[threadIdx.x + o]; sh2[threadIdx.x] += sh2[threadIdx.x + o]; }
        __syncthreads();
    }
    if (threadIdx.x == 0) {
        double mean = sh[0] / M;
        double var  = sh2[0] / M - mean * mean;
        if (var < 0.0) var = 0.0;
        muF[grp * 8 + cg] = (float)mean;
        rF[grp * 8 + cg]  = 1.0f / sqrtf((float)var + 1e-5f);
    }
}

__global__ void k1_sign(const float* __restrict__ v, const float* __restrict__ muF,
                        const float* __restrict__ rF, const float* __restrict__ g,
                        const float* __restrict__ b, int8_t* __restrict__ sgn, int grp) {
    int hw = blockIdx.x * 256 + threadIdx.x;
    if (hw >= 1024) return;
    int cg = blockIdx.y, n = blockIdx.z;
    int c = grp * 8 + cg;
    float d  = v[((size_t)n * 8 + cg) * 1024 + hw] - muF[c];
    float t  = (d * rF[c]) * g[c] + b[c];
    sgn[((size_t)n * 64 + c) * 1024 + hw] = (int8_t)((t > 0.f) - (t < 0.f));
}

__global__ void kpack_sgn8(const int8_t* __restrict__ s, u64* __restrict__ B,
                           u64* __restrict__ NZ, int C, int HW) {
    int hw = blockIdx.x * 64 + threadIdx.x;
    if (hw >= HW) return;
    int wd = blockIdx.y, n = blockIdx.z;
    int WRD = C >> 6;
    u64 b = 0, nz = 0;
    const int8_t* sp = s + ((size_t)n * C + wd * 64) * HW + hw;
    for (int j = 0; j < 64; ++j) {
        int v = sp[(size_t)j * HW];
        b  |= (u64)(v > 0) << j;
        nz |= (u64)(v != 0) << j;
    }
    size_t o = ((size_t)n * HW + hw) * WRD + wd;
    B[o] = b; NZ[o] = nz;
}

// ---------- weight packing ----------
__global__ void kpack_wconv(const float* __restrict__ w, u64* __restrict__ WB,
                            u64* __restrict__ WNZ, int Ci, int Co) {
    int idx = blockIdx.x * 256 + threadIdx.x;
    int WRD = Ci >> 6;
    if (idx >= Co * 9 * WRD) return;
    int wd = idx % WRD, t = (idx / WRD) % 9, co = idx / (9 * WRD);
    u64 b = 0, nz = 0;
    const float* wp = w + ((size_t)co * Ci + wd * 64) * 9 + t;
    for (int j = 0; j < 64; ++j) {
        float v = wp[(size_t)j * 9];
        b  |= (u64)(v > 0.f) << j;
        nz |= (u64)(v != 0.f) << j;
    }
    WB[idx] = b; WNZ[idx] = nz;
}

__global__ void kpack_wlin(const float* __restrict__ w, u64* __restrict__ WB,
                           u64* __restrict__ WNZ, int K, int O) {
    int idx = blockIdx.x * 256 + threadIdx.x;
    int WRD = K >> 6;
    if (idx >= O * WRD) return;
    int wd = idx % WRD, o = idx / WRD;
    u64 b = 0, nz = 0;
    const float* wp = w + (size_t)o * K + wd * 64;
    for (int j = 0; j < 64; ++j) {
        float v = wp[j];
        b  |= (u64)(v > 0.f) << j;
        nz |= (u64)(v != 0.f) << j;
    }
    WB[idx] = b; WNZ[idx] = nz;
}

// ---------- binary conv, co-blocked (integer-exact) ----------
template <int WRD, int CB>
__global__ void kbconv2(const u64* __restrict__ B, const u64* __restrict__ NZ,
                        const u64* __restrict__ WB, const u64* __restrict__ WNZ,
                        int16_t* __restrict__ out, int Co, int H, int Wi) {
    int hw = blockIdx.x * 64 + threadIdx.x;
    if (hw >= H * Wi) return;
    int co0 = blockIdx.y * CB, n = blockIdx.z;
    int y = hw / Wi, x = hw % Wi;
    const u64* ib = B  + (size_t)n * H * Wi * WRD;
    const u64* iz = NZ + (size_t)n * H * Wi * WRD;
    int acc[CB];
#pragma unroll
    for (int c = 0; c < CB; ++c) acc[c] = 0;
    for (int ky = 0; ky < 3; ++ky) {
        int yy = y + ky - 1;
        if ((unsigned)yy >= (unsigned)H) continue;
        for (int kx = 0; kx < 3; ++kx) {
            int xc = x + kx - 1;
            if ((unsigned)xc >= (unsigned)Wi) continue;
            int p = yy * Wi + xc, t = ky * 3 + kx;
            u64 xb[WRD], xz[WRD];
#pragma unroll
            for (int w = 0; w < WRD; ++w) {
                xb[w] = ib[(size_t)p * WRD + w];
                xz[w] = iz[(size_t)p * WRD + w];
            }
#pragma unroll
            for (int c = 0; c < CB; ++c) {
                const u64* wb = WB  + ((size_t)(co0 + c) * 9 + t) * WRD;
                const u64* wz = WNZ + ((size_t)(co0 + c) * 9 + t) * WRD;
#pragma unroll
                for (int w = 0; w < WRD; ++w) {
                    u64 e = xz[w] & wz[w];
                    acc[c] += __popcll(e) - 2 * __popcll((xb[w] ^ wb[w]) & e);
                }
            }
        }
    }
#pragma unroll
    for (int c = 0; c < CB; ++c)
        out[((size_t)n * Co + co0 + c) * H * Wi + hw] = (int16_t)acc[c];
}

template <int WRD, int CB>
__global__ void kbconv_pool2(const u64* __restrict__ B, const u64* __restrict__ NZ,
                             const u64* __restrict__ WB, const u64* __restrict__ WNZ,
                             int16_t* __restrict__ out, int Co, int H, int Wi) {
    int Ho = H >> 1, Wo = Wi >> 1;
    int hw = blockIdx.x * 64 + threadIdx.x;
    if (hw >= Ho * Wo) return;
    int co0 = blockIdx.y * CB, n = blockIdx.z;
    int yo = hw / Wo, xo = hw % Wo;
    const u64* ib = B  + (size_t)n * H * Wi * WRD;
    const u64* iz = NZ + (size_t)n * H * Wi * WRD;
    int best[CB];
#pragma unroll
    for (int c = 0; c < CB; ++c) best[c] = -(1 << 30);
    for (int dy = 0; dy < 2; ++dy)
        for (int dx = 0; dx < 2; ++dx) {
            int y = 2 * yo + dy, x = 2 * xo + dx;
            int acc[CB];
#pragma unroll
            for (int c = 0; c < CB; ++c) acc[c] = 0;
            for (int ky = 0; ky < 3; ++ky) {
                int yy = y + ky - 1;
                if ((unsigned)yy >= (unsigned)H) continue;
                for (int kx = 0; kx < 3; ++kx) {
                    int xc = x + kx - 1;
                    if ((unsigned)xc >= (unsigned)Wi) continue;
                    int p = yy * Wi + xc, t = ky * 3 + kx;
                    u64 xb[WRD], xz[WRD];
#pragma unroll
                    for (int w = 0; w < WRD; ++w) {
                        xb[w] = ib[(size_t)p * WRD + w];
                        xz[w] = iz[(size_t)p * WRD + w];
                    }
#pragma unroll
                    for (int c = 0; c < CB; ++c) {
                        const u64* wb = WB  + ((size_t)(co0 + c) * 9 + t) * WRD;
                        const u64* wz = WNZ + ((size_t)(co0 + c) * 9 + t) * WRD;
#pragma unroll
                        for (int w = 0; w < WRD; ++w) {
                            u64 e = xz[w] & wz[w];
                            acc[c] += __popcll(e) - 2 * __popcll((xb[w] ^ wb[w]) & e);
                        }
                    }
                }
            }
#pragma unroll
            for (int c = 0; c < CB; ++c) best[c] = acc[c] > best[c] ? acc[c] : best[c];
        }
#pragma unroll
    for (int c = 0; c < CB; ++c)
        out[((size_t)n * Co + co0 + c) * Ho * Wo + hw] = (int16_t)best[c];
}

// pool variant for Ho*Wo==16: 64 lanes = 16 pixels x 4 pool positions,
// integer max via shuffles (exact).
template <int WRD, int CB>
__global__ void kbconv_pool2s(const u64* __restrict__ B, const u64* __restrict__ NZ,
                              const u64* __restrict__ WB, const u64* __restrict__ WNZ,
                              int16_t* __restrict__ out, int Co, int H, int Wi) {
    int Ho = H >> 1, Wo = Wi >> 1;       // Ho*Wo == 16
    int t0 = threadIdx.x;
    int pix = t0 & 15, pos = t0 >> 4;    // pos 0..3
    int co0 = blockIdx.y * CB, n = blockIdx.z;
    int yo = pix / Wo, xo = pix % Wo;
    int y = 2 * yo + (pos >> 1), x = 2 * xo + (pos & 1);
    const u64* ib = B  + (size_t)n * H * Wi * WRD;
    const u64* iz = NZ + (size_t)n * H * Wi * WRD;
    int acc[CB];
#pragma unroll
    for (int c = 0; c < CB; ++c) acc[c] = 0;
    for (int ky = 0; ky < 3; ++ky) {
        int yy = y + ky - 1;
        if ((unsigned)yy >= (unsigned)H) continue;
        for (int kx = 0; kx < 3; ++kx) {
            int xc = x + kx - 1;
            if ((unsigned)xc >= (unsigned)Wi) continue;
            int p = yy * Wi + xc, t = ky * 3 + kx;
            u64 xb[WRD], xz[WRD];
#pragma unroll
            for (int w = 0; w < WRD; ++w) {
                xb[w] = ib[(size_t)p * WRD + w];
                xz[w] = iz[(size_t)p * WRD + w];
            }
#pragma unroll
            for (int c = 0; c < CB; ++c) {
                const u64* wb = WB  + ((size_t)(co0 + c) * 9 + t) * WRD;
                const u64* wz = WNZ + ((size_t)(co0 + c) * 9 + t) * WRD;
#pragma unroll
                for (int w = 0; w < WRD; ++w) {
                    u64 e = xz[w] & wz[w];
                    acc[c] += __popcll(e) - 2 * __popcll((xb[w] ^ wb[w]) & e);
                }
            }
        }
    }
#pragma unroll
    for (int c = 0; c < CB; ++c) {
        int v = acc[c];
        int v1 = __shfl_xor(v, 16); v = v1 > v ? v1 : v;
        int v2 = __shfl_xor(v, 32); v = v2 > v ? v2 : v;
        acc[c] = v;
    }
    if (pos == 0) {
#pragma unroll
        for (int c = 0; c < CB; ++c)
            out[((size_t)n * Co + co0 + c) * Ho * Wo + pix] = (int16_t)acc[c];
    }
}

// ---------- conv BN stats (order-independent exact integers) ----------
__global__ void kzero(long long* __restrict__ p, int n) {
    int i = blockIdx.x * 256 + threadIdx.x;
    if (i < n) p[i] = 0;
}

__global__ void kaccum16(const int16_t* __restrict__ v, long long* __restrict__ S,
                         long long* __restrict__ S2, int C, int HW, int M) {
    int c = blockIdx.x;
    long long s = 0, s2 = 0;
    for (int m = blockIdx.y * 256 + threadIdx.x; m < M; m += gridDim.y * 256) {
        int t = v[((size_t)(m / HW) * C + c) * HW + (m % HW)];
        s += t; s2 += (long long)t * t;
    }
    __shared__ long long sh[256], sh2[256];
    sh[threadIdx.x] = s; sh2[threadIdx.x] = s2;
    __syncthreads();
    for (int o = 128; o > 0; o >>= 1) {
        if ((int)threadIdx.x < o) { sh[threadIdx.x] += sh[threadIdx.x + o]; sh2[threadIdx.x] += sh2[threadIdx.x + o]; }
        __syncthreads();
    }
    if (threadIdx.x == 0) {
        atomicAdd((u64*)&S[c],  (u64)sh[0]);
        atomicAdd((u64*)&S2[c], (u64)sh2[0]);
    }
}

__global__ void kfinal(const long long* __restrict__ S, const long long* __restrict__ S2,
                       const float* __restrict__ g, const float* __restrict__ b,
                       double* __restrict__ mu, double* __restrict__ Ad,
                       double* __restrict__ Bd, int C, int M) {
    int c = blockIdx.x * 64 + threadIdx.x;
    if (c >= C) return;
    double mean = (double)S[c] / M;
    double var  = (double)S2[c] / M - mean * mean;
    if (var < 0.0) var = 0.0;
    mu[c] = mean;
    Ad[c] = (g ? (double)g[c] : 1.0) / sqrt(var + 1e-5);
    Bd[c] = b ? (double)b[c] : 0.0;
}

// ---------- BN sign + pack ----------
__global__ void ksp_conv(const int16_t* __restrict__ v, const double* __restrict__ mu,
                         const double* __restrict__ Ad, const double* __restrict__ Bd,
                         u64* __restrict__ B, u64* __restrict__ NZ, int C, int HW) {
    int hw = blockIdx.x * 64 + threadIdx.x;
    if (hw >= HW) return;
    int wd = blockIdx.y, n = blockIdx.z;
    int WRD = C >> 6;
    u64 b = 0, nz = 0;
    for (int j = 0; j < 64; ++j) {
        int c = wd * 64 + j;
        double t = ((double)v[((size_t)n * C + c) * HW + hw] - mu[c]) * Ad[c] + Bd[c];
        b  |= (u64)(t > 0.0) << j;
        nz |= (u64)(t != 0.0) << j;
    }
    size_t o = ((size_t)n * HW + hw) * WRD + wd;
    B[o] = b; NZ[o] = nz;
}

__global__ void ksp_flat(const int16_t* __restrict__ v, const double* __restrict__ mu,
                         const double* __restrict__ Ad, const double* __restrict__ Bd,
                         u64* __restrict__ B, u64* __restrict__ NZ) {
    int wd = threadIdx.x;
    int n  = blockIdx.x;
    u64 b = 0, nz = 0;
    const int16_t* vp = v + (size_t)n * 4096 + wd * 64;
    for (int j = 0; j < 64; ++j) {
        int k = wd * 64 + j;
        int c = k >> 4;
        double t = ((double)vp[j] - mu[c]) * Ad[c] + Bd[c];
        b  |= (u64)(t > 0.0) << j;
        nz |= (u64)(t != 0.0) << j;
    }
    B[(size_t)n * 64 + wd] = b; NZ[(size_t)n * 64 + wd] = nz;
}

__global__ void ksp_fc(const int* __restrict__ v, const double* __restrict__ mu,
                       const double* __restrict__ Ad, const double* __restrict__ Bd,
                       u64* __restrict__ B, u64* __restrict__ NZ, int C, int WRD, int N) {
    int tid = blockIdx.x * 64 + threadIdx.x;
    if (tid >= N * WRD) return;
    int n = tid / WRD, wd = tid % WRD;
    u64 b = 0, nz = 0;
    for (int j = 0; j < 64; ++j) {
        int c = wd * 64 + j;
        double t = ((double)v[(size_t)n * C + c] - mu[c]) * Ad[c] + Bd[c];
        b  |= (u64)(t > 0.0) << j;
        nz |= (u64)(t != 0.0) << j;
    }
    B[(size_t)n * WRD + wd] = b; NZ[(size_t)n * WRD + wd] = nz;
}

// ---------- binary FC ----------
__global__ void kbfc(const u64* __restrict__ aB, const u64* __restrict__ aNZ,
                     const u64* __restrict__ wB, const u64* __restrict__ wNZ,
                     int* __restrict__ out, int WRD, int O) {
    int o = blockIdx.x * 64 + threadIdx.x;
    if (o >= O) return;
    int n = blockIdx.y;
    const u64* ab = aB  + (size_t)n * WRD;
    const u64* az = aNZ + (size_t)n * WRD;
    const u64* wb = wB  + (size_t)o * WRD;
    const u64* wz = wNZ + (size_t)o * WRD;
    int acc = 0;
    for (int w = 0; w < WRD; ++w) {
        u64 e = az[w] & wz[w];
        acc += __popcll(e) - 2 * __popcll((ab[w] ^ wb[w]) & e);
    }
    out[(size_t)n * O + o] = acc;
}

// ---------- FC stats / output ----------
__global__ void k3_stats(const int* __restrict__ v, int N, int C,
                         const float* __restrict__ g, const float* __restrict__ b,
                         double* __restrict__ mu, double* __restrict__ Ad,
                         double* __restrict__ Bd) {
    int c = blockIdx.x;
    __shared__ double sh[256], sh2[256];
    double s = 0.0, s2 = 0.0;
    for (int n = threadIdx.x; n < N; n += 256) {
        double t = (double)v[(size_t)n * C + c];
        s += t; s2 += t * t;
    }
    sh[threadIdx.x] = s; sh2[threadIdx.x] = s2;
    __syncthreads();
    for (int o = 128; o > 0; o >>= 1) {
        if ((int)threadIdx.x < o) { sh[threadIdx.x] += sh[threadIdx.x + o]; sh2[threadIdx.x] += sh2[threadIdx.x + o]; }
        __syncthreads();
    }
    if (threadIdx.x == 0) {
        double mean = sh[0] / N;
        double var  = sh2[0] / N - mean * mean;
        if (var < 0.0) var = 0.0;
        mu[c] = mean;
        Ad[c] = (g ? (double)g[c] : 1.0) / sqrt(var + 1e-5);
        Bd[c] = b ? (double)b[c] : 0.0;
    }
}

__global__ void k4_out(const int* __restrict__ v, const double* __restrict__ mu,
                       const double* __restrict__ Ad, float* __restrict__ out, int N) {
    int n = blockIdx.x * 256 + threadIdx.x;
    if (n >= N) return;
    double z[10];
    double mx = -1e300;
    for (int o = 0; o < 10; ++o) {
        z[o] = ((double)v[n * 10 + o] - mu[o]) * Ad[o];
        if (z[o] > mx) mx = z[o];
    }
    double s = 0.0;
    for (int o = 0; o < 10; ++o) s += exp(z[o] - mx);
    double l = mx + log(s);
    for (int o = 0; o < 10; ++o) out[n * 10 + o] = (float)(z[o] - l);
}

// ---------------- host ----------------
extern "C" void kernel_launch(void* const* d_in, const int* in_sizes, int n_in,
                              void* d_out, int out_size, void* d_ws, size_t ws_size,
                              hipStream_t stream) {
    const int N = in_sizes[0] / (3 * 32 * 32);   // 512

    const float* x   = (const float*)d_in[0];
    const float* w1  = (const float*)d_in[1];
    const float* g1  = (const float*)d_in[2];
    const float* b1  = (const float*)d_in[3];
    const float* w2  = (const float*)d_in[4];
    const float* g2  = (const float*)d_in[5];
    const float* b2  = (const float*)d_in[6];
    const float* w3  = (const float*)d_in[7];
    const float* g3  = (const float*)d_in[8];
    const float* b3  = (const float*)d_in[9];
    const float* w4  = (const float*)d_in[10];
    const float* g4  = (const float*)d_in[11];
    const float* b4  = (const float*)d_in[12];
    const float* w5  = (const float*)d_in[13];
    const float* g5  = (const float*)d_in[14];
    const float* b5  = (const float*)d_in[15];
    const float* w6  = (const float*)d_in[16];
    const float* g6  = (const float*)d_in[17];
    const float* b6  = (const float*)d_in[18];
    const float* wf1 = (const float*)d_in[19];
    const float* gf1 = (const float*)d_in[20];
    const float* bf1 = (const float*)d_in[21];
    const float* wf2 = (const float*)d_in[22];
    const float* gf2 = (const float*)d_in[23];
    const float* bf2 = (const float*)d_in[24];
    const float* wf3 = (const float*)d_in[25];

    char* ws = (char*)d_ws;
    size_t off = 0;
    auto alloc = [&](size_t bytes) -> char* {
        char* p = ws + off;
        off = (off + bytes + 511) & ~(size_t)511;
        return p;
    };

    // ---- DOWN region: all post-L1 buffers at distinct offsets ----
    int16_t* t2  = (int16_t*)alloc((size_t)N * 64 * 256 * 2);
    u64* p2B = (u64*)alloc((size_t)N * 256 * 8);
    u64* p2Z = (u64*)alloc((size_t)N * 256 * 8);
    int16_t* t3  = (int16_t*)alloc((size_t)N * 128 * 256 * 2);
    u64* p3B = (u64*)alloc((size_t)N * 256 * 2 * 8);
    u64* p3Z = (u64*)alloc((size_t)N * 256 * 2 * 8);
    int16_t* t4  = (int16_t*)alloc((size_t)N * 128 * 64 * 2);
    u64* p4B = (u64*)alloc((size_t)N * 64 * 2 * 8);
    u64* p4Z = (u64*)alloc((size_t)N * 64 * 2 * 8);
    int16_t* t5  = (int16_t*)alloc((size_t)N * 256 * 64 * 2);
    u64* p5B = (u64*)alloc((size_t)N * 64 * 4 * 8);
    u64* p5Z = (u64*)alloc((size_t)N * 64 * 4 * 8);
    int16_t* t6  = (int16_t*)alloc((size_t)N * 256 * 16 * 2);
    u64* p6B = (u64*)alloc((size_t)N * 64 * 8);
    u64* p6Z = (u64*)alloc((size_t)N * 64 * 8);
    int* fc1 = (int*)alloc((size_t)N * 512 * 4);
    int* fc2 = (int*)alloc((size_t)N * 512 * 4);
    int* fc3 = (int*)alloc((size_t)N * 10 * 4);
    u64* pF1B = (u64*)alloc((size_t)N * 8 * 8);
    u64* pF1Z = (u64*)alloc((size_t)N * 8 * 8);
    u64* pF2B = (u64*)alloc((size_t)N * 8 * 8);
    u64* pF2Z = (u64*)alloc((size_t)N * 8 * 8);
    size_t down_end = off;

    // ---- L1 head overlays (dead before any DOWN buffer is written) ----
    size_t head_big = (size_t)N * 64 * 1024 * 4;      // 134.2MB f32, 64 channels
    bool big = ws_size >= head_big + ((size_t)20 << 20);
    float*  c1buf = (float*)ws;                        // big: [N][64][1024]
    float*  c1buf8 = (float*)ws;                       // fallback: [N][8][1024]
    int8_t* sgnA  = (int8_t*)(ws + (size_t)N * 8 * 1024 * 4);  // fallback only

    // ---- tail (coexists with L1 head) ----
    off = big ? (head_big > down_end ? head_big : down_end) : down_end;
    off = (off + 511) & ~(size_t)511;
    u64* p1B = (u64*)alloc((size_t)N * 1024 * 8);
    u64* p1Z = (u64*)alloc((size_t)N * 1024 * 8);
    u64* wb2B = (u64*)alloc(64  * 9 * 1 * 8);  u64* wb2Z = (u64*)alloc(64  * 9 * 1 * 8);
    u64* wb3B = (u64*)alloc(128 * 9 * 1 * 8);  u64* wb3Z = (u64*)alloc(128 * 9 * 1 * 8);
    u64* wb4B = (u64*)alloc(128 * 9 * 2 * 8);  u64* wb4Z = (u64*)alloc(128 * 9 * 2 * 8);
    u64* wb5B = (u64*)alloc(256 * 9 * 2 * 8);  u64* wb5Z = (u64*)alloc(256 * 9 * 2 * 8);
    u64* wb6B = (u64*)alloc(256 * 9 * 4 * 8);  u64* wb6Z = (u64*)alloc(256 * 9 * 4 * 8);
    u64* wf1B = (u64*)alloc(512 * 64 * 8);     u64* wf1Z = (u64*)alloc(512 * 64 * 8);
    u64* wf2B = (u64*)alloc(512 * 8 * 8);      u64* wf2Z = (u64*)alloc(512 * 8 * 8);
    u64* wf3B = (u64*)alloc(10 * 8 * 8);       u64* wf3Z = (u64*)alloc(10 * 8 * 8);
    float* wt = (float*)alloc(27 * 64 * 4);
    double* Sp  = (double*)alloc(64 * 256 * 8);
    double* S2p = (double*)alloc(64 * 256 * 8);
    long long* SS = (long long*)alloc(1024 * 8);
    long long* S  = SS;
    long long* S2 = SS + 512;
    double* mu = (double*)alloc(512 * 8);
    double* Ad = (double*)alloc(512 * 8);
    double* Bd = (double*)alloc(512 * 8);
    float*  muF = (float*)alloc(64 * 4);
    float*  rF  = (float*)alloc(64 * 4);

    auto cdiv = [](int a, int b) { return (a + b - 1) / b; };

    // ---- pack weights ----
    kpack_wconv<<<cdiv(64 * 9 * 1, 256), 256, 0, stream>>>(w2, wb2B, wb2Z, 64, 64);
    kpack_wconv<<<cdiv(128 * 9 * 1, 256), 256, 0, stream>>>(w3, wb3B, wb3Z, 64, 128);
    kpack_wconv<<<cdiv(128 * 9 * 2, 256), 256, 0, stream>>>(w4, wb4B, wb4Z, 128, 128);
    kpack_wconv<<<cdiv(256 * 9 * 2, 256), 256, 0, stream>>>(w5, wb5B, wb5Z, 128, 256);
    kpack_wconv<<<cdiv(256 * 9 * 4, 256), 256, 0, stream>>>(w6, wb6B, wb6Z, 256, 256);
    kpack_wlin<<<cdiv(512 * 64, 256), 256, 0, stream>>>(wf1, wf1B, wf1Z, 4096, 512);
    kpack_wlin<<<cdiv(512 * 8, 256), 256, 0, stream>>>(wf2, wf2B, wf2Z, 512, 512);
    kpack_wlin<<<cdiv(10 * 8, 256), 256, 0, stream>>>(wf3, wf3B, wf3Z, 512, 10);

    // ---- L1 ----
    if (big) {
        kw1t<<<27, 64, 0, stream>>>(w1, wt);
        k1_conv_all<<<(N * 1024) / 256, 256, 0, stream>>>(x, wt, c1buf);
        k1_statsA<<<dim3(64, 4), 64, 0, stream>>>(c1buf, Sp, S2p, N);
        k1_statsB<<<64, 256, 0, stream>>>(Sp, S2p, muF, rF, N);
        k1_signpack<<<(N * 1024) / 64, 64, 0, stream>>>(c1buf, muF, rF, g1, b1, p1B, p1Z);
    } else {
        for (int grp = 0; grp < 8; ++grp) {
            k1_conv<<<dim3(16, 8, N), 64, 0, stream>>>(x, w1, c1buf8, grp);
            k1_stats<<<8, 256, 0, stream>>>(c1buf8, muF, rF, grp, N);
            k1_sign<<<dim3(4, 8, N), 256, 0, stream>>>(c1buf8, muF, rF, g1, b1, sgnA, grp);
        }
        kpack_sgn8<<<dim3(16, 1, N), 64, 0, stream>>>(sgnA, p1B, p1Z, 64, 1024);
    }

    // ---- L2: conv+pool (Ci=64, 32x32 -> 16x16) ----
    kbconv_pool2<1, 8><<<dim3(4, 8, N), 64, 0, stream>>>(p1B, p1Z, wb2B, wb2Z, t2, 64, 32, 32);
    kzero<<<4, 256, 0, stream>>>(SS, 1024);
    kaccum16<<<dim3(64, 32), 256, 0, stream>>>(t2, S, S2, 64, 256, N * 256);
    kfinal<<<1, 64, 0, stream>>>(S, S2, g2, b2, mu, Ad, Bd, 64, N * 256);
    ksp_conv<<<dim3(4, 1, N), 64, 0, stream>>>(t2, mu, Ad, Bd, p2B, p2Z, 64, 256);

    // ---- L3: conv (Ci=64, 16x16) ----
    kbconv2<1, 8><<<dim3(4, 16, N), 64, 0, stream>>>(p2B, p2Z, wb3B, wb3Z, t3, 128, 16, 16);
    kzero<<<4, 256, 0, stream>>>(SS, 1024);
    kaccum16<<<dim3(128, 16), 256, 0, stream>>>(t3, S, S2, 128, 256, N * 256);
    kfinal<<<2, 64, 0, stream>>>(S, S2, g3, b3, mu, Ad, Bd, 128, N * 256);
    ksp_conv<<<dim3(4, 2, N), 64, 0, stream>>>(t3, mu, Ad, Bd, p3B, p3Z, 128, 256);

    // ---- L4: conv+pool (Ci=128, 16x16 -> 8x8) ----
    kbconv_pool2<2, 8><<<dim3(1, 16, N), 64, 0, stream>>>(p3B, p3Z, wb4B, wb4Z, t4, 128, 16, 16);
    kzero<<<4, 256, 0, stream>>>(SS, 1024);
    kaccum16<<<dim3(128, 16), 256, 0, stream>>>(t4, S, S2, 128, 64, N * 64);
    kfinal<<<2, 64, 0, stream>>>(S, S2, g4, b4, mu, Ad, Bd, 128, N * 64);
    ksp_conv<<<dim3(1, 2, N), 64, 0, stream>>>(t4, mu, Ad, Bd, p4B, p4Z, 128, 64);

    // ---- L5: conv (Ci=128, 8x8) ----
    kbconv2<2, 8><<<dim3(1, 32, N), 64, 0, stream>>>(p4B, p4Z, wb5B, wb5Z, t5, 256, 8, 8);
    kzero<<<4, 256, 0, stream>>>(SS, 1024);
    kaccum16<<<dim3(256, 8), 256, 0, stream>>>(t5, S, S2, 256, 64, N * 64);
    kfinal<<<4, 64, 0, stream>>>(S, S2, g5, b5, mu, Ad, Bd, 256, N * 64);
    ksp_conv<<<dim3(1, 4, N), 64, 0, stream>>>(t5, mu, Ad, Bd, p5B, p5Z, 256, 64);

    // ---- L6: conv+pool (Ci=256, 8x8 -> 4x4), positions-in-lanes ----
    kbconv_pool2s<4, 8><<<dim3(1, 32, N), 64, 0, stream>>>(p5B, p5Z, wb6B, wb6Z, t6, 256, 8, 8);
    kzero<<<4, 256, 0, stream>>>(SS, 1024);
    kaccum16<<<dim3(256, 2), 256, 0, stream>>>(t6, S, S2, 256, 16, N * 16);
    kfinal<<<4, 64, 0, stream>>>(S, S2, g6, b6, mu, Ad, Bd, 256, N * 16);
    ksp_flat<<<N, 64, 0, stream>>>(t6, mu, Ad, Bd, p6B, p6Z);

    // ---- FC1 ----
    kbfc<<<dim3(8, N), 64, 0, stream>>>(p6B, p6Z, wf1B, wf1Z, fc1, 64, 512);
    k3_stats<<<512, 256, 0, stream>>>(fc1, N, 512, gf1, bf1, mu, Ad, Bd);
    ksp_fc<<<cdiv(N * 8, 64), 64, 0, stream>>>(fc1, mu, Ad, Bd, pF1B, pF1Z, 512, 8, N);

    // ---- FC2 ----
    kbfc<<<dim3(8, N), 64, 0, stream>>>(pF1B, pF1Z, wf2B, wf2Z, fc2, 8, 512);
    k3_stats<<<512, 256, 0, stream>>>(fc2, N, 512, gf2, bf2, mu, Ad, Bd);
    ksp_fc<<<cdiv(N * 8, 64), 64, 0, stream>>>(fc2, mu, Ad, Bd, pF2B, pF2Z, 512, 8, N);

    // ---- FC3 + bn(no affine) + log_softmax ----
    kbfc<<<dim3(1, N), 64, 0, stream>>>(pF2B, pF2Z, wf3B, wf3Z, fc3, 8, 10);
    k3_stats<<<10, 256, 0, stream>>>(fc3, N, 10, nullptr, nullptr, mu, Ad, Bd);
    k4_out<<<cdiv(N, 256), 256, 0, stream>>>(fc3, mu, Ad, (float*)d_out, N);
}

// Round 6
// 886.289 us; speedup vs baseline: 63.1805x; 1.0413x over previous
//
#include <hip/hip_runtime.h>
#include <stdint.h>
#include <math.h>

// Round 19 = R18 + dense-path specialization for binary convs:
// per-layer device flags record whether every weight word (wz==~0) and every
// activation word (nz==~0) is fully nonzero. When both hold (the generic
// case — ternary zeros need exact 0.0f), the conv uses the algebraically
// identical fast form acc = 64*WRD*T - 2*popc(xb^wb) (~2.5x fewer VALU ops,
// half the loads). Slow path is verbatim R18 => bit-exact always.
// Conv BN stats: partials + final sum (int64, order-free) replace kzero+atomics.

typedef unsigned long long u64;

__device__ __forceinline__ void flag_and_wave(u64* flag, u64 nz) {
    nz &= __shfl_xor(nz, 1);
    nz &= __shfl_xor(nz, 2);
    nz &= __shfl_xor(nz, 4);
    nz &= __shfl_xor(nz, 8);
    nz &= __shfl_xor(nz, 16);
    nz &= __shfl_xor(nz, 32);
    if ((threadIdx.x & 63) == 0) atomicAnd(flag, nz);
}

__global__ void kflag_init(u64* __restrict__ f) {
    int i = threadIdx.x;
    if (i < 16) f[i] = ~0ull;
}

// ---------- L1 ----------
__global__ void kw1t(const float* __restrict__ w1, float* __restrict__ wt) {
    int i = blockIdx.x * 64 + threadIdx.x;     // 64*27
    if (i >= 64 * 27) return;
    int co = i / 27, k = i % 27;
    float v = w1[i];
    wt[k * 64 + co] = (v > 0.f) ? 1.f : ((v < 0.f) ? -1.f : 0.f);
}

__global__ __launch_bounds__(256) void k1_conv_all(const float* __restrict__ x,
                                                   const float* __restrict__ wt,
                                                   float* __restrict__ out) {
    int gid = blockIdx.x * 256 + threadIdx.x;  // n*1024 + hw
    int n = gid >> 10, hw = gid & 1023;
    int y = hw >> 5, x0 = hw & 31;
    const float* ip = x + (size_t)n * 3 * 1024;
    float xv[27];
#pragma unroll
    for (int wk = 0; wk < 9; ++wk) {
        int ky = wk / 3, kx = wk % 3;
        int yy = y + ky - 1, xc = x0 + kx - 1;
        bool ok = ((unsigned)yy < 32u) && ((unsigned)xc < 32u);
        int sp = yy * 32 + xc;
        xv[wk]      = ok ? ip[sp]        : 0.f;
        xv[9 + wk]  = ok ? ip[1024 + sp] : 0.f;
        xv[18 + wk] = ok ? ip[2048 + sp] : 0.f;
    }
    float acc[64];
#pragma unroll
    for (int c = 0; c < 64; ++c) acc[c] = 0.f;
    // accumulation order per co: (ky,kx) outer, ci inner — identical to R13.
#pragma unroll
    for (int wk = 0; wk < 9; ++wk)
#pragma unroll
        for (int ci = 0; ci < 3; ++ci) {
            float xs = xv[ci * 9 + wk];
            const float* wrow = wt + (ci * 9 + wk) * 64;
#pragma unroll
            for (int c = 0; c < 64; ++c) acc[c] = fmaf(wrow[c], xs, acc[c]);
        }
    float* op = out + ((size_t)n * 64) * 1024 + hw;
#pragma unroll
    for (int c = 0; c < 64; ++c) op[(size_t)c * 1024] = acc[c];
}

// stage A: per-slot partial chains, identical m-order to R16's k1_stats64.
__global__ void k1_statsA(const float* __restrict__ v, double* __restrict__ Sp,
                          double* __restrict__ S2p, int N) {
    int c = blockIdx.x;                         // 0..63
    int slot = blockIdx.y * 64 + threadIdx.x;   // 0..255
    double s = 0.0, s2 = 0.0;
    int K = N * 4;                              // chain length (m = slot + 256k)
    const float* vp = v + (size_t)c * 1024 + slot;
    int k0 = 0;
    for (; k0 + 32 <= K; k0 += 32) {
        const float* p0 = vp + (size_t)(k0 >> 2) * 65536;
        float buf[32];
#pragma unroll
        for (int j = 0; j < 32; ++j)
            buf[j] = p0[(size_t)(j >> 2) * 65536 + (j & 3) * 256];
#pragma unroll
        for (int j = 0; j < 32; ++j) {
            double t = (double)buf[j];
            s += t; s2 += t * t;
        }
    }
    for (; k0 < K; ++k0) {
        int m = slot + k0 * 256;
        double t = (double)v[((size_t)(m >> 10) * 64 + c) * 1024 + (m & 1023)];
        s += t; s2 += t * t;
    }
    Sp[c * 256 + slot] = s; S2p[c * 256 + slot] = s2;
}

// stage B: verbatim 256-slot tree + mu/r finalization.
__global__ void k1_statsB(const double* __restrict__ Sp, const double* __restrict__ S2p,
                          float* __restrict__ muF, float* __restrict__ rF, int N) {
    int c = blockIdx.x;
    __shared__ double sh[256], sh2[256];
    sh[threadIdx.x]  = Sp[c * 256 + threadIdx.x];
    sh2[threadIdx.x] = S2p[c * 256 + threadIdx.x];
    __syncthreads();
    for (int o = 128; o > 0; o >>= 1) {
        if ((int)threadIdx.x < o) { sh[threadIdx.x] += sh[threadIdx.x + o]; sh2[threadIdx.x] += sh2[threadIdx.x + o]; }
        __syncthreads();
    }
    if (threadIdx.x == 0) {
        int M = N * 1024;
        double mean = sh[0] / M;
        double var  = sh2[0] / M - mean * mean;
        if (var < 0.0) var = 0.0;
        muF[c] = (float)mean;
        rF[c]  = 1.0f / sqrtf((float)var + 1e-5f);
    }
}

__global__ void k1_signpack(const float* __restrict__ v, const float* __restrict__ muF,
                            const float* __restrict__ rF, const float* __restrict__ g,
                            const float* __restrict__ b, u64* __restrict__ B,
                            u64* __restrict__ NZ, u64* __restrict__ aflag) {
    int gid = blockIdx.x * 64 + threadIdx.x;   // n*1024 + hw
    int n = gid >> 10, hw = gid & 1023;
    u64 bb = 0, nz = 0;
    for (int c = 0; c < 64; ++c) {
        float d = v[((size_t)n * 64 + c) * 1024 + hw] - muF[c];
        float t = (d * rF[c]) * g[c] + b[c];
        bb |= (u64)(t > 0.f) << c;
        nz |= (u64)(t != 0.f) << c;
    }
    B[gid] = bb; NZ[gid] = nz;
    flag_and_wave(aflag, nz);
}

// ---------- L1 fallback path (verbatim R13/R14) ----------
__global__ void k1_conv(const float* __restrict__ x, const float* __restrict__ w1,
                        float* __restrict__ out, int grp) {
    int hw = blockIdx.x * 64 + threadIdx.x;
    int cg = blockIdx.y;
    int n  = blockIdx.z;
    int co = grp * 8 + cg;
    int y = hw >> 5, x0 = hw & 31;
    const float* ip0 = x + ((size_t)n * 3 + 0) * 1024;
    const float* ip1 = x + ((size_t)n * 3 + 1) * 1024;
    const float* ip2 = x + ((size_t)n * 3 + 2) * 1024;
    const float* wp  = w1 + (size_t)co * 27;
    float acc = 0.f;
    for (int ky = 0; ky < 3; ++ky) {
        int yy = y + ky - 1;
        if (yy < 0 || yy > 31) continue;
        for (int kx = 0; kx < 3; ++kx) {
            int xc = x0 + kx - 1;
            if (xc < 0 || xc > 31) continue;
            int sp = yy * 32 + xc;
            int wk = ky * 3 + kx;
            float w0 = wp[wk], w1v = wp[9 + wk], w2 = wp[18 + wk];
            acc += (w0  > 0.f) ? ip0[sp] : ((w0  < 0.f) ? -ip0[sp] : 0.f);
            acc += (w1v > 0.f) ? ip1[sp] : ((w1v < 0.f) ? -ip1[sp] : 0.f);
            acc += (w2  > 0.f) ? ip2[sp] : ((w2  < 0.f) ? -ip2[sp] : 0.f);
        }
    }
    out[((size_t)n * 8 + cg) * 1024 + hw] = acc;
}

__device__ __forceinline__ float ld1(const float* v, int cg, int e) {
    return v[((size_t)(e >> 10) * 8 + cg) * 1024 + (e & 1023)];
}

__global__ void k1_stats(const float* __restrict__ v, float* __restrict__ muF,
                         float* __restrict__ rF, int grp, int N) {
    int cg = blockIdx.x;
    __shared__ double sh[256], sh2[256];
    double s = 0.0, s2 = 0.0;
    int M = N * 1024;
    for (int m = threadIdx.x; m < M; m += 256) {
        double t = (double)ld1(v, cg, m);
        s += t; s2 += t * t;
    }
    sh[threadIdx.x] = s; sh2[threadIdx.x] = s2;
    __syncthreads();
    for (int o = 128; o > 0; o >>= 1) {
        if ((int)threadIdx.x < o) { sh[threadIdx.x] += sh[threadIdx.x + o]; sh2[threadIdx.x] += sh2[threadIdx.x + o]; }
        __syncthreads();
    }
    if (threadIdx.x == 0) {
        double mean = sh[0] / M;
        double var  = sh2[0] / M - mean * mean;
        if (var < 0.0) var = 0.0;
        muF[grp * 8 + cg] = (float)mean;
        rF[grp * 8 + cg]  = 1.0f / sqrtf((float)var + 1e-5f);
    }
}

__global__ void k1_sign(const float* __restrict__ v, const float* __restrict__ muF,
                        const float* __restrict__ rF, const float* __restrict__ g,
                        const float* __restrict__ b, int8_t* __restrict__ sgn, int grp) {
    int hw = blockIdx.x * 256 + threadIdx.x;
    if (hw >= 1024) return;
    int cg = blockIdx.y, n = blockIdx.z;
    int c = grp * 8 + cg;
    float d  = v[((size_t)n * 8 + cg) * 1024 + hw] - muF[c];
    float t  = (d * rF[c]) * g[c] + b[c];
    sgn[((size_t)n * 64 + c) * 1024 + hw] = (int8_t)((t > 0.f) - (t < 0.f));
}

__global__ void kpack_sgn8(const int8_t* __restrict__ s, u64* __restrict__ B,
                           u64* __restrict__ NZ, int C, int HW, u64* __restrict__ aflag) {
    int hw = blockIdx.x * 64 + threadIdx.x;
    int wd = blockIdx.y, n = blockIdx.z;
    int WRD = C >> 6;
    u64 b = 0, nz = ~0ull;
    if (hw < HW) {
        nz = 0;
        const int8_t* sp = s + ((size_t)n * C + wd * 64) * HW + hw;
        for (int j = 0; j < 64; ++j) {
            int v = sp[(size_t)j * HW];
            b  |= (u64)(v > 0) << j;
            nz |= (u64)(v != 0) << j;
        }
        size_t o = ((size_t)n * HW + hw) * WRD + wd;
        B[o] = b; NZ[o] = nz;
    }
    flag_and_wave(aflag, nz);
}

// ---------- weight packing ----------
__global__ void kpack_wconv(const float* __restrict__ w, u64* __restrict__ WB,
                            u64* __restrict__ WNZ, int Ci, int Co, u64* __restrict__ flag) {
    int idx = blockIdx.x * 256 + threadIdx.x;
    int WRD = Ci >> 6;
    u64 b = 0, nz = ~0ull;
    if (idx < Co * 9 * WRD) {
        nz = 0;
        int wd = idx % WRD, t = (idx / WRD) % 9, co = idx / (9 * WRD);
        const float* wp = w + ((size_t)co * Ci + wd * 64) * 9 + t;
        for (int j = 0; j < 64; ++j) {
            float v = wp[(size_t)j * 9];
            b  |= (u64)(v > 0.f) << j;
            nz |= (u64)(v != 0.f) << j;
        }
        WB[idx] = b; WNZ[idx] = nz;
    }
    flag_and_wave(flag, nz);
}

__global__ void kpack_wlin(const float* __restrict__ w, u64* __restrict__ WB,
                           u64* __restrict__ WNZ, int K, int O) {
    int idx = blockIdx.x * 256 + threadIdx.x;
    int WRD = K >> 6;
    if (idx >= O * WRD) return;
    int wd = idx % WRD, o = idx / WRD;
    u64 b = 0, nz = 0;
    const float* wp = w + (size_t)o * K + wd * 64;
    for (int j = 0; j < 64; ++j) {
        float v = wp[j];
        b  |= (u64)(v > 0.f) << j;
        nz |= (u64)(v != 0.f) << j;
    }
    WB[idx] = b; WNZ[idx] = nz;
}

// ---------- binary conv cores ----------
template <int WRD, int CB>
__device__ __forceinline__ void conv_slow(const u64* __restrict__ ib, const u64* __restrict__ iz,
                                          const u64* __restrict__ wbp, const u64* __restrict__ wzp,
                                          int H, int Wi, int y, int x, int* acc) {
#pragma unroll
    for (int c = 0; c < CB; ++c) acc[c] = 0;
    for (int ky = 0; ky < 3; ++ky) {
        int yy = y + ky - 1;
        if ((unsigned)yy >= (unsigned)H) continue;
        for (int kx = 0; kx < 3; ++kx) {
            int xc = x + kx - 1;
            if ((unsigned)xc >= (unsigned)Wi) continue;
            int p = yy * Wi + xc, t = ky * 3 + kx;
            u64 xb[WRD], xz[WRD];
#pragma unroll
            for (int w = 0; w < WRD; ++w) {
                xb[w] = ib[(size_t)p * WRD + w];
                xz[w] = iz[(size_t)p * WRD + w];
            }
#pragma unroll
            for (int c = 0; c < CB; ++c) {
#pragma unroll
                for (int w = 0; w < WRD; ++w) {
                    u64 e = xz[w] & wzp[(c * 9 + t) * WRD + w];
                    acc[c] += __popcll(e) - 2 * __popcll((xb[w] ^ wbp[(c * 9 + t) * WRD + w]) & e);
                }
            }
        }
    }
}

template <int WRD, int CB>
__device__ __forceinline__ void conv_fast(const u64* __restrict__ ib,
                                          const u64* __restrict__ wbp,
                                          int H, int Wi, int y, int x, int* acc) {
    int a2[CB];
#pragma unroll
    for (int c = 0; c < CB; ++c) a2[c] = 0;
    int T = 0;
    for (int ky = 0; ky < 3; ++ky) {
        int yy = y + ky - 1;
        if ((unsigned)yy >= (unsigned)H) continue;
        for (int kx = 0; kx < 3; ++kx) {
            int xc = x + kx - 1;
            if ((unsigned)xc >= (unsigned)Wi) continue;
            int p = yy * Wi + xc, t = ky * 3 + kx;
            ++T;
            u64 xb[WRD];
#pragma unroll
            for (int w = 0; w < WRD; ++w) xb[w] = ib[(size_t)p * WRD + w];
#pragma unroll
            for (int c = 0; c < CB; ++c)
#pragma unroll
                for (int w = 0; w < WRD; ++w)
                    a2[c] += __popcll(xb[w] ^ wbp[(c * 9 + t) * WRD + w]);
        }
    }
#pragma unroll
    for (int c = 0; c < CB; ++c) acc[c] = 64 * WRD * T - 2 * a2[c];
}

template <int WRD, int CB>
__global__ void kbconv2(const u64* __restrict__ B, const u64* __restrict__ NZ,
                        const u64* __restrict__ WB, const u64* __restrict__ WNZ,
                        int16_t* __restrict__ out, int Co, int H, int Wi,
                        const u64* __restrict__ wflag, const u64* __restrict__ aflag) {
    int hw = blockIdx.x * 64 + threadIdx.x;
    if (hw >= H * Wi) return;
    int co0 = blockIdx.y * CB, n = blockIdx.z;
    int y = hw / Wi, x = hw % Wi;
    const u64* ib = B  + (size_t)n * H * Wi * WRD;
    const u64* iz = NZ + (size_t)n * H * Wi * WRD;
    const u64* wbp = WB  + (size_t)co0 * 9 * WRD;
    const u64* wzp = WNZ + (size_t)co0 * 9 * WRD;
    bool fast = ((*wflag) & (*aflag)) == ~0ull;
    int acc[CB];
    if (fast) conv_fast<WRD, CB>(ib, wbp, H, Wi, y, x, acc);
    else      conv_slow<WRD, CB>(ib, iz, wbp, wzp, H, Wi, y, x, acc);
#pragma unroll
    for (int c = 0; c < CB; ++c)
        out[((size_t)n * Co + co0 + c) * H * Wi + hw] = (int16_t)acc[c];
}

template <int WRD, int CB>
__global__ void kbconv_pool2(const u64* __restrict__ B, const u64* __restrict__ NZ,
                             const u64* __restrict__ WB, const u64* __restrict__ WNZ,
                             int16_t* __restrict__ out, int Co, int H, int Wi,
                             const u64* __restrict__ wflag, const u64* __restrict__ aflag) {
    int Ho = H >> 1, Wo = Wi >> 1;
    int hw = blockIdx.x * 64 + threadIdx.x;
    if (hw >= Ho * Wo) return;
    int co0 = blockIdx.y * CB, n = blockIdx.z;
    int yo = hw / Wo, xo = hw % Wo;
    const u64* ib = B  + (size_t)n * H * Wi * WRD;
    const u64* iz = NZ + (size_t)n * H * Wi * WRD;
    const u64* wbp = WB  + (size_t)co0 * 9 * WRD;
    const u64* wzp = WNZ + (size_t)co0 * 9 * WRD;
    bool fast = ((*wflag) & (*aflag)) == ~0ull;
    int best[CB];
#pragma unroll
    for (int c = 0; c < CB; ++c) best[c] = -(1 << 30);
    if (fast) {
        for (int dy = 0; dy < 2; ++dy)
            for (int dx = 0; dx < 2; ++dx) {
                int acc[CB];
                conv_fast<WRD, CB>(ib, wbp, H, Wi, 2 * yo + dy, 2 * xo + dx, acc);
#pragma unroll
                for (int c = 0; c < CB; ++c) best[c] = acc[c] > best[c] ? acc[c] : best[c];
            }
    } else {
        for (int dy = 0; dy < 2; ++dy)
            for (int dx = 0; dx < 2; ++dx) {
                int acc[CB];
                conv_slow<WRD, CB>(ib, iz, wbp, wzp, H, Wi, 2 * yo + dy, 2 * xo + dx, acc);
#pragma unroll
                for (int c = 0; c < CB; ++c) best[c] = acc[c] > best[c] ? acc[c] : best[c];
            }
    }
#pragma unroll
    for (int c = 0; c < CB; ++c)
        out[((size_t)n * Co + co0 + c) * Ho * Wo + hw] = (int16_t)best[c];
}

// pool variant for Ho*Wo==16: 64 lanes = 16 pixels x 4 pool positions.
template <int WRD, int CB>
__global__ void kbconv_pool2s(const u64* __restrict__ B, const u64* __restrict__ NZ,
                              const u64* __restrict__ WB, const u64* __restrict__ WNZ,
                              int16_t* __restrict__ out, int Co, int H, int Wi,
                              const u64* __restrict__ wflag, const u64* __restrict__ aflag) {
    int Ho = H >> 1, Wo = Wi >> 1;       // Ho*Wo == 16
    int t0 = threadIdx.x;
    int pix = t0 & 15, pos = t0 >> 4;    // pos 0..3
    int co0 = blockIdx.y * CB, n = blockIdx.z;
    int yo = pix / Wo, xo = pix % Wo;
    int y = 2 * yo + (pos >> 1), x = 2 * xo + (pos & 1);
    const u64* ib = B  + (size_t)n * H * Wi * WRD;
    const u64* iz = NZ + (size_t)n * H * Wi * WRD;
    const u64* wbp = WB  + (size_t)co0 * 9 * WRD;
    const u64* wzp = WNZ + (size_t)co0 * 9 * WRD;
    bool fast = ((*wflag) & (*aflag)) == ~0ull;
    int acc[CB];
    if (fast) conv_fast<WRD, CB>(ib, wbp, H, Wi, y, x, acc);
    else      conv_slow<WRD, CB>(ib, iz, wbp, wzp, H, Wi, y, x, acc);
#pragma unroll
    for (int c = 0; c < CB; ++c) {
        int v = acc[c];
        int v1 = __shfl_xor(v, 16); v = v1 > v ? v1 : v;
        int v2 = __shfl_xor(v, 32); v = v2 > v ? v2 : v;
        acc[c] = v;
    }
    if (pos == 0) {
#pragma unroll
        for (int c = 0; c < CB; ++c)
            out[((size_t)n * Co + co0 + c) * Ho * Wo + pix] = (int16_t)acc[c];
    }
}

// ---------- conv BN stats (int64 partials, order-free, exact) ----------
__global__ void kaccum16(const int16_t* __restrict__ v, long long* __restrict__ Sp,
                         long long* __restrict__ S2p, int C, int HW, int M) {
    int c = blockIdx.x;
    long long s = 0, s2 = 0;
    for (int m = blockIdx.y * 256 + threadIdx.x; m < M; m += gridDim.y * 256) {
        int t = v[((size_t)(m / HW) * C + c) * HW + (m % HW)];
        s += t; s2 += (long long)t * t;
    }
    __shared__ long long sh[256], sh2[256];
    sh[threadIdx.x] = s; sh2[threadIdx.x] = s2;
    __syncthreads();
    for (int o = 128; o > 0; o >>= 1) {
        if ((int)threadIdx.x < o) { sh[threadIdx.x] += sh[threadIdx.x + o]; sh2[threadIdx.x] += sh2[threadIdx.x + o]; }
        __syncthreads();
    }
    if (threadIdx.x == 0) {
        Sp[c * gridDim.y + blockIdx.y]  = sh[0];
        S2p[c * gridDim.y + blockIdx.y] = sh2[0];
    }
}

__global__ void kfinal2(const long long* __restrict__ Sp, const long long* __restrict__ S2p,
                        int NB, const float* __restrict__ g, const float* __restrict__ b,
                        double* __restrict__ mu, double* __restrict__ Ad,
                        double* __restrict__ Bd, int C, int M) {
    int c = blockIdx.x * 64 + threadIdx.x;
    if (c >= C) return;
    long long s = 0, s2 = 0;
    for (int i = 0; i < NB; ++i) { s += Sp[c * NB + i]; s2 += S2p[c * NB + i]; }
    double mean = (double)s / M;
    double var  = (double)s2 / M - mean * mean;
    if (var < 0.0) var = 0.0;
    mu[c] = mean;
    Ad[c] = (g ? (double)g[c] : 1.0) / sqrt(var + 1e-5);
    Bd[c] = b ? (double)b[c] : 0.0;
}

// ---------- BN sign + pack ----------
__global__ void ksp_conv(const int16_t* __restrict__ v, const double* __restrict__ mu,
                         const double* __restrict__ Ad, const double* __restrict__ Bd,
                         u64* __restrict__ B, u64* __restrict__ NZ, int C, int HW,
                         u64* __restrict__ aflag) {
    int hw = blockIdx.x * 64 + threadIdx.x;
    int wd = blockIdx.y, n = blockIdx.z;
    int WRD = C >> 6;
    u64 b = 0, nz = ~0ull;
    if (hw < HW) {
        nz = 0;
        for (int j = 0; j < 64; ++j) {
            int c = wd * 64 + j;
            double t = ((double)v[((size_t)n * C + c) * HW + hw] - mu[c]) * Ad[c] + Bd[c];
            b  |= (u64)(t > 0.0) << j;
            nz |= (u64)(t != 0.0) << j;
        }
        size_t o = ((size_t)n * HW + hw) * WRD + wd;
        B[o] = b; NZ[o] = nz;
    }
    flag_and_wave(aflag, nz);
}

__global__ void ksp_flat(const int16_t* __restrict__ v, const double* __restrict__ mu,
                         const double* __restrict__ Ad, const double* __restrict__ Bd,
                         u64* __restrict__ B, u64* __restrict__ NZ) {
    int wd = threadIdx.x;
    int n  = blockIdx.x;
    u64 b = 0, nz = 0;
    const int16_t* vp = v + (size_t)n * 4096 + wd * 64;
    for (int j = 0; j < 64; ++j) {
        int k = wd * 64 + j;
        int c = k >> 4;
        double t = ((double)vp[j] - mu[c]) * Ad[c] + Bd[c];
        b  |= (u64)(t > 0.0) << j;
        nz |= (u64)(t != 0.0) << j;
    }
    B[(size_t)n * 64 + wd] = b; NZ[(size_t)n * 64 + wd] = nz;
}

__global__ void ksp_fc(const int* __restrict__ v, const double* __restrict__ mu,
                       const double* __restrict__ Ad, const double* __restrict__ Bd,
                       u64* __restrict__ B, u64* __restrict__ NZ, int C, int WRD, int N) {
    int tid = blockIdx.x * 64 + threadIdx.x;
    if (tid >= N * WRD) return;
    int n = tid / WRD, wd = tid % WRD;
    u64 b = 0, nz = 0;
    for (int j = 0; j < 64; ++j) {
        int c = wd * 64 + j;
        double t = ((double)v[(size_t)n * C + c] - mu[c]) * Ad[c] + Bd[c];
        b  |= (u64)(t > 0.0) << j;
        nz |= (u64)(t != 0.0) << j;
    }
    B[(size_t)n * WRD + wd] = b; NZ[(size_t)n * WRD + wd] = nz;
}

// ---------- binary FC ----------
__global__ void kbfc(const u64* __restrict__ aB, const u64* __restrict__ aNZ,
                     const u64* __restrict__ wB, const u64* __restrict__ wNZ,
                     int* __restrict__ out, int WRD, int O) {
    int o = blockIdx.x * 64 + threadIdx.x;
    if (o >= O) return;
    int n = blockIdx.y;
    const u64* ab = aB  + (size_t)n * WRD;
    const u64* az = aNZ + (size_t)n * WRD;
    const u64* wb = wB  + (size_t)o * WRD;
    const u64* wz = wNZ + (size_t)o * WRD;
    int acc = 0;
    for (int w = 0; w < WRD; ++w) {
        u64 e = az[w] & wz[w];
        acc += __popcll(e) - 2 * __popcll((ab[w] ^ wb[w]) & e);
    }
    out[(size_t)n * O + o] = acc;
}

// ---------- FC stats / output ----------
__global__ void k3_stats(const int* __restrict__ v, int N, int C,
                         const float* __restrict__ g, const float* __restrict__ b,
                         double* __restrict__ mu, double* __restrict__ Ad,
                         double* __restrict__ Bd) {
    int c = blockIdx.x;
    __shared__ double sh[256], sh2[256];
    double s = 0.0, s2 = 0.0;
    for (int n = threadIdx.x; n < N; n += 256) {
        double t = (double)v[(size_t)n * C + c];
        s += t; s2 += t * t;
    }
    sh[threadIdx.x] = s; sh2[threadIdx.x] = s2;
    __syncthreads();
    for (int o = 128; o > 0; o >>= 1) {
        if ((int)threadIdx.x < o) { sh[threadIdx.x] += sh[threadIdx.x + o]; sh2[threadIdx.x] += sh2[threadIdx.x + o]; }
        __syncthreads();
    }
    if (threadIdx.x == 0) {
        double mean = sh[0] / N;
        double var  = sh2[0] / N - mean * mean;
        if (var < 0.0) var = 0.0;
        mu[c] = mean;
        Ad[c] = (g ? (double)g[c] : 1.0) / sqrt(var + 1e-5);
        Bd[c] = b ? (double)b[c] : 0.0;
    }
}

__global__ void k4_out(const int* __restrict__ v, const double* __restrict__ mu,
                       const double* __restrict__ Ad, float* __restrict__ out, int N) {
    int n = blockIdx.x * 256 + threadIdx.x;
    if (n >= N) return;
    double z[10];
    double mx = -1e300;
    for (int o = 0; o < 10; ++o) {
        z[o] = ((double)v[n * 10 + o] - mu[o]) * Ad[o];
        if (z[o] > mx) mx = z[o];
    }
    double s = 0.0;
    for (int o = 0; o < 10; ++o) s += exp(z[o] - mx);
    double l = mx + log(s);
    for (int o = 0; o < 10; ++o) out[n * 10 + o] = (float)(z[o] - l);
}

// ---------------- host ----------------
extern "C" void kernel_launch(void* const* d_in, const int* in_sizes, int n_in,
                              void* d_out, int out_size, void* d_ws, size_t ws_size,
                              hipStream_t stream) {
    const int N = in_sizes[0] / (3 * 32 * 32);   // 512

    const float* x   = (const float*)d_in[0];
    const float* w1  = (const float*)d_in[1];
    const float* g1  = (const float*)d_in[2];
    const float* b1  = (const float*)d_in[3];
    const float* w2  = (const float*)d_in[4];
    const float* g2  = (const float*)d_in[5];
    const float* b2  = (const float*)d_in[6];
    const float* w3  = (const float*)d_in[7];
    const float* g3  = (const float*)d_in[8];
    const float* b3  = (const float*)d_in[9];
    const float* w4  = (const float*)d_in[10];
    const float* g4  = (const float*)d_in[11];
    const float* b4  = (const float*)d_in[12];
    const float* w5  = (const float*)d_in[13];
    const float* g5  = (const float*)d_in[14];
    const float* b5  = (const float*)d_in[15];
    const float* w6  = (const float*)d_in[16];
    const float* g6  = (const float*)d_in[17];
    const float* b6  = (const float*)d_in[18];
    const float* wf1 = (const float*)d_in[19];
    const float* gf1 = (const float*)d_in[20];
    const float* bf1 = (const float*)d_in[21];
    const float* wf2 = (const float*)d_in[22];
    const float* gf2 = (const float*)d_in[23];
    const float* bf2 = (const float*)d_in[24];
    const float* wf3 = (const float*)d_in[25];

    char* ws = (char*)d_ws;
    size_t off = 0;
    auto alloc = [&](size_t bytes) -> char* {
        char* p = ws + off;
        off = (off + bytes + 511) & ~(size_t)511;
        return p;
    };

    // ---- DOWN region: all post-L1 buffers at distinct offsets ----
    int16_t* t2  = (int16_t*)alloc((size_t)N * 64 * 256 * 2);
    u64* p2B = (u64*)alloc((size_t)N * 256 * 8);
    u64* p2Z = (u64*)alloc((size_t)N * 256 * 8);
    int16_t* t3  = (int16_t*)alloc((size_t)N * 128 * 256 * 2);
    u64* p3B = (u64*)alloc((size_t)N * 256 * 2 * 8);
    u64* p3Z = (u64*)alloc((size_t)N * 256 * 2 * 8);
    int16_t* t4  = (int16_t*)alloc((size_t)N * 128 * 64 * 2);
    u64* p4B = (u64*)alloc((size_t)N * 64 * 2 * 8);
    u64* p4Z = (u64*)alloc((size_t)N * 64 * 2 * 8);
    int16_t* t5  = (int16_t*)alloc((size_t)N * 256 * 64 * 2);
    u64* p5B = (u64*)alloc((size_t)N * 64 * 4 * 8);
    u64* p5Z = (u64*)alloc((size_t)N * 64 * 4 * 8);
    int16_t* t6  = (int16_t*)alloc((size_t)N * 256 * 16 * 2);
    u64* p6B = (u64*)alloc((size_t)N * 64 * 8);
    u64* p6Z = (u64*)alloc((size_t)N * 64 * 8);
    int* fc1 = (int*)alloc((size_t)N * 512 * 4);
    int* fc2 = (int*)alloc((size_t)N * 512 * 4);
    int* fc3 = (int*)alloc((size_t)N * 10 * 4);
    u64* pF1B = (u64*)alloc((size_t)N * 8 * 8);
    u64* pF1Z = (u64*)alloc((size_t)N * 8 * 8);
    u64* pF2B = (u64*)alloc((size_t)N * 8 * 8);
    u64* pF2Z = (u64*)alloc((size_t)N * 8 * 8);
    size_t down_end = off;

    // ---- L1 head overlays (dead before any DOWN buffer is written) ----
    size_t head_big = (size_t)N * 64 * 1024 * 4;      // 134.2MB f32, 64 channels
    bool big = ws_size >= head_big + ((size_t)20 << 20);
    float*  c1buf = (float*)ws;                        // big: [N][64][1024]
    float*  c1buf8 = (float*)ws;                       // fallback: [N][8][1024]
    int8_t* sgnA  = (int8_t*)(ws + (size_t)N * 8 * 1024 * 4);  // fallback only

    // ---- tail (coexists with L1 head) ----
    off = big ? (head_big > down_end ? head_big : down_end) : down_end;
    off = (off + 511) & ~(size_t)511;
    u64* p1B = (u64*)alloc((size_t)N * 1024 * 8);
    u64* p1Z = (u64*)alloc((size_t)N * 1024 * 8);
    u64* wb2B = (u64*)alloc(64  * 9 * 1 * 8);  u64* wb2Z = (u64*)alloc(64  * 9 * 1 * 8);
    u64* wb3B = (u64*)alloc(128 * 9 * 1 * 8);  u64* wb3Z = (u64*)alloc(128 * 9 * 1 * 8);
    u64* wb4B = (u64*)alloc(128 * 9 * 2 * 8);  u64* wb4Z = (u64*)alloc(128 * 9 * 2 * 8);
    u64* wb5B = (u64*)alloc(256 * 9 * 2 * 8);  u64* wb5Z = (u64*)alloc(256 * 9 * 2 * 8);
    u64* wb6B = (u64*)alloc(256 * 9 * 4 * 8);  u64* wb6Z = (u64*)alloc(256 * 9 * 4 * 8);
    u64* wf1B = (u64*)alloc(512 * 64 * 8);     u64* wf1Z = (u64*)alloc(512 * 64 * 8);
    u64* wf2B = (u64*)alloc(512 * 8 * 8);      u64* wf2Z = (u64*)alloc(512 * 8 * 8);
    u64* wf3B = (u64*)alloc(10 * 8 * 8);       u64* wf3Z = (u64*)alloc(10 * 8 * 8);
    float* wt = (float*)alloc(27 * 64 * 4);
    double* Sp  = (double*)alloc(64 * 256 * 8);
    double* S2p = (double*)alloc(64 * 256 * 8);
    long long* SpI  = (long long*)alloc(256 * 32 * 8);
    long long* S2pI = (long long*)alloc(256 * 32 * 8);
    u64* flags = (u64*)alloc(16 * 8);          // [0..4]=wflag L2..L6, [8..12]=aflag L1..L5
    double* mu = (double*)alloc(512 * 8);
    double* Ad = (double*)alloc(512 * 8);
    double* Bd = (double*)alloc(512 * 8);
    float*  muF = (float*)alloc(64 * 4);
    float*  rF  = (float*)alloc(64 * 4);

    auto cdiv = [](int a, int b) { return (a + b - 1) / b; };

    // ---- flags + pack weights ----
    kflag_init<<<1, 64, 0, stream>>>(flags);
    kpack_wconv<<<cdiv(64 * 9 * 1, 256), 256, 0, stream>>>(w2, wb2B, wb2Z, 64, 64, &flags[0]);
    kpack_wconv<<<cdiv(128 * 9 * 1, 256), 256, 0, stream>>>(w3, wb3B, wb3Z, 64, 128, &flags[1]);
    kpack_wconv<<<cdiv(128 * 9 * 2, 256), 256, 0, stream>>>(w4, wb4B, wb4Z, 128, 128, &flags[2]);
    kpack_wconv<<<cdiv(256 * 9 * 2, 256), 256, 0, stream>>>(w5, wb5B, wb5Z, 128, 256, &flags[3]);
    kpack_wconv<<<cdiv(256 * 9 * 4, 256), 256, 0, stream>>>(w6, wb6B, wb6Z, 256, 256, &flags[4]);
    kpack_wlin<<<cdiv(512 * 64, 256), 256, 0, stream>>>(wf1, wf1B, wf1Z, 4096, 512);
    kpack_wlin<<<cdiv(512 * 8, 256), 256, 0, stream>>>(wf2, wf2B, wf2Z, 512, 512);
    kpack_wlin<<<cdiv(10 * 8, 256), 256, 0, stream>>>(wf3, wf3B, wf3Z, 512, 10);

    // ---- L1 ----
    if (big) {
        kw1t<<<27, 64, 0, stream>>>(w1, wt);
        k1_conv_all<<<(N * 1024) / 256, 256, 0, stream>>>(x, wt, c1buf);
        k1_statsA<<<dim3(64, 4), 64, 0, stream>>>(c1buf, Sp, S2p, N);
        k1_statsB<<<64, 256, 0, stream>>>(Sp, S2p, muF, rF, N);
        k1_signpack<<<(N * 1024) / 64, 64, 0, stream>>>(c1buf, muF, rF, g1, b1, p1B, p1Z, &flags[8]);
    } else {
        for (int grp = 0; grp < 8; ++grp) {
            k1_conv<<<dim3(16, 8, N), 64, 0, stream>>>(x, w1, c1buf8, grp);
            k1_stats<<<8, 256, 0, stream>>>(c1buf8, muF, rF, grp, N);
            k1_sign<<<dim3(4, 8, N), 256, 0, stream>>>(c1buf8, muF, rF, g1, b1, sgnA, grp);
        }
        kpack_sgn8<<<dim3(16, 1, N), 64, 0, stream>>>(sgnA, p1B, p1Z, 64, 1024, &flags[8]);
    }

    // ---- L2: conv+pool (Ci=64, 32x32 -> 16x16) ----
    kbconv_pool2<1, 8><<<dim3(4, 8, N), 64, 0, stream>>>(p1B, p1Z, wb2B, wb2Z, t2, 64, 32, 32, &flags[0], &flags[8]);
    kaccum16<<<dim3(64, 32), 256, 0, stream>>>(t2, SpI, S2pI, 64, 256, N * 256);
    kfinal2<<<1, 64, 0, stream>>>(SpI, S2pI, 32, g2, b2, mu, Ad, Bd, 64, N * 256);
    ksp_conv<<<dim3(4, 1, N), 64, 0, stream>>>(t2, mu, Ad, Bd, p2B, p2Z, 64, 256, &flags[9]);

    // ---- L3: conv (Ci=64, 16x16) ----
    kbconv2<1, 8><<<dim3(4, 16, N), 64, 0, stream>>>(p2B, p2Z, wb3B, wb3Z, t3, 128, 16, 16, &flags[1], &flags[9]);
    kaccum16<<<dim3(128, 16), 256, 0, stream>>>(t3, SpI, S2pI, 128, 256, N * 256);
    kfinal2<<<2, 64, 0, stream>>>(SpI, S2pI, 16, g3, b3, mu, Ad, Bd, 128, N * 256);
    ksp_conv<<<dim3(4, 2, N), 64, 0, stream>>>(t3, mu, Ad, Bd, p3B, p3Z, 128, 256, &flags[10]);

    // ---- L4: conv+pool (Ci=128, 16x16 -> 8x8) ----
    kbconv_pool2<2, 8><<<dim3(1, 16, N), 64, 0, stream>>>(p3B, p3Z, wb4B, wb4Z, t4, 128, 16, 16, &flags[2], &flags[10]);
    kaccum16<<<dim3(128, 16), 256, 0, stream>>>(t4, SpI, S2pI, 128, 64, N * 64);
    kfinal2<<<2, 64, 0, stream>>>(SpI, S2pI, 16, g4, b4, mu, Ad, Bd, 128, N * 64);
    ksp_conv<<<dim3(1, 2, N), 64, 0, stream>>>(t4, mu, Ad, Bd, p4B, p4Z, 128, 64, &flags[11]);

    // ---- L5: conv (Ci=128, 8x8) ----
    kbconv2<2, 8><<<dim3(1, 32, N), 64, 0, stream>>>(p4B, p4Z, wb5B, wb5Z, t5, 256, 8, 8, &flags[3], &flags[11]);
    kaccum16<<<dim3(256, 8), 256, 0, stream>>>(t5, SpI, S2pI, 256, 64, N * 64);
    kfinal2<<<4, 64, 0, stream>>>(SpI, S2pI, 8, g5, b5, mu, Ad, Bd, 256, N * 64);
    ksp_conv<<<dim3(1, 4, N), 64, 0, stream>>>(t5, mu, Ad, Bd, p5B, p5Z, 256, 64, &flags[12]);

    // ---- L6: conv+pool (Ci=256, 8x8 -> 4x4), positions-in-lanes ----
    kbconv_pool2s<4, 8><<<dim3(1, 32, N), 64, 0, stream>>>(p5B, p5Z, wb6B, wb6Z, t6, 256, 8, 8, &flags[4], &flags[12]);
    kaccum16<<<dim3(256, 2), 256, 0, stream>>>(t6, SpI, S2pI, 256, 16, N * 16);
    kfinal2<<<4, 64, 0, stream>>>(SpI, S2pI, 2, g6, b6, mu, Ad, Bd, 256, N * 16);
    ksp_flat<<<N, 64, 0, stream>>>(t6, mu, Ad, Bd, p6B, p6Z);

    // ---- FC1 ----
    kbfc<<<dim3(8, N), 64, 0, stream>>>(p6B, p6Z, wf1B, wf1Z, fc1, 64, 512);
    k3_stats<<<512, 256, 0, stream>>>(fc1, N, 512, gf1, bf1, mu, Ad, Bd);
    ksp_fc<<<cdiv(N * 8, 64), 64, 0, stream>>>(fc1, mu, Ad, Bd, pF1B, pF1Z, 512, 8, N);

    // ---- FC2 ----
    kbfc<<<dim3(8, N), 64, 0, stream>>>(pF1B, pF1Z, wf2B, wf2Z, fc2, 8, 512);
    k3_stats<<<512, 256, 0, stream>>>(fc2, N, 512, gf2, bf2, mu, Ad, Bd);
    ksp_fc<<<cdiv(N * 8, 64), 64, 0, stream>>>(fc2, mu, Ad, Bd, pF2B, pF2Z, 512, 8, N);

    // ---- FC3 + bn(no affine) + log_softmax ----
    kbfc<<<dim3(1, N), 64, 0, stream>>>(pF2B, pF2Z, wf3B, wf3Z, fc3, 8, 10);
    k3_stats<<<10, 256, 0, stream>>>(fc3, N, 10, nullptr, nullptr, mu, Ad, Bd);
    k4_out<<<cdiv(N, 256), 256, 0, stream>>>(fc3, mu, Ad, (float*)d_out, N);
}

// Round 7
// 849.531 us; speedup vs baseline: 65.9141x; 1.0433x over previous
//
#include <hip/hip_runtime.h>
#include <stdint.h>
#include <math.h>

// Round 20 = R19 + ILP-batched loads in k1_signpack / ksp_conv (the rolled
// 64-iter load loops were serial-latency-bound, VGPR=16 signature). Bit-OR
// packing has no ordering => identical results; expressions token-identical.
// All numerics-critical chains (L1 conv order, statsA/B) verbatim R19.

typedef unsigned long long u64;

__device__ __forceinline__ void flag_and_wave(u64* flag, u64 nz) {
    nz &= __shfl_xor(nz, 1);
    nz &= __shfl_xor(nz, 2);
    nz &= __shfl_xor(nz, 4);
    nz &= __shfl_xor(nz, 8);
    nz &= __shfl_xor(nz, 16);
    nz &= __shfl_xor(nz, 32);
    if ((threadIdx.x & 63) == 0) atomicAnd(flag, nz);
}

__global__ void kflag_init(u64* __restrict__ f) {
    int i = threadIdx.x;
    if (i < 16) f[i] = ~0ull;
}

// ---------- L1 ----------
__global__ void kw1t(const float* __restrict__ w1, float* __restrict__ wt) {
    int i = blockIdx.x * 64 + threadIdx.x;     // 64*27
    if (i >= 64 * 27) return;
    int co = i / 27, k = i % 27;
    float v = w1[i];
    wt[k * 64 + co] = (v > 0.f) ? 1.f : ((v < 0.f) ? -1.f : 0.f);
}

__global__ __launch_bounds__(256) void k1_conv_all(const float* __restrict__ x,
                                                   const float* __restrict__ wt,
                                                   float* __restrict__ out) {
    int gid = blockIdx.x * 256 + threadIdx.x;  // n*1024 + hw
    int n = gid >> 10, hw = gid & 1023;
    int y = hw >> 5, x0 = hw & 31;
    const float* ip = x + (size_t)n * 3 * 1024;
    float xv[27];
#pragma unroll
    for (int wk = 0; wk < 9; ++wk) {
        int ky = wk / 3, kx = wk % 3;
        int yy = y + ky - 1, xc = x0 + kx - 1;
        bool ok = ((unsigned)yy < 32u) && ((unsigned)xc < 32u);
        int sp = yy * 32 + xc;
        xv[wk]      = ok ? ip[sp]        : 0.f;
        xv[9 + wk]  = ok ? ip[1024 + sp] : 0.f;
        xv[18 + wk] = ok ? ip[2048 + sp] : 0.f;
    }
    float acc[64];
#pragma unroll
    for (int c = 0; c < 64; ++c) acc[c] = 0.f;
    // accumulation order per co: (ky,kx) outer, ci inner — identical to R13.
#pragma unroll
    for (int wk = 0; wk < 9; ++wk)
#pragma unroll
        for (int ci = 0; ci < 3; ++ci) {
            float xs = xv[ci * 9 + wk];
            const float* wrow = wt + (ci * 9 + wk) * 64;
#pragma unroll
            for (int c = 0; c < 64; ++c) acc[c] = fmaf(wrow[c], xs, acc[c]);
        }
    float* op = out + ((size_t)n * 64) * 1024 + hw;
#pragma unroll
    for (int c = 0; c < 64; ++c) op[(size_t)c * 1024] = acc[c];
}

// stage A: per-slot partial chains, identical m-order to R16's k1_stats64.
__global__ void k1_statsA(const float* __restrict__ v, double* __restrict__ Sp,
                          double* __restrict__ S2p, int N) {
    int c = blockIdx.x;                         // 0..63
    int slot = blockIdx.y * 64 + threadIdx.x;   // 0..255
    double s = 0.0, s2 = 0.0;
    int K = N * 4;                              // chain length (m = slot + 256k)
    const float* vp = v + (size_t)c * 1024 + slot;
    int k0 = 0;
    for (; k0 + 32 <= K; k0 += 32) {
        const float* p0 = vp + (size_t)(k0 >> 2) * 65536;
        float buf[32];
#pragma unroll
        for (int j = 0; j < 32; ++j)
            buf[j] = p0[(size_t)(j >> 2) * 65536 + (j & 3) * 256];
#pragma unroll
        for (int j = 0; j < 32; ++j) {
            double t = (double)buf[j];
            s += t; s2 += t * t;
        }
    }
    for (; k0 < K; ++k0) {
        int m = slot + k0 * 256;
        double t = (double)v[((size_t)(m >> 10) * 64 + c) * 1024 + (m & 1023)];
        s += t; s2 += t * t;
    }
    Sp[c * 256 + slot] = s; S2p[c * 256 + slot] = s2;
}

// stage B: verbatim 256-slot tree + mu/r finalization.
__global__ void k1_statsB(const double* __restrict__ Sp, const double* __restrict__ S2p,
                          float* __restrict__ muF, float* __restrict__ rF, int N) {
    int c = blockIdx.x;
    __shared__ double sh[256], sh2[256];
    sh[threadIdx.x]  = Sp[c * 256 + threadIdx.x];
    sh2[threadIdx.x] = S2p[c * 256 + threadIdx.x];
    __syncthreads();
    for (int o = 128; o > 0; o >>= 1) {
        if ((int)threadIdx.x < o) { sh[threadIdx.x] += sh[threadIdx.x + o]; sh2[threadIdx.x] += sh2[threadIdx.x + o]; }
        __syncthreads();
    }
    if (threadIdx.x == 0) {
        int M = N * 1024;
        double mean = sh[0] / M;
        double var  = sh2[0] / M - mean * mean;
        if (var < 0.0) var = 0.0;
        muF[c] = (float)mean;
        rF[c]  = 1.0f / sqrtf((float)var + 1e-5f);
    }
}

// ILP-batched: 64 independent loads first (bit-OR packing is order-free),
// then token-identical per-channel expressions.
__global__ void k1_signpack(const float* __restrict__ v, const float* __restrict__ muF,
                            const float* __restrict__ rF, const float* __restrict__ g,
                            const float* __restrict__ b, u64* __restrict__ B,
                            u64* __restrict__ NZ, u64* __restrict__ aflag) {
    int gid = blockIdx.x * 64 + threadIdx.x;   // n*1024 + hw
    int n = gid >> 10, hw = gid & 1023;
    const float* vp = v + ((size_t)n * 64) * 1024 + hw;
    float buf[64];
#pragma unroll
    for (int c = 0; c < 64; ++c) buf[c] = vp[(size_t)c * 1024];
    u64 bb = 0, nz = 0;
#pragma unroll
    for (int c = 0; c < 64; ++c) {
        float d = buf[c] - muF[c];
        float t = (d * rF[c]) * g[c] + b[c];
        bb |= (u64)(t > 0.f) << c;
        nz |= (u64)(t != 0.f) << c;
    }
    B[gid] = bb; NZ[gid] = nz;
    flag_and_wave(aflag, nz);
}

// ---------- L1 fallback path (verbatim R13/R14) ----------
__global__ void k1_conv(const float* __restrict__ x, const float* __restrict__ w1,
                        float* __restrict__ out, int grp) {
    int hw = blockIdx.x * 64 + threadIdx.x;
    int cg = blockIdx.y;
    int n  = blockIdx.z;
    int co = grp * 8 + cg;
    int y = hw >> 5, x0 = hw & 31;
    const float* ip0 = x + ((size_t)n * 3 + 0) * 1024;
    const float* ip1 = x + ((size_t)n * 3 + 1) * 1024;
    const float* ip2 = x + ((size_t)n * 3 + 2) * 1024;
    const float* wp  = w1 + (size_t)co * 27;
    float acc = 0.f;
    for (int ky = 0; ky < 3; ++ky) {
        int yy = y + ky - 1;
        if (yy < 0 || yy > 31) continue;
        for (int kx = 0; kx < 3; ++kx) {
            int xc = x0 + kx - 1;
            if (xc < 0 || xc > 31) continue;
            int sp = yy * 32 + xc;
            int wk = ky * 3 + kx;
            float w0 = wp[wk], w1v = wp[9 + wk], w2 = wp[18 + wk];
            acc += (w0  > 0.f) ? ip0[sp] : ((w0  < 0.f) ? -ip0[sp] : 0.f);
            acc += (w1v > 0.f) ? ip1[sp] : ((w1v < 0.f) ? -ip1[sp] : 0.f);
            acc += (w2  > 0.f) ? ip2[sp] : ((w2  < 0.f) ? -ip2[sp] : 0.f);
        }
    }
    out[((size_t)n * 8 + cg) * 1024 + hw] = acc;
}

__device__ __forceinline__ float ld1(const float* v, int cg, int e) {
    return v[((size_t)(e >> 10) * 8 + cg) * 1024 + (e & 1023)];
}

__global__ void k1_stats(const float* __restrict__ v, float* __restrict__ muF,
                         float* __restrict__ rF, int grp, int N) {
    int cg = blockIdx.x;
    __shared__ double sh[256], sh2[256];
    double s = 0.0, s2 = 0.0;
    int M = N * 1024;
    for (int m = threadIdx.x; m < M; m += 256) {
        double t = (double)ld1(v, cg, m);
        s += t; s2 += t * t;
    }
    sh[threadIdx.x] = s; sh2[threadIdx.x] = s2;
    __syncthreads();
    for (int o = 128; o > 0; o >>= 1) {
        if ((int)threadIdx.x < o) { sh[threadIdx.x] += sh[threadIdx.x + o]; sh2[threadIdx.x] += sh2[threadIdx.x + o]; }
        __syncthreads();
    }
    if (threadIdx.x == 0) {
        double mean = sh[0] / M;
        double var  = sh2[0] / M - mean * mean;
        if (var < 0.0) var = 0.0;
        muF[grp * 8 + cg] = (float)mean;
        rF[grp * 8 + cg]  = 1.0f / sqrtf((float)var + 1e-5f);
    }
}

__global__ void k1_sign(const float* __restrict__ v, const float* __restrict__ muF,
                        const float* __restrict__ rF, const float* __restrict__ g,
                        const float* __restrict__ b, int8_t* __restrict__ sgn, int grp) {
    int hw = blockIdx.x * 256 + threadIdx.x;
    if (hw >= 1024) return;
    int cg = blockIdx.y, n = blockIdx.z;
    int c = grp * 8 + cg;
    float d  = v[((size_t)n * 8 + cg) * 1024 + hw] - muF[c];
    float t  = (d * rF[c]) * g[c] + b[c];
    sgn[((size_t)n * 64 + c) * 1024 + hw] = (int8_t)((t > 0.f) - (t < 0.f));
}

__global__ void kpack_sgn8(const int8_t* __restrict__ s, u64* __restrict__ B,
                           u64* __restrict__ NZ, int C, int HW, u64* __restrict__ aflag) {
    int hw = blockIdx.x * 64 + threadIdx.x;
    int wd = blockIdx.y, n = blockIdx.z;
    int WRD = C >> 6;
    u64 b = 0, nz = ~0ull;
    if (hw < HW) {
        nz = 0;
        const int8_t* sp = s + ((size_t)n * C + wd * 64) * HW + hw;
        for (int j = 0; j < 64; ++j) {
            int v = sp[(size_t)j * HW];
            b  |= (u64)(v > 0) << j;
            nz |= (u64)(v != 0) << j;
        }
        size_t o = ((size_t)n * HW + hw) * WRD + wd;
        B[o] = b; NZ[o] = nz;
    }
    flag_and_wave(aflag, nz);
}

// ---------- weight packing ----------
__global__ void kpack_wconv(const float* __restrict__ w, u64* __restrict__ WB,
                            u64* __restrict__ WNZ, int Ci, int Co, u64* __restrict__ flag) {
    int idx = blockIdx.x * 256 + threadIdx.x;
    int WRD = Ci >> 6;
    u64 b = 0, nz = ~0ull;
    if (idx < Co * 9 * WRD) {
        nz = 0;
        int wd = idx % WRD, t = (idx / WRD) % 9, co = idx / (9 * WRD);
        const float* wp = w + ((size_t)co * Ci + wd * 64) * 9 + t;
        float buf[64];
#pragma unroll
        for (int j = 0; j < 64; ++j) buf[j] = wp[(size_t)j * 9];
#pragma unroll
        for (int j = 0; j < 64; ++j) {
            b  |= (u64)(buf[j] > 0.f) << j;
            nz |= (u64)(buf[j] != 0.f) << j;
        }
        WB[idx] = b; WNZ[idx] = nz;
    }
    flag_and_wave(flag, nz);
}

__global__ void kpack_wlin(const float* __restrict__ w, u64* __restrict__ WB,
                           u64* __restrict__ WNZ, int K, int O) {
    int idx = blockIdx.x * 256 + threadIdx.x;
    int WRD = K >> 6;
    if (idx >= O * WRD) return;
    int wd = idx % WRD, o = idx / WRD;
    u64 b = 0, nz = 0;
    const float* wp = w + (size_t)o * K + wd * 64;
#pragma unroll 8
    for (int j = 0; j < 64; ++j) {
        float v = wp[j];
        b  |= (u64)(v > 0.f) << j;
        nz |= (u64)(v != 0.f) << j;
    }
    WB[idx] = b; WNZ[idx] = nz;
}

// ---------- binary conv cores ----------
template <int WRD, int CB>
__device__ __forceinline__ void conv_slow(const u64* __restrict__ ib, const u64* __restrict__ iz,
                                          const u64* __restrict__ wbp, const u64* __restrict__ wzp,
                                          int H, int Wi, int y, int x, int* acc) {
#pragma unroll
    for (int c = 0; c < CB; ++c) acc[c] = 0;
    for (int ky = 0; ky < 3; ++ky) {
        int yy = y + ky - 1;
        if ((unsigned)yy >= (unsigned)H) continue;
        for (int kx = 0; kx < 3; ++kx) {
            int xc = x + kx - 1;
            if ((unsigned)xc >= (unsigned)Wi) continue;
            int p = yy * Wi + xc, t = ky * 3 + kx;
            u64 xb[WRD], xz[WRD];
#pragma unroll
            for (int w = 0; w < WRD; ++w) {
                xb[w] = ib[(size_t)p * WRD + w];
                xz[w] = iz[(size_t)p * WRD + w];
            }
#pragma unroll
            for (int c = 0; c < CB; ++c) {
#pragma unroll
                for (int w = 0; w < WRD; ++w) {
                    u64 e = xz[w] & wzp[(c * 9 + t) * WRD + w];
                    acc[c] += __popcll(e) - 2 * __popcll((xb[w] ^ wbp[(c * 9 + t) * WRD + w]) & e);
                }
            }
        }
    }
}

template <int WRD, int CB>
__device__ __forceinline__ void conv_fast(const u64* __restrict__ ib,
                                          const u64* __restrict__ wbp,
                                          int H, int Wi, int y, int x, int* acc) {
    int a2[CB];
#pragma unroll
    for (int c = 0; c < CB; ++c) a2[c] = 0;
    int T = 0;
    for (int ky = 0; ky < 3; ++ky) {
        int yy = y + ky - 1;
        if ((unsigned)yy >= (unsigned)H) continue;
        for (int kx = 0; kx < 3; ++kx) {
            int xc = x + kx - 1;
            if ((unsigned)xc >= (unsigned)Wi) continue;
            int p = yy * Wi + xc, t = ky * 3 + kx;
            ++T;
            u64 xb[WRD];
#pragma unroll
            for (int w = 0; w < WRD; ++w) xb[w] = ib[(size_t)p * WRD + w];
#pragma unroll
            for (int c = 0; c < CB; ++c)
#pragma unroll
                for (int w = 0; w < WRD; ++w)
                    a2[c] += __popcll(xb[w] ^ wbp[(c * 9 + t) * WRD + w]);
        }
    }
#pragma unroll
    for (int c = 0; c < CB; ++c) acc[c] = 64 * WRD * T - 2 * a2[c];
}

template <int WRD, int CB>
__global__ void kbconv2(const u64* __restrict__ B, const u64* __restrict__ NZ,
                        const u64* __restrict__ WB, const u64* __restrict__ WNZ,
                        int16_t* __restrict__ out, int Co, int H, int Wi,
                        const u64* __restrict__ wflag, const u64* __restrict__ aflag) {
    int hw = blockIdx.x * 64 + threadIdx.x;
    if (hw >= H * Wi) return;
    int co0 = blockIdx.y * CB, n = blockIdx.z;
    int y = hw / Wi, x = hw % Wi;
    const u64* ib = B  + (size_t)n * H * Wi * WRD;
    const u64* iz = NZ + (size_t)n * H * Wi * WRD;
    const u64* wbp = WB  + (size_t)co0 * 9 * WRD;
    const u64* wzp = WNZ + (size_t)co0 * 9 * WRD;
    bool fast = ((*wflag) & (*aflag)) == ~0ull;
    int acc[CB];
    if (fast) conv_fast<WRD, CB>(ib, wbp, H, Wi, y, x, acc);
    else      conv_slow<WRD, CB>(ib, iz, wbp, wzp, H, Wi, y, x, acc);
#pragma unroll
    for (int c = 0; c < CB; ++c)
        out[((size_t)n * Co + co0 + c) * H * Wi + hw] = (int16_t)acc[c];
}

template <int WRD, int CB>
__global__ void kbconv_pool2(const u64* __restrict__ B, const u64* __restrict__ NZ,
                             const u64* __restrict__ WB, const u64* __restrict__ WNZ,
                             int16_t* __restrict__ out, int Co, int H, int Wi,
                             const u64* __restrict__ wflag, const u64* __restrict__ aflag) {
    int Ho = H >> 1, Wo = Wi >> 1;
    int hw = blockIdx.x * 64 + threadIdx.x;
    if (hw >= Ho * Wo) return;
    int co0 = blockIdx.y * CB, n = blockIdx.z;
    int yo = hw / Wo, xo = hw % Wo;
    const u64* ib = B  + (size_t)n * H * Wi * WRD;
    const u64* iz = NZ + (size_t)n * H * Wi * WRD;
    const u64* wbp = WB  + (size_t)co0 * 9 * WRD;
    const u64* wzp = WNZ + (size_t)co0 * 9 * WRD;
    bool fast = ((*wflag) & (*aflag)) == ~0ull;
    int best[CB];
#pragma unroll
    for (int c = 0; c < CB; ++c) best[c] = -(1 << 30);
    if (fast) {
        for (int dy = 0; dy < 2; ++dy)
            for (int dx = 0; dx < 2; ++dx) {
                int acc[CB];
                conv_fast<WRD, CB>(ib, wbp, H, Wi, 2 * yo + dy, 2 * xo + dx, acc);
#pragma unroll
                for (int c = 0; c < CB; ++c) best[c] = acc[c] > best[c] ? acc[c] : best[c];
            }
    } else {
        for (int dy = 0; dy < 2; ++dy)
            for (int dx = 0; dx < 2; ++dx) {
                int acc[CB];
                conv_slow<WRD, CB>(ib, iz, wbp, wzp, H, Wi, 2 * yo + dy, 2 * xo + dx, acc);
#pragma unroll
                for (int c = 0; c < CB; ++c) best[c] = acc[c] > best[c] ? acc[c] : best[c];
            }
    }
#pragma unroll
    for (int c = 0; c < CB; ++c)
        out[((size_t)n * Co + co0 + c) * Ho * Wo + hw] = (int16_t)best[c];
}

// pool variant for Ho*Wo==16: 64 lanes = 16 pixels x 4 pool positions.
template <int WRD, int CB>
__global__ void kbconv_pool2s(const u64* __restrict__ B, const u64* __restrict__ NZ,
                              const u64* __restrict__ WB, const u64* __restrict__ WNZ,
                              int16_t* __restrict__ out, int Co, int H, int Wi,
                              const u64* __restrict__ wflag, const u64* __restrict__ aflag) {
    int Ho = H >> 1, Wo = Wi >> 1;       // Ho*Wo == 16
    int t0 = threadIdx.x;
    int pix = t0 & 15, pos = t0 >> 4;    // pos 0..3
    int co0 = blockIdx.y * CB, n = blockIdx.z;
    int yo = pix / Wo, xo = pix % Wo;
    int y = 2 * yo + (pos >> 1), x = 2 * xo + (pos & 1);
    const u64* ib = B  + (size_t)n * H * Wi * WRD;
    const u64* iz = NZ + (size_t)n * H * Wi * WRD;
    const u64* wbp = WB  + (size_t)co0 * 9 * WRD;
    const u64* wzp = WNZ + (size_t)co0 * 9 * WRD;
    bool fast = ((*wflag) & (*aflag)) == ~0ull;
    int acc[CB];
    if (fast) conv_fast<WRD, CB>(ib, wbp, H, Wi, y, x, acc);
    else      conv_slow<WRD, CB>(ib, iz, wbp, wzp, H, Wi, y, x, acc);
#pragma unroll
    for (int c = 0; c < CB; ++c) {
        int v = acc[c];
        int v1 = __shfl_xor(v, 16); v = v1 > v ? v1 : v;
        int v2 = __shfl_xor(v, 32); v = v2 > v ? v2 : v;
        acc[c] = v;
    }
    if (pos == 0) {
#pragma unroll
        for (int c = 0; c < CB; ++c)
            out[((size_t)n * Co + co0 + c) * Ho * Wo + pix] = (int16_t)acc[c];
    }
}

// ---------- conv BN stats (int64 partials, order-free, exact) ----------
__global__ void kaccum16(const int16_t* __restrict__ v, long long* __restrict__ Sp,
                         long long* __restrict__ S2p, int C, int HW, int M) {
    int c = blockIdx.x;
    long long s = 0, s2 = 0;
    for (int m = blockIdx.y * 256 + threadIdx.x; m < M; m += gridDim.y * 256) {
        int t = v[((size_t)(m / HW) * C + c) * HW + (m % HW)];
        s += t; s2 += (long long)t * t;
    }
    __shared__ long long sh[256], sh2[256];
    sh[threadIdx.x] = s; sh2[threadIdx.x] = s2;
    __syncthreads();
    for (int o = 128; o > 0; o >>= 1) {
        if ((int)threadIdx.x < o) { sh[threadIdx.x] += sh[threadIdx.x + o]; sh2[threadIdx.x] += sh2[threadIdx.x + o]; }
        __syncthreads();
    }
    if (threadIdx.x == 0) {
        Sp[c * gridDim.y + blockIdx.y]  = sh[0];
        S2p[c * gridDim.y + blockIdx.y] = sh2[0];
    }
}

__global__ void kfinal2(const long long* __restrict__ Sp, const long long* __restrict__ S2p,
                        int NB, const float* __restrict__ g, const float* __restrict__ b,
                        double* __restrict__ mu, double* __restrict__ Ad,
                        double* __restrict__ Bd, int C, int M) {
    int c = blockIdx.x * 64 + threadIdx.x;
    if (c >= C) return;
    long long s = 0, s2 = 0;
    for (int i = 0; i < NB; ++i) { s += Sp[c * NB + i]; s2 += S2p[c * NB + i]; }
    double mean = (double)s / M;
    double var  = (double)s2 / M - mean * mean;
    if (var < 0.0) var = 0.0;
    mu[c] = mean;
    Ad[c] = (g ? (double)g[c] : 1.0) / sqrt(var + 1e-5);
    Bd[c] = b ? (double)b[c] : 0.0;
}

// ---------- BN sign + pack (ILP-batched loads; bit-OR is order-free) ----------
__global__ void ksp_conv(const int16_t* __restrict__ v, const double* __restrict__ mu,
                         const double* __restrict__ Ad, const double* __restrict__ Bd,
                         u64* __restrict__ B, u64* __restrict__ NZ, int C, int HW,
                         u64* __restrict__ aflag) {
    int hw = blockIdx.x * 64 + threadIdx.x;
    int wd = blockIdx.y, n = blockIdx.z;
    int WRD = C >> 6;
    u64 b = 0, nz = ~0ull;
    if (hw < HW) {
        const int16_t* vp = v + ((size_t)n * C + wd * 64) * HW + hw;
        int16_t buf[64];
#pragma unroll
        for (int j = 0; j < 64; ++j) buf[j] = vp[(size_t)j * HW];
        nz = 0;
#pragma unroll
        for (int j = 0; j < 64; ++j) {
            int c = wd * 64 + j;
            double t = ((double)buf[j] - mu[c]) * Ad[c] + Bd[c];
            b  |= (u64)(t > 0.0) << j;
            nz |= (u64)(t != 0.0) << j;
        }
        size_t o = ((size_t)n * HW + hw) * WRD + wd;
        B[o] = b; NZ[o] = nz;
    }
    flag_and_wave(aflag, nz);
}

__global__ void ksp_flat(const int16_t* __restrict__ v, const double* __restrict__ mu,
                         const double* __restrict__ Ad, const double* __restrict__ Bd,
                         u64* __restrict__ B, u64* __restrict__ NZ) {
    int wd = threadIdx.x;
    int n  = blockIdx.x;
    const int16_t* vp = v + (size_t)n * 4096 + wd * 64;
    int16_t buf[64];
#pragma unroll
    for (int j = 0; j < 64; ++j) buf[j] = vp[j];
    u64 b = 0, nz = 0;
#pragma unroll
    for (int j = 0; j < 64; ++j) {
        int k = wd * 64 + j;
        int c = k >> 4;
        double t = ((double)buf[j] - mu[c]) * Ad[c] + Bd[c];
        b  |= (u64)(t > 0.0) << j;
        nz |= (u64)(t != 0.0) << j;
    }
    B[(size_t)n * 64 + wd] = b; NZ[(size_t)n * 64 + wd] = nz;
}

__global__ void ksp_fc(const int* __restrict__ v, const double* __restrict__ mu,
                       const double* __restrict__ Ad, const double* __restrict__ Bd,
                       u64* __restrict__ B, u64* __restrict__ NZ, int C, int WRD, int N) {
    int tid = blockIdx.x * 64 + threadIdx.x;
    if (tid >= N * WRD) return;
    int n = tid / WRD, wd = tid % WRD;
    const int* vp = v + (size_t)n * C + wd * 64;
    int buf[64];
#pragma unroll
    for (int j = 0; j < 64; ++j) buf[j] = vp[j];
    u64 b = 0, nz = 0;
#pragma unroll
    for (int j = 0; j < 64; ++j) {
        int c = wd * 64 + j;
        double t = ((double)buf[j] - mu[c]) * Ad[c] + Bd[c];
        b  |= (u64)(t > 0.0) << j;
        nz |= (u64)(t != 0.0) << j;
    }
    B[(size_t)n * WRD + wd] = b; NZ[(size_t)n * WRD + wd] = nz;
}

// ---------- binary FC ----------
__global__ void kbfc(const u64* __restrict__ aB, const u64* __restrict__ aNZ,
                     const u64* __restrict__ wB, const u64* __restrict__ wNZ,
                     int* __restrict__ out, int WRD, int O) {
    int o = blockIdx.x * 64 + threadIdx.x;
    if (o >= O) return;
    int n = blockIdx.y;
    const u64* ab = aB  + (size_t)n * WRD;
    const u64* az = aNZ + (size_t)n * WRD;
    const u64* wb = wB  + (size_t)o * WRD;
    const u64* wz = wNZ + (size_t)o * WRD;
    int acc = 0;
    for (int w = 0; w < WRD; ++w) {
        u64 e = az[w] & wz[w];
        acc += __popcll(e) - 2 * __popcll((ab[w] ^ wb[w]) & e);
    }
    out[(size_t)n * O + o] = acc;
}

// ---------- FC stats / output ----------
__global__ void k3_stats(const int* __restrict__ v, int N, int C,
                         const float* __restrict__ g, const float* __restrict__ b,
                         double* __restrict__ mu, double* __restrict__ Ad,
                         double* __restrict__ Bd) {
    int c = blockIdx.x;
    __shared__ double sh[256], sh2[256];
    double s = 0.0, s2 = 0.0;
    for (int n = threadIdx.x; n < N; n += 256) {
        double t = (double)v[(size_t)n * C + c];
        s += t; s2 += t * t;
    }
    sh[threadIdx.x] = s; sh2[threadIdx.x] = s2;
    __syncthreads();
    for (int o = 128; o > 0; o >>= 1) {
        if ((int)threadIdx.x < o) { sh[threadIdx.x] += sh[threadIdx.x + o]; sh2[threadIdx.x] += sh2[threadIdx.x + o]; }
        __syncthreads();
    }
    if (threadIdx.x == 0) {
        double mean = sh[0] / N;
        double var  = sh2[0] / N - mean * mean;
        if (var < 0.0) var = 0.0;
        mu[c] = mean;
        Ad[c] = (g ? (double)g[c] : 1.0) / sqrt(var + 1e-5);
        Bd[c] = b ? (double)b[c] : 0.0;
    }
}

__global__ void k4_out(const int* __restrict__ v, const double* __restrict__ mu,
                       const double* __restrict__ Ad, float* __restrict__ out, int N) {
    int n = blockIdx.x * 256 + threadIdx.x;
    if (n >= N) return;
    double z[10];
    double mx = -1e300;
    for (int o = 0; o < 10; ++o) {
        z[o] = ((double)v[n * 10 + o] - mu[o]) * Ad[o];
        if (z[o] > mx) mx = z[o];
    }
    double s = 0.0;
    for (int o = 0; o < 10; ++o) s += exp(z[o] - mx);
    double l = mx + log(s);
    for (int o = 0; o < 10; ++o) out[n * 10 + o] = (float)(z[o] - l);
}

// ---------------- host ----------------
extern "C" void kernel_launch(void* const* d_in, const int* in_sizes, int n_in,
                              void* d_out, int out_size, void* d_ws, size_t ws_size,
                              hipStream_t stream) {
    const int N = in_sizes[0] / (3 * 32 * 32);   // 512

    const float* x   = (const float*)d_in[0];
    const float* w1  = (const float*)d_in[1];
    const float* g1  = (const float*)d_in[2];
    const float* b1  = (const float*)d_in[3];
    const float* w2  = (const float*)d_in[4];
    const float* g2  = (const float*)d_in[5];
    const float* b2  = (const float*)d_in[6];
    const float* w3  = (const float*)d_in[7];
    const float* g3  = (const float*)d_in[8];
    const float* b3  = (const float*)d_in[9];
    const float* w4  = (const float*)d_in[10];
    const float* g4  = (const float*)d_in[11];
    const float* b4  = (const float*)d_in[12];
    const float* w5  = (const float*)d_in[13];
    const float* g5  = (const float*)d_in[14];
    const float* b5  = (const float*)d_in[15];
    const float* w6  = (const float*)d_in[16];
    const float* g6  = (const float*)d_in[17];
    const float* b6  = (const float*)d_in[18];
    const float* wf1 = (const float*)d_in[19];
    const float* gf1 = (const float*)d_in[20];
    const float* bf1 = (const float*)d_in[21];
    const float* wf2 = (const float*)d_in[22];
    const float* gf2 = (const float*)d_in[23];
    const float* bf2 = (const float*)d_in[24];
    const float* wf3 = (const float*)d_in[25];

    char* ws = (char*)d_ws;
    size_t off = 0;
    auto alloc = [&](size_t bytes) -> char* {
        char* p = ws + off;
        off = (off + bytes + 511) & ~(size_t)511;
        return p;
    };

    // ---- DOWN region: all post-L1 buffers at distinct offsets ----
    int16_t* t2  = (int16_t*)alloc((size_t)N * 64 * 256 * 2);
    u64* p2B = (u64*)alloc((size_t)N * 256 * 8);
    u64* p2Z = (u64*)alloc((size_t)N * 256 * 8);
    int16_t* t3  = (int16_t*)alloc((size_t)N * 128 * 256 * 2);
    u64* p3B = (u64*)alloc((size_t)N * 256 * 2 * 8);
    u64* p3Z = (u64*)alloc((size_t)N * 256 * 2 * 8);
    int16_t* t4  = (int16_t*)alloc((size_t)N * 128 * 64 * 2);
    u64* p4B = (u64*)alloc((size_t)N * 64 * 2 * 8);
    u64* p4Z = (u64*)alloc((size_t)N * 64 * 2 * 8);
    int16_t* t5  = (int16_t*)alloc((size_t)N * 256 * 64 * 2);
    u64* p5B = (u64*)alloc((size_t)N * 64 * 4 * 8);
    u64* p5Z = (u64*)alloc((size_t)N * 64 * 4 * 8);
    int16_t* t6  = (int16_t*)alloc((size_t)N * 256 * 16 * 2);
    u64* p6B = (u64*)alloc((size_t)N * 64 * 8);
    u64* p6Z = (u64*)alloc((size_t)N * 64 * 8);
    int* fc1 = (int*)alloc((size_t)N * 512 * 4);
    int* fc2 = (int*)alloc((size_t)N * 512 * 4);
    int* fc3 = (int*)alloc((size_t)N * 10 * 4);
    u64* pF1B = (u64*)alloc((size_t)N * 8 * 8);
    u64* pF1Z = (u64*)alloc((size_t)N * 8 * 8);
    u64* pF2B = (u64*)alloc((size_t)N * 8 * 8);
    u64* pF2Z = (u64*)alloc((size_t)N * 8 * 8);
    size_t down_end = off;

    // ---- L1 head overlays (dead before any DOWN buffer is written) ----
    size_t head_big = (size_t)N * 64 * 1024 * 4;      // 134.2MB f32, 64 channels
    bool big = ws_size >= head_big + ((size_t)20 << 20);
    float*  c1buf = (float*)ws;                        // big: [N][64][1024]
    float*  c1buf8 = (float*)ws;                       // fallback: [N][8][1024]
    int8_t* sgnA  = (int8_t*)(ws + (size_t)N * 8 * 1024 * 4);  // fallback only

    // ---- tail (coexists with L1 head) ----
    off = big ? (head_big > down_end ? head_big : down_end) : down_end;
    off = (off + 511) & ~(size_t)511;
    u64* p1B = (u64*)alloc((size_t)N * 1024 * 8);
    u64* p1Z = (u64*)alloc((size_t)N * 1024 * 8);
    u64* wb2B = (u64*)alloc(64  * 9 * 1 * 8);  u64* wb2Z = (u64*)alloc(64  * 9 * 1 * 8);
    u64* wb3B = (u64*)alloc(128 * 9 * 1 * 8);  u64* wb3Z = (u64*)alloc(128 * 9 * 1 * 8);
    u64* wb4B = (u64*)alloc(128 * 9 * 2 * 8);  u64* wb4Z = (u64*)alloc(128 * 9 * 2 * 8);
    u64* wb5B = (u64*)alloc(256 * 9 * 2 * 8);  u64* wb5Z = (u64*)alloc(256 * 9 * 2 * 8);
    u64* wb6B = (u64*)alloc(256 * 9 * 4 * 8);  u64* wb6Z = (u64*)alloc(256 * 9 * 4 * 8);
    u64* wf1B = (u64*)alloc(512 * 64 * 8);     u64* wf1Z = (u64*)alloc(512 * 64 * 8);
    u64* wf2B = (u64*)alloc(512 * 8 * 8);      u64* wf2Z = (u64*)alloc(512 * 8 * 8);
    u64* wf3B = (u64*)alloc(10 * 8 * 8);       u64* wf3Z = (u64*)alloc(10 * 8 * 8);
    float* wt = (float*)alloc(27 * 64 * 4);
    double* Sp  = (double*)alloc(64 * 256 * 8);
    double* S2p = (double*)alloc(64 * 256 * 8);
    long long* SpI  = (long long*)alloc(256 * 32 * 8);
    long long* S2pI = (long long*)alloc(256 * 32 * 8);
    u64* flags = (u64*)alloc(16 * 8);          // [0..4]=wflag L2..L6, [8..12]=aflag L1..L5
    double* mu = (double*)alloc(512 * 8);
    double* Ad = (double*)alloc(512 * 8);
    double* Bd = (double*)alloc(512 * 8);
    float*  muF = (float*)alloc(64 * 4);
    float*  rF  = (float*)alloc(64 * 4);

    auto cdiv = [](int a, int b) { return (a + b - 1) / b; };

    // ---- flags + pack weights ----
    kflag_init<<<1, 64, 0, stream>>>(flags);
    kpack_wconv<<<cdiv(64 * 9 * 1, 256), 256, 0, stream>>>(w2, wb2B, wb2Z, 64, 64, &flags[0]);
    kpack_wconv<<<cdiv(128 * 9 * 1, 256), 256, 0, stream>>>(w3, wb3B, wb3Z, 64, 128, &flags[1]);
    kpack_wconv<<<cdiv(128 * 9 * 2, 256), 256, 0, stream>>>(w4, wb4B, wb4Z, 128, 128, &flags[2]);
    kpack_wconv<<<cdiv(256 * 9 * 2, 256), 256, 0, stream>>>(w5, wb5B, wb5Z, 128, 256, &flags[3]);
    kpack_wconv<<<cdiv(256 * 9 * 4, 256), 256, 0, stream>>>(w6, wb6B, wb6Z, 256, 256, &flags[4]);
    kpack_wlin<<<cdiv(512 * 64, 256), 256, 0, stream>>>(wf1, wf1B, wf1Z, 4096, 512);
    kpack_wlin<<<cdiv(512 * 8, 256), 256, 0, stream>>>(wf2, wf2B, wf2Z, 512, 512);
    kpack_wlin<<<cdiv(10 * 8, 256), 256, 0, stream>>>(wf3, wf3B, wf3Z, 512, 10);

    // ---- L1 ----
    if (big) {
        kw1t<<<27, 64, 0, stream>>>(w1, wt);
        k1_conv_all<<<(N * 1024) / 256, 256, 0, stream>>>(x, wt, c1buf);
        k1_statsA<<<dim3(64, 4), 64, 0, stream>>>(c1buf, Sp, S2p, N);
        k1_statsB<<<64, 256, 0, stream>>>(Sp, S2p, muF, rF, N);
        k1_signpack<<<(N * 1024) / 64, 64, 0, stream>>>(c1buf, muF, rF, g1, b1, p1B, p1Z, &flags[8]);
    } else {
        for (int grp = 0; grp < 8; ++grp) {
            k1_conv<<<dim3(16, 8, N), 64, 0, stream>>>(x, w1, c1buf8, grp);
            k1_stats<<<8, 256, 0, stream>>>(c1buf8, muF, rF, grp, N);
            k1_sign<<<dim3(4, 8, N), 256, 0, stream>>>(c1buf8, muF, rF, g1, b1, sgnA, grp);
        }
        kpack_sgn8<<<dim3(16, 1, N), 64, 0, stream>>>(sgnA, p1B, p1Z, 64, 1024, &flags[8]);
    }

    // ---- L2: conv+pool (Ci=64, 32x32 -> 16x16) ----
    kbconv_pool2<1, 8><<<dim3(4, 8, N), 64, 0, stream>>>(p1B, p1Z, wb2B, wb2Z, t2, 64, 32, 32, &flags[0], &flags[8]);
    kaccum16<<<dim3(64, 32), 256, 0, stream>>>(t2, SpI, S2pI, 64, 256, N * 256);
    kfinal2<<<1, 64, 0, stream>>>(SpI, S2pI, 32, g2, b2, mu, Ad, Bd, 64, N * 256);
    ksp_conv<<<dim3(4, 1, N), 64, 0, stream>>>(t2, mu, Ad, Bd, p2B, p2Z, 64, 256, &flags[9]);

    // ---- L3: conv (Ci=64, 16x16) ----
    kbconv2<1, 8><<<dim3(4, 16, N), 64, 0, stream>>>(p2B, p2Z, wb3B, wb3Z, t3, 128, 16, 16, &flags[1], &flags[9]);
    kaccum16<<<dim3(128, 16), 256, 0, stream>>>(t3, SpI, S2pI, 128, 256, N * 256);
    kfinal2<<<2, 64, 0, stream>>>(SpI, S2pI, 16, g3, b3, mu, Ad, Bd, 128, N * 256);
    ksp_conv<<<dim3(4, 2, N), 64, 0, stream>>>(t3, mu, Ad, Bd, p3B, p3Z, 128, 256, &flags[10]);

    // ---- L4: conv+pool (Ci=128, 16x16 -> 8x8) ----
    kbconv_pool2<2, 8><<<dim3(1, 16, N), 64, 0, stream>>>(p3B, p3Z, wb4B, wb4Z, t4, 128, 16, 16, &flags[2], &flags[10]);
    kaccum16<<<dim3(128, 16), 256, 0, stream>>>(t4, SpI, S2pI, 128, 64, N * 64);
    kfinal2<<<2, 64, 0, stream>>>(SpI, S2pI, 16, g4, b4, mu, Ad, Bd, 128, N * 64);
    ksp_conv<<<dim3(1, 2, N), 64, 0, stream>>>(t4, mu, Ad, Bd, p4B, p4Z, 128, 64, &flags[11]);

    // ---- L5: conv (Ci=128, 8x8) ----
    kbconv2<2, 8><<<dim3(1, 32, N), 64, 0, stream>>>(p4B, p4Z, wb5B, wb5Z, t5, 256, 8, 8, &flags[3], &flags[11]);
    kaccum16<<<dim3(256, 8), 256, 0, stream>>>(t5, SpI, S2pI, 256, 64, N * 64);
    kfinal2<<<4, 64, 0, stream>>>(SpI, S2pI, 8, g5, b5, mu, Ad, Bd, 256, N * 64);
    ksp_conv<<<dim3(1, 4, N), 64, 0, stream>>>(t5, mu, Ad, Bd, p5B, p5Z, 256, 64, &flags[12]);

    // ---- L6: conv+pool (Ci=256, 8x8 -> 4x4), positions-in-lanes ----
    kbconv_pool2s<4, 8><<<dim3(1, 32, N), 64, 0, stream>>>(p5B, p5Z, wb6B, wb6Z, t6, 256, 8, 8, &flags[4], &flags[12]);
    kaccum16<<<dim3(256, 2), 256, 0, stream>>>(t6, SpI, S2pI, 256, 16, N * 16);
    kfinal2<<<4, 64, 0, stream>>>(SpI, S2pI, 2, g6, b6, mu, Ad, Bd, 256, N * 16);
    ksp_flat<<<N, 64, 0, stream>>>(t6, mu, Ad, Bd, p6B, p6Z);

    // ---- FC1 ----
    kbfc<<<dim3(8, N), 64, 0, stream>>>(p6B, p6Z, wf1B, wf1Z, fc1, 64, 512);
    k3_stats<<<512, 256, 0, stream>>>(fc1, N, 512, gf1, bf1, mu, Ad, Bd);
    ksp_fc<<<cdiv(N * 8, 64), 64, 0, stream>>>(fc1, mu, Ad, Bd, pF1B, pF1Z, 512, 8, N);

    // ---- FC2 ----
    kbfc<<<dim3(8, N), 64, 0, stream>>>(pF1B, pF1Z, wf2B, wf2Z, fc2, 8, 512);
    k3_stats<<<512, 256, 0, stream>>>(fc2, N, 512, gf2, bf2, mu, Ad, Bd);
    ksp_fc<<<cdiv(N * 8, 64), 64, 0, stream>>>(fc2, mu, Ad, Bd, pF2B, pF2Z, 512, 8, N);

    // ---- FC3 + bn(no affine) + log_softmax ----
    kbfc<<<dim3(1, N), 64, 0, stream>>>(pF2B, pF2Z, wf3B, wf3Z, fc3, 8, 10);
    k3_stats<<<10, 256, 0, stream>>>(fc3, N, 10, nullptr, nullptr, mu, Ad, Bd);
    k4_out<<<cdiv(N, 256), 256, 0, stream>>>(fc3, mu, Ad, (float*)d_out, N);
}

// Round 8
// 705.137 us; speedup vs baseline: 79.4117x; 1.2048x over previous
//
#include <hip/hip_runtime.h>
#include <stdint.h>
#include <math.h>

// Round 21 = R20 + vectorized memory-bound kernels (issue-width was the cap:
// scalar 4B/2B lane loads = 256/128 B per wave-instruction, ~1.3 TB/s ceiling).
// - k1_signpack: float4 x 4 pixels/thread (bit-OR order-free; BN expr token-identical)
// - kaccum16:    short4 x2 = 8 elems/thread (int64 sums order-free => exact)
// - ksp_conv:    short4 x 4 pixels/thread (same argument)
// All numerics-critical chains (conv1 FMA order, statsA/B, FC stats) verbatim R20.

typedef unsigned long long u64;

__device__ __forceinline__ void flag_and_wave(u64* flag, u64 nz) {
    nz &= __shfl_xor(nz, 1);
    nz &= __shfl_xor(nz, 2);
    nz &= __shfl_xor(nz, 4);
    nz &= __shfl_xor(nz, 8);
    nz &= __shfl_xor(nz, 16);
    nz &= __shfl_xor(nz, 32);
    if ((threadIdx.x & 63) == 0) atomicAnd(flag, nz);
}

__global__ void kflag_init(u64* __restrict__ f) {
    int i = threadIdx.x;
    if (i < 16) f[i] = ~0ull;
}

// ---------- L1 ----------
__global__ void kw1t(const float* __restrict__ w1, float* __restrict__ wt) {
    int i = blockIdx.x * 64 + threadIdx.x;     // 64*27
    if (i >= 64 * 27) return;
    int co = i / 27, k = i % 27;
    float v = w1[i];
    wt[k * 64 + co] = (v > 0.f) ? 1.f : ((v < 0.f) ? -1.f : 0.f);
}

__global__ __launch_bounds__(256) void k1_conv_all(const float* __restrict__ x,
                                                   const float* __restrict__ wt,
                                                   float* __restrict__ out) {
    int gid = blockIdx.x * 256 + threadIdx.x;  // n*1024 + hw
    int n = gid >> 10, hw = gid & 1023;
    int y = hw >> 5, x0 = hw & 31;
    const float* ip = x + (size_t)n * 3 * 1024;
    float xv[27];
#pragma unroll
    for (int wk = 0; wk < 9; ++wk) {
        int ky = wk / 3, kx = wk % 3;
        int yy = y + ky - 1, xc = x0 + kx - 1;
        bool ok = ((unsigned)yy < 32u) && ((unsigned)xc < 32u);
        int sp = yy * 32 + xc;
        xv[wk]      = ok ? ip[sp]        : 0.f;
        xv[9 + wk]  = ok ? ip[1024 + sp] : 0.f;
        xv[18 + wk] = ok ? ip[2048 + sp] : 0.f;
    }
    float acc[64];
#pragma unroll
    for (int c = 0; c < 64; ++c) acc[c] = 0.f;
    // accumulation order per co: (ky,kx) outer, ci inner — identical to R13.
#pragma unroll
    for (int wk = 0; wk < 9; ++wk)
#pragma unroll
        for (int ci = 0; ci < 3; ++ci) {
            float xs = xv[ci * 9 + wk];
            const float* wrow = wt + (ci * 9 + wk) * 64;
#pragma unroll
            for (int c = 0; c < 64; ++c) acc[c] = fmaf(wrow[c], xs, acc[c]);
        }
    float* op = out + ((size_t)n * 64) * 1024 + hw;
#pragma unroll
    for (int c = 0; c < 64; ++c) op[(size_t)c * 1024] = acc[c];
}

// stage A: per-slot partial chains, identical m-order to R16's k1_stats64.
__global__ void k1_statsA(const float* __restrict__ v, double* __restrict__ Sp,
                          double* __restrict__ S2p, int N) {
    int c = blockIdx.x;                         // 0..63
    int slot = blockIdx.y * 64 + threadIdx.x;   // 0..255
    double s = 0.0, s2 = 0.0;
    int K = N * 4;                              // chain length (m = slot + 256k)
    const float* vp = v + (size_t)c * 1024 + slot;
    int k0 = 0;
    for (; k0 + 32 <= K; k0 += 32) {
        const float* p0 = vp + (size_t)(k0 >> 2) * 65536;
        float buf[32];
#pragma unroll
        for (int j = 0; j < 32; ++j)
            buf[j] = p0[(size_t)(j >> 2) * 65536 + (j & 3) * 256];
#pragma unroll
        for (int j = 0; j < 32; ++j) {
            double t = (double)buf[j];
            s += t; s2 += t * t;
        }
    }
    for (; k0 < K; ++k0) {
        int m = slot + k0 * 256;
        double t = (double)v[((size_t)(m >> 10) * 64 + c) * 1024 + (m & 1023)];
        s += t; s2 += t * t;
    }
    Sp[c * 256 + slot] = s; S2p[c * 256 + slot] = s2;
}

// stage B: verbatim 256-slot tree + mu/r finalization.
__global__ void k1_statsB(const double* __restrict__ Sp, const double* __restrict__ S2p,
                          float* __restrict__ muF, float* __restrict__ rF, int N) {
    int c = blockIdx.x;
    __shared__ double sh[256], sh2[256];
    sh[threadIdx.x]  = Sp[c * 256 + threadIdx.x];
    sh2[threadIdx.x] = S2p[c * 256 + threadIdx.x];
    __syncthreads();
    for (int o = 128; o > 0; o >>= 1) {
        if ((int)threadIdx.x < o) { sh[threadIdx.x] += sh[threadIdx.x + o]; sh2[threadIdx.x] += sh2[threadIdx.x + o]; }
        __syncthreads();
    }
    if (threadIdx.x == 0) {
        int M = N * 1024;
        double mean = sh[0] / M;
        double var  = sh2[0] / M - mean * mean;
        if (var < 0.0) var = 0.0;
        muF[c] = (float)mean;
        rF[c]  = 1.0f / sqrtf((float)var + 1e-5f);
    }
}

// 4 pixels/thread, float4 loads along hw (channels chunked x16 for VGPRs).
// Bit-OR packing is order-free; per-element BN expression token-identical.
__global__ void k1_signpack(const float* __restrict__ v, const float* __restrict__ muF,
                            const float* __restrict__ rF, const float* __restrict__ g,
                            const float* __restrict__ b, u64* __restrict__ B,
                            u64* __restrict__ NZ, u64* __restrict__ aflag) {
    int gid = blockIdx.x * 64 + threadIdx.x;   // n*256 + hw4
    int n = gid >> 8, hw0 = (gid & 255) * 4;
    const float* vp = v + ((size_t)n * 64) * 1024 + hw0;
    u64 bb0 = 0, bb1 = 0, bb2 = 0, bb3 = 0;
    u64 nz0 = 0, nz1 = 0, nz2 = 0, nz3 = 0;
    for (int c0 = 0; c0 < 64; c0 += 16) {
        float4 buf[16];
#pragma unroll
        for (int j = 0; j < 16; ++j)
            buf[j] = *(const float4*)(vp + (size_t)(c0 + j) * 1024);
#pragma unroll
        for (int j = 0; j < 16; ++j) {
            int c = c0 + j;
            float mc = muF[c], rc = rF[c], gc = g[c], bc = b[c];
            float d0 = buf[j].x - mc; float t0 = (d0 * rc) * gc + bc;
            float d1 = buf[j].y - mc; float t1 = (d1 * rc) * gc + bc;
            float d2 = buf[j].z - mc; float t2 = (d2 * rc) * gc + bc;
            float d3 = buf[j].w - mc; float t3 = (d3 * rc) * gc + bc;
            bb0 |= (u64)(t0 > 0.f) << c;  nz0 |= (u64)(t0 != 0.f) << c;
            bb1 |= (u64)(t1 > 0.f) << c;  nz1 |= (u64)(t1 != 0.f) << c;
            bb2 |= (u64)(t2 > 0.f) << c;  nz2 |= (u64)(t2 != 0.f) << c;
            bb3 |= (u64)(t3 > 0.f) << c;  nz3 |= (u64)(t3 != 0.f) << c;
        }
    }
    size_t o = (size_t)n * 1024 + hw0;
    B[o]     = bb0; B[o + 1]  = bb1; B[o + 2]  = bb2; B[o + 3]  = bb3;
    NZ[o]    = nz0; NZ[o + 1] = nz1; NZ[o + 2] = nz2; NZ[o + 3] = nz3;
    flag_and_wave(aflag, nz0 & nz1 & nz2 & nz3);
}

// ---------- L1 fallback path (verbatim R13/R14) ----------
__global__ void k1_conv(const float* __restrict__ x, const float* __restrict__ w1,
                        float* __restrict__ out, int grp) {
    int hw = blockIdx.x * 64 + threadIdx.x;
    int cg = blockIdx.y;
    int n  = blockIdx.z;
    int co = grp * 8 + cg;
    int y = hw >> 5, x0 = hw & 31;
    const float* ip0 = x + ((size_t)n * 3 + 0) * 1024;
    const float* ip1 = x + ((size_t)n * 3 + 1) * 1024;
    const float* ip2 = x + ((size_t)n * 3 + 2) * 1024;
    const float* wp  = w1 + (size_t)co * 27;
    float acc = 0.f;
    for (int ky = 0; ky < 3; ++ky) {
        int yy = y + ky - 1;
        if (yy < 0 || yy > 31) continue;
        for (int kx = 0; kx < 3; ++kx) {
            int xc = x0 + kx - 1;
            if (xc < 0 || xc > 31) continue;
            int sp = yy * 32 + xc;
            int wk = ky * 3 + kx;
            float w0 = wp[wk], w1v = wp[9 + wk], w2 = wp[18 + wk];
            acc += (w0  > 0.f) ? ip0[sp] : ((w0  < 0.f) ? -ip0[sp] : 0.f);
            acc += (w1v > 0.f) ? ip1[sp] : ((w1v < 0.f) ? -ip1[sp] : 0.f);
            acc += (w2  > 0.f) ? ip2[sp] : ((w2  < 0.f) ? -ip2[sp] : 0.f);
        }
    }
    out[((size_t)n * 8 + cg) * 1024 + hw] = acc;
}

__device__ __forceinline__ float ld1(const float* v, int cg, int e) {
    return v[((size_t)(e >> 10) * 8 + cg) * 1024 + (e & 1023)];
}

__global__ void k1_stats(const float* __restrict__ v, float* __restrict__ muF,
                         float* __restrict__ rF, int grp, int N) {
    int cg = blockIdx.x;
    __shared__ double sh[256], sh2[256];
    double s = 0.0, s2 = 0.0;
    int M = N * 1024;
    for (int m = threadIdx.x; m < M; m += 256) {
        double t = (double)ld1(v, cg, m);
        s += t; s2 += t * t;
    }
    sh[threadIdx.x] = s; sh2[threadIdx.x] = s2;
    __syncthreads();
    for (int o = 128; o > 0; o >>= 1) {
        if ((int)threadIdx.x < o) { sh[threadIdx.x] += sh[threadIdx.x + o]; sh2[threadIdx.x] += sh2[threadIdx.x + o]; }
        __syncthreads();
    }
    if (threadIdx.x == 0) {
        double mean = sh[0] / M;
        double var  = sh2[0] / M - mean * mean;
        if (var < 0.0) var = 0.0;
        muF[grp * 8 + cg] = (float)mean;
        rF[grp * 8 + cg]  = 1.0f / sqrtf((float)var + 1e-5f);
    }
}

__global__ void k1_sign(const float* __restrict__ v, const float* __restrict__ muF,
                        const float* __restrict__ rF, const float* __restrict__ g,
                        const float* __restrict__ b, int8_t* __restrict__ sgn, int grp) {
    int hw = blockIdx.x * 256 + threadIdx.x;
    if (hw >= 1024) return;
    int cg = blockIdx.y, n = blockIdx.z;
    int c = grp * 8 + cg;
    float d  = v[((size_t)n * 8 + cg) * 1024 + hw] - muF[c];
    float t  = (d * rF[c]) * g[c] + b[c];
    sgn[((size_t)n * 64 + c) * 1024 + hw] = (int8_t)((t > 0.f) - (t < 0.f));
}

__global__ void kpack_sgn8(const int8_t* __restrict__ s, u64* __restrict__ B,
                           u64* __restrict__ NZ, int C, int HW, u64* __restrict__ aflag) {
    int hw = blockIdx.x * 64 + threadIdx.x;
    int wd = blockIdx.y, n = blockIdx.z;
    int WRD = C >> 6;
    u64 b = 0, nz = ~0ull;
    if (hw < HW) {
        nz = 0;
        const int8_t* sp = s + ((size_t)n * C + wd * 64) * HW + hw;
        for (int j = 0; j < 64; ++j) {
            int v = sp[(size_t)j * HW];
            b  |= (u64)(v > 0) << j;
            nz |= (u64)(v != 0) << j;
        }
        size_t o = ((size_t)n * HW + hw) * WRD + wd;
        B[o] = b; NZ[o] = nz;
    }
    flag_and_wave(aflag, nz);
}

// ---------- weight packing ----------
__global__ void kpack_wconv(const float* __restrict__ w, u64* __restrict__ WB,
                            u64* __restrict__ WNZ, int Ci, int Co, u64* __restrict__ flag) {
    int idx = blockIdx.x * 256 + threadIdx.x;
    int WRD = Ci >> 6;
    u64 b = 0, nz = ~0ull;
    if (idx < Co * 9 * WRD) {
        nz = 0;
        int wd = idx % WRD, t = (idx / WRD) % 9, co = idx / (9 * WRD);
        const float* wp = w + ((size_t)co * Ci + wd * 64) * 9 + t;
        float buf[64];
#pragma unroll
        for (int j = 0; j < 64; ++j) buf[j] = wp[(size_t)j * 9];
#pragma unroll
        for (int j = 0; j < 64; ++j) {
            b  |= (u64)(buf[j] > 0.f) << j;
            nz |= (u64)(buf[j] != 0.f) << j;
        }
        WB[idx] = b; WNZ[idx] = nz;
    }
    flag_and_wave(flag, nz);
}

__global__ void kpack_wlin(const float* __restrict__ w, u64* __restrict__ WB,
                           u64* __restrict__ WNZ, int K, int O) {
    int idx = blockIdx.x * 256 + threadIdx.x;
    int WRD = K >> 6;
    if (idx >= O * WRD) return;
    int wd = idx % WRD, o = idx / WRD;
    u64 b = 0, nz = 0;
    const float* wp = w + (size_t)o * K + wd * 64;
#pragma unroll 8
    for (int j = 0; j < 64; ++j) {
        float v = wp[j];
        b  |= (u64)(v > 0.f) << j;
        nz |= (u64)(v != 0.f) << j;
    }
    WB[idx] = b; WNZ[idx] = nz;
}

// ---------- binary conv cores ----------
template <int WRD, int CB>
__device__ __forceinline__ void conv_slow(const u64* __restrict__ ib, const u64* __restrict__ iz,
                                          const u64* __restrict__ wbp, const u64* __restrict__ wzp,
                                          int H, int Wi, int y, int x, int* acc) {
#pragma unroll
    for (int c = 0; c < CB; ++c) acc[c] = 0;
    for (int ky = 0; ky < 3; ++ky) {
        int yy = y + ky - 1;
        if ((unsigned)yy >= (unsigned)H) continue;
        for (int kx = 0; kx < 3; ++kx) {
            int xc = x + kx - 1;
            if ((unsigned)xc >= (unsigned)Wi) continue;
            int p = yy * Wi + xc, t = ky * 3 + kx;
            u64 xb[WRD], xz[WRD];
#pragma unroll
            for (int w = 0; w < WRD; ++w) {
                xb[w] = ib[(size_t)p * WRD + w];
                xz[w] = iz[(size_t)p * WRD + w];
            }
#pragma unroll
            for (int c = 0; c < CB; ++c) {
#pragma unroll
                for (int w = 0; w < WRD; ++w) {
                    u64 e = xz[w] & wzp[(c * 9 + t) * WRD + w];
                    acc[c] += __popcll(e) - 2 * __popcll((xb[w] ^ wbp[(c * 9 + t) * WRD + w]) & e);
                }
            }
        }
    }
}

template <int WRD, int CB>
__device__ __forceinline__ void conv_fast(const u64* __restrict__ ib,
                                          const u64* __restrict__ wbp,
                                          int H, int Wi, int y, int x, int* acc) {
    int a2[CB];
#pragma unroll
    for (int c = 0; c < CB; ++c) a2[c] = 0;
    int T = 0;
    for (int ky = 0; ky < 3; ++ky) {
        int yy = y + ky - 1;
        if ((unsigned)yy >= (unsigned)H) continue;
        for (int kx = 0; kx < 3; ++kx) {
            int xc = x + kx - 1;
            if ((unsigned)xc >= (unsigned)Wi) continue;
            int p = yy * Wi + xc, t = ky * 3 + kx;
            ++T;
            u64 xb[WRD];
#pragma unroll
            for (int w = 0; w < WRD; ++w) xb[w] = ib[(size_t)p * WRD + w];
#pragma unroll
            for (int c = 0; c < CB; ++c)
#pragma unroll
                for (int w = 0; w < WRD; ++w)
                    a2[c] += __popcll(xb[w] ^ wbp[(c * 9 + t) * WRD + w]);
        }
    }
#pragma unroll
    for (int c = 0; c < CB; ++c) acc[c] = 64 * WRD * T - 2 * a2[c];
}

template <int WRD, int CB>
__global__ void kbconv2(const u64* __restrict__ B, const u64* __restrict__ NZ,
                        const u64* __restrict__ WB, const u64* __restrict__ WNZ,
                        int16_t* __restrict__ out, int Co, int H, int Wi,
                        const u64* __restrict__ wflag, const u64* __restrict__ aflag) {
    int hw = blockIdx.x * 64 + threadIdx.x;
    if (hw >= H * Wi) return;
    int co0 = blockIdx.y * CB, n = blockIdx.z;
    int y = hw / Wi, x = hw % Wi;
    const u64* ib = B  + (size_t)n * H * Wi * WRD;
    const u64* iz = NZ + (size_t)n * H * Wi * WRD;
    const u64* wbp = WB  + (size_t)co0 * 9 * WRD;
    const u64* wzp = WNZ + (size_t)co0 * 9 * WRD;
    bool fast = ((*wflag) & (*aflag)) == ~0ull;
    int acc[CB];
    if (fast) conv_fast<WRD, CB>(ib, wbp, H, Wi, y, x, acc);
    else      conv_slow<WRD, CB>(ib, iz, wbp, wzp, H, Wi, y, x, acc);
#pragma unroll
    for (int c = 0; c < CB; ++c)
        out[((size_t)n * Co + co0 + c) * H * Wi + hw] = (int16_t)acc[c];
}

template <int WRD, int CB>
__global__ void kbconv_pool2(const u64* __restrict__ B, const u64* __restrict__ NZ,
                             const u64* __restrict__ WB, const u64* __restrict__ WNZ,
                             int16_t* __restrict__ out, int Co, int H, int Wi,
                             const u64* __restrict__ wflag, const u64* __restrict__ aflag) {
    int Ho = H >> 1, Wo = Wi >> 1;
    int hw = blockIdx.x * 64 + threadIdx.x;
    if (hw >= Ho * Wo) return;
    int co0 = blockIdx.y * CB, n = blockIdx.z;
    int yo = hw / Wo, xo = hw % Wo;
    const u64* ib = B  + (size_t)n * H * Wi * WRD;
    const u64* iz = NZ + (size_t)n * H * Wi * WRD;
    const u64* wbp = WB  + (size_t)co0 * 9 * WRD;
    const u64* wzp = WNZ + (size_t)co0 * 9 * WRD;
    bool fast = ((*wflag) & (*aflag)) == ~0ull;
    int best[CB];
#pragma unroll
    for (int c = 0; c < CB; ++c) best[c] = -(1 << 30);
    if (fast) {
        for (int dy = 0; dy < 2; ++dy)
            for (int dx = 0; dx < 2; ++dx) {
                int acc[CB];
                conv_fast<WRD, CB>(ib, wbp, H, Wi, 2 * yo + dy, 2 * xo + dx, acc);
#pragma unroll
                for (int c = 0; c < CB; ++c) best[c] = acc[c] > best[c] ? acc[c] : best[c];
            }
    } else {
        for (int dy = 0; dy < 2; ++dy)
            for (int dx = 0; dx < 2; ++dx) {
                int acc[CB];
                conv_slow<WRD, CB>(ib, iz, wbp, wzp, H, Wi, 2 * yo + dy, 2 * xo + dx, acc);
#pragma unroll
                for (int c = 0; c < CB; ++c) best[c] = acc[c] > best[c] ? acc[c] : best[c];
            }
    }
#pragma unroll
    for (int c = 0; c < CB; ++c)
        out[((size_t)n * Co + co0 + c) * Ho * Wo + hw] = (int16_t)best[c];
}

// pool variant for Ho*Wo==16: 64 lanes = 16 pixels x 4 pool positions.
template <int WRD, int CB>
__global__ void kbconv_pool2s(const u64* __restrict__ B, const u64* __restrict__ NZ,
                              const u64* __restrict__ WB, const u64* __restrict__ WNZ,
                              int16_t* __restrict__ out, int Co, int H, int Wi,
                              const u64* __restrict__ wflag, const u64* __restrict__ aflag) {
    int Ho = H >> 1, Wo = Wi >> 1;       // Ho*Wo == 16
    int t0 = threadIdx.x;
    int pix = t0 & 15, pos = t0 >> 4;    // pos 0..3
    int co0 = blockIdx.y * CB, n = blockIdx.z;
    int yo = pix / Wo, xo = pix % Wo;
    int y = 2 * yo + (pos >> 1), x = 2 * xo + (pos & 1);
    const u64* ib = B  + (size_t)n * H * Wi * WRD;
    const u64* iz = NZ + (size_t)n * H * Wi * WRD;
    const u64* wbp = WB  + (size_t)co0 * 9 * WRD;
    const u64* wzp = WNZ + (size_t)co0 * 9 * WRD;
    bool fast = ((*wflag) & (*aflag)) == ~0ull;
    int acc[CB];
    if (fast) conv_fast<WRD, CB>(ib, wbp, H, Wi, y, x, acc);
    else      conv_slow<WRD, CB>(ib, iz, wbp, wzp, H, Wi, y, x, acc);
#pragma unroll
    for (int c = 0; c < CB; ++c) {
        int v = acc[c];
        int v1 = __shfl_xor(v, 16); v = v1 > v ? v1 : v;
        int v2 = __shfl_xor(v, 32); v = v2 > v ? v2 : v;
        acc[c] = v;
    }
    if (pos == 0) {
#pragma unroll
        for (int c = 0; c < CB; ++c)
            out[((size_t)n * Co + co0 + c) * Ho * Wo + pix] = (int16_t)acc[c];
    }
}

// ---------- conv BN stats (int64, order-free => regrouping exact) ----------
// 8 int16 per thread-iteration via two short4 loads.
__global__ void kaccum16(const int16_t* __restrict__ v, long long* __restrict__ Sp,
                         long long* __restrict__ S2p, int C, int HW, int M) {
    int c = blockIdx.x;
    long long s = 0, s2 = 0;
    int M8 = M >> 3;                     // M divisible by 8 for all layers
    for (int g = blockIdx.y * 256 + threadIdx.x; g < M8; g += gridDim.y * 256) {
        int m0 = g * 8;
        const int16_t* p = v + ((size_t)(m0 / HW) * C + c) * HW + (m0 % HW);
        short4 a = *(const short4*)p;
        short4 b = *(const short4*)(p + 4);
        int v0 = a.x, v1 = a.y, v2 = a.z, v3 = a.w;
        int v4 = b.x, v5 = b.y, v6 = b.z, v7 = b.w;
        s  += v0 + v1 + v2 + v3 + v4 + v5 + v6 + v7;
        s2 += (long long)v0 * v0 + (long long)v1 * v1 + (long long)v2 * v2 + (long long)v3 * v3
            + (long long)v4 * v4 + (long long)v5 * v5 + (long long)v6 * v6 + (long long)v7 * v7;
    }
    __shared__ long long sh[256], sh2[256];
    sh[threadIdx.x] = s; sh2[threadIdx.x] = s2;
    __syncthreads();
    for (int o = 128; o > 0; o >>= 1) {
        if ((int)threadIdx.x < o) { sh[threadIdx.x] += sh[threadIdx.x + o]; sh2[threadIdx.x] += sh2[threadIdx.x + o]; }
        __syncthreads();
    }
    if (threadIdx.x == 0) {
        Sp[c * gridDim.y + blockIdx.y]  = sh[0];
        S2p[c * gridDim.y + blockIdx.y] = sh2[0];
    }
}

__global__ void kfinal2(const long long* __restrict__ Sp, const long long* __restrict__ S2p,
                        int NB, const float* __restrict__ g, const float* __restrict__ b,
                        double* __restrict__ mu, double* __restrict__ Ad,
                        double* __restrict__ Bd, int C, int M) {
    int c = blockIdx.x * 64 + threadIdx.x;
    if (c >= C) return;
    long long s = 0, s2 = 0;
    for (int i = 0; i < NB; ++i) { s += Sp[c * NB + i]; s2 += S2p[c * NB + i]; }
    double mean = (double)s / M;
    double var  = (double)s2 / M - mean * mean;
    if (var < 0.0) var = 0.0;
    mu[c] = mean;
    Ad[c] = (g ? (double)g[c] : 1.0) / sqrt(var + 1e-5);
    Bd[c] = b ? (double)b[c] : 0.0;
}

// ---------- BN sign + pack: 4 pixels/thread via short4 (order-free bit-OR) ----------
__global__ void ksp_conv(const int16_t* __restrict__ v, const double* __restrict__ mu,
                         const double* __restrict__ Ad, const double* __restrict__ Bd,
                         u64* __restrict__ B, u64* __restrict__ NZ, int C, int HW, int N,
                         u64* __restrict__ aflag) {
    int tid = blockIdx.x * 64 + threadIdx.x;
    int WRD = C >> 6;
    int HW4 = HW >> 2;
    int total = N * WRD * HW4;
    u64 nzall = ~0ull;
    if (tid < total) {
        int hw4 = tid % HW4;
        int wd  = (tid / HW4) % WRD;
        int n   = tid / (HW4 * WRD);
        const int16_t* vp = v + ((size_t)n * C + wd * 64) * HW + hw4 * 4;
        u64 b0 = 0, b1 = 0, b2 = 0, b3 = 0;
        u64 n0 = 0, n1 = 0, n2 = 0, n3 = 0;
        for (int j0 = 0; j0 < 64; j0 += 16) {
            short4 buf[16];
#pragma unroll
            for (int j = 0; j < 16; ++j)
                buf[j] = *(const short4*)(vp + (size_t)(j0 + j) * HW);
#pragma unroll
            for (int j = 0; j < 16; ++j) {
                int c = wd * 64 + j0 + j;
                double Mu = mu[c], A = Ad[c], Bb = Bd[c];
                double t0 = ((double)buf[j].x - Mu) * A + Bb;
                double t1 = ((double)buf[j].y - Mu) * A + Bb;
                double t2 = ((double)buf[j].z - Mu) * A + Bb;
                double t3 = ((double)buf[j].w - Mu) * A + Bb;
                int sh = j0 + j;
                b0 |= (u64)(t0 > 0.0) << sh;  n0 |= (u64)(t0 != 0.0) << sh;
                b1 |= (u64)(t1 > 0.0) << sh;  n1 |= (u64)(t1 != 0.0) << sh;
                b2 |= (u64)(t2 > 0.0) << sh;  n2 |= (u64)(t2 != 0.0) << sh;
                b3 |= (u64)(t3 > 0.0) << sh;  n3 |= (u64)(t3 != 0.0) << sh;
            }
        }
        size_t o = ((size_t)n * HW + hw4 * 4) * WRD + wd;
        B[o] = b0;  B[o + WRD] = b1;  B[o + 2 * WRD] = b2;  B[o + 3 * WRD] = b3;
        NZ[o] = n0; NZ[o + WRD] = n1; NZ[o + 2 * WRD] = n2; NZ[o + 3 * WRD] = n3;
        nzall = n0 & n1 & n2 & n3;
    }
    flag_and_wave(aflag, nzall);
}

__global__ void ksp_flat(const int16_t* __restrict__ v, const double* __restrict__ mu,
                         const double* __restrict__ Ad, const double* __restrict__ Bd,
                         u64* __restrict__ B, u64* __restrict__ NZ) {
    int wd = threadIdx.x;
    int n  = blockIdx.x;
    const int16_t* vp = v + (size_t)n * 4096 + wd * 64;
    int16_t buf[64];
#pragma unroll
    for (int j = 0; j < 64; ++j) buf[j] = vp[j];
    u64 b = 0, nz = 0;
#pragma unroll
    for (int j = 0; j < 64; ++j) {
        int k = wd * 64 + j;
        int c = k >> 4;
        double t = ((double)buf[j] - mu[c]) * Ad[c] + Bd[c];
        b  |= (u64)(t > 0.0) << j;
        nz |= (u64)(t != 0.0) << j;
    }
    B[(size_t)n * 64 + wd] = b; NZ[(size_t)n * 64 + wd] = nz;
}

__global__ void ksp_fc(const int* __restrict__ v, const double* __restrict__ mu,
                       const double* __restrict__ Ad, const double* __restrict__ Bd,
                       u64* __restrict__ B, u64* __restrict__ NZ, int C, int WRD, int N) {
    int tid = blockIdx.x * 64 + threadIdx.x;
    if (tid >= N * WRD) return;
    int n = tid / WRD, wd = tid % WRD;
    const int* vp = v + (size_t)n * C + wd * 64;
    int buf[64];
#pragma unroll
    for (int j = 0; j < 64; ++j) buf[j] = vp[j];
    u64 b = 0, nz = 0;
#pragma unroll
    for (int j = 0; j < 64; ++j) {
        int c = wd * 64 + j;
        double t = ((double)buf[j] - mu[c]) * Ad[c] + Bd[c];
        b  |= (u64)(t > 0.0) << j;
        nz |= (u64)(t != 0.0) << j;
    }
    B[(size_t)n * WRD + wd] = b; NZ[(size_t)n * WRD + wd] = nz;
}

// ---------- binary FC ----------
__global__ void kbfc(const u64* __restrict__ aB, const u64* __restrict__ aNZ,
                     const u64* __restrict__ wB, const u64* __restrict__ wNZ,
                     int* __restrict__ out, int WRD, int O) {
    int o = blockIdx.x * 64 + threadIdx.x;
    if (o >= O) return;
    int n = blockIdx.y;
    const u64* ab = aB  + (size_t)n * WRD;
    const u64* az = aNZ + (size_t)n * WRD;
    const u64* wb = wB  + (size_t)o * WRD;
    const u64* wz = wNZ + (size_t)o * WRD;
    int acc = 0;
    for (int w = 0; w < WRD; ++w) {
        u64 e = az[w] & wz[w];
        acc += __popcll(e) - 2 * __popcll((ab[w] ^ wb[w]) & e);
    }
    out[(size_t)n * O + o] = acc;
}

// ---------- FC stats / output ----------
__global__ void k3_stats(const int* __restrict__ v, int N, int C,
                         const float* __restrict__ g, const float* __restrict__ b,
                         double* __restrict__ mu, double* __restrict__ Ad,
                         double* __restrict__ Bd) {
    int c = blockIdx.x;
    __shared__ double sh[256], sh2[256];
    double s = 0.0, s2 = 0.0;
    for (int n = threadIdx.x; n < N; n += 256) {
        double t = (double)v[(size_t)n * C + c];
        s += t; s2 += t * t;
    }
    sh[threadIdx.x] = s; sh2[threadIdx.x] = s2;
    __syncthreads();
    for (int o = 128; o > 0; o >>= 1) {
        if ((int)threadIdx.x < o) { sh[threadIdx.x] += sh[threadIdx.x + o]; sh2[threadIdx.x] += sh2[threadIdx.x + o]; }
        __syncthreads();
    }
    if (threadIdx.x == 0) {
        double mean = sh[0] / N;
        double var  = sh2[0] / N - mean * mean;
        if (var < 0.0) var = 0.0;
        mu[c] = mean;
        Ad[c] = (g ? (double)g[c] : 1.0) / sqrt(var + 1e-5);
        Bd[c] = b ? (double)b[c] : 0.0;
    }
}

__global__ void k4_out(const int* __restrict__ v, const double* __restrict__ mu,
                       const double* __restrict__ Ad, float* __restrict__ out, int N) {
    int n = blockIdx.x * 256 + threadIdx.x;
    if (n >= N) return;
    double z[10];
    double mx = -1e300;
    for (int o = 0; o < 10; ++o) {
        z[o] = ((double)v[n * 10 + o] - mu[o]) * Ad[o];
        if (z[o] > mx) mx = z[o];
    }
    double s = 0.0;
    for (int o = 0; o < 10; ++o) s += exp(z[o] - mx);
    double l = mx + log(s);
    for (int o = 0; o < 10; ++o) out[n * 10 + o] = (float)(z[o] - l);
}

// ---------------- host ----------------
extern "C" void kernel_launch(void* const* d_in, const int* in_sizes, int n_in,
                              void* d_out, int out_size, void* d_ws, size_t ws_size,
                              hipStream_t stream) {
    const int N = in_sizes[0] / (3 * 32 * 32);   // 512

    const float* x   = (const float*)d_in[0];
    const float* w1  = (const float*)d_in[1];
    const float* g1  = (const float*)d_in[2];
    const float* b1  = (const float*)d_in[3];
    const float* w2  = (const float*)d_in[4];
    const float* g2  = (const float*)d_in[5];
    const float* b2  = (const float*)d_in[6];
    const float* w3  = (const float*)d_in[7];
    const float* g3  = (const float*)d_in[8];
    const float* b3  = (const float*)d_in[9];
    const float* w4  = (const float*)d_in[10];
    const float* g4  = (const float*)d_in[11];
    const float* b4  = (const float*)d_in[12];
    const float* w5  = (const float*)d_in[13];
    const float* g5  = (const float*)d_in[14];
    const float* b5  = (const float*)d_in[15];
    const float* w6  = (const float*)d_in[16];
    const float* g6  = (const float*)d_in[17];
    const float* b6  = (const float*)d_in[18];
    const float* wf1 = (const float*)d_in[19];
    const float* gf1 = (const float*)d_in[20];
    const float* bf1 = (const float*)d_in[21];
    const float* wf2 = (const float*)d_in[22];
    const float* gf2 = (const float*)d_in[23];
    const float* bf2 = (const float*)d_in[24];
    const float* wf3 = (const float*)d_in[25];

    char* ws = (char*)d_ws;
    size_t off = 0;
    auto alloc = [&](size_t bytes) -> char* {
        char* p = ws + off;
        off = (off + bytes + 511) & ~(size_t)511;
        return p;
    };

    // ---- DOWN region: all post-L1 buffers at distinct offsets ----
    int16_t* t2  = (int16_t*)alloc((size_t)N * 64 * 256 * 2);
    u64* p2B = (u64*)alloc((size_t)N * 256 * 8);
    u64* p2Z = (u64*)alloc((size_t)N * 256 * 8);
    int16_t* t3  = (int16_t*)alloc((size_t)N * 128 * 256 * 2);
    u64* p3B = (u64*)alloc((size_t)N * 256 * 2 * 8);
    u64* p3Z = (u64*)alloc((size_t)N * 256 * 2 * 8);
    int16_t* t4  = (int16_t*)alloc((size_t)N * 128 * 64 * 2);
    u64* p4B = (u64*)alloc((size_t)N * 64 * 2 * 8);
    u64* p4Z = (u64*)alloc((size_t)N * 64 * 2 * 8);
    int16_t* t5  = (int16_t*)alloc((size_t)N * 256 * 64 * 2);
    u64* p5B = (u64*)alloc((size_t)N * 64 * 4 * 8);
    u64* p5Z = (u64*)alloc((size_t)N * 64 * 4 * 8);
    int16_t* t6  = (int16_t*)alloc((size_t)N * 256 * 16 * 2);
    u64* p6B = (u64*)alloc((size_t)N * 64 * 8);
    u64* p6Z = (u64*)alloc((size_t)N * 64 * 8);
    int* fc1 = (int*)alloc((size_t)N * 512 * 4);
    int* fc2 = (int*)alloc((size_t)N * 512 * 4);
    int* fc3 = (int*)alloc((size_t)N * 10 * 4);
    u64* pF1B = (u64*)alloc((size_t)N * 8 * 8);
    u64* pF1Z = (u64*)alloc((size_t)N * 8 * 8);
    u64* pF2B = (u64*)alloc((size_t)N * 8 * 8);
    u64* pF2Z = (u64*)alloc((size_t)N * 8 * 8);
    size_t down_end = off;

    // ---- L1 head overlays (dead before any DOWN buffer is written) ----
    size_t head_big = (size_t)N * 64 * 1024 * 4;      // 134.2MB f32, 64 channels
    bool big = ws_size >= head_big + ((size_t)20 << 20);
    float*  c1buf = (float*)ws;                        // big: [N][64][1024]
    float*  c1buf8 = (float*)ws;                       // fallback: [N][8][1024]
    int8_t* sgnA  = (int8_t*)(ws + (size_t)N * 8 * 1024 * 4);  // fallback only

    // ---- tail (coexists with L1 head) ----
    off = big ? (head_big > down_end ? head_big : down_end) : down_end;
    off = (off + 511) & ~(size_t)511;
    u64* p1B = (u64*)alloc((size_t)N * 1024 * 8);
    u64* p1Z = (u64*)alloc((size_t)N * 1024 * 8);
    u64* wb2B = (u64*)alloc(64  * 9 * 1 * 8);  u64* wb2Z = (u64*)alloc(64  * 9 * 1 * 8);
    u64* wb3B = (u64*)alloc(128 * 9 * 1 * 8);  u64* wb3Z = (u64*)alloc(128 * 9 * 1 * 8);
    u64* wb4B = (u64*)alloc(128 * 9 * 2 * 8);  u64* wb4Z = (u64*)alloc(128 * 9 * 2 * 8);
    u64* wb5B = (u64*)alloc(256 * 9 * 2 * 8);  u64* wb5Z = (u64*)alloc(256 * 9 * 2 * 8);
    u64* wb6B = (u64*)alloc(256 * 9 * 4 * 8);  u64* wb6Z = (u64*)alloc(256 * 9 * 4 * 8);
    u64* wf1B = (u64*)alloc(512 * 64 * 8);     u64* wf1Z = (u64*)alloc(512 * 64 * 8);
    u64* wf2B = (u64*)alloc(512 * 8 * 8);      u64* wf2Z = (u64*)alloc(512 * 8 * 8);
    u64* wf3B = (u64*)alloc(10 * 8 * 8);       u64* wf3Z = (u64*)alloc(10 * 8 * 8);
    float* wt = (float*)alloc(27 * 64 * 4);
    double* Sp  = (double*)alloc(64 * 256 * 8);
    double* S2p = (double*)alloc(64 * 256 * 8);
    long long* SpI  = (long long*)alloc(256 * 32 * 8);
    long long* S2pI = (long long*)alloc(256 * 32 * 8);
    u64* flags = (u64*)alloc(16 * 8);          // [0..4]=wflag L2..L6, [8..12]=aflag L1..L5
    double* mu = (double*)alloc(512 * 8);
    double* Ad = (double*)alloc(512 * 8);
    double* Bd = (double*)alloc(512 * 8);
    float*  muF = (float*)alloc(64 * 4);
    float*  rF  = (float*)alloc(64 * 4);

    auto cdiv = [](int a, int b) { return (a + b - 1) / b; };

    // ---- flags + pack weights ----
    kflag_init<<<1, 64, 0, stream>>>(flags);
    kpack_wconv<<<cdiv(64 * 9 * 1, 256), 256, 0, stream>>>(w2, wb2B, wb2Z, 64, 64, &flags[0]);
    kpack_wconv<<<cdiv(128 * 9 * 1, 256), 256, 0, stream>>>(w3, wb3B, wb3Z, 64, 128, &flags[1]);
    kpack_wconv<<<cdiv(128 * 9 * 2, 256), 256, 0, stream>>>(w4, wb4B, wb4Z, 128, 128, &flags[2]);
    kpack_wconv<<<cdiv(256 * 9 * 2, 256), 256, 0, stream>>>(w5, wb5B, wb5Z, 128, 256, &flags[3]);
    kpack_wconv<<<cdiv(256 * 9 * 4, 256), 256, 0, stream>>>(w6, wb6B, wb6Z, 256, 256, &flags[4]);
    kpack_wlin<<<cdiv(512 * 64, 256), 256, 0, stream>>>(wf1, wf1B, wf1Z, 4096, 512);
    kpack_wlin<<<cdiv(512 * 8, 256), 256, 0, stream>>>(wf2, wf2B, wf2Z, 512, 512);
    kpack_wlin<<<cdiv(10 * 8, 256), 256, 0, stream>>>(wf3, wf3B, wf3Z, 512, 10);

    // ---- L1 ----
    if (big) {
        kw1t<<<27, 64, 0, stream>>>(w1, wt);
        k1_conv_all<<<(N * 1024) / 256, 256, 0, stream>>>(x, wt, c1buf);
        k1_statsA<<<dim3(64, 4), 64, 0, stream>>>(c1buf, Sp, S2p, N);
        k1_statsB<<<64, 256, 0, stream>>>(Sp, S2p, muF, rF, N);
        k1_signpack<<<(N * 256) / 64, 64, 0, stream>>>(c1buf, muF, rF, g1, b1, p1B, p1Z, &flags[8]);
    } else {
        for (int grp = 0; grp < 8; ++grp) {
            k1_conv<<<dim3(16, 8, N), 64, 0, stream>>>(x, w1, c1buf8, grp);
            k1_stats<<<8, 256, 0, stream>>>(c1buf8, muF, rF, grp, N);
            k1_sign<<<dim3(4, 8, N), 256, 0, stream>>>(c1buf8, muF, rF, g1, b1, sgnA, grp);
        }
        kpack_sgn8<<<dim3(16, 1, N), 64, 0, stream>>>(sgnA, p1B, p1Z, 64, 1024, &flags[8]);
    }

    // ---- L2: conv+pool (Ci=64, 32x32 -> 16x16) ----
    kbconv_pool2<1, 8><<<dim3(4, 8, N), 64, 0, stream>>>(p1B, p1Z, wb2B, wb2Z, t2, 64, 32, 32, &flags[0], &flags[8]);
    kaccum16<<<dim3(64, 32), 256, 0, stream>>>(t2, SpI, S2pI, 64, 256, N * 256);
    kfinal2<<<1, 64, 0, stream>>>(SpI, S2pI, 32, g2, b2, mu, Ad, Bd, 64, N * 256);
    ksp_conv<<<cdiv(N * 1 * 64, 64), 64, 0, stream>>>(t2, mu, Ad, Bd, p2B, p2Z, 64, 256, N, &flags[9]);

    // ---- L3: conv (Ci=64, 16x16) ----
    kbconv2<1, 8><<<dim3(4, 16, N), 64, 0, stream>>>(p2B, p2Z, wb3B, wb3Z, t3, 128, 16, 16, &flags[1], &flags[9]);
    kaccum16<<<dim3(128, 16), 256, 0, stream>>>(t3, SpI, S2pI, 128, 256, N * 256);
    kfinal2<<<2, 64, 0, stream>>>(SpI, S2pI, 16, g3, b3, mu, Ad, Bd, 128, N * 256);
    ksp_conv<<<cdiv(N * 2 * 64, 64), 64, 0, stream>>>(t3, mu, Ad, Bd, p3B, p3Z, 128, 256, N, &flags[10]);

    // ---- L4: conv+pool (Ci=128, 16x16 -> 8x8) ----
    kbconv_pool2<2, 8><<<dim3(1, 16, N), 64, 0, stream>>>(p3B, p3Z, wb4B, wb4Z, t4, 128, 16, 16, &flags[2], &flags[10]);
    kaccum16<<<dim3(128, 16), 256, 0, stream>>>(t4, SpI, S2pI, 128, 64, N * 64);
    kfinal2<<<2, 64, 0, stream>>>(SpI, S2pI, 16, g4, b4, mu, Ad, Bd, 128, N * 64);
    ksp_conv<<<cdiv(N * 2 * 16, 64), 64, 0, stream>>>(t4, mu, Ad, Bd, p4B, p4Z, 128, 64, N, &flags[11]);

    // ---- L5: conv (Ci=128, 8x8) ----
    kbconv2<2, 8><<<dim3(1, 32, N), 64, 0, stream>>>(p4B, p4Z, wb5B, wb5Z, t5, 256, 8, 8, &flags[3], &flags[11]);
    kaccum16<<<dim3(256, 8), 256, 0, stream>>>(t5, SpI, S2pI, 256, 64, N * 64);
    kfinal2<<<4, 64, 0, stream>>>(SpI, S2pI, 8, g5, b5, mu, Ad, Bd, 256, N * 64);
    ksp_conv<<<cdiv(N * 4 * 16, 64), 64, 0, stream>>>(t5, mu, Ad, Bd, p5B, p5Z, 256, 64, N, &flags[12]);

    // ---- L6: conv+pool (Ci=256, 8x8 -> 4x4), positions-in-lanes ----
    kbconv_pool2s<4, 8><<<dim3(1, 32, N), 64, 0, stream>>>(p5B, p5Z, wb6B, wb6Z, t6, 256, 8, 8, &flags[4], &flags[12]);
    kaccum16<<<dim3(256, 2), 256, 0, stream>>>(t6, SpI, S2pI, 256, 16, N * 16);
    kfinal2<<<4, 64, 0, stream>>>(SpI, S2pI, 2, g6, b6, mu, Ad, Bd, 256, N * 16);
    ksp_flat<<<N, 64, 0, stream>>>(t6, mu, Ad, Bd, p6B, p6Z);

    // ---- FC1 ----
    kbfc<<<dim3(8, N), 64, 0, stream>>>(p6B, p6Z, wf1B, wf1Z, fc1, 64, 512);
    k3_stats<<<512, 256, 0, stream>>>(fc1, N, 512, gf1, bf1, mu, Ad, Bd);
    ksp_fc<<<cdiv(N * 8, 64), 64, 0, stream>>>(fc1, mu, Ad, Bd, pF1B, pF1Z, 512, 8, N);

    // ---- FC2 ----
    kbfc<<<dim3(8, N), 64, 0, stream>>>(pF1B, pF1Z, wf2B, wf2Z, fc2, 8, 512);
    k3_stats<<<512, 256, 0, stream>>>(fc2, N, 512, gf2, bf2, mu, Ad, Bd);
    ksp_fc<<<cdiv(N * 8, 64), 64, 0, stream>>>(fc2, mu, Ad, Bd, pF2B, pF2Z, 512, 8, N);

    // ---- FC3 + bn(no affine) + log_softmax ----
    kbfc<<<dim3(1, N), 64, 0, stream>>>(pF2B, pF2Z, wf3B, wf3Z, fc3, 8, 10);
    k3_stats<<<10, 256, 0, stream>>>(fc3, N, 10, nullptr, nullptr, mu, Ad, Bd);
    k4_out<<<cdiv(N, 256), 256, 0, stream>>>(fc3, mu, Ad, (float*)d_out, N);
}

// Round 9
// 679.874 us; speedup vs baseline: 82.3625x; 1.0372x over previous
//
#include <hip/hip_runtime.h>
#include <stdint.h>
#include <math.h>

// Round 22 = R21 + FC overhaul:
// - packed FC weights transposed to [w][O] (coalesced lane reads; activation
//   word is wave-uniform broadcast)
// - dense fast path in kbfc (flags for wlin weights + FC activations),
//   acc = 64*WRD - 2*popc(a^w), exact when no ternary zeros anywhere
// - 8-deep unrolled load batches (ILP)
// All other kernels verbatim R21.

typedef unsigned long long u64;

__device__ __forceinline__ void flag_and_wave(u64* flag, u64 nz) {
    nz &= __shfl_xor(nz, 1);
    nz &= __shfl_xor(nz, 2);
    nz &= __shfl_xor(nz, 4);
    nz &= __shfl_xor(nz, 8);
    nz &= __shfl_xor(nz, 16);
    nz &= __shfl_xor(nz, 32);
    if ((threadIdx.x & 63) == 0) atomicAnd(flag, nz);
}

__global__ void kflag_init(u64* __restrict__ f) {
    int i = threadIdx.x;
    if (i < 16) f[i] = ~0ull;
}

// ---------- L1 ----------
__global__ void kw1t(const float* __restrict__ w1, float* __restrict__ wt) {
    int i = blockIdx.x * 64 + threadIdx.x;     // 64*27
    if (i >= 64 * 27) return;
    int co = i / 27, k = i % 27;
    float v = w1[i];
    wt[k * 64 + co] = (v > 0.f) ? 1.f : ((v < 0.f) ? -1.f : 0.f);
}

__global__ __launch_bounds__(256) void k1_conv_all(const float* __restrict__ x,
                                                   const float* __restrict__ wt,
                                                   float* __restrict__ out) {
    int gid = blockIdx.x * 256 + threadIdx.x;  // n*1024 + hw
    int n = gid >> 10, hw = gid & 1023;
    int y = hw >> 5, x0 = hw & 31;
    const float* ip = x + (size_t)n * 3 * 1024;
    float xv[27];
#pragma unroll
    for (int wk = 0; wk < 9; ++wk) {
        int ky = wk / 3, kx = wk % 3;
        int yy = y + ky - 1, xc = x0 + kx - 1;
        bool ok = ((unsigned)yy < 32u) && ((unsigned)xc < 32u);
        int sp = yy * 32 + xc;
        xv[wk]      = ok ? ip[sp]        : 0.f;
        xv[9 + wk]  = ok ? ip[1024 + sp] : 0.f;
        xv[18 + wk] = ok ? ip[2048 + sp] : 0.f;
    }
    float acc[64];
#pragma unroll
    for (int c = 0; c < 64; ++c) acc[c] = 0.f;
    // accumulation order per co: (ky,kx) outer, ci inner — identical to R13.
#pragma unroll
    for (int wk = 0; wk < 9; ++wk)
#pragma unroll
        for (int ci = 0; ci < 3; ++ci) {
            float xs = xv[ci * 9 + wk];
            const float* wrow = wt + (ci * 9 + wk) * 64;
#pragma unroll
            for (int c = 0; c < 64; ++c) acc[c] = fmaf(wrow[c], xs, acc[c]);
        }
    float* op = out + ((size_t)n * 64) * 1024 + hw;
#pragma unroll
    for (int c = 0; c < 64; ++c) op[(size_t)c * 1024] = acc[c];
}

// stage A: per-slot partial chains, identical m-order to R16's k1_stats64.
__global__ void k1_statsA(const float* __restrict__ v, double* __restrict__ Sp,
                          double* __restrict__ S2p, int N) {
    int c = blockIdx.x;                         // 0..63
    int slot = blockIdx.y * 64 + threadIdx.x;   // 0..255
    double s = 0.0, s2 = 0.0;
    int K = N * 4;                              // chain length (m = slot + 256k)
    const float* vp = v + (size_t)c * 1024 + slot;
    int k0 = 0;
    for (; k0 + 32 <= K; k0 += 32) {
        const float* p0 = vp + (size_t)(k0 >> 2) * 65536;
        float buf[32];
#pragma unroll
        for (int j = 0; j < 32; ++j)
            buf[j] = p0[(size_t)(j >> 2) * 65536 + (j & 3) * 256];
#pragma unroll
        for (int j = 0; j < 32; ++j) {
            double t = (double)buf[j];
            s += t; s2 += t * t;
        }
    }
    for (; k0 < K; ++k0) {
        int m = slot + k0 * 256;
        double t = (double)v[((size_t)(m >> 10) * 64 + c) * 1024 + (m & 1023)];
        s += t; s2 += t * t;
    }
    Sp[c * 256 + slot] = s; S2p[c * 256 + slot] = s2;
}

// stage B: verbatim 256-slot tree + mu/r finalization.
__global__ void k1_statsB(const double* __restrict__ Sp, const double* __restrict__ S2p,
                          float* __restrict__ muF, float* __restrict__ rF, int N) {
    int c = blockIdx.x;
    __shared__ double sh[256], sh2[256];
    sh[threadIdx.x]  = Sp[c * 256 + threadIdx.x];
    sh2[threadIdx.x] = S2p[c * 256 + threadIdx.x];
    __syncthreads();
    for (int o = 128; o > 0; o >>= 1) {
        if ((int)threadIdx.x < o) { sh[threadIdx.x] += sh[threadIdx.x + o]; sh2[threadIdx.x] += sh2[threadIdx.x + o]; }
        __syncthreads();
    }
    if (threadIdx.x == 0) {
        int M = N * 1024;
        double mean = sh[0] / M;
        double var  = sh2[0] / M - mean * mean;
        if (var < 0.0) var = 0.0;
        muF[c] = (float)mean;
        rF[c]  = 1.0f / sqrtf((float)var + 1e-5f);
    }
}

// 4 pixels/thread, float4 loads along hw (channels chunked x16 for VGPRs).
__global__ void k1_signpack(const float* __restrict__ v, const float* __restrict__ muF,
                            const float* __restrict__ rF, const float* __restrict__ g,
                            const float* __restrict__ b, u64* __restrict__ B,
                            u64* __restrict__ NZ, u64* __restrict__ aflag) {
    int gid = blockIdx.x * 64 + threadIdx.x;   // n*256 + hw4
    int n = gid >> 8, hw0 = (gid & 255) * 4;
    const float* vp = v + ((size_t)n * 64) * 1024 + hw0;
    u64 bb0 = 0, bb1 = 0, bb2 = 0, bb3 = 0;
    u64 nz0 = 0, nz1 = 0, nz2 = 0, nz3 = 0;
    for (int c0 = 0; c0 < 64; c0 += 16) {
        float4 buf[16];
#pragma unroll
        for (int j = 0; j < 16; ++j)
            buf[j] = *(const float4*)(vp + (size_t)(c0 + j) * 1024);
#pragma unroll
        for (int j = 0; j < 16; ++j) {
            int c = c0 + j;
            float mc = muF[c], rc = rF[c], gc = g[c], bc = b[c];
            float d0 = buf[j].x - mc; float t0 = (d0 * rc) * gc + bc;
            float d1 = buf[j].y - mc; float t1 = (d1 * rc) * gc + bc;
            float d2 = buf[j].z - mc; float t2 = (d2 * rc) * gc + bc;
            float d3 = buf[j].w - mc; float t3 = (d3 * rc) * gc + bc;
            bb0 |= (u64)(t0 > 0.f) << c;  nz0 |= (u64)(t0 != 0.f) << c;
            bb1 |= (u64)(t1 > 0.f) << c;  nz1 |= (u64)(t1 != 0.f) << c;
            bb2 |= (u64)(t2 > 0.f) << c;  nz2 |= (u64)(t2 != 0.f) << c;
            bb3 |= (u64)(t3 > 0.f) << c;  nz3 |= (u64)(t3 != 0.f) << c;
        }
    }
    size_t o = (size_t)n * 1024 + hw0;
    B[o]     = bb0; B[o + 1]  = bb1; B[o + 2]  = bb2; B[o + 3]  = bb3;
    NZ[o]    = nz0; NZ[o + 1] = nz1; NZ[o + 2] = nz2; NZ[o + 3] = nz3;
    flag_and_wave(aflag, nz0 & nz1 & nz2 & nz3);
}

// ---------- L1 fallback path (verbatim R13/R14) ----------
__global__ void k1_conv(const float* __restrict__ x, const float* __restrict__ w1,
                        float* __restrict__ out, int grp) {
    int hw = blockIdx.x * 64 + threadIdx.x;
    int cg = blockIdx.y;
    int n  = blockIdx.z;
    int co = grp * 8 + cg;
    int y = hw >> 5, x0 = hw & 31;
    const float* ip0 = x + ((size_t)n * 3 + 0) * 1024;
    const float* ip1 = x + ((size_t)n * 3 + 1) * 1024;
    const float* ip2 = x + ((size_t)n * 3 + 2) * 1024;
    const float* wp  = w1 + (size_t)co * 27;
    float acc = 0.f;
    for (int ky = 0; ky < 3; ++ky) {
        int yy = y + ky - 1;
        if (yy < 0 || yy > 31) continue;
        for (int kx = 0; kx < 3; ++kx) {
            int xc = x0 + kx - 1;
            if (xc < 0 || xc > 31) continue;
            int sp = yy * 32 + xc;
            int wk = ky * 3 + kx;
            float w0 = wp[wk], w1v = wp[9 + wk], w2 = wp[18 + wk];
            acc += (w0  > 0.f) ? ip0[sp] : ((w0  < 0.f) ? -ip0[sp] : 0.f);
            acc += (w1v > 0.f) ? ip1[sp] : ((w1v < 0.f) ? -ip1[sp] : 0.f);
            acc += (w2  > 0.f) ? ip2[sp] : ((w2  < 0.f) ? -ip2[sp] : 0.f);
        }
    }
    out[((size_t)n * 8 + cg) * 1024 + hw] = acc;
}

__device__ __forceinline__ float ld1(const float* v, int cg, int e) {
    return v[((size_t)(e >> 10) * 8 + cg) * 1024 + (e & 1023)];
}

__global__ void k1_stats(const float* __restrict__ v, float* __restrict__ muF,
                         float* __restrict__ rF, int grp, int N) {
    int cg = blockIdx.x;
    __shared__ double sh[256], sh2[256];
    double s = 0.0, s2 = 0.0;
    int M = N * 1024;
    for (int m = threadIdx.x; m < M; m += 256) {
        double t = (double)ld1(v, cg, m);
        s += t; s2 += t * t;
    }
    sh[threadIdx.x] = s; sh2[threadIdx.x] = s2;
    __syncthreads();
    for (int o = 128; o > 0; o >>= 1) {
        if ((int)threadIdx.x < o) { sh[threadIdx.x] += sh[threadIdx.x + o]; sh2[threadIdx.x] += sh2[threadIdx.x + o]; }
        __syncthreads();
    }
    if (threadIdx.x == 0) {
        double mean = sh[0] / M;
        double var  = sh2[0] / M - mean * mean;
        if (var < 0.0) var = 0.0;
        muF[grp * 8 + cg] = (float)mean;
        rF[grp * 8 + cg]  = 1.0f / sqrtf((float)var + 1e-5f);
    }
}

__global__ void k1_sign(const float* __restrict__ v, const float* __restrict__ muF,
                        const float* __restrict__ rF, const float* __restrict__ g,
                        const float* __restrict__ b, int8_t* __restrict__ sgn, int grp) {
    int hw = blockIdx.x * 256 + threadIdx.x;
    if (hw >= 1024) return;
    int cg = blockIdx.y, n = blockIdx.z;
    int c = grp * 8 + cg;
    float d  = v[((size_t)n * 8 + cg) * 1024 + hw] - muF[c];
    float t  = (d * rF[c]) * g[c] + b[c];
    sgn[((size_t)n * 64 + c) * 1024 + hw] = (int8_t)((t > 0.f) - (t < 0.f));
}

__global__ void kpack_sgn8(const int8_t* __restrict__ s, u64* __restrict__ B,
                           u64* __restrict__ NZ, int C, int HW, u64* __restrict__ aflag) {
    int hw = blockIdx.x * 64 + threadIdx.x;
    int wd = blockIdx.y, n = blockIdx.z;
    int WRD = C >> 6;
    u64 b = 0, nz = ~0ull;
    if (hw < HW) {
        nz = 0;
        const int8_t* sp = s + ((size_t)n * C + wd * 64) * HW + hw;
        for (int j = 0; j < 64; ++j) {
            int v = sp[(size_t)j * HW];
            b  |= (u64)(v > 0) << j;
            nz |= (u64)(v != 0) << j;
        }
        size_t o = ((size_t)n * HW + hw) * WRD + wd;
        B[o] = b; NZ[o] = nz;
    }
    flag_and_wave(aflag, nz);
}

// ---------- weight packing ----------
__global__ void kpack_wconv(const float* __restrict__ w, u64* __restrict__ WB,
                            u64* __restrict__ WNZ, int Ci, int Co, u64* __restrict__ flag) {
    int idx = blockIdx.x * 256 + threadIdx.x;
    int WRD = Ci >> 6;
    u64 b = 0, nz = ~0ull;
    if (idx < Co * 9 * WRD) {
        nz = 0;
        int wd = idx % WRD, t = (idx / WRD) % 9, co = idx / (9 * WRD);
        const float* wp = w + ((size_t)co * Ci + wd * 64) * 9 + t;
        float buf[64];
#pragma unroll
        for (int j = 0; j < 64; ++j) buf[j] = wp[(size_t)j * 9];
#pragma unroll
        for (int j = 0; j < 64; ++j) {
            b  |= (u64)(buf[j] > 0.f) << j;
            nz |= (u64)(buf[j] != 0.f) << j;
        }
        WB[idx] = b; WNZ[idx] = nz;
    }
    flag_and_wave(flag, nz);
}

// linear weights [O,K] float -> TRANSPOSED packed [wd*O + o]
__global__ void kpack_wlinT(const float* __restrict__ w, u64* __restrict__ WBt,
                            u64* __restrict__ WZt, int K, int O, u64* __restrict__ flag) {
    int idx = blockIdx.x * 256 + threadIdx.x;
    int WRD = K >> 6;
    u64 b = 0, nz = ~0ull;
    if (idx < O * WRD) {
        nz = 0;
        int wd = idx % WRD, o = idx / WRD;
        const float* wp = w + (size_t)o * K + wd * 64;
#pragma unroll 8
        for (int j = 0; j < 64; ++j) {
            float v = wp[j];
            b  |= (u64)(v > 0.f) << j;
            nz |= (u64)(v != 0.f) << j;
        }
        WBt[(size_t)wd * O + o] = b; WZt[(size_t)wd * O + o] = nz;
    }
    flag_and_wave(flag, nz);
}

// ---------- binary conv cores ----------
template <int WRD, int CB>
__device__ __forceinline__ void conv_slow(const u64* __restrict__ ib, const u64* __restrict__ iz,
                                          const u64* __restrict__ wbp, const u64* __restrict__ wzp,
                                          int H, int Wi, int y, int x, int* acc) {
#pragma unroll
    for (int c = 0; c < CB; ++c) acc[c] = 0;
    for (int ky = 0; ky < 3; ++ky) {
        int yy = y + ky - 1;
        if ((unsigned)yy >= (unsigned)H) continue;
        for (int kx = 0; kx < 3; ++kx) {
            int xc = x + kx - 1;
            if ((unsigned)xc >= (unsigned)Wi) continue;
            int p = yy * Wi + xc, t = ky * 3 + kx;
            u64 xb[WRD], xz[WRD];
#pragma unroll
            for (int w = 0; w < WRD; ++w) {
                xb[w] = ib[(size_t)p * WRD + w];
                xz[w] = iz[(size_t)p * WRD + w];
            }
#pragma unroll
            for (int c = 0; c < CB; ++c) {
#pragma unroll
                for (int w = 0; w < WRD; ++w) {
                    u64 e = xz[w] & wzp[(c * 9 + t) * WRD + w];
                    acc[c] += __popcll(e) - 2 * __popcll((xb[w] ^ wbp[(c * 9 + t) * WRD + w]) & e);
                }
            }
        }
    }
}

template <int WRD, int CB>
__device__ __forceinline__ void conv_fast(const u64* __restrict__ ib,
                                          const u64* __restrict__ wbp,
                                          int H, int Wi, int y, int x, int* acc) {
    int a2[CB];
#pragma unroll
    for (int c = 0; c < CB; ++c) a2[c] = 0;
    int T = 0;
    for (int ky = 0; ky < 3; ++ky) {
        int yy = y + ky - 1;
        if ((unsigned)yy >= (unsigned)H) continue;
        for (int kx = 0; kx < 3; ++kx) {
            int xc = x + kx - 1;
            if ((unsigned)xc >= (unsigned)Wi) continue;
            int p = yy * Wi + xc, t = ky * 3 + kx;
            ++T;
            u64 xb[WRD];
#pragma unroll
            for (int w = 0; w < WRD; ++w) xb[w] = ib[(size_t)p * WRD + w];
#pragma unroll
            for (int c = 0; c < CB; ++c)
#pragma unroll
                for (int w = 0; w < WRD; ++w)
                    a2[c] += __popcll(xb[w] ^ wbp[(c * 9 + t) * WRD + w]);
        }
    }
#pragma unroll
    for (int c = 0; c < CB; ++c) acc[c] = 64 * WRD * T - 2 * a2[c];
}

template <int WRD, int CB>
__global__ void kbconv2(const u64* __restrict__ B, const u64* __restrict__ NZ,
                        const u64* __restrict__ WB, const u64* __restrict__ WNZ,
                        int16_t* __restrict__ out, int Co, int H, int Wi,
                        const u64* __restrict__ wflag, const u64* __restrict__ aflag) {
    int hw = blockIdx.x * 64 + threadIdx.x;
    if (hw >= H * Wi) return;
    int co0 = blockIdx.y * CB, n = blockIdx.z;
    int y = hw / Wi, x = hw % Wi;
    const u64* ib = B  + (size_t)n * H * Wi * WRD;
    const u64* iz = NZ + (size_t)n * H * Wi * WRD;
    const u64* wbp = WB  + (size_t)co0 * 9 * WRD;
    const u64* wzp = WNZ + (size_t)co0 * 9 * WRD;
    bool fast = ((*wflag) & (*aflag)) == ~0ull;
    int acc[CB];
    if (fast) conv_fast<WRD, CB>(ib, wbp, H, Wi, y, x, acc);
    else      conv_slow<WRD, CB>(ib, iz, wbp, wzp, H, Wi, y, x, acc);
#pragma unroll
    for (int c = 0; c < CB; ++c)
        out[((size_t)n * Co + co0 + c) * H * Wi + hw] = (int16_t)acc[c];
}

template <int WRD, int CB>
__global__ void kbconv_pool2(const u64* __restrict__ B, const u64* __restrict__ NZ,
                             const u64* __restrict__ WB, const u64* __restrict__ WNZ,
                             int16_t* __restrict__ out, int Co, int H, int Wi,
                             const u64* __restrict__ wflag, const u64* __restrict__ aflag) {
    int Ho = H >> 1, Wo = Wi >> 1;
    int hw = blockIdx.x * 64 + threadIdx.x;
    if (hw >= Ho * Wo) return;
    int co0 = blockIdx.y * CB, n = blockIdx.z;
    int yo = hw / Wo, xo = hw % Wo;
    const u64* ib = B  + (size_t)n * H * Wi * WRD;
    const u64* iz = NZ + (size_t)n * H * Wi * WRD;
    const u64* wbp = WB  + (size_t)co0 * 9 * WRD;
    const u64* wzp = WNZ + (size_t)co0 * 9 * WRD;
    bool fast = ((*wflag) & (*aflag)) == ~0ull;
    int best[CB];
#pragma unroll
    for (int c = 0; c < CB; ++c) best[c] = -(1 << 30);
    if (fast) {
        for (int dy = 0; dy < 2; ++dy)
            for (int dx = 0; dx < 2; ++dx) {
                int acc[CB];
                conv_fast<WRD, CB>(ib, wbp, H, Wi, 2 * yo + dy, 2 * xo + dx, acc);
#pragma unroll
                for (int c = 0; c < CB; ++c) best[c] = acc[c] > best[c] ? acc[c] : best[c];
            }
    } else {
        for (int dy = 0; dy < 2; ++dy)
            for (int dx = 0; dx < 2; ++dx) {
                int acc[CB];
                conv_slow<WRD, CB>(ib, iz, wbp, wzp, H, Wi, 2 * yo + dy, 2 * xo + dx, acc);
#pragma unroll
                for (int c = 0; c < CB; ++c) best[c] = acc[c] > best[c] ? acc[c] : best[c];
            }
    }
#pragma unroll
    for (int c = 0; c < CB; ++c)
        out[((size_t)n * Co + co0 + c) * Ho * Wo + hw] = (int16_t)best[c];
}

// pool variant for Ho*Wo==16: 64 lanes = 16 pixels x 4 pool positions.
template <int WRD, int CB>
__global__ void kbconv_pool2s(const u64* __restrict__ B, const u64* __restrict__ NZ,
                              const u64* __restrict__ WB, const u64* __restrict__ WNZ,
                              int16_t* __restrict__ out, int Co, int H, int Wi,
                              const u64* __restrict__ wflag, const u64* __restrict__ aflag) {
    int Ho = H >> 1, Wo = Wi >> 1;       // Ho*Wo == 16
    int t0 = threadIdx.x;
    int pix = t0 & 15, pos = t0 >> 4;    // pos 0..3
    int co0 = blockIdx.y * CB, n = blockIdx.z;
    int yo = pix / Wo, xo = pix % Wo;
    int y = 2 * yo + (pos >> 1), x = 2 * xo + (pos & 1);
    const u64* ib = B  + (size_t)n * H * Wi * WRD;
    const u64* iz = NZ + (size_t)n * H * Wi * WRD;
    const u64* wbp = WB  + (size_t)co0 * 9 * WRD;
    const u64* wzp = WNZ + (size_t)co0 * 9 * WRD;
    bool fast = ((*wflag) & (*aflag)) == ~0ull;
    int acc[CB];
    if (fast) conv_fast<WRD, CB>(ib, wbp, H, Wi, y, x, acc);
    else      conv_slow<WRD, CB>(ib, iz, wbp, wzp, H, Wi, y, x, acc);
#pragma unroll
    for (int c = 0; c < CB; ++c) {
        int v = acc[c];
        int v1 = __shfl_xor(v, 16); v = v1 > v ? v1 : v;
        int v2 = __shfl_xor(v, 32); v = v2 > v ? v2 : v;
        acc[c] = v;
    }
    if (pos == 0) {
#pragma unroll
        for (int c = 0; c < CB; ++c)
            out[((size_t)n * Co + co0 + c) * Ho * Wo + pix] = (int16_t)acc[c];
    }
}

// ---------- conv BN stats (int64, order-free => regrouping exact) ----------
__global__ void kaccum16(const int16_t* __restrict__ v, long long* __restrict__ Sp,
                         long long* __restrict__ S2p, int C, int HW, int M) {
    int c = blockIdx.x;
    long long s = 0, s2 = 0;
    int M8 = M >> 3;
    for (int g = blockIdx.y * 256 + threadIdx.x; g < M8; g += gridDim.y * 256) {
        int m0 = g * 8;
        const int16_t* p = v + ((size_t)(m0 / HW) * C + c) * HW + (m0 % HW);
        short4 a = *(const short4*)p;
        short4 b = *(const short4*)(p + 4);
        int v0 = a.x, v1 = a.y, v2 = a.z, v3 = a.w;
        int v4 = b.x, v5 = b.y, v6 = b.z, v7 = b.w;
        s  += v0 + v1 + v2 + v3 + v4 + v5 + v6 + v7;
        s2 += (long long)v0 * v0 + (long long)v1 * v1 + (long long)v2 * v2 + (long long)v3 * v3
            + (long long)v4 * v4 + (long long)v5 * v5 + (long long)v6 * v6 + (long long)v7 * v7;
    }
    __shared__ long long sh[256], sh2[256];
    sh[threadIdx.x] = s; sh2[threadIdx.x] = s2;
    __syncthreads();
    for (int o = 128; o > 0; o >>= 1) {
        if ((int)threadIdx.x < o) { sh[threadIdx.x] += sh[threadIdx.x + o]; sh2[threadIdx.x] += sh2[threadIdx.x + o]; }
        __syncthreads();
    }
    if (threadIdx.x == 0) {
        Sp[c * gridDim.y + blockIdx.y]  = sh[0];
        S2p[c * gridDim.y + blockIdx.y] = sh2[0];
    }
}

__global__ void kfinal2(const long long* __restrict__ Sp, const long long* __restrict__ S2p,
                        int NB, const float* __restrict__ g, const float* __restrict__ b,
                        double* __restrict__ mu, double* __restrict__ Ad,
                        double* __restrict__ Bd, int C, int M) {
    int c = blockIdx.x * 64 + threadIdx.x;
    if (c >= C) return;
    long long s = 0, s2 = 0;
    for (int i = 0; i < NB; ++i) { s += Sp[c * NB + i]; s2 += S2p[c * NB + i]; }
    double mean = (double)s / M;
    double var  = (double)s2 / M - mean * mean;
    if (var < 0.0) var = 0.0;
    mu[c] = mean;
    Ad[c] = (g ? (double)g[c] : 1.0) / sqrt(var + 1e-5);
    Bd[c] = b ? (double)b[c] : 0.0;
}

// ---------- BN sign + pack: 4 pixels/thread via short4 ----------
__global__ void ksp_conv(const int16_t* __restrict__ v, const double* __restrict__ mu,
                         const double* __restrict__ Ad, const double* __restrict__ Bd,
                         u64* __restrict__ B, u64* __restrict__ NZ, int C, int HW, int N,
                         u64* __restrict__ aflag) {
    int tid = blockIdx.x * 64 + threadIdx.x;
    int WRD = C >> 6;
    int HW4 = HW >> 2;
    int total = N * WRD * HW4;
    u64 nzall = ~0ull;
    if (tid < total) {
        int hw4 = tid % HW4;
        int wd  = (tid / HW4) % WRD;
        int n   = tid / (HW4 * WRD);
        const int16_t* vp = v + ((size_t)n * C + wd * 64) * HW + hw4 * 4;
        u64 b0 = 0, b1 = 0, b2 = 0, b3 = 0;
        u64 n0 = 0, n1 = 0, n2 = 0, n3 = 0;
        for (int j0 = 0; j0 < 64; j0 += 16) {
            short4 buf[16];
#pragma unroll
            for (int j = 0; j < 16; ++j)
                buf[j] = *(const short4*)(vp + (size_t)(j0 + j) * HW);
#pragma unroll
            for (int j = 0; j < 16; ++j) {
                int c = wd * 64 + j0 + j;
                double Mu = mu[c], A = Ad[c], Bb = Bd[c];
                double t0 = ((double)buf[j].x - Mu) * A + Bb;
                double t1 = ((double)buf[j].y - Mu) * A + Bb;
                double t2 = ((double)buf[j].z - Mu) * A + Bb;
                double t3 = ((double)buf[j].w - Mu) * A + Bb;
                int sh = j0 + j;
                b0 |= (u64)(t0 > 0.0) << sh;  n0 |= (u64)(t0 != 0.0) << sh;
                b1 |= (u64)(t1 > 0.0) << sh;  n1 |= (u64)(t1 != 0.0) << sh;
                b2 |= (u64)(t2 > 0.0) << sh;  n2 |= (u64)(t2 != 0.0) << sh;
                b3 |= (u64)(t3 > 0.0) << sh;  n3 |= (u64)(t3 != 0.0) << sh;
            }
        }
        size_t o = ((size_t)n * HW + hw4 * 4) * WRD + wd;
        B[o] = b0;  B[o + WRD] = b1;  B[o + 2 * WRD] = b2;  B[o + 3 * WRD] = b3;
        NZ[o] = n0; NZ[o + WRD] = n1; NZ[o + 2 * WRD] = n2; NZ[o + 3 * WRD] = n3;
        nzall = n0 & n1 & n2 & n3;
    }
    flag_and_wave(aflag, nzall);
}

__global__ void ksp_flat(const int16_t* __restrict__ v, const double* __restrict__ mu,
                         const double* __restrict__ Ad, const double* __restrict__ Bd,
                         u64* __restrict__ B, u64* __restrict__ NZ, u64* __restrict__ aflag) {
    int wd = threadIdx.x;
    int n  = blockIdx.x;
    const int16_t* vp = v + (size_t)n * 4096 + wd * 64;
    int16_t buf[64];
#pragma unroll
    for (int j = 0; j < 64; ++j) buf[j] = vp[j];
    u64 b = 0, nz = 0;
#pragma unroll
    for (int j = 0; j < 64; ++j) {
        int k = wd * 64 + j;
        int c = k >> 4;
        double t = ((double)buf[j] - mu[c]) * Ad[c] + Bd[c];
        b  |= (u64)(t > 0.0) << j;
        nz |= (u64)(t != 0.0) << j;
    }
    B[(size_t)n * 64 + wd] = b; NZ[(size_t)n * 64 + wd] = nz;
    flag_and_wave(aflag, nz);
}

__global__ void ksp_fc(const int* __restrict__ v, const double* __restrict__ mu,
                       const double* __restrict__ Ad, const double* __restrict__ Bd,
                       u64* __restrict__ B, u64* __restrict__ NZ, int C, int WRD, int N,
                       u64* __restrict__ aflag) {
    int tid = blockIdx.x * 64 + threadIdx.x;
    u64 nz = ~0ull;
    if (tid < N * WRD) {
        int n = tid / WRD, wd = tid % WRD;
        const int* vp = v + (size_t)n * C + wd * 64;
        int buf[64];
#pragma unroll
        for (int j = 0; j < 64; ++j) buf[j] = vp[j];
        u64 b = 0; nz = 0;
#pragma unroll
        for (int j = 0; j < 64; ++j) {
            int c = wd * 64 + j;
            double t = ((double)buf[j] - mu[c]) * Ad[c] + Bd[c];
            b  |= (u64)(t > 0.0) << j;
            nz |= (u64)(t != 0.0) << j;
        }
        B[(size_t)n * WRD + wd] = b; NZ[(size_t)n * WRD + wd] = nz;
    }
    flag_and_wave(aflag, nz);
}

// ---------- binary FC: transposed coalesced weights + dense fast path ----------
__global__ void kbfc(const u64* __restrict__ aB, const u64* __restrict__ aNZ,
                     const u64* __restrict__ wBt, const u64* __restrict__ wZt,
                     int* __restrict__ out, int WRD, int O,
                     const u64* __restrict__ wflag, const u64* __restrict__ aflag) {
    int o = blockIdx.x * 64 + threadIdx.x;
    if (o >= O) return;
    int n = blockIdx.y;
    const u64* ab = aB  + (size_t)n * WRD;
    const u64* az = aNZ + (size_t)n * WRD;
    bool fast = ((*wflag) & (*aflag)) == ~0ull;
    int acc;
    if (fast) {
        int a2 = 0;
        for (int w = 0; w < WRD; w += 8) {
            u64 aw[8], ww[8];
#pragma unroll
            for (int j = 0; j < 8; ++j) {
                aw[j] = ab[w + j];
                ww[j] = wBt[(size_t)(w + j) * O + o];
            }
#pragma unroll
            for (int j = 0; j < 8; ++j) a2 += __popcll(aw[j] ^ ww[j]);
        }
        acc = 64 * WRD - 2 * a2;
    } else {
        acc = 0;
        for (int w = 0; w < WRD; ++w) {
            u64 wb = wBt[(size_t)w * O + o];
            u64 wz = wZt[(size_t)w * O + o];
            u64 e = az[w] & wz;
            acc += __popcll(e) - 2 * __popcll((ab[w] ^ wb) & e);
        }
    }
    out[(size_t)n * O + o] = acc;
}

// ---------- FC stats / output ----------
__global__ void k3_stats(const int* __restrict__ v, int N, int C,
                         const float* __restrict__ g, const float* __restrict__ b,
                         double* __restrict__ mu, double* __restrict__ Ad,
                         double* __restrict__ Bd) {
    int c = blockIdx.x;
    __shared__ double sh[256], sh2[256];
    double s = 0.0, s2 = 0.0;
    for (int n = threadIdx.x; n < N; n += 256) {
        double t = (double)v[(size_t)n * C + c];
        s += t; s2 += t * t;
    }
    sh[threadIdx.x] = s; sh2[threadIdx.x] = s2;
    __syncthreads();
    for (int o = 128; o > 0; o >>= 1) {
        if ((int)threadIdx.x < o) { sh[threadIdx.x] += sh[threadIdx.x + o]; sh2[threadIdx.x] += sh2[threadIdx.x + o]; }
        __syncthreads();
    }
    if (threadIdx.x == 0) {
        double mean = sh[0] / N;
        double var  = sh2[0] / N - mean * mean;
        if (var < 0.0) var = 0.0;
        mu[c] = mean;
        Ad[c] = (g ? (double)g[c] : 1.0) / sqrt(var + 1e-5);
        Bd[c] = b ? (double)b[c] : 0.0;
    }
}

__global__ void k4_out(const int* __restrict__ v, const double* __restrict__ mu,
                       const double* __restrict__ Ad, float* __restrict__ out, int N) {
    int n = blockIdx.x * 256 + threadIdx.x;
    if (n >= N) return;
    double z[10];
    double mx = -1e300;
    for (int o = 0; o < 10; ++o) {
        z[o] = ((double)v[n * 10 + o] - mu[o]) * Ad[o];
        if (z[o] > mx) mx = z[o];
    }
    double s = 0.0;
    for (int o = 0; o < 10; ++o) s += exp(z[o] - mx);
    double l = mx + log(s);
    for (int o = 0; o < 10; ++o) out[n * 10 + o] = (float)(z[o] - l);
}

// ---------------- host ----------------
extern "C" void kernel_launch(void* const* d_in, const int* in_sizes, int n_in,
                              void* d_out, int out_size, void* d_ws, size_t ws_size,
                              hipStream_t stream) {
    const int N = in_sizes[0] / (3 * 32 * 32);   // 512

    const float* x   = (const float*)d_in[0];
    const float* w1  = (const float*)d_in[1];
    const float* g1  = (const float*)d_in[2];
    const float* b1  = (const float*)d_in[3];
    const float* w2  = (const float*)d_in[4];
    const float* g2  = (const float*)d_in[5];
    const float* b2  = (const float*)d_in[6];
    const float* w3  = (const float*)d_in[7];
    const float* g3  = (const float*)d_in[8];
    const float* b3  = (const float*)d_in[9];
    const float* w4  = (const float*)d_in[10];
    const float* g4  = (const float*)d_in[11];
    const float* b4  = (const float*)d_in[12];
    const float* w5  = (const float*)d_in[13];
    const float* g5  = (const float*)d_in[14];
    const float* b5  = (const float*)d_in[15];
    const float* w6  = (const float*)d_in[16];
    const float* g6  = (const float*)d_in[17];
    const float* b6  = (const float*)d_in[18];
    const float* wf1 = (const float*)d_in[19];
    const float* gf1 = (const float*)d_in[20];
    const float* bf1 = (const float*)d_in[21];
    const float* wf2 = (const float*)d_in[22];
    const float* gf2 = (const float*)d_in[23];
    const float* bf2 = (const float*)d_in[24];
    const float* wf3 = (const float*)d_in[25];

    char* ws = (char*)d_ws;
    size_t off = 0;
    auto alloc = [&](size_t bytes) -> char* {
        char* p = ws + off;
        off = (off + bytes + 511) & ~(size_t)511;
        return p;
    };

    // ---- DOWN region: all post-L1 buffers at distinct offsets ----
    int16_t* t2  = (int16_t*)alloc((size_t)N * 64 * 256 * 2);
    u64* p2B = (u64*)alloc((size_t)N * 256 * 8);
    u64* p2Z = (u64*)alloc((size_t)N * 256 * 8);
    int16_t* t3  = (int16_t*)alloc((size_t)N * 128 * 256 * 2);
    u64* p3B = (u64*)alloc((size_t)N * 256 * 2 * 8);
    u64* p3Z = (u64*)alloc((size_t)N * 256 * 2 * 8);
    int16_t* t4  = (int16_t*)alloc((size_t)N * 128 * 64 * 2);
    u64* p4B = (u64*)alloc((size_t)N * 64 * 2 * 8);
    u64* p4Z = (u64*)alloc((size_t)N * 64 * 2 * 8);
    int16_t* t5  = (int16_t*)alloc((size_t)N * 256 * 64 * 2);
    u64* p5B = (u64*)alloc((size_t)N * 64 * 4 * 8);
    u64* p5Z = (u64*)alloc((size_t)N * 64 * 4 * 8);
    int16_t* t6  = (int16_t*)alloc((size_t)N * 256 * 16 * 2);
    u64* p6B = (u64*)alloc((size_t)N * 64 * 8);
    u64* p6Z = (u64*)alloc((size_t)N * 64 * 8);
    int* fc1 = (int*)alloc((size_t)N * 512 * 4);
    int* fc2 = (int*)alloc((size_t)N * 512 * 4);
    int* fc3 = (int*)alloc((size_t)N * 10 * 4);
    u64* pF1B = (u64*)alloc((size_t)N * 8 * 8);
    u64* pF1Z = (u64*)alloc((size_t)N * 8 * 8);
    u64* pF2B = (u64*)alloc((size_t)N * 8 * 8);
    u64* pF2Z = (u64*)alloc((size_t)N * 8 * 8);
    size_t down_end = off;

    // ---- L1 head overlays (dead before any DOWN buffer is written) ----
    size_t head_big = (size_t)N * 64 * 1024 * 4;      // 134.2MB f32, 64 channels
    bool big = ws_size >= head_big + ((size_t)20 << 20);
    float*  c1buf = (float*)ws;                        // big: [N][64][1024]
    float*  c1buf8 = (float*)ws;                       // fallback: [N][8][1024]
    int8_t* sgnA  = (int8_t*)(ws + (size_t)N * 8 * 1024 * 4);  // fallback only

    // ---- tail (coexists with L1 head) ----
    off = big ? (head_big > down_end ? head_big : down_end) : down_end;
    off = (off + 511) & ~(size_t)511;
    u64* p1B = (u64*)alloc((size_t)N * 1024 * 8);
    u64* p1Z = (u64*)alloc((size_t)N * 1024 * 8);
    u64* wb2B = (u64*)alloc(64  * 9 * 1 * 8);  u64* wb2Z = (u64*)alloc(64  * 9 * 1 * 8);
    u64* wb3B = (u64*)alloc(128 * 9 * 1 * 8);  u64* wb3Z = (u64*)alloc(128 * 9 * 1 * 8);
    u64* wb4B = (u64*)alloc(128 * 9 * 2 * 8);  u64* wb4Z = (u64*)alloc(128 * 9 * 2 * 8);
    u64* wb5B = (u64*)alloc(256 * 9 * 2 * 8);  u64* wb5Z = (u64*)alloc(256 * 9 * 2 * 8);
    u64* wb6B = (u64*)alloc(256 * 9 * 4 * 8);  u64* wb6Z = (u64*)alloc(256 * 9 * 4 * 8);
    u64* wf1B = (u64*)alloc(512 * 64 * 8);     u64* wf1Z = (u64*)alloc(512 * 64 * 8);
    u64* wf2B = (u64*)alloc(512 * 8 * 8);      u64* wf2Z = (u64*)alloc(512 * 8 * 8);
    u64* wf3B = (u64*)alloc(10 * 8 * 8);       u64* wf3Z = (u64*)alloc(10 * 8 * 8);
    float* wt = (float*)alloc(27 * 64 * 4);
    double* Sp  = (double*)alloc(64 * 256 * 8);
    double* S2p = (double*)alloc(64 * 256 * 8);
    long long* SpI  = (long long*)alloc(256 * 32 * 8);
    long long* S2pI = (long long*)alloc(256 * 32 * 8);
    u64* flags = (u64*)alloc(16 * 8);
    // [0..4]=wconv L2..L6, [5..7]=wlin FC1..FC3, [8..12]=act L1..L5,
    // [13]=act flat(L6), [14]=act FC1sign, [15]=act FC2sign
    double* mu = (double*)alloc(512 * 8);
    double* Ad = (double*)alloc(512 * 8);
    double* Bd = (double*)alloc(512 * 8);
    float*  muF = (float*)alloc(64 * 4);
    float*  rF  = (float*)alloc(64 * 4);

    auto cdiv = [](int a, int b) { return (a + b - 1) / b; };

    // ---- flags + pack weights ----
    kflag_init<<<1, 64, 0, stream>>>(flags);
    kpack_wconv<<<cdiv(64 * 9 * 1, 256), 256, 0, stream>>>(w2, wb2B, wb2Z, 64, 64, &flags[0]);
    kpack_wconv<<<cdiv(128 * 9 * 1, 256), 256, 0, stream>>>(w3, wb3B, wb3Z, 64, 128, &flags[1]);
    kpack_wconv<<<cdiv(128 * 9 * 2, 256), 256, 0, stream>>>(w4, wb4B, wb4Z, 128, 128, &flags[2]);
    kpack_wconv<<<cdiv(256 * 9 * 2, 256), 256, 0, stream>>>(w5, wb5B, wb5Z, 128, 256, &flags[3]);
    kpack_wconv<<<cdiv(256 * 9 * 4, 256), 256, 0, stream>>>(w6, wb6B, wb6Z, 256, 256, &flags[4]);
    kpack_wlinT<<<cdiv(512 * 64, 256), 256, 0, stream>>>(wf1, wf1B, wf1Z, 4096, 512, &flags[5]);
    kpack_wlinT<<<cdiv(512 * 8, 256), 256, 0, stream>>>(wf2, wf2B, wf2Z, 512, 512, &flags[6]);
    kpack_wlinT<<<cdiv(10 * 8, 256), 256, 0, stream>>>(wf3, wf3B, wf3Z, 512, 10, &flags[7]);

    // ---- L1 ----
    if (big) {
        kw1t<<<27, 64, 0, stream>>>(w1, wt);
        k1_conv_all<<<(N * 1024) / 256, 256, 0, stream>>>(x, wt, c1buf);
        k1_statsA<<<dim3(64, 4), 64, 0, stream>>>(c1buf, Sp, S2p, N);
        k1_statsB<<<64, 256, 0, stream>>>(Sp, S2p, muF, rF, N);
        k1_signpack<<<(N * 256) / 64, 64, 0, stream>>>(c1buf, muF, rF, g1, b1, p1B, p1Z, &flags[8]);
    } else {
        for (int grp = 0; grp < 8; ++grp) {
            k1_conv<<<dim3(16, 8, N), 64, 0, stream>>>(x, w1, c1buf8, grp);
            k1_stats<<<8, 256, 0, stream>>>(c1buf8, muF, rF, grp, N);
            k1_sign<<<dim3(4, 8, N), 256, 0, stream>>>(c1buf8, muF, rF, g1, b1, sgnA, grp);
        }
        kpack_sgn8<<<dim3(16, 1, N), 64, 0, stream>>>(sgnA, p1B, p1Z, 64, 1024, &flags[8]);
    }

    // ---- L2: conv+pool (Ci=64, 32x32 -> 16x16) ----
    kbconv_pool2<1, 8><<<dim3(4, 8, N), 64, 0, stream>>>(p1B, p1Z, wb2B, wb2Z, t2, 64, 32, 32, &flags[0], &flags[8]);
    kaccum16<<<dim3(64, 32), 256, 0, stream>>>(t2, SpI, S2pI, 64, 256, N * 256);
    kfinal2<<<1, 64, 0, stream>>>(SpI, S2pI, 32, g2, b2, mu, Ad, Bd, 64, N * 256);
    ksp_conv<<<cdiv(N * 1 * 64, 64), 64, 0, stream>>>(t2, mu, Ad, Bd, p2B, p2Z, 64, 256, N, &flags[9]);

    // ---- L3: conv (Ci=64, 16x16) ----
    kbconv2<1, 8><<<dim3(4, 16, N), 64, 0, stream>>>(p2B, p2Z, wb3B, wb3Z, t3, 128, 16, 16, &flags[1], &flags[9]);
    kaccum16<<<dim3(128, 16), 256, 0, stream>>>(t3, SpI, S2pI, 128, 256, N * 256);
    kfinal2<<<2, 64, 0, stream>>>(SpI, S2pI, 16, g3, b3, mu, Ad, Bd, 128, N * 256);
    ksp_conv<<<cdiv(N * 2 * 64, 64), 64, 0, stream>>>(t3, mu, Ad, Bd, p3B, p3Z, 128, 256, N, &flags[10]);

    // ---- L4: conv+pool (Ci=128, 16x16 -> 8x8) ----
    kbconv_pool2<2, 8><<<dim3(1, 16, N), 64, 0, stream>>>(p3B, p3Z, wb4B, wb4Z, t4, 128, 16, 16, &flags[2], &flags[10]);
    kaccum16<<<dim3(128, 16), 256, 0, stream>>>(t4, SpI, S2pI, 128, 64, N * 64);
    kfinal2<<<2, 64, 0, stream>>>(SpI, S2pI, 16, g4, b4, mu, Ad, Bd, 128, N * 64);
    ksp_conv<<<cdiv(N * 2 * 16, 64), 64, 0, stream>>>(t4, mu, Ad, Bd, p4B, p4Z, 128, 64, N, &flags[11]);

    // ---- L5: conv (Ci=128, 8x8) ----
    kbconv2<2, 8><<<dim3(1, 32, N), 64, 0, stream>>>(p4B, p4Z, wb5B, wb5Z, t5, 256, 8, 8, &flags[3], &flags[11]);
    kaccum16<<<dim3(256, 8), 256, 0, stream>>>(t5, SpI, S2pI, 256, 64, N * 64);
    kfinal2<<<4, 64, 0, stream>>>(SpI, S2pI, 8, g5, b5, mu, Ad, Bd, 256, N * 64);
    ksp_conv<<<cdiv(N * 4 * 16, 64), 64, 0, stream>>>(t5, mu, Ad, Bd, p5B, p5Z, 256, 64, N, &flags[12]);

    // ---- L6: conv+pool (Ci=256, 8x8 -> 4x4), positions-in-lanes ----
    kbconv_pool2s<4, 8><<<dim3(1, 32, N), 64, 0, stream>>>(p5B, p5Z, wb6B, wb6Z, t6, 256, 8, 8, &flags[4], &flags[12]);
    kaccum16<<<dim3(256, 2), 256, 0, stream>>>(t6, SpI, S2pI, 256, 16, N * 16);
    kfinal2<<<4, 64, 0, stream>>>(SpI, S2pI, 2, g6, b6, mu, Ad, Bd, 256, N * 16);
    ksp_flat<<<N, 64, 0, stream>>>(t6, mu, Ad, Bd, p6B, p6Z, &flags[13]);

    // ---- FC1 ----
    kbfc<<<dim3(8, N), 64, 0, stream>>>(p6B, p6Z, wf1B, wf1Z, fc1, 64, 512, &flags[5], &flags[13]);
    k3_stats<<<512, 256, 0, stream>>>(fc1, N, 512, gf1, bf1, mu, Ad, Bd);
    ksp_fc<<<cdiv(N * 8, 64), 64, 0, stream>>>(fc1, mu, Ad, Bd, pF1B, pF1Z, 512, 8, N, &flags[14]);

    // ---- FC2 ----
    kbfc<<<dim3(8, N), 64, 0, stream>>>(pF1B, pF1Z, wf2B, wf2Z, fc2, 8, 512, &flags[6], &flags[14]);
    k3_stats<<<512, 256, 0, stream>>>(fc2, N, 512, gf2, bf2, mu, Ad, Bd);
    ksp_fc<<<cdiv(N * 8, 64), 64, 0, stream>>>(fc2, mu, Ad, Bd, pF2B, pF2Z, 512, 8, N, &flags[15]);

    // ---- FC3 + bn(no affine) + log_softmax ----
    kbfc<<<dim3(1, N), 64, 0, stream>>>(pF2B, pF2Z, wf3B, wf3Z, fc3, 8, 10, &flags[7], &flags[15]);
    k3_stats<<<10, 256, 0, stream>>>(fc3, N, 10, nullptr, nullptr, mu, Ad, Bd);
    k4_out<<<cdiv(N, 256), 256, 0, stream>>>(fc3, mu, Ad, (float*)d_out, N);
}

// Round 10
// 665.135 us; speedup vs baseline: 84.1876x; 1.0222x over previous
//
#include <hip/hip_runtime.h>
#include <stdint.h>
#include <math.h>

// Round 23 = R22 + two changes:
// - k1_conv_all4: 4 pixels x 16 channels per thread, float4 stores (the old
//   kernel was store-issue-bound: 64 scalar f32 stores at 4KB stride). The
//   per-output fmaf chain is token-order identical ((ky,kx) outer, ci inner,
//   one f32 acc) => bit-exact.
// - kpack_all: all 8 weight-pack launches fused into one 216-block kernel
//   (verbatim bodies, whole-block segments; flags unchanged).
// All other kernels verbatim R22.

typedef unsigned long long u64;

__device__ __forceinline__ void flag_and_wave(u64* flag, u64 nz) {
    nz &= __shfl_xor(nz, 1);
    nz &= __shfl_xor(nz, 2);
    nz &= __shfl_xor(nz, 4);
    nz &= __shfl_xor(nz, 8);
    nz &= __shfl_xor(nz, 16);
    nz &= __shfl_xor(nz, 32);
    if ((threadIdx.x & 63) == 0) atomicAnd(flag, nz);
}

__global__ void kflag_init(u64* __restrict__ f) {
    int i = threadIdx.x;
    if (i < 16) f[i] = ~0ull;
}

// ---------- L1 ----------
__global__ void kw1t(const float* __restrict__ w1, float* __restrict__ wt) {
    int i = blockIdx.x * 64 + threadIdx.x;     // 64*27
    if (i >= 64 * 27) return;
    int co = i / 27, k = i % 27;
    float v = w1[i];
    wt[k * 64 + co] = (v > 0.f) ? 1.f : ((v < 0.f) ? -1.f : 0.f);
}

// 4 pixels x 16 channels per thread; float4 stores. Chain per output is
// token-order identical to R16..R22: (ky,kx) lexicographic outer, ci inner.
__global__ __launch_bounds__(64) void k1_conv_all4(const float* __restrict__ x,
                                                   const float* __restrict__ wt,
                                                   float* __restrict__ out) {
    int gid = blockIdx.x * 64 + threadIdx.x;   // n*256 + hw4
    int n = gid >> 8, hw0 = (gid & 255) * 4;
    int c0 = blockIdx.y * 16;
    int y = hw0 >> 5, x0 = hw0 & 31;           // 4 pixels share row y
    const float* ip = x + (size_t)n * 3 * 1024;
    float4 a[16];
#pragma unroll
    for (int c = 0; c < 16; ++c) a[c] = make_float4(0.f, 0.f, 0.f, 0.f);
    for (int ky = 0; ky < 3; ++ky) {
        int yy = y + ky - 1;
        bool rowok = (unsigned)yy < 32u;
        float win[3][6];
#pragma unroll
        for (int ci = 0; ci < 3; ++ci)
#pragma unroll
            for (int j = 0; j < 6; ++j) {
                int cc = x0 - 1 + j;
                bool ok = rowok && ((unsigned)cc < 32u);
                win[ci][j] = ok ? ip[ci * 1024 + yy * 32 + cc] : 0.f;
            }
#pragma unroll
        for (int kx = 0; kx < 3; ++kx)
#pragma unroll
            for (int ci = 0; ci < 3; ++ci) {
                const float* wrow = wt + (ci * 9 + ky * 3 + kx) * 64 + c0;
                float s0 = win[ci][kx], s1 = win[ci][kx + 1];
                float s2 = win[ci][kx + 2], s3 = win[ci][kx + 3];
#pragma unroll
                for (int c = 0; c < 16; ++c) {
                    float wv = wrow[c];
                    a[c].x = fmaf(wv, s0, a[c].x);
                    a[c].y = fmaf(wv, s1, a[c].y);
                    a[c].z = fmaf(wv, s2, a[c].z);
                    a[c].w = fmaf(wv, s3, a[c].w);
                }
            }
    }
#pragma unroll
    for (int c = 0; c < 16; ++c)
        *(float4*)(out + ((size_t)n * 64 + c0 + c) * 1024 + hw0) = a[c];
}

// stage A: per-slot partial chains, identical m-order to R16's k1_stats64.
__global__ void k1_statsA(const float* __restrict__ v, double* __restrict__ Sp,
                          double* __restrict__ S2p, int N) {
    int c = blockIdx.x;                         // 0..63
    int slot = blockIdx.y * 64 + threadIdx.x;   // 0..255
    double s = 0.0, s2 = 0.0;
    int K = N * 4;                              // chain length (m = slot + 256k)
    const float* vp = v + (size_t)c * 1024 + slot;
    int k0 = 0;
    for (; k0 + 32 <= K; k0 += 32) {
        const float* p0 = vp + (size_t)(k0 >> 2) * 65536;
        float buf[32];
#pragma unroll
        for (int j = 0; j < 32; ++j)
            buf[j] = p0[(size_t)(j >> 2) * 65536 + (j & 3) * 256];
#pragma unroll
        for (int j = 0; j < 32; ++j) {
            double t = (double)buf[j];
            s += t; s2 += t * t;
        }
    }
    for (; k0 < K; ++k0) {
        int m = slot + k0 * 256;
        double t = (double)v[((size_t)(m >> 10) * 64 + c) * 1024 + (m & 1023)];
        s += t; s2 += t * t;
    }
    Sp[c * 256 + slot] = s; S2p[c * 256 + slot] = s2;
}

// stage B: verbatim 256-slot tree + mu/r finalization.
__global__ void k1_statsB(const double* __restrict__ Sp, const double* __restrict__ S2p,
                          float* __restrict__ muF, float* __restrict__ rF, int N) {
    int c = blockIdx.x;
    __shared__ double sh[256], sh2[256];
    sh[threadIdx.x]  = Sp[c * 256 + threadIdx.x];
    sh2[threadIdx.x] = S2p[c * 256 + threadIdx.x];
    __syncthreads();
    for (int o = 128; o > 0; o >>= 1) {
        if ((int)threadIdx.x < o) { sh[threadIdx.x] += sh[threadIdx.x + o]; sh2[threadIdx.x] += sh2[threadIdx.x + o]; }
        __syncthreads();
    }
    if (threadIdx.x == 0) {
        int M = N * 1024;
        double mean = sh[0] / M;
        double var  = sh2[0] / M - mean * mean;
        if (var < 0.0) var = 0.0;
        muF[c] = (float)mean;
        rF[c]  = 1.0f / sqrtf((float)var + 1e-5f);
    }
}

// 4 pixels/thread, float4 loads along hw (channels chunked x16 for VGPRs).
__global__ void k1_signpack(const float* __restrict__ v, const float* __restrict__ muF,
                            const float* __restrict__ rF, const float* __restrict__ g,
                            const float* __restrict__ b, u64* __restrict__ B,
                            u64* __restrict__ NZ, u64* __restrict__ aflag) {
    int gid = blockIdx.x * 64 + threadIdx.x;   // n*256 + hw4
    int n = gid >> 8, hw0 = (gid & 255) * 4;
    const float* vp = v + ((size_t)n * 64) * 1024 + hw0;
    u64 bb0 = 0, bb1 = 0, bb2 = 0, bb3 = 0;
    u64 nz0 = 0, nz1 = 0, nz2 = 0, nz3 = 0;
    for (int c0 = 0; c0 < 64; c0 += 16) {
        float4 buf[16];
#pragma unroll
        for (int j = 0; j < 16; ++j)
            buf[j] = *(const float4*)(vp + (size_t)(c0 + j) * 1024);
#pragma unroll
        for (int j = 0; j < 16; ++j) {
            int c = c0 + j;
            float mc = muF[c], rc = rF[c], gc = g[c], bc = b[c];
            float d0 = buf[j].x - mc; float t0 = (d0 * rc) * gc + bc;
            float d1 = buf[j].y - mc; float t1 = (d1 * rc) * gc + bc;
            float d2 = buf[j].z - mc; float t2 = (d2 * rc) * gc + bc;
            float d3 = buf[j].w - mc; float t3 = (d3 * rc) * gc + bc;
            bb0 |= (u64)(t0 > 0.f) << c;  nz0 |= (u64)(t0 != 0.f) << c;
            bb1 |= (u64)(t1 > 0.f) << c;  nz1 |= (u64)(t1 != 0.f) << c;
            bb2 |= (u64)(t2 > 0.f) << c;  nz2 |= (u64)(t2 != 0.f) << c;
            bb3 |= (u64)(t3 > 0.f) << c;  nz3 |= (u64)(t3 != 0.f) << c;
        }
    }
    size_t o = (size_t)n * 1024 + hw0;
    B[o]     = bb0; B[o + 1]  = bb1; B[o + 2]  = bb2; B[o + 3]  = bb3;
    NZ[o]    = nz0; NZ[o + 1] = nz1; NZ[o + 2] = nz2; NZ[o + 3] = nz3;
    flag_and_wave(aflag, nz0 & nz1 & nz2 & nz3);
}

// ---------- L1 fallback path (verbatim R13/R14) ----------
__global__ void k1_conv(const float* __restrict__ x, const float* __restrict__ w1,
                        float* __restrict__ out, int grp) {
    int hw = blockIdx.x * 64 + threadIdx.x;
    int cg = blockIdx.y;
    int n  = blockIdx.z;
    int co = grp * 8 + cg;
    int y = hw >> 5, x0 = hw & 31;
    const float* ip0 = x + ((size_t)n * 3 + 0) * 1024;
    const float* ip1 = x + ((size_t)n * 3 + 1) * 1024;
    const float* ip2 = x + ((size_t)n * 3 + 2) * 1024;
    const float* wp  = w1 + (size_t)co * 27;
    float acc = 0.f;
    for (int ky = 0; ky < 3; ++ky) {
        int yy = y + ky - 1;
        if (yy < 0 || yy > 31) continue;
        for (int kx = 0; kx < 3; ++kx) {
            int xc = x0 + kx - 1;
            if (xc < 0 || xc > 31) continue;
            int sp = yy * 32 + xc;
            int wk = ky * 3 + kx;
            float w0 = wp[wk], w1v = wp[9 + wk], w2 = wp[18 + wk];
            acc += (w0  > 0.f) ? ip0[sp] : ((w0  < 0.f) ? -ip0[sp] : 0.f);
            acc += (w1v > 0.f) ? ip1[sp] : ((w1v < 0.f) ? -ip1[sp] : 0.f);
            acc += (w2  > 0.f) ? ip2[sp] : ((w2  < 0.f) ? -ip2[sp] : 0.f);
        }
    }
    out[((size_t)n * 8 + cg) * 1024 + hw] = acc;
}

__device__ __forceinline__ float ld1(const float* v, int cg, int e) {
    return v[((size_t)(e >> 10) * 8 + cg) * 1024 + (e & 1023)];
}

__global__ void k1_stats(const float* __restrict__ v, float* __restrict__ muF,
                         float* __restrict__ rF, int grp, int N) {
    int cg = blockIdx.x;
    __shared__ double sh[256], sh2[256];
    double s = 0.0, s2 = 0.0;
    int M = N * 1024;
    for (int m = threadIdx.x; m < M; m += 256) {
        double t = (double)ld1(v, cg, m);
        s += t; s2 += t * t;
    }
    sh[threadIdx.x] = s; sh2[threadIdx.x] = s2;
    __syncthreads();
    for (int o = 128; o > 0; o >>= 1) {
        if ((int)threadIdx.x < o) { sh[threadIdx.x] += sh[threadIdx.x + o]; sh2[threadIdx.x] += sh2[threadIdx.x + o]; }
        __syncthreads();
    }
    if (threadIdx.x == 0) {
        double mean = sh[0] / M;
        double var  = sh2[0] / M - mean * mean;
        if (var < 0.0) var = 0.0;
        muF[grp * 8 + cg] = (float)mean;
        rF[grp * 8 + cg]  = 1.0f / sqrtf((float)var + 1e-5f);
    }
}

__global__ void k1_sign(const float* __restrict__ v, const float* __restrict__ muF,
                        const float* __restrict__ rF, const float* __restrict__ g,
                        const float* __restrict__ b, int8_t* __restrict__ sgn, int grp) {
    int hw = blockIdx.x * 256 + threadIdx.x;
    if (hw >= 1024) return;
    int cg = blockIdx.y, n = blockIdx.z;
    int c = grp * 8 + cg;
    float d  = v[((size_t)n * 8 + cg) * 1024 + hw] - muF[c];
    float t  = (d * rF[c]) * g[c] + b[c];
    sgn[((size_t)n * 64 + c) * 1024 + hw] = (int8_t)((t > 0.f) - (t < 0.f));
}

__global__ void kpack_sgn8(const int8_t* __restrict__ s, u64* __restrict__ B,
                           u64* __restrict__ NZ, int C, int HW, u64* __restrict__ aflag) {
    int hw = blockIdx.x * 64 + threadIdx.x;
    int wd = blockIdx.y, n = blockIdx.z;
    int WRD = C >> 6;
    u64 b = 0, nz = ~0ull;
    if (hw < HW) {
        nz = 0;
        const int8_t* sp = s + ((size_t)n * C + wd * 64) * HW + hw;
        for (int j = 0; j < 64; ++j) {
            int v = sp[(size_t)j * HW];
            b  |= (u64)(v > 0) << j;
            nz |= (u64)(v != 0) << j;
        }
        size_t o = ((size_t)n * HW + hw) * WRD + wd;
        B[o] = b; NZ[o] = nz;
    }
    flag_and_wave(aflag, nz);
}

// ---------- weight packing (fused single launch) ----------
__device__ __forceinline__ void pack_wconv_body(const float* __restrict__ w,
                                                u64* __restrict__ WB, u64* __restrict__ WNZ,
                                                int Ci, int Co, u64* flag, int idx) {
    int WRD = Ci >> 6;
    u64 b = 0, nz = ~0ull;
    if (idx < Co * 9 * WRD) {
        nz = 0;
        int wd = idx % WRD, t = (idx / WRD) % 9, co = idx / (9 * WRD);
        const float* wp = w + ((size_t)co * Ci + wd * 64) * 9 + t;
        float buf[64];
#pragma unroll
        for (int j = 0; j < 64; ++j) buf[j] = wp[(size_t)j * 9];
#pragma unroll
        for (int j = 0; j < 64; ++j) {
            b  |= (u64)(buf[j] > 0.f) << j;
            nz |= (u64)(buf[j] != 0.f) << j;
        }
        WB[idx] = b; WNZ[idx] = nz;
    }
    flag_and_wave(flag, nz);
}

__device__ __forceinline__ void pack_wlinT_body(const float* __restrict__ w,
                                                u64* __restrict__ WBt, u64* __restrict__ WZt,
                                                int K, int O, u64* flag, int idx) {
    int WRD = K >> 6;
    u64 b = 0, nz = ~0ull;
    if (idx < O * WRD) {
        nz = 0;
        int wd = idx % WRD, o = idx / WRD;
        const float* wp = w + (size_t)o * K + wd * 64;
#pragma unroll 8
        for (int j = 0; j < 64; ++j) {
            float v = wp[j];
            b  |= (u64)(v > 0.f) << j;
            nz |= (u64)(v != 0.f) << j;
        }
        WBt[(size_t)wd * O + o] = b; WZt[(size_t)wd * O + o] = nz;
    }
    flag_and_wave(flag, nz);
}

__global__ void kpack_all(const float* __restrict__ w2, const float* __restrict__ w3,
                          const float* __restrict__ w4, const float* __restrict__ w5,
                          const float* __restrict__ w6, const float* __restrict__ wf1,
                          const float* __restrict__ wf2, const float* __restrict__ wf3,
                          u64* wb2B, u64* wb2Z, u64* wb3B, u64* wb3Z,
                          u64* wb4B, u64* wb4Z, u64* wb5B, u64* wb5Z,
                          u64* wb6B, u64* wb6Z, u64* wf1B, u64* wf1Z,
                          u64* wf2B, u64* wf2Z, u64* wf3B, u64* wf3Z,
                          u64* flags) {
    int b = blockIdx.x, t = threadIdx.x;
    if      (b <   3) pack_wconv_body(w2, wb2B, wb2Z,  64,  64, &flags[0], b * 256 + t);
    else if (b <   8) pack_wconv_body(w3, wb3B, wb3Z,  64, 128, &flags[1], (b - 3) * 256 + t);
    else if (b <  17) pack_wconv_body(w4, wb4B, wb4Z, 128, 128, &flags[2], (b - 8) * 256 + t);
    else if (b <  35) pack_wconv_body(w5, wb5B, wb5Z, 128, 256, &flags[3], (b - 17) * 256 + t);
    else if (b <  71) pack_wconv_body(w6, wb6B, wb6Z, 256, 256, &flags[4], (b - 35) * 256 + t);
    else if (b < 199) pack_wlinT_body(wf1, wf1B, wf1Z, 4096, 512, &flags[5], (b - 71) * 256 + t);
    else if (b < 215) pack_wlinT_body(wf2, wf2B, wf2Z,  512, 512, &flags[6], (b - 199) * 256 + t);
    else              pack_wlinT_body(wf3, wf3B, wf3Z,  512,  10, &flags[7], (b - 215) * 256 + t);
}

// ---------- binary conv cores ----------
template <int WRD, int CB>
__device__ __forceinline__ void conv_slow(const u64* __restrict__ ib, const u64* __restrict__ iz,
                                          const u64* __restrict__ wbp, const u64* __restrict__ wzp,
                                          int H, int Wi, int y, int x, int* acc) {
#pragma unroll
    for (int c = 0; c < CB; ++c) acc[c] = 0;
    for (int ky = 0; ky < 3; ++ky) {
        int yy = y + ky - 1;
        if ((unsigned)yy >= (unsigned)H) continue;
        for (int kx = 0; kx < 3; ++kx) {
            int xc = x + kx - 1;
            if ((unsigned)xc >= (unsigned)Wi) continue;
            int p = yy * Wi + xc, t = ky * 3 + kx;
            u64 xb[WRD], xz[WRD];
#pragma unroll
            for (int w = 0; w < WRD; ++w) {
                xb[w] = ib[(size_t)p * WRD + w];
                xz[w] = iz[(size_t)p * WRD + w];
            }
#pragma unroll
            for (int c = 0; c < CB; ++c) {
#pragma unroll
                for (int w = 0; w < WRD; ++w) {
                    u64 e = xz[w] & wzp[(c * 9 + t) * WRD + w];
                    acc[c] += __popcll(e) - 2 * __popcll((xb[w] ^ wbp[(c * 9 + t) * WRD + w]) & e);
                }
            }
        }
    }
}

template <int WRD, int CB>
__device__ __forceinline__ void conv_fast(const u64* __restrict__ ib,
                                          const u64* __restrict__ wbp,
                                          int H, int Wi, int y, int x, int* acc) {
    int a2[CB];
#pragma unroll
    for (int c = 0; c < CB; ++c) a2[c] = 0;
    int T = 0;
    for (int ky = 0; ky < 3; ++ky) {
        int yy = y + ky - 1;
        if ((unsigned)yy >= (unsigned)H) continue;
        for (int kx = 0; kx < 3; ++kx) {
            int xc = x + kx - 1;
            if ((unsigned)xc >= (unsigned)Wi) continue;
            int p = yy * Wi + xc, t = ky * 3 + kx;
            ++T;
            u64 xb[WRD];
#pragma unroll
            for (int w = 0; w < WRD; ++w) xb[w] = ib[(size_t)p * WRD + w];
#pragma unroll
            for (int c = 0; c < CB; ++c)
#pragma unroll
                for (int w = 0; w < WRD; ++w)
                    a2[c] += __popcll(xb[w] ^ wbp[(c * 9 + t) * WRD + w]);
        }
    }
#pragma unroll
    for (int c = 0; c < CB; ++c) acc[c] = 64 * WRD * T - 2 * a2[c];
}

template <int WRD, int CB>
__global__ void kbconv2(const u64* __restrict__ B, const u64* __restrict__ NZ,
                        const u64* __restrict__ WB, const u64* __restrict__ WNZ,
                        int16_t* __restrict__ out, int Co, int H, int Wi,
                        const u64* __restrict__ wflag, const u64* __restrict__ aflag) {
    int hw = blockIdx.x * 64 + threadIdx.x;
    if (hw >= H * Wi) return;
    int co0 = blockIdx.y * CB, n = blockIdx.z;
    int y = hw / Wi, x = hw % Wi;
    const u64* ib = B  + (size_t)n * H * Wi * WRD;
    const u64* iz = NZ + (size_t)n * H * Wi * WRD;
    const u64* wbp = WB  + (size_t)co0 * 9 * WRD;
    const u64* wzp = WNZ + (size_t)co0 * 9 * WRD;
    bool fast = ((*wflag) & (*aflag)) == ~0ull;
    int acc[CB];
    if (fast) conv_fast<WRD, CB>(ib, wbp, H, Wi, y, x, acc);
    else      conv_slow<WRD, CB>(ib, iz, wbp, wzp, H, Wi, y, x, acc);
#pragma unroll
    for (int c = 0; c < CB; ++c)
        out[((size_t)n * Co + co0 + c) * H * Wi + hw] = (int16_t)acc[c];
}

template <int WRD, int CB>
__global__ void kbconv_pool2(const u64* __restrict__ B, const u64* __restrict__ NZ,
                             const u64* __restrict__ WB, const u64* __restrict__ WNZ,
                             int16_t* __restrict__ out, int Co, int H, int Wi,
                             const u64* __restrict__ wflag, const u64* __restrict__ aflag) {
    int Ho = H >> 1, Wo = Wi >> 1;
    int hw = blockIdx.x * 64 + threadIdx.x;
    if (hw >= Ho * Wo) return;
    int co0 = blockIdx.y * CB, n = blockIdx.z;
    int yo = hw / Wo, xo = hw % Wo;
    const u64* ib = B  + (size_t)n * H * Wi * WRD;
    const u64* iz = NZ + (size_t)n * H * Wi * WRD;
    const u64* wbp = WB  + (size_t)co0 * 9 * WRD;
    const u64* wzp = WNZ + (size_t)co0 * 9 * WRD;
    bool fast = ((*wflag) & (*aflag)) == ~0ull;
    int best[CB];
#pragma unroll
    for (int c = 0; c < CB; ++c) best[c] = -(1 << 30);
    if (fast) {
        for (int dy = 0; dy < 2; ++dy)
            for (int dx = 0; dx < 2; ++dx) {
                int acc[CB];
                conv_fast<WRD, CB>(ib, wbp, H, Wi, 2 * yo + dy, 2 * xo + dx, acc);
#pragma unroll
                for (int c = 0; c < CB; ++c) best[c] = acc[c] > best[c] ? acc[c] : best[c];
            }
    } else {
        for (int dy = 0; dy < 2; ++dy)
            for (int dx = 0; dx < 2; ++dx) {
                int acc[CB];
                conv_slow<WRD, CB>(ib, iz, wbp, wzp, H, Wi, 2 * yo + dy, 2 * xo + dx, acc);
#pragma unroll
                for (int c = 0; c < CB; ++c) best[c] = acc[c] > best[c] ? acc[c] : best[c];
            }
    }
#pragma unroll
    for (int c = 0; c < CB; ++c)
        out[((size_t)n * Co + co0 + c) * Ho * Wo + hw] = (int16_t)best[c];
}

// pool variant for Ho*Wo==16: 64 lanes = 16 pixels x 4 pool positions.
template <int WRD, int CB>
__global__ void kbconv_pool2s(const u64* __restrict__ B, const u64* __restrict__ NZ,
                              const u64* __restrict__ WB, const u64* __restrict__ WNZ,
                              int16_t* __restrict__ out, int Co, int H, int Wi,
                              const u64* __restrict__ wflag, const u64* __restrict__ aflag) {
    int Ho = H >> 1, Wo = Wi >> 1;       // Ho*Wo == 16
    int t0 = threadIdx.x;
    int pix = t0 & 15, pos = t0 >> 4;    // pos 0..3
    int co0 = blockIdx.y * CB, n = blockIdx.z;
    int yo = pix / Wo, xo = pix % Wo;
    int y = 2 * yo + (pos >> 1), x = 2 * xo + (pos & 1);
    const u64* ib = B  + (size_t)n * H * Wi * WRD;
    const u64* iz = NZ + (size_t)n * H * Wi * WRD;
    const u64* wbp = WB  + (size_t)co0 * 9 * WRD;
    const u64* wzp = WNZ + (size_t)co0 * 9 * WRD;
    bool fast = ((*wflag) & (*aflag)) == ~0ull;
    int acc[CB];
    if (fast) conv_fast<WRD, CB>(ib, wbp, H, Wi, y, x, acc);
    else      conv_slow<WRD, CB>(ib, iz, wbp, wzp, H, Wi, y, x, acc);
#pragma unroll
    for (int c = 0; c < CB; ++c) {
        int v = acc[c];
        int v1 = __shfl_xor(v, 16); v = v1 > v ? v1 : v;
        int v2 = __shfl_xor(v, 32); v = v2 > v ? v2 : v;
        acc[c] = v;
    }
    if (pos == 0) {
#pragma unroll
        for (int c = 0; c < CB; ++c)
            out[((size_t)n * Co + co0 + c) * Ho * Wo + pix] = (int16_t)acc[c];
    }
}

// ---------- conv BN stats (int64, order-free => regrouping exact) ----------
__global__ void kaccum16(const int16_t* __restrict__ v, long long* __restrict__ Sp,
                         long long* __restrict__ S2p, int C, int HW, int M) {
    int c = blockIdx.x;
    long long s = 0, s2 = 0;
    int M8 = M >> 3;
    for (int g = blockIdx.y * 256 + threadIdx.x; g < M8; g += gridDim.y * 256) {
        int m0 = g * 8;
        const int16_t* p = v + ((size_t)(m0 / HW) * C + c) * HW + (m0 % HW);
        short4 a = *(const short4*)p;
        short4 b = *(const short4*)(p + 4);
        int v0 = a.x, v1 = a.y, v2 = a.z, v3 = a.w;
        int v4 = b.x, v5 = b.y, v6 = b.z, v7 = b.w;
        s  += v0 + v1 + v2 + v3 + v4 + v5 + v6 + v7;
        s2 += (long long)v0 * v0 + (long long)v1 * v1 + (long long)v2 * v2 + (long long)v3 * v3
            + (long long)v4 * v4 + (long long)v5 * v5 + (long long)v6 * v6 + (long long)v7 * v7;
    }
    __shared__ long long sh[256], sh2[256];
    sh[threadIdx.x] = s; sh2[threadIdx.x] = s2;
    __syncthreads();
    for (int o = 128; o > 0; o >>= 1) {
        if ((int)threadIdx.x < o) { sh[threadIdx.x] += sh[threadIdx.x + o]; sh2[threadIdx.x] += sh2[threadIdx.x + o]; }
        __syncthreads();
    }
    if (threadIdx.x == 0) {
        Sp[c * gridDim.y + blockIdx.y]  = sh[0];
        S2p[c * gridDim.y + blockIdx.y] = sh2[0];
    }
}

__global__ void kfinal2(const long long* __restrict__ Sp, const long long* __restrict__ S2p,
                        int NB, const float* __restrict__ g, const float* __restrict__ b,
                        double* __restrict__ mu, double* __restrict__ Ad,
                        double* __restrict__ Bd, int C, int M) {
    int c = blockIdx.x * 64 + threadIdx.x;
    if (c >= C) return;
    long long s = 0, s2 = 0;
    for (int i = 0; i < NB; ++i) { s += Sp[c * NB + i]; s2 += S2p[c * NB + i]; }
    double mean = (double)s / M;
    double var  = (double)s2 / M - mean * mean;
    if (var < 0.0) var = 0.0;
    mu[c] = mean;
    Ad[c] = (g ? (double)g[c] : 1.0) / sqrt(var + 1e-5);
    Bd[c] = b ? (double)b[c] : 0.0;
}

// ---------- BN sign + pack: 4 pixels/thread via short4 ----------
__global__ void ksp_conv(const int16_t* __restrict__ v, const double* __restrict__ mu,
                         const double* __restrict__ Ad, const double* __restrict__ Bd,
                         u64* __restrict__ B, u64* __restrict__ NZ, int C, int HW, int N,
                         u64* __restrict__ aflag) {
    int tid = blockIdx.x * 64 + threadIdx.x;
    int WRD = C >> 6;
    int HW4 = HW >> 2;
    int total = N * WRD * HW4;
    u64 nzall = ~0ull;
    if (tid < total) {
        int hw4 = tid % HW4;
        int wd  = (tid / HW4) % WRD;
        int n   = tid / (HW4 * WRD);
        const int16_t* vp = v + ((size_t)n * C + wd * 64) * HW + hw4 * 4;
        u64 b0 = 0, b1 = 0, b2 = 0, b3 = 0;
        u64 n0 = 0, n1 = 0, n2 = 0, n3 = 0;
        for (int j0 = 0; j0 < 64; j0 += 16) {
            short4 buf[16];
#pragma unroll
            for (int j = 0; j < 16; ++j)
                buf[j] = *(const short4*)(vp + (size_t)(j0 + j) * HW);
#pragma unroll
            for (int j = 0; j < 16; ++j) {
                int c = wd * 64 + j0 + j;
                double Mu = mu[c], A = Ad[c], Bb = Bd[c];
                double t0 = ((double)buf[j].x - Mu) * A + Bb;
                double t1 = ((double)buf[j].y - Mu) * A + Bb;
                double t2 = ((double)buf[j].z - Mu) * A + Bb;
                double t3 = ((double)buf[j].w - Mu) * A + Bb;
                int sh = j0 + j;
                b0 |= (u64)(t0 > 0.0) << sh;  n0 |= (u64)(t0 != 0.0) << sh;
                b1 |= (u64)(t1 > 0.0) << sh;  n1 |= (u64)(t1 != 0.0) << sh;
                b2 |= (u64)(t2 > 0.0) << sh;  n2 |= (u64)(t2 != 0.0) << sh;
                b3 |= (u64)(t3 > 0.0) << sh;  n3 |= (u64)(t3 != 0.0) << sh;
            }
        }
        size_t o = ((size_t)n * HW + hw4 * 4) * WRD + wd;
        B[o] = b0;  B[o + WRD] = b1;  B[o + 2 * WRD] = b2;  B[o + 3 * WRD] = b3;
        NZ[o] = n0; NZ[o + WRD] = n1; NZ[o + 2 * WRD] = n2; NZ[o + 3 * WRD] = n3;
        nzall = n0 & n1 & n2 & n3;
    }
    flag_and_wave(aflag, nzall);
}

__global__ void ksp_flat(const int16_t* __restrict__ v, const double* __restrict__ mu,
                         const double* __restrict__ Ad, const double* __restrict__ Bd,
                         u64* __restrict__ B, u64* __restrict__ NZ, u64* __restrict__ aflag) {
    int wd = threadIdx.x;
    int n  = blockIdx.x;
    const int16_t* vp = v + (size_t)n * 4096 + wd * 64;
    int16_t buf[64];
#pragma unroll
    for (int j = 0; j < 64; ++j) buf[j] = vp[j];
    u64 b = 0, nz = 0;
#pragma unroll
    for (int j = 0; j < 64; ++j) {
        int k = wd * 64 + j;
        int c = k >> 4;
        double t = ((double)buf[j] - mu[c]) * Ad[c] + Bd[c];
        b  |= (u64)(t > 0.0) << j;
        nz |= (u64)(t != 0.0) << j;
    }
    B[(size_t)n * 64 + wd] = b; NZ[(size_t)n * 64 + wd] = nz;
    flag_and_wave(aflag, nz);
}

__global__ void ksp_fc(const int* __restrict__ v, const double* __restrict__ mu,
                       const double* __restrict__ Ad, const double* __restrict__ Bd,
                       u64* __restrict__ B, u64* __restrict__ NZ, int C, int WRD, int N,
                       u64* __restrict__ aflag) {
    int tid = blockIdx.x * 64 + threadIdx.x;
    u64 nz = ~0ull;
    if (tid < N * WRD) {
        int n = tid / WRD, wd = tid % WRD;
        const int* vp = v + (size_t)n * C + wd * 64;
        int buf[64];
#pragma unroll
        for (int j = 0; j < 64; ++j) buf[j] = vp[j];
        u64 b = 0; nz = 0;
#pragma unroll
        for (int j = 0; j < 64; ++j) {
            int c = wd * 64 + j;
            double t = ((double)buf[j] - mu[c]) * Ad[c] + Bd[c];
            b  |= (u64)(t > 0.0) << j;
            nz |= (u64)(t != 0.0) << j;
        }
        B[(size_t)n * WRD + wd] = b; NZ[(size_t)n * WRD + wd] = nz;
    }
    flag_and_wave(aflag, nz);
}

// ---------- binary FC: transposed coalesced weights + dense fast path ----------
__global__ void kbfc(const u64* __restrict__ aB, const u64* __restrict__ aNZ,
                     const u64* __restrict__ wBt, const u64* __restrict__ wZt,
                     int* __restrict__ out, int WRD, int O,
                     const u64* __restrict__ wflag, const u64* __restrict__ aflag) {
    int o = blockIdx.x * 64 + threadIdx.x;
    if (o >= O) return;
    int n = blockIdx.y;
    const u64* ab = aB  + (size_t)n * WRD;
    const u64* az = aNZ + (size_t)n * WRD;
    bool fast = ((*wflag) & (*aflag)) == ~0ull;
    int acc;
    if (fast) {
        int a2 = 0;
        for (int w = 0; w < WRD; w += 8) {
            u64 aw[8], ww[8];
#pragma unroll
            for (int j = 0; j < 8; ++j) {
                aw[j] = ab[w + j];
                ww[j] = wBt[(size_t)(w + j) * O + o];
            }
#pragma unroll
            for (int j = 0; j < 8; ++j) a2 += __popcll(aw[j] ^ ww[j]);
        }
        acc = 64 * WRD - 2 * a2;
    } else {
        acc = 0;
        for (int w = 0; w < WRD; ++w) {
            u64 wb = wBt[(size_t)w * O + o];
            u64 wz = wZt[(size_t)w * O + o];
            u64 e = az[w] & wz;
            acc += __popcll(e) - 2 * __popcll((ab[w] ^ wb) & e);
        }
    }
    out[(size_t)n * O + o] = acc;
}

// ---------- FC stats / output ----------
__global__ void k3_stats(const int* __restrict__ v, int N, int C,
                         const float* __restrict__ g, const float* __restrict__ b,
                         double* __restrict__ mu, double* __restrict__ Ad,
                         double* __restrict__ Bd) {
    int c = blockIdx.x;
    __shared__ double sh[256], sh2[256];
    double s = 0.0, s2 = 0.0;
    for (int n = threadIdx.x; n < N; n += 256) {
        double t = (double)v[(size_t)n * C + c];
        s += t; s2 += t * t;
    }
    sh[threadIdx.x] = s; sh2[threadIdx.x] = s2;
    __syncthreads();
    for (int o = 128; o > 0; o >>= 1) {
        if ((int)threadIdx.x < o) { sh[threadIdx.x] += sh[threadIdx.x + o]; sh2[threadIdx.x] += sh2[threadIdx.x + o]; }
        __syncthreads();
    }
    if (threadIdx.x == 0) {
        double mean = sh[0] / N;
        double var  = sh2[0] / N - mean * mean;
        if (var < 0.0) var = 0.0;
        mu[c] = mean;
        Ad[c] = (g ? (double)g[c] : 1.0) / sqrt(var + 1e-5);
        Bd[c] = b ? (double)b[c] : 0.0;
    }
}

__global__ void k4_out(const int* __restrict__ v, const double* __restrict__ mu,
                       const double* __restrict__ Ad, float* __restrict__ out, int N) {
    int n = blockIdx.x * 256 + threadIdx.x;
    if (n >= N) return;
    double z[10];
    double mx = -1e300;
    for (int o = 0; o < 10; ++o) {
        z[o] = ((double)v[n * 10 + o] - mu[o]) * Ad[o];
        if (z[o] > mx) mx = z[o];
    }
    double s = 0.0;
    for (int o = 0; o < 10; ++o) s += exp(z[o] - mx);
    double l = mx + log(s);
    for (int o = 0; o < 10; ++o) out[n * 10 + o] = (float)(z[o] - l);
}

// ---------------- host ----------------
extern "C" void kernel_launch(void* const* d_in, const int* in_sizes, int n_in,
                              void* d_out, int out_size, void* d_ws, size_t ws_size,
                              hipStream_t stream) {
    const int N = in_sizes[0] / (3 * 32 * 32);   // 512

    const float* x   = (const float*)d_in[0];
    const float* w1  = (const float*)d_in[1];
    const float* g1  = (const float*)d_in[2];
    const float* b1  = (const float*)d_in[3];
    const float* w2  = (const float*)d_in[4];
    const float* g2  = (const float*)d_in[5];
    const float* b2  = (const float*)d_in[6];
    const float* w3  = (const float*)d_in[7];
    const float* g3  = (const float*)d_in[8];
    const float* b3  = (const float*)d_in[9];
    const float* w4  = (const float*)d_in[10];
    const float* g4  = (const float*)d_in[11];
    const float* b4  = (const float*)d_in[12];
    const float* w5  = (const float*)d_in[13];
    const float* g5  = (const float*)d_in[14];
    const float* b5  = (const float*)d_in[15];
    const float* w6  = (const float*)d_in[16];
    const float* g6  = (const float*)d_in[17];
    const float* b6  = (const float*)d_in[18];
    const float* wf1 = (const float*)d_in[19];
    const float* gf1 = (const float*)d_in[20];
    const float* bf1 = (const float*)d_in[21];
    const float* wf2 = (const float*)d_in[22];
    const float* gf2 = (const float*)d_in[23];
    const float* bf2 = (const float*)d_in[24];
    const float* wf3 = (const float*)d_in[25];

    char* ws = (char*)d_ws;
    size_t off = 0;
    auto alloc = [&](size_t bytes) -> char* {
        char* p = ws + off;
        off = (off + bytes + 511) & ~(size_t)511;
        return p;
    };

    // ---- DOWN region: all post-L1 buffers at distinct offsets ----
    int16_t* t2  = (int16_t*)alloc((size_t)N * 64 * 256 * 2);
    u64* p2B = (u64*)alloc((size_t)N * 256 * 8);
    u64* p2Z = (u64*)alloc((size_t)N * 256 * 8);
    int16_t* t3  = (int16_t*)alloc((size_t)N * 128 * 256 * 2);
    u64* p3B = (u64*)alloc((size_t)N * 256 * 2 * 8);
    u64* p3Z = (u64*)alloc((size_t)N * 256 * 2 * 8);
    int16_t* t4  = (int16_t*)alloc((size_t)N * 128 * 64 * 2);
    u64* p4B = (u64*)alloc((size_t)N * 64 * 2 * 8);
    u64* p4Z = (u64*)alloc((size_t)N * 64 * 2 * 8);
    int16_t* t5  = (int16_t*)alloc((size_t)N * 256 * 64 * 2);
    u64* p5B = (u64*)alloc((size_t)N * 64 * 4 * 8);
    u64* p5Z = (u64*)alloc((size_t)N * 64 * 4 * 8);
    int16_t* t6  = (int16_t*)alloc((size_t)N * 256 * 16 * 2);
    u64* p6B = (u64*)alloc((size_t)N * 64 * 8);
    u64* p6Z = (u64*)alloc((size_t)N * 64 * 8);
    int* fc1 = (int*)alloc((size_t)N * 512 * 4);
    int* fc2 = (int*)alloc((size_t)N * 512 * 4);
    int* fc3 = (int*)alloc((size_t)N * 10 * 4);
    u64* pF1B = (u64*)alloc((size_t)N * 8 * 8);
    u64* pF1Z = (u64*)alloc((size_t)N * 8 * 8);
    u64* pF2B = (u64*)alloc((size_t)N * 8 * 8);
    u64* pF2Z = (u64*)alloc((size_t)N * 8 * 8);
    size_t down_end = off;

    // ---- L1 head overlays (dead before any DOWN buffer is written) ----
    size_t head_big = (size_t)N * 64 * 1024 * 4;      // 134.2MB f32, 64 channels
    bool big = ws_size >= head_big + ((size_t)20 << 20);
    float*  c1buf = (float*)ws;                        // big: [N][64][1024]
    float*  c1buf8 = (float*)ws;                       // fallback: [N][8][1024]
    int8_t* sgnA  = (int8_t*)(ws + (size_t)N * 8 * 1024 * 4);  // fallback only

    // ---- tail (coexists with L1 head) ----
    off = big ? (head_big > down_end ? head_big : down_end) : down_end;
    off = (off + 511) & ~(size_t)511;
    u64* p1B = (u64*)alloc((size_t)N * 1024 * 8);
    u64* p1Z = (u64*)alloc((size_t)N * 1024 * 8);
    u64* wb2B = (u64*)alloc(64  * 9 * 1 * 8);  u64* wb2Z = (u64*)alloc(64  * 9 * 1 * 8);
    u64* wb3B = (u64*)alloc(128 * 9 * 1 * 8);  u64* wb3Z = (u64*)alloc(128 * 9 * 1 * 8);
    u64* wb4B = (u64*)alloc(128 * 9 * 2 * 8);  u64* wb4Z = (u64*)alloc(128 * 9 * 2 * 8);
    u64* wb5B = (u64*)alloc(256 * 9 * 2 * 8);  u64* wb5Z = (u64*)alloc(256 * 9 * 2 * 8);
    u64* wb6B = (u64*)alloc(256 * 9 * 4 * 8);  u64* wb6Z = (u64*)alloc(256 * 9 * 4 * 8);
    u64* wf1B = (u64*)alloc(512 * 64 * 8);     u64* wf1Z = (u64*)alloc(512 * 64 * 8);
    u64* wf2B = (u64*)alloc(512 * 8 * 8);      u64* wf2Z = (u64*)alloc(512 * 8 * 8);
    u64* wf3B = (u64*)alloc(10 * 8 * 8);       u64* wf3Z = (u64*)alloc(10 * 8 * 8);
    float* wt = (float*)alloc(27 * 64 * 4);
    double* Sp  = (double*)alloc(64 * 256 * 8);
    double* S2p = (double*)alloc(64 * 256 * 8);
    long long* SpI  = (long long*)alloc(256 * 32 * 8);
    long long* S2pI = (long long*)alloc(256 * 32 * 8);
    u64* flags = (u64*)alloc(16 * 8);
    // [0..4]=wconv L2..L6, [5..7]=wlin FC1..FC3, [8..12]=act L1..L5,
    // [13]=act flat(L6), [14]=act FC1sign, [15]=act FC2sign
    double* mu = (double*)alloc(512 * 8);
    double* Ad = (double*)alloc(512 * 8);
    double* Bd = (double*)alloc(512 * 8);
    float*  muF = (float*)alloc(64 * 4);
    float*  rF  = (float*)alloc(64 * 4);

    auto cdiv = [](int a, int b) { return (a + b - 1) / b; };

    // ---- flags + fused weight pack (1 launch) ----
    kflag_init<<<1, 64, 0, stream>>>(flags);
    kpack_all<<<216, 256, 0, stream>>>(w2, w3, w4, w5, w6, wf1, wf2, wf3,
                                       wb2B, wb2Z, wb3B, wb3Z, wb4B, wb4Z,
                                       wb5B, wb5Z, wb6B, wb6Z, wf1B, wf1Z,
                                       wf2B, wf2Z, wf3B, wf3Z, flags);

    // ---- L1 ----
    if (big) {
        kw1t<<<27, 64, 0, stream>>>(w1, wt);
        k1_conv_all4<<<dim3((N * 256) / 64, 4), 64, 0, stream>>>(x, wt, c1buf);
        k1_statsA<<<dim3(64, 4), 64, 0, stream>>>(c1buf, Sp, S2p, N);
        k1_statsB<<<64, 256, 0, stream>>>(Sp, S2p, muF, rF, N);
        k1_signpack<<<(N * 256) / 64, 64, 0, stream>>>(c1buf, muF, rF, g1, b1, p1B, p1Z, &flags[8]);
    } else {
        for (int grp = 0; grp < 8; ++grp) {
            k1_conv<<<dim3(16, 8, N), 64, 0, stream>>>(x, w1, c1buf8, grp);
            k1_stats<<<8, 256, 0, stream>>>(c1buf8, muF, rF, grp, N);
            k1_sign<<<dim3(4, 8, N), 256, 0, stream>>>(c1buf8, muF, rF, g1, b1, sgnA, grp);
        }
        kpack_sgn8<<<dim3(16, 1, N), 64, 0, stream>>>(sgnA, p1B, p1Z, 64, 1024, &flags[8]);
    }

    // ---- L2: conv+pool (Ci=64, 32x32 -> 16x16) ----
    kbconv_pool2<1, 8><<<dim3(4, 8, N), 64, 0, stream>>>(p1B, p1Z, wb2B, wb2Z, t2, 64, 32, 32, &flags[0], &flags[8]);
    kaccum16<<<dim3(64, 32), 256, 0, stream>>>(t2, SpI, S2pI, 64, 256, N * 256);
    kfinal2<<<1, 64, 0, stream>>>(SpI, S2pI, 32, g2, b2, mu, Ad, Bd, 64, N * 256);
    ksp_conv<<<cdiv(N * 1 * 64, 64), 64, 0, stream>>>(t2, mu, Ad, Bd, p2B, p2Z, 64, 256, N, &flags[9]);

    // ---- L3: conv (Ci=64, 16x16) ----
    kbconv2<1, 8><<<dim3(4, 16, N), 64, 0, stream>>>(p2B, p2Z, wb3B, wb3Z, t3, 128, 16, 16, &flags[1], &flags[9]);
    kaccum16<<<dim3(128, 16), 256, 0, stream>>>(t3, SpI, S2pI, 128, 256, N * 256);
    kfinal2<<<2, 64, 0, stream>>>(SpI, S2pI, 16, g3, b3, mu, Ad, Bd, 128, N * 256);
    ksp_conv<<<cdiv(N * 2 * 64, 64), 64, 0, stream>>>(t3, mu, Ad, Bd, p3B, p3Z, 128, 256, N, &flags[10]);

    // ---- L4: conv+pool (Ci=128, 16x16 -> 8x8) ----
    kbconv_pool2<2, 8><<<dim3(1, 16, N), 64, 0, stream>>>(p3B, p3Z, wb4B, wb4Z, t4, 128, 16, 16, &flags[2], &flags[10]);
    kaccum16<<<dim3(128, 16), 256, 0, stream>>>(t4, SpI, S2pI, 128, 64, N * 64);
    kfinal2<<<2, 64, 0, stream>>>(SpI, S2pI, 16, g4, b4, mu, Ad, Bd, 128, N * 64);
    ksp_conv<<<cdiv(N * 2 * 16, 64), 64, 0, stream>>>(t4, mu, Ad, Bd, p4B, p4Z, 128, 64, N, &flags[11]);

    // ---- L5: conv (Ci=128, 8x8) ----
    kbconv2<2, 8><<<dim3(1, 32, N), 64, 0, stream>>>(p4B, p4Z, wb5B, wb5Z, t5, 256, 8, 8, &flags[3], &flags[11]);
    kaccum16<<<dim3(256, 8), 256, 0, stream>>>(t5, SpI, S2pI, 256, 64, N * 64);
    kfinal2<<<4, 64, 0, stream>>>(SpI, S2pI, 8, g5, b5, mu, Ad, Bd, 256, N * 64);
    ksp_conv<<<cdiv(N * 4 * 16, 64), 64, 0, stream>>>(t5, mu, Ad, Bd, p5B, p5Z, 256, 64, N, &flags[12]);

    // ---- L6: conv+pool (Ci=256, 8x8 -> 4x4), positions-in-lanes ----
    kbconv_pool2s<4, 8><<<dim3(1, 32, N), 64, 0, stream>>>(p5B, p5Z, wb6B, wb6Z, t6, 256, 8, 8, &flags[4], &flags[12]);
    kaccum16<<<dim3(256, 2), 256, 0, stream>>>(t6, SpI, S2pI, 256, 16, N * 16);
    kfinal2<<<4, 64, 0, stream>>>(SpI, S2pI, 2, g6, b6, mu, Ad, Bd, 256, N * 16);
    ksp_flat<<<N, 64, 0, stream>>>(t6, mu, Ad, Bd, p6B, p6Z, &flags[13]);

    // ---- FC1 ----
    kbfc<<<dim3(8, N), 64, 0, stream>>>(p6B, p6Z, wf1B, wf1Z, fc1, 64, 512, &flags[5], &flags[13]);
    k3_stats<<<512, 256, 0, stream>>>(fc1, N, 512, gf1, bf1, mu, Ad, Bd);
    ksp_fc<<<cdiv(N * 8, 64), 64, 0, stream>>>(fc1, mu, Ad, Bd, pF1B, pF1Z, 512, 8, N, &flags[14]);

    // ---- FC2 ----
    kbfc<<<dim3(8, N), 64, 0, stream>>>(pF1B, pF1Z, wf2B, wf2Z, fc2, 8, 512, &flags[6], &flags[14]);
    k3_stats<<<512, 256, 0, stream>>>(fc2, N, 512, gf2, bf2, mu, Ad, Bd);
    ksp_fc<<<cdiv(N * 8, 64), 64, 0, stream>>>(fc2, mu, Ad, Bd, pF2B, pF2Z, 512, 8, N, &flags[15]);

    // ---- FC3 + bn(no affine) + log_softmax ----
    kbfc<<<dim3(1, N), 64, 0, stream>>>(pF2B, pF2Z, wf3B, wf3Z, fc3, 8, 10, &flags[7], &flags[15]);
    k3_stats<<<10, 256, 0, stream>>>(fc3, N, 10, nullptr, nullptr, mu, Ad, Bd);
    k4_out<<<cdiv(N, 256), 256, 0, stream>>>(fc3, mu, Ad, (float*)d_out, N);
}

// Round 11
// 642.593 us; speedup vs baseline: 87.1409x; 1.0351x over previous
//
#include <hip/hip_runtime.h>
#include <stdint.h>
#include <math.h>

// Round 24 = R23 with the L1 conv store-fix done right: k1_conv_allv keeps
// float4 stores but drops the blockIdx.y channel split (which quadrupled
// input reads and starved occupancy at VGPR=80/64-thr). One thread = 4 pixels,
// internal loop over 4 channel chunks reusing 16 float4 accumulators.
// Per-output chain token-identical ((ky,kx) outer, ci inner) => bit-exact.
// All other kernels verbatim R23.

typedef unsigned long long u64;

__device__ __forceinline__ void flag_and_wave(u64* flag, u64 nz) {
    nz &= __shfl_xor(nz, 1);
    nz &= __shfl_xor(nz, 2);
    nz &= __shfl_xor(nz, 4);
    nz &= __shfl_xor(nz, 8);
    nz &= __shfl_xor(nz, 16);
    nz &= __shfl_xor(nz, 32);
    if ((threadIdx.x & 63) == 0) atomicAnd(flag, nz);
}

__global__ void kflag_init(u64* __restrict__ f) {
    int i = threadIdx.x;
    if (i < 16) f[i] = ~0ull;
}

// ---------- L1 ----------
__global__ void kw1t(const float* __restrict__ w1, float* __restrict__ wt) {
    int i = blockIdx.x * 64 + threadIdx.x;     // 64*27
    if (i >= 64 * 27) return;
    int co = i / 27, k = i % 27;
    float v = w1[i];
    wt[k * 64 + co] = (v > 0.f) ? 1.f : ((v < 0.f) ? -1.f : 0.f);
}

// 4 pixels/thread, 4x16-channel chunks internally, float4 stores.
// Chain per output token-identical to R16..R23: (ky,kx) outer, ci inner.
__global__ __launch_bounds__(256) void k1_conv_allv(const float* __restrict__ x,
                                                    const float* __restrict__ wt,
                                                    float* __restrict__ out) {
    int gid = blockIdx.x * 256 + threadIdx.x;  // n*256 + hw4
    int n = gid >> 8, hw0 = (gid & 255) * 4;
    int y = hw0 >> 5, x0 = hw0 & 31;           // 4 pixels share row y
    const float* ip = x + (size_t)n * 3 * 1024;
    for (int c0 = 0; c0 < 64; c0 += 16) {
        float4 a[16];
#pragma unroll
        for (int c = 0; c < 16; ++c) a[c] = make_float4(0.f, 0.f, 0.f, 0.f);
        for (int ky = 0; ky < 3; ++ky) {
            int yy = y + ky - 1;
            bool rowok = (unsigned)yy < 32u;
            float win[3][6];
#pragma unroll
            for (int ci = 0; ci < 3; ++ci)
#pragma unroll
                for (int j = 0; j < 6; ++j) {
                    int cc = x0 - 1 + j;
                    bool ok = rowok && ((unsigned)cc < 32u);
                    win[ci][j] = ok ? ip[ci * 1024 + yy * 32 + cc] : 0.f;
                }
#pragma unroll
            for (int kx = 0; kx < 3; ++kx)
#pragma unroll
                for (int ci = 0; ci < 3; ++ci) {
                    const float* wrow = wt + (ci * 9 + ky * 3 + kx) * 64 + c0;
                    float s0 = win[ci][kx], s1 = win[ci][kx + 1];
                    float s2 = win[ci][kx + 2], s3 = win[ci][kx + 3];
#pragma unroll
                    for (int c = 0; c < 16; ++c) {
                        float wv = wrow[c];
                        a[c].x = fmaf(wv, s0, a[c].x);
                        a[c].y = fmaf(wv, s1, a[c].y);
                        a[c].z = fmaf(wv, s2, a[c].z);
                        a[c].w = fmaf(wv, s3, a[c].w);
                    }
                }
        }
#pragma unroll
        for (int c = 0; c < 16; ++c)
            *(float4*)(out + ((size_t)n * 64 + c0 + c) * 1024 + hw0) = a[c];
    }
}

// stage A: per-slot partial chains, identical m-order to R16's k1_stats64.
__global__ void k1_statsA(const float* __restrict__ v, double* __restrict__ Sp,
                          double* __restrict__ S2p, int N) {
    int c = blockIdx.x;                         // 0..63
    int slot = blockIdx.y * 64 + threadIdx.x;   // 0..255
    double s = 0.0, s2 = 0.0;
    int K = N * 4;                              // chain length (m = slot + 256k)
    const float* vp = v + (size_t)c * 1024 + slot;
    int k0 = 0;
    for (; k0 + 32 <= K; k0 += 32) {
        const float* p0 = vp + (size_t)(k0 >> 2) * 65536;
        float buf[32];
#pragma unroll
        for (int j = 0; j < 32; ++j)
            buf[j] = p0[(size_t)(j >> 2) * 65536 + (j & 3) * 256];
#pragma unroll
        for (int j = 0; j < 32; ++j) {
            double t = (double)buf[j];
            s += t; s2 += t * t;
        }
    }
    for (; k0 < K; ++k0) {
        int m = slot + k0 * 256;
        double t = (double)v[((size_t)(m >> 10) * 64 + c) * 1024 + (m & 1023)];
        s += t; s2 += t * t;
    }
    Sp[c * 256 + slot] = s; S2p[c * 256 + slot] = s2;
}

// stage B: verbatim 256-slot tree + mu/r finalization.
__global__ void k1_statsB(const double* __restrict__ Sp, const double* __restrict__ S2p,
                          float* __restrict__ muF, float* __restrict__ rF, int N) {
    int c = blockIdx.x;
    __shared__ double sh[256], sh2[256];
    sh[threadIdx.x]  = Sp[c * 256 + threadIdx.x];
    sh2[threadIdx.x] = S2p[c * 256 + threadIdx.x];
    __syncthreads();
    for (int o = 128; o > 0; o >>= 1) {
        if ((int)threadIdx.x < o) { sh[threadIdx.x] += sh[threadIdx.x + o]; sh2[threadIdx.x] += sh2[threadIdx.x + o]; }
        __syncthreads();
    }
    if (threadIdx.x == 0) {
        int M = N * 1024;
        double mean = sh[0] / M;
        double var  = sh2[0] / M - mean * mean;
        if (var < 0.0) var = 0.0;
        muF[c] = (float)mean;
        rF[c]  = 1.0f / sqrtf((float)var + 1e-5f);
    }
}

// 4 pixels/thread, float4 loads along hw (channels chunked x16 for VGPRs).
__global__ void k1_signpack(const float* __restrict__ v, const float* __restrict__ muF,
                            const float* __restrict__ rF, const float* __restrict__ g,
                            const float* __restrict__ b, u64* __restrict__ B,
                            u64* __restrict__ NZ, u64* __restrict__ aflag) {
    int gid = blockIdx.x * 64 + threadIdx.x;   // n*256 + hw4
    int n = gid >> 8, hw0 = (gid & 255) * 4;
    const float* vp = v + ((size_t)n * 64) * 1024 + hw0;
    u64 bb0 = 0, bb1 = 0, bb2 = 0, bb3 = 0;
    u64 nz0 = 0, nz1 = 0, nz2 = 0, nz3 = 0;
    for (int c0 = 0; c0 < 64; c0 += 16) {
        float4 buf[16];
#pragma unroll
        for (int j = 0; j < 16; ++j)
            buf[j] = *(const float4*)(vp + (size_t)(c0 + j) * 1024);
#pragma unroll
        for (int j = 0; j < 16; ++j) {
            int c = c0 + j;
            float mc = muF[c], rc = rF[c], gc = g[c], bc = b[c];
            float d0 = buf[j].x - mc; float t0 = (d0 * rc) * gc + bc;
            float d1 = buf[j].y - mc; float t1 = (d1 * rc) * gc + bc;
            float d2 = buf[j].z - mc; float t2 = (d2 * rc) * gc + bc;
            float d3 = buf[j].w - mc; float t3 = (d3 * rc) * gc + bc;
            bb0 |= (u64)(t0 > 0.f) << c;  nz0 |= (u64)(t0 != 0.f) << c;
            bb1 |= (u64)(t1 > 0.f) << c;  nz1 |= (u64)(t1 != 0.f) << c;
            bb2 |= (u64)(t2 > 0.f) << c;  nz2 |= (u64)(t2 != 0.f) << c;
            bb3 |= (u64)(t3 > 0.f) << c;  nz3 |= (u64)(t3 != 0.f) << c;
        }
    }
    size_t o = (size_t)n * 1024 + hw0;
    B[o]     = bb0; B[o + 1]  = bb1; B[o + 2]  = bb2; B[o + 3]  = bb3;
    NZ[o]    = nz0; NZ[o + 1] = nz1; NZ[o + 2] = nz2; NZ[o + 3] = nz3;
    flag_and_wave(aflag, nz0 & nz1 & nz2 & nz3);
}

// ---------- L1 fallback path (verbatim R13/R14) ----------
__global__ void k1_conv(const float* __restrict__ x, const float* __restrict__ w1,
                        float* __restrict__ out, int grp) {
    int hw = blockIdx.x * 64 + threadIdx.x;
    int cg = blockIdx.y;
    int n  = blockIdx.z;
    int co = grp * 8 + cg;
    int y = hw >> 5, x0 = hw & 31;
    const float* ip0 = x + ((size_t)n * 3 + 0) * 1024;
    const float* ip1 = x + ((size_t)n * 3 + 1) * 1024;
    const float* ip2 = x + ((size_t)n * 3 + 2) * 1024;
    const float* wp  = w1 + (size_t)co * 27;
    float acc = 0.f;
    for (int ky = 0; ky < 3; ++ky) {
        int yy = y + ky - 1;
        if (yy < 0 || yy > 31) continue;
        for (int kx = 0; kx < 3; ++kx) {
            int xc = x0 + kx - 1;
            if (xc < 0 || xc > 31) continue;
            int sp = yy * 32 + xc;
            int wk = ky * 3 + kx;
            float w0 = wp[wk], w1v = wp[9 + wk], w2 = wp[18 + wk];
            acc += (w0  > 0.f) ? ip0[sp] : ((w0  < 0.f) ? -ip0[sp] : 0.f);
            acc += (w1v > 0.f) ? ip1[sp] : ((w1v < 0.f) ? -ip1[sp] : 0.f);
            acc += (w2  > 0.f) ? ip2[sp] : ((w2  < 0.f) ? -ip2[sp] : 0.f);
        }
    }
    out[((size_t)n * 8 + cg) * 1024 + hw] = acc;
}

__device__ __forceinline__ float ld1(const float* v, int cg, int e) {
    return v[((size_t)(e >> 10) * 8 + cg) * 1024 + (e & 1023)];
}

__global__ void k1_stats(const float* __restrict__ v, float* __restrict__ muF,
                         float* __restrict__ rF, int grp, int N) {
    int cg = blockIdx.x;
    __shared__ double sh[256], sh2[256];
    double s = 0.0, s2 = 0.0;
    int M = N * 1024;
    for (int m = threadIdx.x; m < M; m += 256) {
        double t = (double)ld1(v, cg, m);
        s += t; s2 += t * t;
    }
    sh[threadIdx.x] = s; sh2[threadIdx.x] = s2;
    __syncthreads();
    for (int o = 128; o > 0; o >>= 1) {
        if ((int)threadIdx.x < o) { sh[threadIdx.x] += sh[threadIdx.x + o]; sh2[threadIdx.x] += sh2[threadIdx.x + o]; }
        __syncthreads();
    }
    if (threadIdx.x == 0) {
        double mean = sh[0] / M;
        double var  = sh2[0] / M - mean * mean;
        if (var < 0.0) var = 0.0;
        muF[grp * 8 + cg] = (float)mean;
        rF[grp * 8 + cg]  = 1.0f / sqrtf((float)var + 1e-5f);
    }
}

__global__ void k1_sign(const float* __restrict__ v, const float* __restrict__ muF,
                        const float* __restrict__ rF, const float* __restrict__ g,
                        const float* __restrict__ b, int8_t* __restrict__ sgn, int grp) {
    int hw = blockIdx.x * 256 + threadIdx.x;
    if (hw >= 1024) return;
    int cg = blockIdx.y, n = blockIdx.z;
    int c = grp * 8 + cg;
    float d  = v[((size_t)n * 8 + cg) * 1024 + hw] - muF[c];
    float t  = (d * rF[c]) * g[c] + b[c];
    sgn[((size_t)n * 64 + c) * 1024 + hw] = (int8_t)((t > 0.f) - (t < 0.f));
}

__global__ void kpack_sgn8(const int8_t* __restrict__ s, u64* __restrict__ B,
                           u64* __restrict__ NZ, int C, int HW, u64* __restrict__ aflag) {
    int hw = blockIdx.x * 64 + threadIdx.x;
    int wd = blockIdx.y, n = blockIdx.z;
    int WRD = C >> 6;
    u64 b = 0, nz = ~0ull;
    if (hw < HW) {
        nz = 0;
        const int8_t* sp = s + ((size_t)n * C + wd * 64) * HW + hw;
        for (int j = 0; j < 64; ++j) {
            int v = sp[(size_t)j * HW];
            b  |= (u64)(v > 0) << j;
            nz |= (u64)(v != 0) << j;
        }
        size_t o = ((size_t)n * HW + hw) * WRD + wd;
        B[o] = b; NZ[o] = nz;
    }
    flag_and_wave(aflag, nz);
}

// ---------- weight packing (fused single launch) ----------
__device__ __forceinline__ void pack_wconv_body(const float* __restrict__ w,
                                                u64* __restrict__ WB, u64* __restrict__ WNZ,
                                                int Ci, int Co, u64* flag, int idx) {
    int WRD = Ci >> 6;
    u64 b = 0, nz = ~0ull;
    if (idx < Co * 9 * WRD) {
        nz = 0;
        int wd = idx % WRD, t = (idx / WRD) % 9, co = idx / (9 * WRD);
        const float* wp = w + ((size_t)co * Ci + wd * 64) * 9 + t;
        float buf[64];
#pragma unroll
        for (int j = 0; j < 64; ++j) buf[j] = wp[(size_t)j * 9];
#pragma unroll
        for (int j = 0; j < 64; ++j) {
            b  |= (u64)(buf[j] > 0.f) << j;
            nz |= (u64)(buf[j] != 0.f) << j;
        }
        WB[idx] = b; WNZ[idx] = nz;
    }
    flag_and_wave(flag, nz);
}

__device__ __forceinline__ void pack_wlinT_body(const float* __restrict__ w,
                                                u64* __restrict__ WBt, u64* __restrict__ WZt,
                                                int K, int O, u64* flag, int idx) {
    int WRD = K >> 6;
    u64 b = 0, nz = ~0ull;
    if (idx < O * WRD) {
        nz = 0;
        int wd = idx % WRD, o = idx / WRD;
        const float* wp = w + (size_t)o * K + wd * 64;
#pragma unroll 8
        for (int j = 0; j < 64; ++j) {
            float v = wp[j];
            b  |= (u64)(v > 0.f) << j;
            nz |= (u64)(v != 0.f) << j;
        }
        WBt[(size_t)wd * O + o] = b; WZt[(size_t)wd * O + o] = nz;
    }
    flag_and_wave(flag, nz);
}

__global__ void kpack_all(const float* __restrict__ w2, const float* __restrict__ w3,
                          const float* __restrict__ w4, const float* __restrict__ w5,
                          const float* __restrict__ w6, const float* __restrict__ wf1,
                          const float* __restrict__ wf2, const float* __restrict__ wf3,
                          u64* wb2B, u64* wb2Z, u64* wb3B, u64* wb3Z,
                          u64* wb4B, u64* wb4Z, u64* wb5B, u64* wb5Z,
                          u64* wb6B, u64* wb6Z, u64* wf1B, u64* wf1Z,
                          u64* wf2B, u64* wf2Z, u64* wf3B, u64* wf3Z,
                          u64* flags) {
    int b = blockIdx.x, t = threadIdx.x;
    if      (b <   3) pack_wconv_body(w2, wb2B, wb2Z,  64,  64, &flags[0], b * 256 + t);
    else if (b <   8) pack_wconv_body(w3, wb3B, wb3Z,  64, 128, &flags[1], (b - 3) * 256 + t);
    else if (b <  17) pack_wconv_body(w4, wb4B, wb4Z, 128, 128, &flags[2], (b - 8) * 256 + t);
    else if (b <  35) pack_wconv_body(w5, wb5B, wb5Z, 128, 256, &flags[3], (b - 17) * 256 + t);
    else if (b <  71) pack_wconv_body(w6, wb6B, wb6Z, 256, 256, &flags[4], (b - 35) * 256 + t);
    else if (b < 199) pack_wlinT_body(wf1, wf1B, wf1Z, 4096, 512, &flags[5], (b - 71) * 256 + t);
    else if (b < 215) pack_wlinT_body(wf2, wf2B, wf2Z,  512, 512, &flags[6], (b - 199) * 256 + t);
    else              pack_wlinT_body(wf3, wf3B, wf3Z,  512,  10, &flags[7], (b - 215) * 256 + t);
}

// ---------- binary conv cores ----------
template <int WRD, int CB>
__device__ __forceinline__ void conv_slow(const u64* __restrict__ ib, const u64* __restrict__ iz,
                                          const u64* __restrict__ wbp, const u64* __restrict__ wzp,
                                          int H, int Wi, int y, int x, int* acc) {
#pragma unroll
    for (int c = 0; c < CB; ++c) acc[c] = 0;
    for (int ky = 0; ky < 3; ++ky) {
        int yy = y + ky - 1;
        if ((unsigned)yy >= (unsigned)H) continue;
        for (int kx = 0; kx < 3; ++kx) {
            int xc = x + kx - 1;
            if ((unsigned)xc >= (unsigned)Wi) continue;
            int p = yy * Wi + xc, t = ky * 3 + kx;
            u64 xb[WRD], xz[WRD];
#pragma unroll
            for (int w = 0; w < WRD; ++w) {
                xb[w] = ib[(size_t)p * WRD + w];
                xz[w] = iz[(size_t)p * WRD + w];
            }
#pragma unroll
            for (int c = 0; c < CB; ++c) {
#pragma unroll
                for (int w = 0; w < WRD; ++w) {
                    u64 e = xz[w] & wzp[(c * 9 + t) * WRD + w];
                    acc[c] += __popcll(e) - 2 * __popcll((xb[w] ^ wbp[(c * 9 + t) * WRD + w]) & e);
                }
            }
        }
    }
}

template <int WRD, int CB>
__device__ __forceinline__ void conv_fast(const u64* __restrict__ ib,
                                          const u64* __restrict__ wbp,
                                          int H, int Wi, int y, int x, int* acc) {
    int a2[CB];
#pragma unroll
    for (int c = 0; c < CB; ++c) a2[c] = 0;
    int T = 0;
    for (int ky = 0; ky < 3; ++ky) {
        int yy = y + ky - 1;
        if ((unsigned)yy >= (unsigned)H) continue;
        for (int kx = 0; kx < 3; ++kx) {
            int xc = x + kx - 1;
            if ((unsigned)xc >= (unsigned)Wi) continue;
            int p = yy * Wi + xc, t = ky * 3 + kx;
            ++T;
            u64 xb[WRD];
#pragma unroll
            for (int w = 0; w < WRD; ++w) xb[w] = ib[(size_t)p * WRD + w];
#pragma unroll
            for (int c = 0; c < CB; ++c)
#pragma unroll
                for (int w = 0; w < WRD; ++w)
                    a2[c] += __popcll(xb[w] ^ wbp[(c * 9 + t) * WRD + w]);
        }
    }
#pragma unroll
    for (int c = 0; c < CB; ++c) acc[c] = 64 * WRD * T - 2 * a2[c];
}

template <int WRD, int CB>
__global__ void kbconv2(const u64* __restrict__ B, const u64* __restrict__ NZ,
                        const u64* __restrict__ WB, const u64* __restrict__ WNZ,
                        int16_t* __restrict__ out, int Co, int H, int Wi,
                        const u64* __restrict__ wflag, const u64* __restrict__ aflag) {
    int hw = blockIdx.x * 64 + threadIdx.x;
    if (hw >= H * Wi) return;
    int co0 = blockIdx.y * CB, n = blockIdx.z;
    int y = hw / Wi, x = hw % Wi;
    const u64* ib = B  + (size_t)n * H * Wi * WRD;
    const u64* iz = NZ + (size_t)n * H * Wi * WRD;
    const u64* wbp = WB  + (size_t)co0 * 9 * WRD;
    const u64* wzp = WNZ + (size_t)co0 * 9 * WRD;
    bool fast = ((*wflag) & (*aflag)) == ~0ull;
    int acc[CB];
    if (fast) conv_fast<WRD, CB>(ib, wbp, H, Wi, y, x, acc);
    else      conv_slow<WRD, CB>(ib, iz, wbp, wzp, H, Wi, y, x, acc);
#pragma unroll
    for (int c = 0; c < CB; ++c)
        out[((size_t)n * Co + co0 + c) * H * Wi + hw] = (int16_t)acc[c];
}

template <int WRD, int CB>
__global__ void kbconv_pool2(const u64* __restrict__ B, const u64* __restrict__ NZ,
                             const u64* __restrict__ WB, const u64* __restrict__ WNZ,
                             int16_t* __restrict__ out, int Co, int H, int Wi,
                             const u64* __restrict__ wflag, const u64* __restrict__ aflag) {
    int Ho = H >> 1, Wo = Wi >> 1;
    int hw = blockIdx.x * 64 + threadIdx.x;
    if (hw >= Ho * Wo) return;
    int co0 = blockIdx.y * CB, n = blockIdx.z;
    int yo = hw / Wo, xo = hw % Wo;
    const u64* ib = B  + (size_t)n * H * Wi * WRD;
    const u64* iz = NZ + (size_t)n * H * Wi * WRD;
    const u64* wbp = WB  + (size_t)co0 * 9 * WRD;
    const u64* wzp = WNZ + (size_t)co0 * 9 * WRD;
    bool fast = ((*wflag) & (*aflag)) == ~0ull;
    int best[CB];
#pragma unroll
    for (int c = 0; c < CB; ++c) best[c] = -(1 << 30);
    if (fast) {
        for (int dy = 0; dy < 2; ++dy)
            for (int dx = 0; dx < 2; ++dx) {
                int acc[CB];
                conv_fast<WRD, CB>(ib, wbp, H, Wi, 2 * yo + dy, 2 * xo + dx, acc);
#pragma unroll
                for (int c = 0; c < CB; ++c) best[c] = acc[c] > best[c] ? acc[c] : best[c];
            }
    } else {
        for (int dy = 0; dy < 2; ++dy)
            for (int dx = 0; dx < 2; ++dx) {
                int acc[CB];
                conv_slow<WRD, CB>(ib, iz, wbp, wzp, H, Wi, 2 * yo + dy, 2 * xo + dx, acc);
#pragma unroll
                for (int c = 0; c < CB; ++c) best[c] = acc[c] > best[c] ? acc[c] : best[c];
            }
    }
#pragma unroll
    for (int c = 0; c < CB; ++c)
        out[((size_t)n * Co + co0 + c) * Ho * Wo + hw] = (int16_t)best[c];
}

// pool variant for Ho*Wo==16: 64 lanes = 16 pixels x 4 pool positions.
template <int WRD, int CB>
__global__ void kbconv_pool2s(const u64* __restrict__ B, const u64* __restrict__ NZ,
                              const u64* __restrict__ WB, const u64* __restrict__ WNZ,
                              int16_t* __restrict__ out, int Co, int H, int Wi,
                              const u64* __restrict__ wflag, const u64* __restrict__ aflag) {
    int Ho = H >> 1, Wo = Wi >> 1;       // Ho*Wo == 16
    int t0 = threadIdx.x;
    int pix = t0 & 15, pos = t0 >> 4;    // pos 0..3
    int co0 = blockIdx.y * CB, n = blockIdx.z;
    int yo = pix / Wo, xo = pix % Wo;
    int y = 2 * yo + (pos >> 1), x = 2 * xo + (pos & 1);
    const u64* ib = B  + (size_t)n * H * Wi * WRD;
    const u64* iz = NZ + (size_t)n * H * Wi * WRD;
    const u64* wbp = WB  + (size_t)co0 * 9 * WRD;
    const u64* wzp = WNZ + (size_t)co0 * 9 * WRD;
    bool fast = ((*wflag) & (*aflag)) == ~0ull;
    int acc[CB];
    if (fast) conv_fast<WRD, CB>(ib, wbp, H, Wi, y, x, acc);
    else      conv_slow<WRD, CB>(ib, iz, wbp, wzp, H, Wi, y, x, acc);
#pragma unroll
    for (int c = 0; c < CB; ++c) {
        int v = acc[c];
        int v1 = __shfl_xor(v, 16); v = v1 > v ? v1 : v;
        int v2 = __shfl_xor(v, 32); v = v2 > v ? v2 : v;
        acc[c] = v;
    }
    if (pos == 0) {
#pragma unroll
        for (int c = 0; c < CB; ++c)
            out[((size_t)n * Co + co0 + c) * Ho * Wo + pix] = (int16_t)acc[c];
    }
}

// ---------- conv BN stats (int64, order-free => regrouping exact) ----------
__global__ void kaccum16(const int16_t* __restrict__ v, long long* __restrict__ Sp,
                         long long* __restrict__ S2p, int C, int HW, int M) {
    int c = blockIdx.x;
    long long s = 0, s2 = 0;
    int M8 = M >> 3;
    for (int g = blockIdx.y * 256 + threadIdx.x; g < M8; g += gridDim.y * 256) {
        int m0 = g * 8;
        const int16_t* p = v + ((size_t)(m0 / HW) * C + c) * HW + (m0 % HW);
        short4 a = *(const short4*)p;
        short4 b = *(const short4*)(p + 4);
        int v0 = a.x, v1 = a.y, v2 = a.z, v3 = a.w;
        int v4 = b.x, v5 = b.y, v6 = b.z, v7 = b.w;
        s  += v0 + v1 + v2 + v3 + v4 + v5 + v6 + v7;
        s2 += (long long)v0 * v0 + (long long)v1 * v1 + (long long)v2 * v2 + (long long)v3 * v3
            + (long long)v4 * v4 + (long long)v5 * v5 + (long long)v6 * v6 + (long long)v7 * v7;
    }
    __shared__ long long sh[256], sh2[256];
    sh[threadIdx.x] = s; sh2[threadIdx.x] = s2;
    __syncthreads();
    for (int o = 128; o > 0; o >>= 1) {
        if ((int)threadIdx.x < o) { sh[threadIdx.x] += sh[threadIdx.x + o]; sh2[threadIdx.x] += sh2[threadIdx.x + o]; }
        __syncthreads();
    }
    if (threadIdx.x == 0) {
        Sp[c * gridDim.y + blockIdx.y]  = sh[0];
        S2p[c * gridDim.y + blockIdx.y] = sh2[0];
    }
}

__global__ void kfinal2(const long long* __restrict__ Sp, const long long* __restrict__ S2p,
                        int NB, const float* __restrict__ g, const float* __restrict__ b,
                        double* __restrict__ mu, double* __restrict__ Ad,
                        double* __restrict__ Bd, int C, int M) {
    int c = blockIdx.x * 64 + threadIdx.x;
    if (c >= C) return;
    long long s = 0, s2 = 0;
    for (int i = 0; i < NB; ++i) { s += Sp[c * NB + i]; s2 += S2p[c * NB + i]; }
    double mean = (double)s / M;
    double var  = (double)s2 / M - mean * mean;
    if (var < 0.0) var = 0.0;
    mu[c] = mean;
    Ad[c] = (g ? (double)g[c] : 1.0) / sqrt(var + 1e-5);
    Bd[c] = b ? (double)b[c] : 0.0;
}

// ---------- BN sign + pack: 4 pixels/thread via short4 ----------
__global__ void ksp_conv(const int16_t* __restrict__ v, const double* __restrict__ mu,
                         const double* __restrict__ Ad, const double* __restrict__ Bd,
                         u64* __restrict__ B, u64* __restrict__ NZ, int C, int HW, int N,
                         u64* __restrict__ aflag) {
    int tid = blockIdx.x * 64 + threadIdx.x;
    int WRD = C >> 6;
    int HW4 = HW >> 2;
    int total = N * WRD * HW4;
    u64 nzall = ~0ull;
    if (tid < total) {
        int hw4 = tid % HW4;
        int wd  = (tid / HW4) % WRD;
        int n   = tid / (HW4 * WRD);
        const int16_t* vp = v + ((size_t)n * C + wd * 64) * HW + hw4 * 4;
        u64 b0 = 0, b1 = 0, b2 = 0, b3 = 0;
        u64 n0 = 0, n1 = 0, n2 = 0, n3 = 0;
        for (int j0 = 0; j0 < 64; j0 += 16) {
            short4 buf[16];
#pragma unroll
            for (int j = 0; j < 16; ++j)
                buf[j] = *(const short4*)(vp + (size_t)(j0 + j) * HW);
#pragma unroll
            for (int j = 0; j < 16; ++j) {
                int c = wd * 64 + j0 + j;
                double Mu = mu[c], A = Ad[c], Bb = Bd[c];
                double t0 = ((double)buf[j].x - Mu) * A + Bb;
                double t1 = ((double)buf[j].y - Mu) * A + Bb;
                double t2 = ((double)buf[j].z - Mu) * A + Bb;
                double t3 = ((double)buf[j].w - Mu) * A + Bb;
                int sh = j0 + j;
                b0 |= (u64)(t0 > 0.0) << sh;  n0 |= (u64)(t0 != 0.0) << sh;
                b1 |= (u64)(t1 > 0.0) << sh;  n1 |= (u64)(t1 != 0.0) << sh;
                b2 |= (u64)(t2 > 0.0) << sh;  n2 |= (u64)(t2 != 0.0) << sh;
                b3 |= (u64)(t3 > 0.0) << sh;  n3 |= (u64)(t3 != 0.0) << sh;
            }
        }
        size_t o = ((size_t)n * HW + hw4 * 4) * WRD + wd;
        B[o] = b0;  B[o + WRD] = b1;  B[o + 2 * WRD] = b2;  B[o + 3 * WRD] = b3;
        NZ[o] = n0; NZ[o + WRD] = n1; NZ[o + 2 * WRD] = n2; NZ[o + 3 * WRD] = n3;
        nzall = n0 & n1 & n2 & n3;
    }
    flag_and_wave(aflag, nzall);
}

__global__ void ksp_flat(const int16_t* __restrict__ v, const double* __restrict__ mu,
                         const double* __restrict__ Ad, const double* __restrict__ Bd,
                         u64* __restrict__ B, u64* __restrict__ NZ, u64* __restrict__ aflag) {
    int wd = threadIdx.x;
    int n  = blockIdx.x;
    const int16_t* vp = v + (size_t)n * 4096 + wd * 64;
    int16_t buf[64];
#pragma unroll
    for (int j = 0; j < 64; ++j) buf[j] = vp[j];
    u64 b = 0, nz = 0;
#pragma unroll
    for (int j = 0; j < 64; ++j) {
        int k = wd * 64 + j;
        int c = k >> 4;
        double t = ((double)buf[j] - mu[c]) * Ad[c] + Bd[c];
        b  |= (u64)(t > 0.0) << j;
        nz |= (u64)(t != 0.0) << j;
    }
    B[(size_t)n * 64 + wd] = b; NZ[(size_t)n * 64 + wd] = nz;
    flag_and_wave(aflag, nz);
}

__global__ void ksp_fc(const int* __restrict__ v, const double* __restrict__ mu,
                       const double* __restrict__ Ad, const double* __restrict__ Bd,
                       u64* __restrict__ B, u64* __restrict__ NZ, int C, int WRD, int N,
                       u64* __restrict__ aflag) {
    int tid = blockIdx.x * 64 + threadIdx.x;
    u64 nz = ~0ull;
    if (tid < N * WRD) {
        int n = tid / WRD, wd = tid % WRD;
        const int* vp = v + (size_t)n * C + wd * 64;
        int buf[64];
#pragma unroll
        for (int j = 0; j < 64; ++j) buf[j] = vp[j];
        u64 b = 0; nz = 0;
#pragma unroll
        for (int j = 0; j < 64; ++j) {
            int c = wd * 64 + j;
            double t = ((double)buf[j] - mu[c]) * Ad[c] + Bd[c];
            b  |= (u64)(t > 0.0) << j;
            nz |= (u64)(t != 0.0) << j;
        }
        B[(size_t)n * WRD + wd] = b; NZ[(size_t)n * WRD + wd] = nz;
    }
    flag_and_wave(aflag, nz);
}

// ---------- binary FC: transposed coalesced weights + dense fast path ----------
__global__ void kbfc(const u64* __restrict__ aB, const u64* __restrict__ aNZ,
                     const u64* __restrict__ wBt, const u64* __restrict__ wZt,
                     int* __restrict__ out, int WRD, int O,
                     const u64* __restrict__ wflag, const u64* __restrict__ aflag) {
    int o = blockIdx.x * 64 + threadIdx.x;
    if (o >= O) return;
    int n = blockIdx.y;
    const u64* ab = aB  + (size_t)n * WRD;
    const u64* az = aNZ + (size_t)n * WRD;
    bool fast = ((*wflag) & (*aflag)) == ~0ull;
    int acc;
    if (fast) {
        int a2 = 0;
        for (int w = 0; w < WRD; w += 8) {
            u64 aw[8], ww[8];
#pragma unroll
            for (int j = 0; j < 8; ++j) {
                aw[j] = ab[w + j];
                ww[j] = wBt[(size_t)(w + j) * O + o];
            }
#pragma unroll
            for (int j = 0; j < 8; ++j) a2 += __popcll(aw[j] ^ ww[j]);
        }
        acc = 64 * WRD - 2 * a2;
    } else {
        acc = 0;
        for (int w = 0; w < WRD; ++w) {
            u64 wb = wBt[(size_t)w * O + o];
            u64 wz = wZt[(size_t)w * O + o];
            u64 e = az[w] & wz;
            acc += __popcll(e) - 2 * __popcll((ab[w] ^ wb) & e);
        }
    }
    out[(size_t)n * O + o] = acc;
}

// ---------- FC stats / output ----------
__global__ void k3_stats(const int* __restrict__ v, int N, int C,
                         const float* __restrict__ g, const float* __restrict__ b,
                         double* __restrict__ mu, double* __restrict__ Ad,
                         double* __restrict__ Bd) {
    int c = blockIdx.x;
    __shared__ double sh[256], sh2[256];
    double s = 0.0, s2 = 0.0;
    for (int n = threadIdx.x; n < N; n += 256) {
        double t = (double)v[(size_t)n * C + c];
        s += t; s2 += t * t;
    }
    sh[threadIdx.x] = s; sh2[threadIdx.x] = s2;
    __syncthreads();
    for (int o = 128; o > 0; o >>= 1) {
        if ((int)threadIdx.x < o) { sh[threadIdx.x] += sh[threadIdx.x + o]; sh2[threadIdx.x] += sh2[threadIdx.x + o]; }
        __syncthreads();
    }
    if (threadIdx.x == 0) {
        double mean = sh[0] / N;
        double var  = sh2[0] / N - mean * mean;
        if (var < 0.0) var = 0.0;
        mu[c] = mean;
        Ad[c] = (g ? (double)g[c] : 1.0) / sqrt(var + 1e-5);
        Bd[c] = b ? (double)b[c] : 0.0;
    }
}

__global__ void k4_out(const int* __restrict__ v, const double* __restrict__ mu,
                       const double* __restrict__ Ad, float* __restrict__ out, int N) {
    int n = blockIdx.x * 256 + threadIdx.x;
    if (n >= N) return;
    double z[10];
    double mx = -1e300;
    for (int o = 0; o < 10; ++o) {
        z[o] = ((double)v[n * 10 + o] - mu[o]) * Ad[o];
        if (z[o] > mx) mx = z[o];
    }
    double s = 0.0;
    for (int o = 0; o < 10; ++o) s += exp(z[o] - mx);
    double l = mx + log(s);
    for (int o = 0; o < 10; ++o) out[n * 10 + o] = (float)(z[o] - l);
}

// ---------------- host ----------------
extern "C" void kernel_launch(void* const* d_in, const int* in_sizes, int n_in,
                              void* d_out, int out_size, void* d_ws, size_t ws_size,
                              hipStream_t stream) {
    const int N = in_sizes[0] / (3 * 32 * 32);   // 512

    const float* x   = (const float*)d_in[0];
    const float* w1  = (const float*)d_in[1];
    const float* g1  = (const float*)d_in[2];
    const float* b1  = (const float*)d_in[3];
    const float* w2  = (const float*)d_in[4];
    const float* g2  = (const float*)d_in[5];
    const float* b2  = (const float*)d_in[6];
    const float* w3  = (const float*)d_in[7];
    const float* g3  = (const float*)d_in[8];
    const float* b3  = (const float*)d_in[9];
    const float* w4  = (const float*)d_in[10];
    const float* g4  = (const float*)d_in[11];
    const float* b4  = (const float*)d_in[12];
    const float* w5  = (const float*)d_in[13];
    const float* g5  = (const float*)d_in[14];
    const float* b5  = (const float*)d_in[15];
    const float* w6  = (const float*)d_in[16];
    const float* g6  = (const float*)d_in[17];
    const float* b6  = (const float*)d_in[18];
    const float* wf1 = (const float*)d_in[19];
    const float* gf1 = (const float*)d_in[20];
    const float* bf1 = (const float*)d_in[21];
    const float* wf2 = (const float*)d_in[22];
    const float* gf2 = (const float*)d_in[23];
    const float* bf2 = (const float*)d_in[24];
    const float* wf3 = (const float*)d_in[25];

    char* ws = (char*)d_ws;
    size_t off = 0;
    auto alloc = [&](size_t bytes) -> char* {
        char* p = ws + off;
        off = (off + bytes + 511) & ~(size_t)511;
        return p;
    };

    // ---- DOWN region: all post-L1 buffers at distinct offsets ----
    int16_t* t2  = (int16_t*)alloc((size_t)N * 64 * 256 * 2);
    u64* p2B = (u64*)alloc((size_t)N * 256 * 8);
    u64* p2Z = (u64*)alloc((size_t)N * 256 * 8);
    int16_t* t3  = (int16_t*)alloc((size_t)N * 128 * 256 * 2);
    u64* p3B = (u64*)alloc((size_t)N * 256 * 2 * 8);
    u64* p3Z = (u64*)alloc((size_t)N * 256 * 2 * 8);
    int16_t* t4  = (int16_t*)alloc((size_t)N * 128 * 64 * 2);
    u64* p4B = (u64*)alloc((size_t)N * 64 * 2 * 8);
    u64* p4Z = (u64*)alloc((size_t)N * 64 * 2 * 8);
    int16_t* t5  = (int16_t*)alloc((size_t)N * 256 * 64 * 2);
    u64* p5B = (u64*)alloc((size_t)N * 64 * 4 * 8);
    u64* p5Z = (u64*)alloc((size_t)N * 64 * 4 * 8);
    int16_t* t6  = (int16_t*)alloc((size_t)N * 256 * 16 * 2);
    u64* p6B = (u64*)alloc((size_t)N * 64 * 8);
    u64* p6Z = (u64*)alloc((size_t)N * 64 * 8);
    int* fc1 = (int*)alloc((size_t)N * 512 * 4);
    int* fc2 = (int*)alloc((size_t)N * 512 * 4);
    int* fc3 = (int*)alloc((size_t)N * 10 * 4);
    u64* pF1B = (u64*)alloc((size_t)N * 8 * 8);
    u64* pF1Z = (u64*)alloc((size_t)N * 8 * 8);
    u64* pF2B = (u64*)alloc((size_t)N * 8 * 8);
    u64* pF2Z = (u64*)alloc((size_t)N * 8 * 8);
    size_t down_end = off;

    // ---- L1 head overlays (dead before any DOWN buffer is written) ----
    size_t head_big = (size_t)N * 64 * 1024 * 4;      // 134.2MB f32, 64 channels
    bool big = ws_size >= head_big + ((size_t)20 << 20);
    float*  c1buf = (float*)ws;                        // big: [N][64][1024]
    float*  c1buf8 = (float*)ws;                       // fallback: [N][8][1024]
    int8_t* sgnA  = (int8_t*)(ws + (size_t)N * 8 * 1024 * 4);  // fallback only

    // ---- tail (coexists with L1 head) ----
    off = big ? (head_big > down_end ? head_big : down_end) : down_end;
    off = (off + 511) & ~(size_t)511;
    u64* p1B = (u64*)alloc((size_t)N * 1024 * 8);
    u64* p1Z = (u64*)alloc((size_t)N * 1024 * 8);
    u64* wb2B = (u64*)alloc(64  * 9 * 1 * 8);  u64* wb2Z = (u64*)alloc(64  * 9 * 1 * 8);
    u64* wb3B = (u64*)alloc(128 * 9 * 1 * 8);  u64* wb3Z = (u64*)alloc(128 * 9 * 1 * 8);
    u64* wb4B = (u64*)alloc(128 * 9 * 2 * 8);  u64* wb4Z = (u64*)alloc(128 * 9 * 2 * 8);
    u64* wb5B = (u64*)alloc(256 * 9 * 2 * 8);  u64* wb5Z = (u64*)alloc(256 * 9 * 2 * 8);
    u64* wb6B = (u64*)alloc(256 * 9 * 4 * 8);  u64* wb6Z = (u64*)alloc(256 * 9 * 4 * 8);
    u64* wf1B = (u64*)alloc(512 * 64 * 8);     u64* wf1Z = (u64*)alloc(512 * 64 * 8);
    u64* wf2B = (u64*)alloc(512 * 8 * 8);      u64* wf2Z = (u64*)alloc(512 * 8 * 8);
    u64* wf3B = (u64*)alloc(10 * 8 * 8);       u64* wf3Z = (u64*)alloc(10 * 8 * 8);
    float* wt = (float*)alloc(27 * 64 * 4);
    double* Sp  = (double*)alloc(64 * 256 * 8);
    double* S2p = (double*)alloc(64 * 256 * 8);
    long long* SpI  = (long long*)alloc(256 * 32 * 8);
    long long* S2pI = (long long*)alloc(256 * 32 * 8);
    u64* flags = (u64*)alloc(16 * 8);
    // [0..4]=wconv L2..L6, [5..7]=wlin FC1..FC3, [8..12]=act L1..L5,
    // [13]=act flat(L6), [14]=act FC1sign, [15]=act FC2sign
    double* mu = (double*)alloc(512 * 8);
    double* Ad = (double*)alloc(512 * 8);
    double* Bd = (double*)alloc(512 * 8);
    float*  muF = (float*)alloc(64 * 4);
    float*  rF  = (float*)alloc(64 * 4);

    auto cdiv = [](int a, int b) { return (a + b - 1) / b; };

    // ---- flags + fused weight pack (1 launch) ----
    kflag_init<<<1, 64, 0, stream>>>(flags);
    kpack_all<<<216, 256, 0, stream>>>(w2, w3, w4, w5, w6, wf1, wf2, wf3,
                                       wb2B, wb2Z, wb3B, wb3Z, wb4B, wb4Z,
                                       wb5B, wb5Z, wb6B, wb6Z, wf1B, wf1Z,
                                       wf2B, wf2Z, wf3B, wf3Z, flags);

    // ---- L1 ----
    if (big) {
        kw1t<<<27, 64, 0, stream>>>(w1, wt);
        k1_conv_allv<<<(N * 256) / 256, 256, 0, stream>>>(x, wt, c1buf);
        k1_statsA<<<dim3(64, 4), 64, 0, stream>>>(c1buf, Sp, S2p, N);
        k1_statsB<<<64, 256, 0, stream>>>(Sp, S2p, muF, rF, N);
        k1_signpack<<<(N * 256) / 64, 64, 0, stream>>>(c1buf, muF, rF, g1, b1, p1B, p1Z, &flags[8]);
    } else {
        for (int grp = 0; grp < 8; ++grp) {
            k1_conv<<<dim3(16, 8, N), 64, 0, stream>>>(x, w1, c1buf8, grp);
            k1_stats<<<8, 256, 0, stream>>>(c1buf8, muF, rF, grp, N);
            k1_sign<<<dim3(4, 8, N), 256, 0, stream>>>(c1buf8, muF, rF, g1, b1, sgnA, grp);
        }
        kpack_sgn8<<<dim3(16, 1, N), 64, 0, stream>>>(sgnA, p1B, p1Z, 64, 1024, &flags[8]);
    }

    // ---- L2: conv+pool (Ci=64, 32x32 -> 16x16) ----
    kbconv_pool2<1, 8><<<dim3(4, 8, N), 64, 0, stream>>>(p1B, p1Z, wb2B, wb2Z, t2, 64, 32, 32, &flags[0], &flags[8]);
    kaccum16<<<dim3(64, 32), 256, 0, stream>>>(t2, SpI, S2pI, 64, 256, N * 256);
    kfinal2<<<1, 64, 0, stream>>>(SpI, S2pI, 32, g2, b2, mu, Ad, Bd, 64, N * 256);
    ksp_conv<<<cdiv(N * 1 * 64, 64), 64, 0, stream>>>(t2, mu, Ad, Bd, p2B, p2Z, 64, 256, N, &flags[9]);

    // ---- L3: conv (Ci=64, 16x16) ----
    kbconv2<1, 8><<<dim3(4, 16, N), 64, 0, stream>>>(p2B, p2Z, wb3B, wb3Z, t3, 128, 16, 16, &flags[1], &flags[9]);
    kaccum16<<<dim3(128, 16), 256, 0, stream>>>(t3, SpI, S2pI, 128, 256, N * 256);
    kfinal2<<<2, 64, 0, stream>>>(SpI, S2pI, 16, g3, b3, mu, Ad, Bd, 128, N * 256);
    ksp_conv<<<cdiv(N * 2 * 64, 64), 64, 0, stream>>>(t3, mu, Ad, Bd, p3B, p3Z, 128, 256, N, &flags[10]);

    // ---- L4: conv+pool (Ci=128, 16x16 -> 8x8) ----
    kbconv_pool2<2, 8><<<dim3(1, 16, N), 64, 0, stream>>>(p3B, p3Z, wb4B, wb4Z, t4, 128, 16, 16, &flags[2], &flags[10]);
    kaccum16<<<dim3(128, 16), 256, 0, stream>>>(t4, SpI, S2pI, 128, 64, N * 64);
    kfinal2<<<2, 64, 0, stream>>>(SpI, S2pI, 16, g4, b4, mu, Ad, Bd, 128, N * 64);
    ksp_conv<<<cdiv(N * 2 * 16, 64), 64, 0, stream>>>(t4, mu, Ad, Bd, p4B, p4Z, 128, 64, N, &flags[11]);

    // ---- L5: conv (Ci=128, 8x8) ----
    kbconv2<2, 8><<<dim3(1, 32, N), 64, 0, stream>>>(p4B, p4Z, wb5B, wb5Z, t5, 256, 8, 8, &flags[3], &flags[11]);
    kaccum16<<<dim3(256, 8), 256, 0, stream>>>(t5, SpI, S2pI, 256, 64, N * 64);
    kfinal2<<<4, 64, 0, stream>>>(SpI, S2pI, 8, g5, b5, mu, Ad, Bd, 256, N * 64);
    ksp_conv<<<cdiv(N * 4 * 16, 64), 64, 0, stream>>>(t5, mu, Ad, Bd, p5B, p5Z, 256, 64, N, &flags[12]);

    // ---- L6: conv+pool (Ci=256, 8x8 -> 4x4), positions-in-lanes ----
    kbconv_pool2s<4, 8><<<dim3(1, 32, N), 64, 0, stream>>>(p5B, p5Z, wb6B, wb6Z, t6, 256, 8, 8, &flags[4], &flags[12]);
    kaccum16<<<dim3(256, 2), 256, 0, stream>>>(t6, SpI, S2pI, 256, 16, N * 16);
    kfinal2<<<4, 64, 0, stream>>>(SpI, S2pI, 2, g6, b6, mu, Ad, Bd, 256, N * 16);
    ksp_flat<<<N, 64, 0, stream>>>(t6, mu, Ad, Bd, p6B, p6Z, &flags[13]);

    // ---- FC1 ----
    kbfc<<<dim3(8, N), 64, 0, stream>>>(p6B, p6Z, wf1B, wf1Z, fc1, 64, 512, &flags[5], &flags[13]);
    k3_stats<<<512, 256, 0, stream>>>(fc1, N, 512, gf1, bf1, mu, Ad, Bd);
    ksp_fc<<<cdiv(N * 8, 64), 64, 0, stream>>>(fc1, mu, Ad, Bd, pF1B, pF1Z, 512, 8, N, &flags[14]);

    // ---- FC2 ----
    kbfc<<<dim3(8, N), 64, 0, stream>>>(pF1B, pF1Z, wf2B, wf2Z, fc2, 8, 512, &flags[6], &flags[14]);
    k3_stats<<<512, 256, 0, stream>>>(fc2, N, 512, gf2, bf2, mu, Ad, Bd);
    ksp_fc<<<cdiv(N * 8, 64), 64, 0, stream>>>(fc2, mu, Ad, Bd, pF2B, pF2Z, 512, 8, N, &flags[15]);

    // ---- FC3 + bn(no affine) + log_softmax ----
    kbfc<<<dim3(1, N), 64, 0, stream>>>(pF2B, pF2Z, wf3B, wf3Z, fc3, 8, 10, &flags[7], &flags[15]);
    k3_stats<<<10, 256, 0, stream>>>(fc3, N, 10, nullptr, nullptr, mu, Ad, Bd);
    k4_out<<<cdiv(N, 256), 256, 0, stream>>>(fc3, mu, Ad, (float*)d_out, N);
}